// Round 1
// baseline (2313.686 us; speedup 1.0000x reference)
//
#include <hip/hip_runtime.h>
#include <math.h>

#define H 128
#define D 256

__device__ __forceinline__ float sigmoidf_(float x){ return 1.0f/(1.0f+__expf(-x)); }

__global__ void k_init_deg(float* degI, float* degC, int N){
  int i = blockIdx.x*blockDim.x + threadIdx.x;
  if (i < N){ degI[i]=1.f; degC[i]=1.f; }
}

// h = relu(x @ Wsel + bsel), per-node select. Wave handles 64 nodes x 64 cols.
__global__ __launch_bounds__(256) void k_proj(
    const float* __restrict__ x, const int* __restrict__ em,
    const float* __restrict__ We, const float* __restrict__ be,
    const float* __restrict__ Wf, const float* __restrict__ bf,
    float* __restrict__ h, int N)
{
  int lane = threadIdx.x & 63;
  int w = blockIdx.x*4 + (threadIdx.x>>6);
  int half = __builtin_amdgcn_readfirstlane((w & 1) << 6);
  int node = (w >> 1)*64 + lane;
  if (node >= N) return;
  const float4* xv = reinterpret_cast<const float4*>(x + (size_t)node*D);
  float accE[64], accF[64];
  #pragma unroll
  for (int o=0;o<64;o++){ accE[o]=be[half+o]; accF[o]=bf[half+o]; }
  for (int kc=0;kc<D/4;kc++){
    float4 v = xv[kc];
    const float xs[4] = {v.x, v.y, v.z, v.w};
    const float* wer = We + (size_t)(kc*4)*H + half;
    const float* wfr = Wf + (size_t)(kc*4)*H + half;
    #pragma unroll
    for (int c=0;c<4;c++){
      float xe = xs[c];
      #pragma unroll
      for (int o=0;o<64;o++){
        accE[o] = fmaf(xe, wer[c*H+o], accE[o]);
        accF[o] = fmaf(xe, wfr[c*H+o], accF[o]);
      }
    }
  }
  bool e = em[node] != 0;
  float4* hr = reinterpret_cast<float4*>(h + (size_t)node*H + half);
  #pragma unroll
  for (int o4=0;o4<16;o4++){
    float4 s;
    s.x = fmaxf(e?accE[o4*4+0]:accF[o4*4+0], 0.f);
    s.y = fmaxf(e?accE[o4*4+1]:accF[o4*4+1], 0.f);
    s.z = fmaxf(e?accE[o4*4+2]:accF[o4*4+2], 0.f);
    s.w = fmaxf(e?accE[o4*4+3]:accF[o4*4+3], 0.f);
    hr[o4] = s;
  }
}

// Co = A @ W, A:[N,H], W:[H,H]. Wave = 64 nodes x 64 cols.
__global__ __launch_bounds__(256) void k_gemm(
    const float* __restrict__ A, const float* __restrict__ W,
    float* __restrict__ Co, int N)
{
  int lane = threadIdx.x & 63;
  int w = blockIdx.x*4 + (threadIdx.x>>6);
  int half = __builtin_amdgcn_readfirstlane((w & 1) << 6);
  int node = (w >> 1)*64 + lane;
  if (node >= N) return;
  const float4* av = reinterpret_cast<const float4*>(A + (size_t)node*H);
  float acc[64];
  #pragma unroll
  for (int o=0;o<64;o++) acc[o]=0.f;
  for (int kc=0;kc<H/4;kc++){
    float4 v = av[kc];
    const float xs[4] = {v.x, v.y, v.z, v.w};
    const float* wr = W + (size_t)(kc*4)*H + half;
    #pragma unroll
    for (int c=0;c<4;c++){
      float xe = xs[c];
      #pragma unroll
      for (int o=0;o<64;o++) acc[o] = fmaf(xe, wr[c*H+o], acc[o]);
    }
  }
  float4* cr = reinterpret_cast<float4*>(Co + (size_t)node*H + half);
  #pragma unroll
  for (int o4=0;o4<16;o4++)
    cr[o4] = make_float4(acc[o4*4],acc[o4*4+1],acc[o4*4+2],acc[o4*4+3]);
}

// per-edge MLP gate + relation split + degree accumulation
__global__ __launch_bounds__(256) void k_edge(
    const float* __restrict__ h, const int* __restrict__ ei,
    const float* __restrict__ ew, const int* __restrict__ em,
    const float* __restrict__ W1, const float* __restrict__ b1,
    const float* __restrict__ W2, const float* __restrict__ b2,
    float* __restrict__ ewI, float* __restrict__ ewC,
    float* __restrict__ degI, float* __restrict__ degC, int E)
{
  int e = blockIdx.x*blockDim.x + threadIdx.x;
  if (e >= E) return;
  int s = ei[e], d = ei[E+e];
  float wgt = ew[e];
  const float4* hs = reinterpret_cast<const float4*>(h + (size_t)s*H);
  const float4* hd = reinterpret_cast<const float4*>(h + (size_t)d*H);
  float acc[64];
  #pragma unroll
  for (int o=0;o<64;o++) acc[o] = b1[o];
  for (int kc=0;kc<8;kc++){
    float4 av[4], dv[4];
    #pragma unroll
    for (int q=0;q<4;q++){ av[q]=hs[kc*4+q]; dv[q]=hd[kc*4+q]; }
    const float* w1r = W1 + (size_t)(kc*16)*64;
    #pragma unroll
    for (int q=0;q<4;q++){
      const float as[4] = {av[q].x,av[q].y,av[q].z,av[q].w};
      const float ds[4] = {dv[q].x,dv[q].y,dv[q].z,dv[q].w};
      #pragma unroll
      for (int c=0;c<4;c++){
        float df = fabsf(as[c]-ds[c]);
        const float* w1e = w1r + (q*4+c)*64;
        #pragma unroll
        for (int o=0;o<64;o++) acc[o] = fmaf(df, w1e[o], acc[o]);
      }
    }
  }
  const float* w1last = W1 + 128*64;
  float t = b2[0];
  #pragma unroll
  for (int o=0;o<64;o++){
    float v = fmaxf(fmaf(wgt, w1last[o], acc[o]), 0.f);
    t = fmaf(v, W2[o], t);
  }
  float g = sigmoidf_(t);
  g = fminf(fmaxf(g, 0.2f), 1.2f);
  float ehat = wgt * g;
  bool intra = (em[s] == em[d]);
  ewI[e] = intra ? ehat : 0.f;
  ewC[e] = intra ? 0.f : ehat;
  atomicAdd(intra ? (degI+d) : (degC+d), ehat);
}

__global__ void k_dinv(const float* __restrict__ degI, const float* __restrict__ degC,
                       float* dinvI, float* dinvC, float* rdegI, float* rdegC, int N){
  int i = blockIdx.x*blockDim.x + threadIdx.x;
  if (i < N){
    float a = rsqrtf(degI[i]), b = rsqrtf(degC[i]);
    dinvI[i]=a; dinvC[i]=b; rdegI[i]=a*a; rdegC[i]=b*b;
  }
}

// h_pre = self-loop + bias terms (combined intra + sig*cross)
__global__ void k_pre(const float* __restrict__ tI, const float* __restrict__ tC,
    const float* __restrict__ rdegI, const float* __restrict__ rdegC,
    const float* __restrict__ bI, const float* __restrict__ bC,
    const float* __restrict__ relg, int l, float* __restrict__ h, int NH)
{
  int i = blockIdx.x*blockDim.x + threadIdx.x;
  if (i >= NH) return;
  int n = i >> 7, j = i & (H-1);
  float sig = sigmoidf_(relg[l]);
  h[i] = tI[i]*rdegI[n] + bI[j] + sig*(tC[i]*rdegC[n] + bC[j]);
}

// one wave per edge: gather selected t-row, scale, atomic scatter to dst
__global__ __launch_bounds__(256) void k_agg(
    const float* __restrict__ tI, const float* __restrict__ tC,
    const int* __restrict__ ei, const float* __restrict__ ewI,
    const float* __restrict__ ewC, const float* __restrict__ dinvI,
    const float* __restrict__ dinvC, const float* __restrict__ relg, int l,
    float* __restrict__ h, int E)
{
  int lane = threadIdx.x & 63;
  int e = blockIdx.x*4 + (threadIdx.x>>6);
  if (e >= E) return;
  e = __builtin_amdgcn_readfirstlane(e);
  float wi = ewI[e], wc = ewC[e];
  int s = ei[e], d = ei[E+e];
  const float* t; float coef;
  if (wi != 0.f){ t = tI + (size_t)s*H; coef = dinvI[s]*wi*dinvI[d]; }
  else {
    if (wc == 0.f) return;
    t = tC + (size_t)s*H;
    coef = sigmoidf_(relg[l])*dinvC[s]*wc*dinvC[d];
  }
  float2 v = *reinterpret_cast<const float2*>(t + lane*2);
  atomicAdd(h + (size_t)d*H + lane*2,     coef*v.x);
  atomicAdd(h + (size_t)d*H + lane*2 + 1, coef*v.y);
}

__global__ __launch_bounds__(128) void k_stats(const float* __restrict__ h,
    float* __restrict__ bnsum, float* __restrict__ bnsq, int N, int nper)
{
  int j = threadIdx.x;
  int n0 = blockIdx.x*nper, n1 = min(n0+nper, N);
  float sl=0.f, sq=0.f;
  for (int n=n0;n<n1;n++){
    float v = h[(size_t)n*H+j];
    sl += v; sq = fmaf(v,v,sq);
  }
  atomicAdd(bnsum+j, sl); atomicAdd(bnsq+j, sq);
}

__global__ void k_bn(float* __restrict__ h, const float* __restrict__ bnsum,
                     const float* __restrict__ bnsq,
                     const float* __restrict__ gamma, const float* __restrict__ beta,
                     float invN, int NH)
{
  int i = blockIdx.x*blockDim.x + threadIdx.x;
  if (i >= NH) return;
  int j = i & (H-1);
  float mu = bnsum[j]*invN;
  float var = bnsq[j]*invN - mu*mu;
  float r = rsqrtf(var + 1e-5f);
  h[i] = fmaxf(fmaf(gamma[j], (h[i]-mu)*r, beta[j]), 0.f);
}

__global__ void k_cnt(const int* __restrict__ batch, const int* __restrict__ em,
                      float* cntE, float* cntF, int N){
  int i = blockIdx.x*blockDim.x + threadIdx.x;
  if (i < N){ int g = batch[i]; atomicAdd((em[i] ? cntE : cntF)+g, 1.f); }
}

__global__ __launch_bounds__(128) void k_pool(
    const float* __restrict__ h, const int* __restrict__ batch, const int* __restrict__ em,
    float* __restrict__ sumE, float* __restrict__ sumF, int N, int nper)
{
  int j = threadIdx.x;
  int n0 = blockIdx.x*nper, n1 = min(n0+nper, N);
  if (n0 >= N) return;
  float aE=0.f, aF=0.f; int cg = batch[n0];
  for (int n=n0;n<n1;n++){
    int g = batch[n];
    if (g != cg){
      atomicAdd(sumE+(size_t)cg*H+j, aE);
      atomicAdd(sumF+(size_t)cg*H+j, aF);
      aE=aF=0.f; cg=g;
    }
    float v = h[(size_t)n*H+j];
    if (em[n]) aE += v; else aF += v;
  }
  atomicAdd(sumE+(size_t)cg*H+j, aE);
  atomicAdd(sumF+(size_t)cg*H+j, aF);
}

__device__ __forceinline__ float blockReduceSum(float v, float* red){
  int t = threadIdx.x;
  red[t] = v; __syncthreads();
  #pragma unroll
  for (int s=64;s>0;s>>=1){ if (t<s) red[t]+=red[t+s]; __syncthreads(); }
  float r = red[0]; __syncthreads();
  return r;
}

__global__ __launch_bounds__(128) void k_head(
    const float* __restrict__ sumE, const float* __restrict__ sumF,
    const float* __restrict__ cntE, const float* __restrict__ cntF,
    const float* __restrict__ coW1, const float* __restrict__ cob1,
    const float* __restrict__ coW2, const float* __restrict__ cob2,
    const float* __restrict__ gW1, const float* __restrict__ gb1,
    const float* __restrict__ gW2, const float* __restrict__ gb2,
    const float* __restrict__ cW1, const float* __restrict__ cb1,
    const float* __restrict__ cW2, const float* __restrict__ cb2,
    const float* __restrict__ peW1, const float* __restrict__ peb1,
    const float* __restrict__ peW2, const float* __restrict__ peb2,
    const float* __restrict__ pfW1, const float* __restrict__ pfb1,
    const float* __restrict__ pfW2, const float* __restrict__ pfb2,
    float* __restrict__ out, int G)
{
  int g = blockIdx.x, j = threadIdx.x;
  __shared__ float sh[384];
  __shared__ float red[128];
  __shared__ float hfin[128], c1s[64], buf[128];
  float cE = cntE[g], cF = cntF[g];
  float se = sumE[(size_t)g*H+j], sf = sumF[(size_t)g*H+j];
  float he = se/fmaxf(cE,1.f), hf = sf/fmaxf(cF,1.f);
  float hg = (se+sf)/fmaxf(cE+cF,1.f);
  sh[j]=he; sh[128+j]=hf; sh[256+j]=he*hf;
  __syncthreads();
  float a = cob1[j];
  for (int k=0;k<384;k++) a = fmaf(sh[k], coW1[k*H+j], a);
  a = fmaxf(a, 0.f);
  float r0 = blockReduceSum(a*coW2[2*j],   red);
  float r1 = blockReduceSum(a*coW2[2*j+1], red);
  float al0 = sigmoidf_(r0 + cob2[0]);
  float al1 = sigmoidf_(r1 + cob2[1]);
  float asum = al0+al1+1e-6f; al0/=asum; al1/=asum;
  float hc = al0*he + al1*hf;
  __syncthreads();
  sh[j]=hc; sh[128+j]=hg;
  __syncthreads();
  float gg = gb1[j];
  for (int k=0;k<256;k++) gg = fmaf(sh[k], gW1[k*H+j], gg);
  gg = fmaxf(gg, 0.f);
  float gt = sigmoidf_(blockReduceSum(gg*gW2[j], red) + gb2[0]);
  float hfj = gt*hc + (1.f-gt)*hg;
  hfin[j] = hfj;
  __syncthreads();
  float c1v = 0.f;
  if (j < 64){
    float c1 = cb1[j];
    for (int k=0;k<128;k++) c1 = fmaf(hfin[k], cW1[k*64+j], c1);
    c1v = fmaxf(c1, 0.f);
  }
  float l0 = blockReduceSum(j<64 ? c1v*cW2[2*j]   : 0.f, red);
  float l1 = blockReduceSum(j<64 ? c1v*cW2[2*j+1] : 0.f, red);
  if (j==0){ out[(size_t)g*2] = l0 + cb2[0]; out[(size_t)g*2+1] = l1 + cb2[1]; }
  // z_e
  buf[j] = he; __syncthreads();
  float q = peb1[j];
  for (int k=0;k<128;k++) q = fmaf(buf[k], peW1[k*H+j], q);
  q = fmaxf(q, 0.f);
  __syncthreads(); sh[j] = q; __syncthreads();
  float z = peb2[j];
  for (int k=0;k<128;k++) z = fmaf(sh[k], peW2[k*H+j], z);
  float nr = sqrtf(blockReduceSum(z*z, red));
  out[(size_t)G*2 + (size_t)g*H + j] = z / fmaxf(nr, 1e-12f);
  // z_f
  __syncthreads(); buf[j] = hf; __syncthreads();
  float q2 = pfb1[j];
  for (int k=0;k<128;k++) q2 = fmaf(buf[k], pfW1[k*H+j], q2);
  q2 = fmaxf(q2, 0.f);
  __syncthreads(); sh[j] = q2; __syncthreads();
  float z2 = pfb2[j];
  for (int k=0;k<128;k++) z2 = fmaf(sh[k], pfW2[k*H+j], z2);
  float nr2 = sqrtf(blockReduceSum(z2*z2, red));
  out[(size_t)G*2 + (size_t)G*H + (size_t)g*H + j] = z2 / fmaxf(nr2, 1e-12f);
}

extern "C" void kernel_launch(void* const* d_in, const int* in_sizes, int n_in,
                              void* d_out, int out_size, void* d_ws, size_t ws_size,
                              hipStream_t stream)
{
  const float* x    = (const float*)d_in[0];
  const int*   ei   = (const int*)d_in[1];
  const float* ew   = (const float*)d_in[2];
  const int*   batch= (const int*)d_in[3];
  const int*   em   = (const int*)d_in[4];
  const float* eegW = (const float*)d_in[6];  const float* eegB = (const float*)d_in[7];
  const float* fnW  = (const float*)d_in[8];  const float* fnB  = (const float*)d_in[9];
  const float* eW1  = (const float*)d_in[10]; const float* eb1  = (const float*)d_in[11];
  const float* eW2  = (const float*)d_in[12]; const float* eb2  = (const float*)d_in[13];
  const float* cIW  = (const float*)d_in[14]; const float* cIb  = (const float*)d_in[15];
  const float* cCW  = (const float*)d_in[16]; const float* cCb  = (const float*)d_in[17];
  const float* relg = (const float*)d_in[18];
  const float* bng  = (const float*)d_in[19]; const float* bnb  = (const float*)d_in[20];
  const float* coW1 = (const float*)d_in[21]; const float* cob1 = (const float*)d_in[22];
  const float* coW2 = (const float*)d_in[23]; const float* cob2 = (const float*)d_in[24];
  const float* gW1  = (const float*)d_in[25]; const float* gb1  = (const float*)d_in[26];
  const float* gW2  = (const float*)d_in[27]; const float* gb2  = (const float*)d_in[28];
  const float* cW1  = (const float*)d_in[29]; const float* cb1  = (const float*)d_in[30];
  const float* cW2  = (const float*)d_in[31]; const float* cb2  = (const float*)d_in[32];
  const float* peW1 = (const float*)d_in[33]; const float* peb1 = (const float*)d_in[34];
  const float* peW2 = (const float*)d_in[35]; const float* peb2 = (const float*)d_in[36];
  const float* pfW1 = (const float*)d_in[37]; const float* pfb1 = (const float*)d_in[38];
  const float* pfW2 = (const float*)d_in[39]; const float* pfb2 = (const float*)d_in[40];
  float* out = (float*)d_out;

  int N = in_sizes[0] / D;           // 50000
  int E = in_sizes[2];               // 800000
  int G = out_size / (2 + 2*H);      // 500
  int NH = N*H;

  float* p = (float*)d_ws;
  float* h    = p; p += (size_t)NH;
  float* tI   = p; p += (size_t)NH;
  float* tC   = p; p += (size_t)NH;
  float* ewI  = p; p += E;
  float* ewC  = p; p += E;
  float* degI = p; p += N;
  float* degC = p; p += N;
  float* dinvI= p; p += N;
  float* dinvC= p; p += N;
  float* rdegI= p; p += N;
  float* rdegC= p; p += N;
  float* bnsum= p; p += H;
  float* bnsq = p; p += H;
  float* sumE = p; p += (size_t)G*H;
  float* sumF = p; p += (size_t)G*H;
  float* cntE = p; p += G;
  float* cntF = p; p += G;

  int nwaves = ((N+63)/64)*2;                 // node-blocks x 2 col-halves
  int gemmBlocks = (nwaves+3)/4;
  int nper_fin = (N + 511)/512;

  k_init_deg<<<(N+255)/256,256,0,stream>>>(degI, degC, N);
  k_proj<<<gemmBlocks,256,0,stream>>>(x, em, eegW,eegB, fnW,fnB, h, N);
  k_edge<<<(E+255)/256,256,0,stream>>>(h, ei, ew, em, eW1,eb1,eW2,eb2,
                                       ewI,ewC,degI,degC, E);
  k_dinv<<<(N+255)/256,256,0,stream>>>(degI,degC,dinvI,dinvC,rdegI,rdegC,N);

  for (int l=0;l<2;l++){
    k_gemm<<<gemmBlocks,256,0,stream>>>(h, cIW + (size_t)l*H*H, tI, N);
    k_gemm<<<gemmBlocks,256,0,stream>>>(h, cCW + (size_t)l*H*H, tC, N);
    k_pre<<<(NH+255)/256,256,0,stream>>>(tI,tC,rdegI,rdegC, cIb+(size_t)l*H,
                                         cCb+(size_t)l*H, relg, l, h, NH);
    k_agg<<<(E+3)/4,256,0,stream>>>(tI,tC,ei,ewI,ewC,dinvI,dinvC,relg,l,h,E);
    hipMemsetAsync(bnsum, 0, 2*H*sizeof(float), stream);   // bnsum+bnsq contiguous
    k_stats<<<512,128,0,stream>>>(h, bnsum, bnsq, N, nper_fin);
    k_bn<<<(NH+255)/256,256,0,stream>>>(h, bnsum, bnsq,
                                        bng+(size_t)l*H, bnb+(size_t)l*H,
                                        1.0f/(float)N, NH);
  }

  hipMemsetAsync(sumE, 0, ((size_t)2*G*H + 2*G)*sizeof(float), stream);
  k_cnt<<<(N+255)/256,256,0,stream>>>(batch, em, cntE, cntF, N);
  k_pool<<<(N+511)/512,128,0,stream>>>(h, batch, em, sumE, sumF, N, 512);
  k_head<<<G,128,0,stream>>>(sumE,sumF,cntE,cntF,
                             coW1,cob1,coW2,cob2, gW1,gb1,gW2,gb2,
                             cW1,cb1,cW2,cb2, peW1,peb1,peW2,peb2,
                             pfW1,pfb1,pfW2,pfb2, out, G);
}

// Round 2
// 1321.531 us; speedup vs baseline: 1.7508x; 1.7508x over previous
//
#include <hip/hip_runtime.h>
#include <math.h>

#define H 128
#define D 256

__device__ __forceinline__ float sigmoidf_(float x){ return 1.0f/(1.0f+__expf(-x)); }

__global__ void k_init_deg(float* degI, float* degC, int N){
  int i = blockIdx.x*blockDim.x + threadIdx.x;
  if (i < N){ degI[i]=1.f; degC[i]=1.f; }
}

// h = relu(x @ Wsel + bsel), per-node select. Wave handles 64 nodes x 64 cols.
__global__ __launch_bounds__(256) void k_proj(
    const float* __restrict__ x, const int* __restrict__ em,
    const float* __restrict__ We, const float* __restrict__ be,
    const float* __restrict__ Wf, const float* __restrict__ bf,
    float* __restrict__ h, int N)
{
  int lane = threadIdx.x & 63;
  int w = blockIdx.x*4 + (threadIdx.x>>6);
  int half = __builtin_amdgcn_readfirstlane((w & 1) << 6);
  int node = (w >> 1)*64 + lane;
  if (node >= N) return;
  const float4* xv = reinterpret_cast<const float4*>(x + (size_t)node*D);
  float accE[64], accF[64];
  #pragma unroll
  for (int o=0;o<64;o++){ accE[o]=be[half+o]; accF[o]=bf[half+o]; }
  for (int kc=0;kc<D/4;kc++){
    float4 v = xv[kc];
    const float xs[4] = {v.x, v.y, v.z, v.w};
    const float* wer = We + (size_t)(kc*4)*H + half;
    const float* wfr = Wf + (size_t)(kc*4)*H + half;
    #pragma unroll
    for (int c=0;c<4;c++){
      float xe = xs[c];
      #pragma unroll
      for (int o=0;o<64;o++){
        accE[o] = fmaf(xe, wer[c*H+o], accE[o]);
        accF[o] = fmaf(xe, wfr[c*H+o], accF[o]);
      }
    }
  }
  bool e = em[node] != 0;
  float4* hr = reinterpret_cast<float4*>(h + (size_t)node*H + half);
  #pragma unroll
  for (int o4=0;o4<16;o4++){
    float4 s;
    s.x = fmaxf(e?accE[o4*4+0]:accF[o4*4+0], 0.f);
    s.y = fmaxf(e?accE[o4*4+1]:accF[o4*4+1], 0.f);
    s.z = fmaxf(e?accE[o4*4+2]:accF[o4*4+2], 0.f);
    s.w = fmaxf(e?accE[o4*4+3]:accF[o4*4+3], 0.f);
    hr[o4] = s;
  }
}

// Co = A @ W, A:[N,H], W:[H,H]. Wave = 64 nodes x 64 cols.
__global__ __launch_bounds__(256) void k_gemm(
    const float* __restrict__ A, const float* __restrict__ W,
    float* __restrict__ Co, int N)
{
  int lane = threadIdx.x & 63;
  int w = blockIdx.x*4 + (threadIdx.x>>6);
  int half = __builtin_amdgcn_readfirstlane((w & 1) << 6);
  int node = (w >> 1)*64 + lane;
  if (node >= N) return;
  const float4* av = reinterpret_cast<const float4*>(A + (size_t)node*H);
  float acc[64];
  #pragma unroll
  for (int o=0;o<64;o++) acc[o]=0.f;
  for (int kc=0;kc<H/4;kc++){
    float4 v = av[kc];
    const float xs[4] = {v.x, v.y, v.z, v.w};
    const float* wr = W + (size_t)(kc*4)*H + half;
    #pragma unroll
    for (int c=0;c<4;c++){
      float xe = xs[c];
      #pragma unroll
      for (int o=0;o<64;o++) acc[o] = fmaf(xe, wr[c*H+o], acc[o]);
    }
  }
  float4* cr = reinterpret_cast<float4*>(Co + (size_t)node*H + half);
  #pragma unroll
  for (int o4=0;o4<16;o4++)
    cr[o4] = make_float4(acc[o4*4],acc[o4*4+1],acc[o4*4+2],acc[o4*4+3]);
}

// per-edge MLP gate + relation split + degree accumulation
__global__ __launch_bounds__(256) void k_edge(
    const float* __restrict__ h, const int* __restrict__ ei,
    const float* __restrict__ ew, const int* __restrict__ em,
    const float* __restrict__ W1, const float* __restrict__ b1,
    const float* __restrict__ W2, const float* __restrict__ b2,
    float* __restrict__ ewI, float* __restrict__ ewC,
    float* __restrict__ degI, float* __restrict__ degC, int E)
{
  int e = blockIdx.x*blockDim.x + threadIdx.x;
  if (e >= E) return;
  int s = ei[e], d = ei[E+e];
  float wgt = ew[e];
  const float4* hs = reinterpret_cast<const float4*>(h + (size_t)s*H);
  const float4* hd = reinterpret_cast<const float4*>(h + (size_t)d*H);
  float acc[64];
  #pragma unroll
  for (int o=0;o<64;o++) acc[o] = b1[o];
  for (int kc=0;kc<8;kc++){
    float4 av[4], dv[4];
    #pragma unroll
    for (int q=0;q<4;q++){ av[q]=hs[kc*4+q]; dv[q]=hd[kc*4+q]; }
    const float* w1r = W1 + (size_t)(kc*16)*64;
    #pragma unroll
    for (int q=0;q<4;q++){
      const float as[4] = {av[q].x,av[q].y,av[q].z,av[q].w};
      const float ds[4] = {dv[q].x,dv[q].y,dv[q].z,dv[q].w};
      #pragma unroll
      for (int c=0;c<4;c++){
        float df = fabsf(as[c]-ds[c]);
        const float* w1e = w1r + (q*4+c)*64;
        #pragma unroll
        for (int o=0;o<64;o++) acc[o] = fmaf(df, w1e[o], acc[o]);
      }
    }
  }
  const float* w1last = W1 + 128*64;
  float t = b2[0];
  #pragma unroll
  for (int o=0;o<64;o++){
    float v = fmaxf(fmaf(wgt, w1last[o], acc[o]), 0.f);
    t = fmaf(v, W2[o], t);
  }
  float g = sigmoidf_(t);
  g = fminf(fmaxf(g, 0.2f), 1.2f);
  float ehat = wgt * g;
  bool intra = (em[s] == em[d]);
  ewI[e] = intra ? ehat : 0.f;
  ewC[e] = intra ? 0.f : ehat;
  atomicAdd(intra ? (degI+d) : (degC+d), ehat);
}

__global__ void k_dinv(const float* __restrict__ degI, const float* __restrict__ degC,
                       float* dinvI, float* dinvC, int N){
  int i = blockIdx.x*blockDim.x + threadIdx.x;
  if (i < N){
    dinvI[i] = rsqrtf(degI[i]);
    dinvC[i] = rsqrtf(degC[i]);
  }
}

// ---- CSR build: histogram by dst, scan, fill with packed (src,chan)+coef ----
__global__ void k_hist(const int* __restrict__ ei, int* __restrict__ cnt, int E){
  int e = blockIdx.x*blockDim.x + threadIdx.x;
  if (e < E) atomicAdd(cnt + ei[E+e], 1);
}

__global__ __launch_bounds__(1024) void k_scan(const int* __restrict__ cnt,
                                               int* __restrict__ start, int N){
  __shared__ int sm[1024];
  int t = threadIdx.x;
  int chunk = (N + 1023)/1024;
  int i0 = t*chunk, i1 = min(i0+chunk, N);
  int s = 0;
  for (int i=i0;i<i1;i++) s += cnt[i];
  sm[t] = s; __syncthreads();
  for (int d=1; d<1024; d<<=1){
    int v = (t>=d)? sm[t-d] : 0;
    __syncthreads();
    sm[t] += v;
    __syncthreads();
  }
  int base = (t==0)? 0 : sm[t-1];
  for (int i=i0;i<i1;i++){ start[i] = base; base += cnt[i]; }
  if (t == 1023) start[N] = sm[1023];
}

__global__ void k_fill(const int* __restrict__ ei, const int* __restrict__ em,
                       const float* __restrict__ ewI, const float* __restrict__ ewC,
                       const float* __restrict__ dinvI, const float* __restrict__ dinvC,
                       const int* __restrict__ start, int* __restrict__ wcnt,
                       int* __restrict__ csr_sc, float* __restrict__ csr_cf, int E){
  int e = blockIdx.x*blockDim.x + threadIdx.x;
  if (e >= E) return;
  int s = ei[e], d = ei[E+e];
  bool intra = (em[s] == em[d]);
  float coef = intra ? dinvI[s]*ewI[e]*dinvI[d] : dinvC[s]*ewC[e]*dinvC[d];
  int pos = start[d] + atomicAdd(wcnt + d, 1);
  csr_sc[pos] = (s<<1) | (intra ? 0 : 1);
  csr_cf[pos] = coef;
}

// one wave per dst node: gather CSR edges + fused self-loop/bias epilogue.
// h[d] = tI[d]*rdegI + bI + sig*(tC[d]*rdegC + bC) + sum_e coef_e*(sig?)*t[src_e]
__global__ __launch_bounds__(256) void k_aggr(
    const float* __restrict__ tI, const float* __restrict__ tC,
    const int* __restrict__ start, const int* __restrict__ csr_sc,
    const float* __restrict__ csr_cf,
    const float* __restrict__ dinvI, const float* __restrict__ dinvC,
    const float* __restrict__ bI, const float* __restrict__ bC,
    const float* __restrict__ relg, int l,
    float* __restrict__ h, int N)
{
  int lane = threadIdx.x & 63;
  int d = blockIdx.x*4 + (threadIdx.x>>6);
  if (d >= N) return;
  float sig = sigmoidf_(relg[l]);
  int k0 = start[d], k1 = start[d+1];
  int off = lane*2;
  float ax=0.f, ay=0.f;
  for (int k=k0;k<k1;k++){
    int sc = csr_sc[k];
    float cf = csr_cf[k];
    int src = sc>>1;
    const float* t = (sc&1) ? tC : tI;
    float ce = (sc&1) ? sig*cf : cf;
    float2 v = *reinterpret_cast<const float2*>(t + (size_t)src*H + off);
    ax = fmaf(ce, v.x, ax);
    ay = fmaf(ce, v.y, ay);
  }
  float diI = dinvI[d], diC = dinvC[d];
  float rI = diI*diI, rC = diC*diC;
  float2 ti = *reinterpret_cast<const float2*>(tI + (size_t)d*H + off);
  float2 tc = *reinterpret_cast<const float2*>(tC + (size_t)d*H + off);
  float2 o;
  o.x = fmaf(ti.x, rI, bI[off])   + sig*fmaf(tc.x, rC, bC[off])   + ax;
  o.y = fmaf(ti.y, rI, bI[off+1]) + sig*fmaf(tc.y, rC, bC[off+1]) + ay;
  *reinterpret_cast<float2*>(h + (size_t)d*H + off) = o;
}

__global__ __launch_bounds__(128) void k_stats(const float* __restrict__ h,
    float* __restrict__ bnsum, float* __restrict__ bnsq, int N, int nper)
{
  int j = threadIdx.x;
  int n0 = blockIdx.x*nper, n1 = min(n0+nper, N);
  float sl=0.f, sq=0.f;
  for (int n=n0;n<n1;n++){
    float v = h[(size_t)n*H+j];
    sl += v; sq = fmaf(v,v,sq);
  }
  atomicAdd(bnsum+j, sl); atomicAdd(bnsq+j, sq);
}

__global__ void k_bn(float* __restrict__ h, const float* __restrict__ bnsum,
                     const float* __restrict__ bnsq,
                     const float* __restrict__ gamma, const float* __restrict__ beta,
                     float invN, int NH)
{
  int i = blockIdx.x*blockDim.x + threadIdx.x;
  if (i >= NH) return;
  int j = i & (H-1);
  float mu = bnsum[j]*invN;
  float var = bnsq[j]*invN - mu*mu;
  float r = rsqrtf(var + 1e-5f);
  h[i] = fmaxf(fmaf(gamma[j], (h[i]-mu)*r, beta[j]), 0.f);
}

__global__ void k_cnt(const int* __restrict__ batch, const int* __restrict__ em,
                      float* cntE, float* cntF, int N){
  int i = blockIdx.x*blockDim.x + threadIdx.x;
  if (i < N){ int g = batch[i]; atomicAdd((em[i] ? cntE : cntF)+g, 1.f); }
}

__global__ __launch_bounds__(128) void k_pool(
    const float* __restrict__ h, const int* __restrict__ batch, const int* __restrict__ em,
    float* __restrict__ sumE, float* __restrict__ sumF, int N, int nper)
{
  int j = threadIdx.x;
  int n0 = blockIdx.x*nper, n1 = min(n0+nper, N);
  if (n0 >= N) return;
  float aE=0.f, aF=0.f; int cg = batch[n0];
  for (int n=n0;n<n1;n++){
    int g = batch[n];
    if (g != cg){
      atomicAdd(sumE+(size_t)cg*H+j, aE);
      atomicAdd(sumF+(size_t)cg*H+j, aF);
      aE=aF=0.f; cg=g;
    }
    float v = h[(size_t)n*H+j];
    if (em[n]) aE += v; else aF += v;
  }
  atomicAdd(sumE+(size_t)cg*H+j, aE);
  atomicAdd(sumF+(size_t)cg*H+j, aF);
}

__device__ __forceinline__ float blockReduceSum(float v, float* red){
  int t = threadIdx.x;
  red[t] = v; __syncthreads();
  #pragma unroll
  for (int s=64;s>0;s>>=1){ if (t<s) red[t]+=red[t+s]; __syncthreads(); }
  float r = red[0]; __syncthreads();
  return r;
}

__global__ __launch_bounds__(128) void k_head(
    const float* __restrict__ sumE, const float* __restrict__ sumF,
    const float* __restrict__ cntE, const float* __restrict__ cntF,
    const float* __restrict__ coW1, const float* __restrict__ cob1,
    const float* __restrict__ coW2, const float* __restrict__ cob2,
    const float* __restrict__ gW1, const float* __restrict__ gb1,
    const float* __restrict__ gW2, const float* __restrict__ gb2,
    const float* __restrict__ cW1, const float* __restrict__ cb1,
    const float* __restrict__ cW2, const float* __restrict__ cb2,
    const float* __restrict__ peW1, const float* __restrict__ peb1,
    const float* __restrict__ peW2, const float* __restrict__ peb2,
    const float* __restrict__ pfW1, const float* __restrict__ pfb1,
    const float* __restrict__ pfW2, const float* __restrict__ pfb2,
    float* __restrict__ out, int G)
{
  int g = blockIdx.x, j = threadIdx.x;
  __shared__ float sh[384];
  __shared__ float red[128];
  __shared__ float hfin[128], buf[128];
  float cE = cntE[g], cF = cntF[g];
  float se = sumE[(size_t)g*H+j], sf = sumF[(size_t)g*H+j];
  float he = se/fmaxf(cE,1.f), hf = sf/fmaxf(cF,1.f);
  float hg = (se+sf)/fmaxf(cE+cF,1.f);
  sh[j]=he; sh[128+j]=hf; sh[256+j]=he*hf;
  __syncthreads();
  float a = cob1[j];
  for (int k=0;k<384;k++) a = fmaf(sh[k], coW1[k*H+j], a);
  a = fmaxf(a, 0.f);
  float r0 = blockReduceSum(a*coW2[2*j],   red);
  float r1 = blockReduceSum(a*coW2[2*j+1], red);
  float al0 = sigmoidf_(r0 + cob2[0]);
  float al1 = sigmoidf_(r1 + cob2[1]);
  float asum = al0+al1+1e-6f; al0/=asum; al1/=asum;
  float hc = al0*he + al1*hf;
  __syncthreads();
  sh[j]=hc; sh[128+j]=hg;
  __syncthreads();
  float gg = gb1[j];
  for (int k=0;k<256;k++) gg = fmaf(sh[k], gW1[k*H+j], gg);
  gg = fmaxf(gg, 0.f);
  float gt = sigmoidf_(blockReduceSum(gg*gW2[j], red) + gb2[0]);
  float hfj = gt*hc + (1.f-gt)*hg;
  hfin[j] = hfj;
  __syncthreads();
  float c1v = 0.f;
  if (j < 64){
    float c1 = cb1[j];
    for (int k=0;k<128;k++) c1 = fmaf(hfin[k], cW1[k*64+j], c1);
    c1v = fmaxf(c1, 0.f);
  }
  float l0 = blockReduceSum(j<64 ? c1v*cW2[2*j]   : 0.f, red);
  float l1 = blockReduceSum(j<64 ? c1v*cW2[2*j+1] : 0.f, red);
  if (j==0){ out[(size_t)g*2] = l0 + cb2[0]; out[(size_t)g*2+1] = l1 + cb2[1]; }
  // z_e
  buf[j] = he; __syncthreads();
  float q = peb1[j];
  for (int k=0;k<128;k++) q = fmaf(buf[k], peW1[k*H+j], q);
  q = fmaxf(q, 0.f);
  __syncthreads(); sh[j] = q; __syncthreads();
  float z = peb2[j];
  for (int k=0;k<128;k++) z = fmaf(sh[k], peW2[k*H+j], z);
  float nr = sqrtf(blockReduceSum(z*z, red));
  out[(size_t)G*2 + (size_t)g*H + j] = z / fmaxf(nr, 1e-12f);
  // z_f
  __syncthreads(); buf[j] = hf; __syncthreads();
  float q2 = pfb1[j];
  for (int k=0;k<128;k++) q2 = fmaf(buf[k], pfW1[k*H+j], q2);
  q2 = fmaxf(q2, 0.f);
  __syncthreads(); sh[j] = q2; __syncthreads();
  float z2 = pfb2[j];
  for (int k=0;k<128;k++) z2 = fmaf(sh[k], pfW2[k*H+j], z2);
  float nr2 = sqrtf(blockReduceSum(z2*z2, red));
  out[(size_t)G*2 + (size_t)G*H + (size_t)g*H + j] = z2 / fmaxf(nr2, 1e-12f);
}

extern "C" void kernel_launch(void* const* d_in, const int* in_sizes, int n_in,
                              void* d_out, int out_size, void* d_ws, size_t ws_size,
                              hipStream_t stream)
{
  const float* x    = (const float*)d_in[0];
  const int*   ei   = (const int*)d_in[1];
  const float* ew   = (const float*)d_in[2];
  const int*   batch= (const int*)d_in[3];
  const int*   em   = (const int*)d_in[4];
  const float* eegW = (const float*)d_in[6];  const float* eegB = (const float*)d_in[7];
  const float* fnW  = (const float*)d_in[8];  const float* fnB  = (const float*)d_in[9];
  const float* eW1  = (const float*)d_in[10]; const float* eb1  = (const float*)d_in[11];
  const float* eW2  = (const float*)d_in[12]; const float* eb2  = (const float*)d_in[13];
  const float* cIW  = (const float*)d_in[14]; const float* cIb  = (const float*)d_in[15];
  const float* cCW  = (const float*)d_in[16]; const float* cCb  = (const float*)d_in[17];
  const float* relg = (const float*)d_in[18];
  const float* bng  = (const float*)d_in[19]; const float* bnb  = (const float*)d_in[20];
  const float* coW1 = (const float*)d_in[21]; const float* cob1 = (const float*)d_in[22];
  const float* coW2 = (const float*)d_in[23]; const float* cob2 = (const float*)d_in[24];
  const float* gW1  = (const float*)d_in[25]; const float* gb1  = (const float*)d_in[26];
  const float* gW2  = (const float*)d_in[27]; const float* gb2  = (const float*)d_in[28];
  const float* cW1  = (const float*)d_in[29]; const float* cb1  = (const float*)d_in[30];
  const float* cW2  = (const float*)d_in[31]; const float* cb2  = (const float*)d_in[32];
  const float* peW1 = (const float*)d_in[33]; const float* peb1 = (const float*)d_in[34];
  const float* peW2 = (const float*)d_in[35]; const float* peb2 = (const float*)d_in[36];
  const float* pfW1 = (const float*)d_in[37]; const float* pfb1 = (const float*)d_in[38];
  const float* pfW2 = (const float*)d_in[39]; const float* pfb2 = (const float*)d_in[40];
  float* out = (float*)d_out;

  int N = in_sizes[0] / D;           // 50000
  int E = in_sizes[2];               // 800000
  int G = out_size / (2 + 2*H);      // 500
  int NH = N*H;

  float* p = (float*)d_ws;
  float* h    = p; p += (size_t)NH;
  float* tI   = p; p += (size_t)NH;
  float* tC   = p; p += (size_t)NH;
  float* ewI  = p; p += E;
  float* ewC  = p; p += E;
  float* degI = p; p += N;
  float* degC = p; p += N;
  float* dinvI= p; p += N;
  float* dinvC= p; p += N;
  float* bnsum= p; p += H;
  float* bnsq = p; p += H;
  float* sumE = p; p += (size_t)G*H;
  float* sumF = p; p += (size_t)G*H;
  float* cntE = p; p += G;
  float* cntF = p; p += G;
  float* csr_cf = p; p += E;
  int* cnt   = (int*)p; p += N;
  int* wcnt  = (int*)p; p += N;
  int* start = (int*)p; p += (N+1);
  int* csr_sc= (int*)p; p += E;

  int nwaves = ((N+63)/64)*2;                 // node-blocks x 2 col-halves
  int gemmBlocks = (nwaves+3)/4;
  int nper_fin = (N + 511)/512;

  // zero: cnt + wcnt (contiguous)
  hipMemsetAsync(cnt, 0, (size_t)2*N*sizeof(int), stream);
  k_hist<<<(E+255)/256,256,0,stream>>>(ei, cnt, E);
  k_scan<<<1,1024,0,stream>>>(cnt, start, N);

  k_init_deg<<<(N+255)/256,256,0,stream>>>(degI, degC, N);
  k_proj<<<gemmBlocks,256,0,stream>>>(x, em, eegW,eegB, fnW,fnB, h, N);
  k_edge<<<(E+255)/256,256,0,stream>>>(h, ei, ew, em, eW1,eb1,eW2,eb2,
                                       ewI,ewC,degI,degC, E);
  k_dinv<<<(N+255)/256,256,0,stream>>>(degI,degC,dinvI,dinvC,N);
  k_fill<<<(E+255)/256,256,0,stream>>>(ei, em, ewI, ewC, dinvI, dinvC,
                                       start, wcnt, csr_sc, csr_cf, E);

  for (int l=0;l<2;l++){
    k_gemm<<<gemmBlocks,256,0,stream>>>(h, cIW + (size_t)l*H*H, tI, N);
    k_gemm<<<gemmBlocks,256,0,stream>>>(h, cCW + (size_t)l*H*H, tC, N);
    k_aggr<<<(N+3)/4,256,0,stream>>>(tI, tC, start, csr_sc, csr_cf,
                                     dinvI, dinvC, cIb+(size_t)l*H,
                                     cCb+(size_t)l*H, relg, l, h, N);
    hipMemsetAsync(bnsum, 0, 2*H*sizeof(float), stream);   // bnsum+bnsq contiguous
    k_stats<<<512,128,0,stream>>>(h, bnsum, bnsq, N, nper_fin);
    k_bn<<<(NH+255)/256,256,0,stream>>>(h, bnsum, bnsq,
                                        bng+(size_t)l*H, bnb+(size_t)l*H,
                                        1.0f/(float)N, NH);
  }

  hipMemsetAsync(sumE, 0, ((size_t)2*G*H + 2*G)*sizeof(float), stream);
  k_cnt<<<(N+255)/256,256,0,stream>>>(batch, em, cntE, cntF, N);
  k_pool<<<(N+511)/512,128,0,stream>>>(h, batch, em, sumE, sumF, N, 512);
  k_head<<<G,128,0,stream>>>(sumE,sumF,cntE,cntF,
                             coW1,cob1,coW2,cob2, gW1,gb1,gW2,gb2,
                             cW1,cb1,cW2,cb2, peW1,peb1,peW2,peb2,
                             pfW1,pfb1,pfW2,pfb2, out, G);
}

// Round 3
// 1241.529 us; speedup vs baseline: 1.8636x; 1.0644x over previous
//
#include <hip/hip_runtime.h>
#include <math.h>

#define H 128
#define D 256

__device__ __forceinline__ float sigmoidf_(float x){ return 1.0f/(1.0f+__expf(-x)); }

// RNE float->bf16 (as ushort in low 16 bits)
__device__ __forceinline__ unsigned int bfr_(float f){
  unsigned int u = __float_as_uint(f);
  return (u + 0x7fffu + ((u>>16)&1u)) >> 16;
}

// h = relu(x @ Wsel + bsel), per-node select; writes fp32 h and bf16 hb.
__global__ __launch_bounds__(256) void k_proj(
    const float* __restrict__ x, const int* __restrict__ em,
    const float* __restrict__ We, const float* __restrict__ be,
    const float* __restrict__ Wf, const float* __restrict__ bf,
    float* __restrict__ h, unsigned int* __restrict__ hb, int N)
{
  int lane = threadIdx.x & 63;
  int w = blockIdx.x*4 + (threadIdx.x>>6);
  int half = __builtin_amdgcn_readfirstlane((w & 1) << 6);
  int node = (w >> 1)*64 + lane;
  if (node >= N) return;
  const float4* xv = reinterpret_cast<const float4*>(x + (size_t)node*D);
  float accE[64], accF[64];
  #pragma unroll
  for (int o=0;o<64;o++){ accE[o]=be[half+o]; accF[o]=bf[half+o]; }
  for (int kc=0;kc<D/4;kc++){
    float4 v = xv[kc];
    const float xs[4] = {v.x, v.y, v.z, v.w};
    const float* wer = We + (size_t)(kc*4)*H + half;
    const float* wfr = Wf + (size_t)(kc*4)*H + half;
    #pragma unroll
    for (int c=0;c<4;c++){
      float xe = xs[c];
      #pragma unroll
      for (int o=0;o<64;o++){
        accE[o] = fmaf(xe, wer[c*H+o], accE[o]);
        accF[o] = fmaf(xe, wfr[c*H+o], accF[o]);
      }
    }
  }
  bool e = em[node] != 0;
  float sv[64];
  #pragma unroll
  for (int o=0;o<64;o++) sv[o] = fmaxf(e?accE[o]:accF[o], 0.f);
  float4* hr = reinterpret_cast<float4*>(h + (size_t)node*H + half);
  #pragma unroll
  for (int o4=0;o4<16;o4++)
    hr[o4] = make_float4(sv[o4*4],sv[o4*4+1],sv[o4*4+2],sv[o4*4+3]);
  // bf16 half-row: 64 vals = 32 uints, uint index node*64 + half/2
  unsigned int* hbr = hb + (size_t)node*64 + (half>>1);
  #pragma unroll
  for (int o2=0;o2<32;o2++)
    hbr[o2] = bfr_(sv[o2*2]) | (bfr_(sv[o2*2+1])<<16);
}

// two GEMMs sharing A: tI = A@WI, tC = A@WC
__global__ __launch_bounds__(256) void k_gemm2(
    const float* __restrict__ A, const float* __restrict__ WI,
    const float* __restrict__ WC,
    float* __restrict__ tI, float* __restrict__ tC, int N)
{
  int lane = threadIdx.x & 63;
  int w = blockIdx.x*4 + (threadIdx.x>>6);
  int half = __builtin_amdgcn_readfirstlane((w & 1) << 6);
  int node = (w >> 1)*64 + lane;
  if (node >= N) return;
  const float4* av = reinterpret_cast<const float4*>(A + (size_t)node*H);
  float accI[64], accC[64];
  #pragma unroll
  for (int o=0;o<64;o++){ accI[o]=0.f; accC[o]=0.f; }
  for (int kc=0;kc<H/4;kc++){
    float4 v = av[kc];
    const float xs[4] = {v.x, v.y, v.z, v.w};
    const float* wi = WI + (size_t)(kc*4)*H + half;
    const float* wc = WC + (size_t)(kc*4)*H + half;
    #pragma unroll
    for (int c=0;c<4;c++){
      float xe = xs[c];
      #pragma unroll
      for (int o=0;o<64;o++){
        accI[o] = fmaf(xe, wi[c*H+o], accI[o]);
        accC[o] = fmaf(xe, wc[c*H+o], accC[o]);
      }
    }
  }
  float4* ci = reinterpret_cast<float4*>(tI + (size_t)node*H + half);
  float4* cc = reinterpret_cast<float4*>(tC + (size_t)node*H + half);
  #pragma unroll
  for (int o4=0;o4<16;o4++){
    ci[o4] = make_float4(accI[o4*4],accI[o4*4+1],accI[o4*4+2],accI[o4*4+3]);
    cc[o4] = make_float4(accC[o4*4],accC[o4*4+1],accC[o4*4+2],accC[o4*4+3]);
  }
}

// ---- CSR build ----
__global__ void k_hist(const int* __restrict__ ei, int* __restrict__ cnt, int E){
  int e = blockIdx.x*blockDim.x + threadIdx.x;
  if (e < E) atomicAdd(cnt + ei[E+e], 1);
}

__global__ __launch_bounds__(1024) void k_scan(const int* __restrict__ cnt,
                                               int* __restrict__ start, int N){
  __shared__ int sm[1024];
  int t = threadIdx.x;
  int chunk = (N + 1023)/1024;
  int i0 = t*chunk, i1 = min(i0+chunk, N);
  int s = 0;
  for (int i=i0;i<i1;i++) s += cnt[i];
  sm[t] = s; __syncthreads();
  for (int d=1; d<1024; d<<=1){
    int v = (t>=d)? sm[t-d] : 0;
    __syncthreads();
    sm[t] += v;
    __syncthreads();
  }
  int base = (t==0)? 0 : sm[t-1];
  for (int i=i0;i<i1;i++){ start[i] = base; base += cnt[i]; }
  if (t == 1023) start[N] = base;
}

// place per-edge records in dst-sorted CSR slots
__global__ void k_fill2(const int* __restrict__ ei, const int* __restrict__ em,
                        const float* __restrict__ ew,
                        const int* __restrict__ start, int* __restrict__ wcnt,
                        int* __restrict__ csr_sc, int* __restrict__ csr_d,
                        float* __restrict__ csr_w, int E){
  int e = blockIdx.x*blockDim.x + threadIdx.x;
  if (e >= E) return;
  int s = ei[e], d = ei[E+e];
  int chan = (em[s] == em[d]) ? 0 : 1;
  int pos = start[d] + atomicAdd(wcnt + d, 1);
  csr_sc[pos] = (s<<1) | chan;
  csr_d[pos] = d;
  csr_w[pos] = ew[e];
}

// per-edge MLP gate in CSR (dst-sorted) order, bf16 h gathers.
__global__ __launch_bounds__(256) void k_edge(
    const unsigned int* __restrict__ hb,
    const int* __restrict__ csr_sc, const int* __restrict__ csr_d,
    const float* __restrict__ csr_w,
    const float* __restrict__ W1, const float* __restrict__ b1,
    const float* __restrict__ W2, const float* __restrict__ b2,
    float* __restrict__ csr_cf,
    float* __restrict__ degI, float* __restrict__ degC, int E)
{
  int k = blockIdx.x*blockDim.x + threadIdx.x;
  if (k >= E) return;
  int sc = csr_sc[k];
  int s = sc>>1, chan = sc&1;
  int d = csr_d[k];
  float wgt = csr_w[k];
  const uint4* hs = reinterpret_cast<const uint4*>(hb + (size_t)s*64);
  const uint4* hd = reinterpret_cast<const uint4*>(hb + (size_t)d*64);
  float acc[64];
  #pragma unroll
  for (int o=0;o<64;o++) acc[o] = b1[o];
  for (int kc=0;kc<8;kc++){
    #pragma unroll
    for (int q=0;q<2;q++){
      uint4 ua = hs[kc*2+q], ub = hd[kc*2+q];
      const unsigned int us[4]={ua.x,ua.y,ua.z,ua.w};
      const unsigned int ud[4]={ub.x,ub.y,ub.z,ub.w};
      #pragma unroll
      for (int c=0;c<4;c++){
        float s0=__uint_as_float(us[c]<<16), s1=__uint_as_float(us[c]&0xffff0000u);
        float d0=__uint_as_float(ud[c]<<16), d1=__uint_as_float(ud[c]&0xffff0000u);
        float df0=fabsf(s0-d0), df1=fabsf(s1-d1);
        const float* w0 = W1 + (size_t)(kc*16 + q*8 + c*2)*64;
        #pragma unroll
        for (int o=0;o<64;o++) acc[o] = fmaf(df0, w0[o], acc[o]);
        #pragma unroll
        for (int o=0;o<64;o++) acc[o] = fmaf(df1, w0[64+o], acc[o]);
      }
    }
  }
  const float* w1last = W1 + 128*64;
  float t = b2[0];
  #pragma unroll
  for (int o=0;o<64;o++){
    float v = fmaxf(fmaf(wgt, w1last[o], acc[o]), 0.f);
    t = fmaf(v, W2[o], t);
  }
  float g = sigmoidf_(t);
  g = fminf(fmaxf(g, 0.2f), 1.2f);
  float ehat = wgt * g;
  csr_cf[k] = ehat;
  atomicAdd((chan ? degC : degI)+d, ehat);
}

__global__ void k_dinv(const float* __restrict__ degI, const float* __restrict__ degC,
                       float* dinvI, float* dinvC, int N){
  int i = blockIdx.x*blockDim.x + threadIdx.x;
  if (i < N){
    dinvI[i] = rsqrtf(1.f + degI[i]);
    dinvC[i] = rsqrtf(1.f + degC[i]);
  }
}

__global__ void k_scale(const int* __restrict__ csr_sc, const int* __restrict__ csr_d,
                        const float* __restrict__ dinvI, const float* __restrict__ dinvC,
                        float* __restrict__ csr_cf, int E){
  int k = blockIdx.x*blockDim.x + threadIdx.x;
  if (k >= E) return;
  int sc = csr_sc[k];
  int s = sc>>1;
  int d = csr_d[k];
  const float* dv = (sc&1) ? dinvC : dinvI;
  csr_cf[k] *= dv[s]*dv[d];
}

// one wave per dst node: gather CSR edges + fused self-loop/bias epilogue.
__global__ __launch_bounds__(256) void k_aggr(
    const float* __restrict__ tI, const float* __restrict__ tC,
    const int* __restrict__ start, const int* __restrict__ csr_sc,
    const float* __restrict__ csr_cf,
    const float* __restrict__ dinvI, const float* __restrict__ dinvC,
    const float* __restrict__ bI, const float* __restrict__ bC,
    const float* __restrict__ relg, int l,
    float* __restrict__ h, int N)
{
  int lane = threadIdx.x & 63;
  int d = blockIdx.x*4 + (threadIdx.x>>6);
  if (d >= N) return;
  float sig = sigmoidf_(relg[l]);
  int k0 = start[d], k1 = start[d+1];
  int off = lane*2;
  float ax=0.f, ay=0.f;
  for (int k=k0;k<k1;k++){
    int sc = csr_sc[k];
    float cf = csr_cf[k];
    int src = sc>>1;
    const float* t = (sc&1) ? tC : tI;
    float ce = (sc&1) ? sig*cf : cf;
    float2 v = *reinterpret_cast<const float2*>(t + (size_t)src*H + off);
    ax = fmaf(ce, v.x, ax);
    ay = fmaf(ce, v.y, ay);
  }
  float diI = dinvI[d], diC = dinvC[d];
  float rI = diI*diI, rC = diC*diC;
  float2 ti = *reinterpret_cast<const float2*>(tI + (size_t)d*H + off);
  float2 tc = *reinterpret_cast<const float2*>(tC + (size_t)d*H + off);
  float2 o;
  o.x = fmaf(ti.x, rI, bI[off])   + sig*fmaf(tc.x, rC, bC[off])   + ax;
  o.y = fmaf(ti.y, rI, bI[off+1]) + sig*fmaf(tc.y, rC, bC[off+1]) + ay;
  *reinterpret_cast<float2*>(h + (size_t)d*H + off) = o;
}

__global__ __launch_bounds__(128) void k_stats(const float* __restrict__ h,
    float* __restrict__ bnsum, float* __restrict__ bnsq, int N, int nper)
{
  int j = threadIdx.x;
  int n0 = blockIdx.x*nper, n1 = min(n0+nper, N);
  float sl=0.f, sq=0.f;
  for (int n=n0;n<n1;n++){
    float v = h[(size_t)n*H+j];
    sl += v; sq = fmaf(v,v,sq);
  }
  atomicAdd(bnsum+j, sl); atomicAdd(bnsq+j, sq);
}

__global__ void k_bn(float* __restrict__ h, const float* __restrict__ bnsum,
                     const float* __restrict__ bnsq,
                     const float* __restrict__ gamma, const float* __restrict__ beta,
                     float invN, int NH)
{
  int i = blockIdx.x*blockDim.x + threadIdx.x;
  if (i >= NH) return;
  int j = i & (H-1);
  float mu = bnsum[j]*invN;
  float var = bnsq[j]*invN - mu*mu;
  float r = rsqrtf(var + 1e-5f);
  h[i] = fmaxf(fmaf(gamma[j], (h[i]-mu)*r, beta[j]), 0.f);
}

__global__ __launch_bounds__(128) void k_pool(
    const float* __restrict__ h, const int* __restrict__ batch, const int* __restrict__ em,
    float* __restrict__ sumE, float* __restrict__ sumF,
    float* __restrict__ cntE, float* __restrict__ cntF, int N, int nper)
{
  int j = threadIdx.x;
  int n0 = blockIdx.x*nper, n1 = min(n0+nper, N);
  if (n0 >= N) return;
  float aE=0.f, aF=0.f, ce=0.f, cfc=0.f;
  int cg = batch[n0];
  for (int n=n0;n<n1;n++){
    int g = batch[n];
    if (g != cg){
      atomicAdd(sumE+(size_t)cg*H+j, aE);
      atomicAdd(sumF+(size_t)cg*H+j, aF);
      if (j==0){ atomicAdd(cntE+cg, ce); atomicAdd(cntF+cg, cfc); }
      aE=aF=ce=cfc=0.f; cg=g;
    }
    float v = h[(size_t)n*H+j];
    bool e = em[n] != 0;
    if (e) aE += v; else aF += v;
    if (j==0){ if (e) ce += 1.f; else cfc += 1.f; }
  }
  atomicAdd(sumE+(size_t)cg*H+j, aE);
  atomicAdd(sumF+(size_t)cg*H+j, aF);
  if (j==0){ atomicAdd(cntE+cg, ce); atomicAdd(cntF+cg, cfc); }
}

__device__ __forceinline__ float blockReduceSum(float v, float* red){
  int t = threadIdx.x;
  red[t] = v; __syncthreads();
  #pragma unroll
  for (int s=64;s>0;s>>=1){ if (t<s) red[t]+=red[t+s]; __syncthreads(); }
  float r = red[0]; __syncthreads();
  return r;
}

__global__ __launch_bounds__(128) void k_head(
    const float* __restrict__ sumE, const float* __restrict__ sumF,
    const float* __restrict__ cntE, const float* __restrict__ cntF,
    const float* __restrict__ coW1, const float* __restrict__ cob1,
    const float* __restrict__ coW2, const float* __restrict__ cob2,
    const float* __restrict__ gW1, const float* __restrict__ gb1,
    const float* __restrict__ gW2, const float* __restrict__ gb2,
    const float* __restrict__ cW1, const float* __restrict__ cb1,
    const float* __restrict__ cW2, const float* __restrict__ cb2,
    const float* __restrict__ peW1, const float* __restrict__ peb1,
    const float* __restrict__ peW2, const float* __restrict__ peb2,
    const float* __restrict__ pfW1, const float* __restrict__ pfb1,
    const float* __restrict__ pfW2, const float* __restrict__ pfb2,
    float* __restrict__ out, int G)
{
  int g = blockIdx.x, j = threadIdx.x;
  __shared__ float sh[384];
  __shared__ float red[128];
  __shared__ float hfin[128], buf[128];
  float cE = cntE[g], cF = cntF[g];
  float se = sumE[(size_t)g*H+j], sf = sumF[(size_t)g*H+j];
  float he = se/fmaxf(cE,1.f), hf = sf/fmaxf(cF,1.f);
  float hg = (se+sf)/fmaxf(cE+cF,1.f);
  sh[j]=he; sh[128+j]=hf; sh[256+j]=he*hf;
  __syncthreads();
  float a = cob1[j];
  for (int k=0;k<384;k++) a = fmaf(sh[k], coW1[k*H+j], a);
  a = fmaxf(a, 0.f);
  float r0 = blockReduceSum(a*coW2[2*j],   red);
  float r1 = blockReduceSum(a*coW2[2*j+1], red);
  float al0 = sigmoidf_(r0 + cob2[0]);
  float al1 = sigmoidf_(r1 + cob2[1]);
  float asum = al0+al1+1e-6f; al0/=asum; al1/=asum;
  float hc = al0*he + al1*hf;
  __syncthreads();
  sh[j]=hc; sh[128+j]=hg;
  __syncthreads();
  float gg = gb1[j];
  for (int k=0;k<256;k++) gg = fmaf(sh[k], gW1[k*H+j], gg);
  gg = fmaxf(gg, 0.f);
  float gt = sigmoidf_(blockReduceSum(gg*gW2[j], red) + gb2[0]);
  float hfj = gt*hc + (1.f-gt)*hg;
  hfin[j] = hfj;
  __syncthreads();
  float c1v = 0.f;
  if (j < 64){
    float c1 = cb1[j];
    for (int k=0;k<128;k++) c1 = fmaf(hfin[k], cW1[k*64+j], c1);
    c1v = fmaxf(c1, 0.f);
  }
  float l0 = blockReduceSum(j<64 ? c1v*cW2[2*j]   : 0.f, red);
  float l1 = blockReduceSum(j<64 ? c1v*cW2[2*j+1] : 0.f, red);
  if (j==0){ out[(size_t)g*2] = l0 + cb2[0]; out[(size_t)g*2+1] = l1 + cb2[1]; }
  // z_e
  buf[j] = he; __syncthreads();
  float q = peb1[j];
  for (int k=0;k<128;k++) q = fmaf(buf[k], peW1[k*H+j], q);
  q = fmaxf(q, 0.f);
  __syncthreads(); sh[j] = q; __syncthreads();
  float z = peb2[j];
  for (int k=0;k<128;k++) z = fmaf(sh[k], peW2[k*H+j], z);
  float nr = sqrtf(blockReduceSum(z*z, red));
  out[(size_t)G*2 + (size_t)g*H + j] = z / fmaxf(nr, 1e-12f);
  // z_f
  __syncthreads(); buf[j] = hf; __syncthreads();
  float q2 = pfb1[j];
  for (int k=0;k<128;k++) q2 = fmaf(buf[k], pfW1[k*H+j], q2);
  q2 = fmaxf(q2, 0.f);
  __syncthreads(); sh[j] = q2; __syncthreads();
  float z2 = pfb2[j];
  for (int k=0;k<128;k++) z2 = fmaf(sh[k], pfW2[k*H+j], z2);
  float nr2 = sqrtf(blockReduceSum(z2*z2, red));
  out[(size_t)G*2 + (size_t)G*H + (size_t)g*H + j] = z2 / fmaxf(nr2, 1e-12f);
}

extern "C" void kernel_launch(void* const* d_in, const int* in_sizes, int n_in,
                              void* d_out, int out_size, void* d_ws, size_t ws_size,
                              hipStream_t stream)
{
  const float* x    = (const float*)d_in[0];
  const int*   ei   = (const int*)d_in[1];
  const float* ew   = (const float*)d_in[2];
  const int*   batch= (const int*)d_in[3];
  const int*   em   = (const int*)d_in[4];
  const float* eegW = (const float*)d_in[6];  const float* eegB = (const float*)d_in[7];
  const float* fnW  = (const float*)d_in[8];  const float* fnB  = (const float*)d_in[9];
  const float* eW1  = (const float*)d_in[10]; const float* eb1  = (const float*)d_in[11];
  const float* eW2  = (const float*)d_in[12]; const float* eb2  = (const float*)d_in[13];
  const float* cIW  = (const float*)d_in[14]; const float* cIb  = (const float*)d_in[15];
  const float* cCW  = (const float*)d_in[16]; const float* cCb  = (const float*)d_in[17];
  const float* relg = (const float*)d_in[18];
  const float* bng  = (const float*)d_in[19]; const float* bnb  = (const float*)d_in[20];
  const float* coW1 = (const float*)d_in[21]; const float* cob1 = (const float*)d_in[22];
  const float* coW2 = (const float*)d_in[23]; const float* cob2 = (const float*)d_in[24];
  const float* gW1  = (const float*)d_in[25]; const float* gb1  = (const float*)d_in[26];
  const float* gW2  = (const float*)d_in[27]; const float* gb2  = (const float*)d_in[28];
  const float* cW1  = (const float*)d_in[29]; const float* cb1  = (const float*)d_in[30];
  const float* cW2  = (const float*)d_in[31]; const float* cb2  = (const float*)d_in[32];
  const float* peW1 = (const float*)d_in[33]; const float* peb1 = (const float*)d_in[34];
  const float* peW2 = (const float*)d_in[35]; const float* peb2 = (const float*)d_in[36];
  const float* pfW1 = (const float*)d_in[37]; const float* pfb1 = (const float*)d_in[38];
  const float* pfW2 = (const float*)d_in[39]; const float* pfb2 = (const float*)d_in[40];
  float* out = (float*)d_out;

  int N = in_sizes[0] / D;           // 50000
  int E = in_sizes[2];               // 800000
  int G = out_size / (2 + 2*H);      // 500
  int NH = N*H;

  float* p = (float*)d_ws;
  float* h    = p; p += (size_t)NH;
  float* tI   = p; p += (size_t)NH;   // also overlaid as bf16 hb before layer loop
  float* tC   = p; p += (size_t)NH;
  float* csr_cf = p; p += E;
  float* csr_w  = p; p += E;
  int* csr_sc = (int*)p; p += E;
  int* csr_d  = (int*)p; p += E;
  int* start  = (int*)p; p += (N+1);
  int* cnt    = (int*)p; p += N;      // cnt, wcnt, degI, degC contiguous -> one memset
  int* wcnt   = (int*)p; p += N;
  float* degI = p; p += N;
  float* degC = p; p += N;
  float* dinvI= p; p += N;
  float* dinvC= p; p += N;
  float* bnsum= p; p += H;            // bnsum+bnsq contiguous
  float* bnsq = p; p += H;
  float* sumE = p; p += (size_t)G*H;  // sumE..cntF contiguous
  float* sumF = p; p += (size_t)G*H;
  float* cntE = p; p += G;
  float* cntF = p; p += G;

  unsigned int* hb = (unsigned int*)tI;   // bf16 h, used only before layer loop

  int nwaves = ((N+63)/64)*2;
  int gemmBlocks = (nwaves+3)/4;
  int nper_fin = (N + 511)/512;

  hipMemsetAsync(cnt, 0, (size_t)4*N*sizeof(int), stream);  // cnt,wcnt,degI,degC
  k_hist<<<(E+255)/256,256,0,stream>>>(ei, cnt, E);
  k_scan<<<1,1024,0,stream>>>(cnt, start, N);
  k_fill2<<<(E+255)/256,256,0,stream>>>(ei, em, ew, start, wcnt,
                                        csr_sc, csr_d, csr_w, E);
  k_proj<<<gemmBlocks,256,0,stream>>>(x, em, eegW,eegB, fnW,fnB, h, hb, N);
  k_edge<<<(E+255)/256,256,0,stream>>>(hb, csr_sc, csr_d, csr_w,
                                       eW1,eb1,eW2,eb2, csr_cf, degI,degC, E);
  k_dinv<<<(N+255)/256,256,0,stream>>>(degI,degC,dinvI,dinvC,N);
  k_scale<<<(E+255)/256,256,0,stream>>>(csr_sc, csr_d, dinvI, dinvC, csr_cf, E);

  for (int l=0;l<2;l++){
    k_gemm2<<<gemmBlocks,256,0,stream>>>(h, cIW + (size_t)l*H*H,
                                         cCW + (size_t)l*H*H, tI, tC, N);
    k_aggr<<<(N+3)/4,256,0,stream>>>(tI, tC, start, csr_sc, csr_cf,
                                     dinvI, dinvC, cIb+(size_t)l*H,
                                     cCb+(size_t)l*H, relg, l, h, N);
    hipMemsetAsync(bnsum, 0, 2*H*sizeof(float), stream);
    k_stats<<<512,128,0,stream>>>(h, bnsum, bnsq, N, nper_fin);
    k_bn<<<(NH+255)/256,256,0,stream>>>(h, bnsum, bnsq,
                                        bng+(size_t)l*H, bnb+(size_t)l*H,
                                        1.0f/(float)N, NH);
  }

  hipMemsetAsync(sumE, 0, ((size_t)2*G*H + 2*G)*sizeof(float), stream);
  k_pool<<<(N+511)/512,128,0,stream>>>(h, batch, em, sumE, sumF, cntE, cntF, N, 512);
  k_head<<<G,128,0,stream>>>(sumE,sumF,cntE,cntF,
                             coW1,cob1,coW2,cob2, gW1,gb1,gW2,gb2,
                             cW1,cb1,cW2,cb2, peW1,peb1,peW2,peb2,
                             pfW1,pfb1,pfW2,pfb2, out, G);
}

// Round 4
// 1045.502 us; speedup vs baseline: 2.2130x; 1.1875x over previous
//
#include <hip/hip_runtime.h>
#include <math.h>

#define H 128
#define D 256

__device__ __forceinline__ float sigmoidf_(float x){ return 1.0f/(1.0f+__expf(-x)); }

// RNE float->bf16 (as ushort in low 16 bits)
__device__ __forceinline__ unsigned int bfr_(float f){
  unsigned int u = __float_as_uint(f);
  return (u + 0x7fffu + ((u>>16)&1u)) >> 16;
}

// h = relu(x @ Wsel + bsel), per-node select; writes fp32 h and bf16 hb.
// LDS-staged: 64-node tile, A transposed in LDS, wave = 32 cols.
__global__ __launch_bounds__(256) void k_proj(
    const float* __restrict__ x, const int* __restrict__ em,
    const float* __restrict__ We, const float* __restrict__ be,
    const float* __restrict__ Wf, const float* __restrict__ bf,
    float* __restrict__ h, unsigned int* __restrict__ hb, int N)
{
  __shared__ float lds[128][65];
  int t = threadIdx.x;
  int lane = t & 63;
  int col0 = __builtin_amdgcn_readfirstlane((t >> 6) * 32);
  int n0 = blockIdx.x * 64;
  int node = n0 + lane;

  float accE[32], accF[32];
  #pragma unroll
  for (int o=0;o<32;o++){ accE[o]=be[col0+o]; accF[o]=bf[col0+o]; }

  for (int half=0; half<2; half++){
    if (half) __syncthreads();
    // stage 64 nodes x 128 k (transposed)
    #pragma unroll
    for (int c=0;c<8;c++){
      int idx = (c*256 + t)*4;
      int n = idx >> 7, k = idx & 127;
      int nn = n0 + n;
      float4 v = (nn < N) ? *reinterpret_cast<const float4*>(x + (size_t)nn*D + half*128 + k)
                          : make_float4(0.f,0.f,0.f,0.f);
      lds[k+0][n]=v.x; lds[k+1][n]=v.y; lds[k+2][n]=v.z; lds[k+3][n]=v.w;
    }
    __syncthreads();
    const float* weB = We + (size_t)(half*128)*H + col0;
    const float* wfB = Wf + (size_t)(half*128)*H + col0;
    #pragma unroll 4
    for (int k=0;k<128;k++){
      float a = lds[k][lane];
      const float* we = weB + (size_t)k*H;
      const float* wf = wfB + (size_t)k*H;
      #pragma unroll
      for (int o=0;o<32;o++){
        accE[o] = fmaf(a, we[o], accE[o]);
        accF[o] = fmaf(a, wf[o], accF[o]);
      }
    }
  }
  if (node >= N) return;
  bool e = em[node] != 0;
  float sv[32];
  #pragma unroll
  for (int o=0;o<32;o++) sv[o] = fmaxf(e?accE[o]:accF[o], 0.f);
  float4* hr = reinterpret_cast<float4*>(h + (size_t)node*H + col0);
  #pragma unroll
  for (int o4=0;o4<8;o4++)
    hr[o4] = make_float4(sv[o4*4],sv[o4*4+1],sv[o4*4+2],sv[o4*4+3]);
  unsigned int* hbr = hb + (size_t)node*64 + (col0>>1);
  #pragma unroll
  for (int o2=0;o2<16;o2++)
    hbr[o2] = bfr_(sv[o2*2]) | (bfr_(sv[o2*2+1])<<16);
}

// two GEMMs sharing A: tI = A@WI, tC = A@WC. LDS-staged like k_proj, K=128.
__global__ __launch_bounds__(256) void k_gemm2(
    const float* __restrict__ A, const float* __restrict__ WI,
    const float* __restrict__ WC,
    float* __restrict__ tI, float* __restrict__ tC, int N)
{
  __shared__ float lds[128][65];
  int t = threadIdx.x;
  int lane = t & 63;
  int col0 = __builtin_amdgcn_readfirstlane((t >> 6) * 32);
  int n0 = blockIdx.x * 64;
  int node = n0 + lane;

  #pragma unroll
  for (int c=0;c<8;c++){
    int idx = (c*256 + t)*4;
    int n = idx >> 7, k = idx & 127;
    int nn = n0 + n;
    float4 v = (nn < N) ? *reinterpret_cast<const float4*>(A + (size_t)nn*H + k)
                        : make_float4(0.f,0.f,0.f,0.f);
    lds[k+0][n]=v.x; lds[k+1][n]=v.y; lds[k+2][n]=v.z; lds[k+3][n]=v.w;
  }
  __syncthreads();

  float accI[32], accC[32];
  #pragma unroll
  for (int o=0;o<32;o++){ accI[o]=0.f; accC[o]=0.f; }
  const float* wiB = WI + col0;
  const float* wcB = WC + col0;
  #pragma unroll 4
  for (int k=0;k<128;k++){
    float a = lds[k][lane];
    const float* wi = wiB + (size_t)k*H;
    const float* wc = wcB + (size_t)k*H;
    #pragma unroll
    for (int o=0;o<32;o++){
      accI[o] = fmaf(a, wi[o], accI[o]);
      accC[o] = fmaf(a, wc[o], accC[o]);
    }
  }
  if (node >= N) return;
  float4* ci = reinterpret_cast<float4*>(tI + (size_t)node*H + col0);
  float4* cc = reinterpret_cast<float4*>(tC + (size_t)node*H + col0);
  #pragma unroll
  for (int o4=0;o4<8;o4++){
    ci[o4] = make_float4(accI[o4*4],accI[o4*4+1],accI[o4*4+2],accI[o4*4+3]);
    cc[o4] = make_float4(accC[o4*4],accC[o4*4+1],accC[o4*4+2],accC[o4*4+3]);
  }
}

// ---- CSR build ----
__global__ void k_hist(const int* __restrict__ ei, int* __restrict__ cnt, int E){
  int e = blockIdx.x*blockDim.x + threadIdx.x;
  if (e < E) atomicAdd(cnt + ei[E+e], 1);
}

__global__ __launch_bounds__(1024) void k_scan(const int* __restrict__ cnt,
                                               int* __restrict__ start, int N){
  __shared__ int sm[1024];
  int t = threadIdx.x;
  int chunk = (N + 1023)/1024;
  int i0 = t*chunk, i1 = min(i0+chunk, N);
  int s = 0;
  for (int i=i0;i<i1;i++) s += cnt[i];
  sm[t] = s; __syncthreads();
  for (int d=1; d<1024; d<<=1){
    int v = (t>=d)? sm[t-d] : 0;
    __syncthreads();
    sm[t] += v;
    __syncthreads();
  }
  int base = (t==0)? 0 : sm[t-1];
  for (int i=i0;i<i1;i++){ start[i] = base; base += cnt[i]; }
  if (t == 1023) start[N] = base;
}

// place per-edge records in dst-sorted CSR slots
__global__ void k_fill2(const int* __restrict__ ei, const int* __restrict__ em,
                        const float* __restrict__ ew,
                        const int* __restrict__ start, int* __restrict__ wcnt,
                        int* __restrict__ csr_sc, int* __restrict__ csr_d,
                        float* __restrict__ csr_w, int E){
  int e = blockIdx.x*blockDim.x + threadIdx.x;
  if (e >= E) return;
  int s = ei[e], d = ei[E+e];
  int chan = (em[s] == em[d]) ? 0 : 1;
  int pos = start[d] + atomicAdd(wcnt + d, 1);
  csr_sc[pos] = (s<<1) | chan;
  csr_d[pos] = d;
  csr_w[pos] = ew[e];
}

// per-edge MLP gate in CSR (dst-sorted) order, bf16 h gathers.
__global__ __launch_bounds__(256) void k_edge(
    const unsigned int* __restrict__ hb,
    const int* __restrict__ csr_sc, const int* __restrict__ csr_d,
    const float* __restrict__ csr_w,
    const float* __restrict__ W1, const float* __restrict__ b1,
    const float* __restrict__ W2, const float* __restrict__ b2,
    float* __restrict__ csr_cf,
    float* __restrict__ degI, float* __restrict__ degC, int E)
{
  int k = blockIdx.x*blockDim.x + threadIdx.x;
  if (k >= E) return;
  int sc = csr_sc[k];
  int s = sc>>1, chan = sc&1;
  int d = csr_d[k];
  float wgt = csr_w[k];
  const uint4* hs = reinterpret_cast<const uint4*>(hb + (size_t)s*64);
  const uint4* hd = reinterpret_cast<const uint4*>(hb + (size_t)d*64);
  float acc[64];
  #pragma unroll
  for (int o=0;o<64;o++) acc[o] = b1[o];
  for (int kc=0;kc<8;kc++){
    #pragma unroll
    for (int q=0;q<2;q++){
      uint4 ua = hs[kc*2+q], ub = hd[kc*2+q];
      const unsigned int us[4]={ua.x,ua.y,ua.z,ua.w};
      const unsigned int ud[4]={ub.x,ub.y,ub.z,ub.w};
      #pragma unroll
      for (int c=0;c<4;c++){
        float s0=__uint_as_float(us[c]<<16), s1=__uint_as_float(us[c]&0xffff0000u);
        float d0=__uint_as_float(ud[c]<<16), d1=__uint_as_float(ud[c]&0xffff0000u);
        float df0=fabsf(s0-d0), df1=fabsf(s1-d1);
        const float* w0 = W1 + (size_t)(kc*16 + q*8 + c*2)*64;
        #pragma unroll
        for (int o=0;o<64;o++) acc[o] = fmaf(df0, w0[o], acc[o]);
        #pragma unroll
        for (int o=0;o<64;o++) acc[o] = fmaf(df1, w0[64+o], acc[o]);
      }
    }
  }
  const float* w1last = W1 + 128*64;
  float t = b2[0];
  #pragma unroll
  for (int o=0;o<64;o++){
    float v = fmaxf(fmaf(wgt, w1last[o], acc[o]), 0.f);
    t = fmaf(v, W2[o], t);
  }
  float g = sigmoidf_(t);
  g = fminf(fmaxf(g, 0.2f), 1.2f);
  float ehat = wgt * g;
  csr_cf[k] = ehat;
  atomicAdd((chan ? degC : degI)+d, ehat);
}

__global__ void k_dinv(const float* __restrict__ degI, const float* __restrict__ degC,
                       float* dinvI, float* dinvC, int N){
  int i = blockIdx.x*blockDim.x + threadIdx.x;
  if (i < N){
    dinvI[i] = rsqrtf(1.f + degI[i]);
    dinvC[i] = rsqrtf(1.f + degC[i]);
  }
}

__global__ void k_scale(const int* __restrict__ csr_sc, const int* __restrict__ csr_d,
                        const float* __restrict__ dinvI, const float* __restrict__ dinvC,
                        float* __restrict__ csr_cf, int E){
  int k = blockIdx.x*blockDim.x + threadIdx.x;
  if (k >= E) return;
  int sc = csr_sc[k];
  int s = sc>>1;
  int d = csr_d[k];
  const float* dv = (sc&1) ? dinvC : dinvI;
  csr_cf[k] *= dv[s]*dv[d];
}

// one wave per dst node: gather CSR edges + fused self-loop/bias epilogue.
__global__ __launch_bounds__(256) void k_aggr(
    const float* __restrict__ tI, const float* __restrict__ tC,
    const int* __restrict__ start, const int* __restrict__ csr_sc,
    const float* __restrict__ csr_cf,
    const float* __restrict__ dinvI, const float* __restrict__ dinvC,
    const float* __restrict__ bI, const float* __restrict__ bC,
    const float* __restrict__ relg, int l,
    float* __restrict__ h, int N)
{
  int lane = threadIdx.x & 63;
  int d = blockIdx.x*4 + (threadIdx.x>>6);
  if (d >= N) return;
  float sig = sigmoidf_(relg[l]);
  int k0 = start[d], k1 = start[d+1];
  int off = lane*2;
  float ax=0.f, ay=0.f;
  for (int k=k0;k<k1;k++){
    int sc = csr_sc[k];
    float cf = csr_cf[k];
    int src = sc>>1;
    const float* t = (sc&1) ? tC : tI;
    float ce = (sc&1) ? sig*cf : cf;
    float2 v = *reinterpret_cast<const float2*>(t + (size_t)src*H + off);
    ax = fmaf(ce, v.x, ax);
    ay = fmaf(ce, v.y, ay);
  }
  float diI = dinvI[d], diC = dinvC[d];
  float rI = diI*diI, rC = diC*diC;
  float2 ti = *reinterpret_cast<const float2*>(tI + (size_t)d*H + off);
  float2 tc = *reinterpret_cast<const float2*>(tC + (size_t)d*H + off);
  float2 o;
  o.x = fmaf(ti.x, rI, bI[off])   + sig*fmaf(tc.x, rC, bC[off])   + ax;
  o.y = fmaf(ti.y, rI, bI[off+1]) + sig*fmaf(tc.y, rC, bC[off+1]) + ay;
  *reinterpret_cast<float2*>(h + (size_t)d*H + off) = o;
}

__global__ __launch_bounds__(128) void k_stats(const float* __restrict__ h,
    float* __restrict__ bnsum, float* __restrict__ bnsq, int N, int nper)
{
  int j = threadIdx.x;
  int n0 = blockIdx.x*nper, n1 = min(n0+nper, N);
  float sl=0.f, sq=0.f;
  for (int n=n0;n<n1;n++){
    float v = h[(size_t)n*H+j];
    sl += v; sq = fmaf(v,v,sq);
  }
  atomicAdd(bnsum+j, sl); atomicAdd(bnsq+j, sq);
}

__global__ void k_bn(float* __restrict__ h, const float* __restrict__ bnsum,
                     const float* __restrict__ bnsq,
                     const float* __restrict__ gamma, const float* __restrict__ beta,
                     float invN, int NH)
{
  int i = blockIdx.x*blockDim.x + threadIdx.x;
  if (i >= NH) return;
  int j = i & (H-1);
  float mu = bnsum[j]*invN;
  float var = bnsq[j]*invN - mu*mu;
  float r = rsqrtf(var + 1e-5f);
  h[i] = fmaxf(fmaf(gamma[j], (h[i]-mu)*r, beta[j]), 0.f);
}

__global__ __launch_bounds__(128) void k_pool(
    const float* __restrict__ h, const int* __restrict__ batch, const int* __restrict__ em,
    float* __restrict__ sumE, float* __restrict__ sumF,
    float* __restrict__ cntE, float* __restrict__ cntF, int N, int nper)
{
  int j = threadIdx.x;
  int n0 = blockIdx.x*nper, n1 = min(n0+nper, N);
  if (n0 >= N) return;
  float aE=0.f, aF=0.f, ce=0.f, cfc=0.f;
  int cg = batch[n0];
  for (int n=n0;n<n1;n++){
    int g = batch[n];
    if (g != cg){
      atomicAdd(sumE+(size_t)cg*H+j, aE);
      atomicAdd(sumF+(size_t)cg*H+j, aF);
      if (j==0){ atomicAdd(cntE+cg, ce); atomicAdd(cntF+cg, cfc); }
      aE=aF=ce=cfc=0.f; cg=g;
    }
    float v = h[(size_t)n*H+j];
    bool e = em[n] != 0;
    if (e) aE += v; else aF += v;
    if (j==0){ if (e) ce += 1.f; else cfc += 1.f; }
  }
  atomicAdd(sumE+(size_t)cg*H+j, aE);
  atomicAdd(sumF+(size_t)cg*H+j, aF);
  if (j==0){ atomicAdd(cntE+cg, ce); atomicAdd(cntF+cg, cfc); }
}

__device__ __forceinline__ float blockReduceSum(float v, float* red){
  int t = threadIdx.x;
  red[t] = v; __syncthreads();
  #pragma unroll
  for (int s=64;s>0;s>>=1){ if (t<s) red[t]+=red[t+s]; __syncthreads(); }
  float r = red[0]; __syncthreads();
  return r;
}

__global__ __launch_bounds__(128) void k_head(
    const float* __restrict__ sumE, const float* __restrict__ sumF,
    const float* __restrict__ cntE, const float* __restrict__ cntF,
    const float* __restrict__ coW1, const float* __restrict__ cob1,
    const float* __restrict__ coW2, const float* __restrict__ cob2,
    const float* __restrict__ gW1, const float* __restrict__ gb1,
    const float* __restrict__ gW2, const float* __restrict__ gb2,
    const float* __restrict__ cW1, const float* __restrict__ cb1,
    const float* __restrict__ cW2, const float* __restrict__ cb2,
    const float* __restrict__ peW1, const float* __restrict__ peb1,
    const float* __restrict__ peW2, const float* __restrict__ peb2,
    const float* __restrict__ pfW1, const float* __restrict__ pfb1,
    const float* __restrict__ pfW2, const float* __restrict__ pfb2,
    float* __restrict__ out, int G)
{
  int g = blockIdx.x, j = threadIdx.x;
  __shared__ float sh[384];
  __shared__ float red[128];
  __shared__ float hfin[128], buf[128];
  float cE = cntE[g], cF = cntF[g];
  float se = sumE[(size_t)g*H+j], sf = sumF[(size_t)g*H+j];
  float he = se/fmaxf(cE,1.f), hf = sf/fmaxf(cF,1.f);
  float hg = (se+sf)/fmaxf(cE+cF,1.f);
  sh[j]=he; sh[128+j]=hf; sh[256+j]=he*hf;
  __syncthreads();
  float a = cob1[j];
  for (int k=0;k<384;k++) a = fmaf(sh[k], coW1[k*H+j], a);
  a = fmaxf(a, 0.f);
  float r0 = blockReduceSum(a*coW2[2*j],   red);
  float r1 = blockReduceSum(a*coW2[2*j+1], red);
  float al0 = sigmoidf_(r0 + cob2[0]);
  float al1 = sigmoidf_(r1 + cob2[1]);
  float asum = al0+al1+1e-6f; al0/=asum; al1/=asum;
  float hc = al0*he + al1*hf;
  __syncthreads();
  sh[j]=hc; sh[128+j]=hg;
  __syncthreads();
  float gg = gb1[j];
  for (int k=0;k<256;k++) gg = fmaf(sh[k], gW1[k*H+j], gg);
  gg = fmaxf(gg, 0.f);
  float gt = sigmoidf_(blockReduceSum(gg*gW2[j], red) + gb2[0]);
  float hfj = gt*hc + (1.f-gt)*hg;
  hfin[j] = hfj;
  __syncthreads();
  float c1v = 0.f;
  if (j < 64){
    float c1 = cb1[j];
    for (int k=0;k<128;k++) c1 = fmaf(hfin[k], cW1[k*64+j], c1);
    c1v = fmaxf(c1, 0.f);
  }
  float l0 = blockReduceSum(j<64 ? c1v*cW2[2*j]   : 0.f, red);
  float l1 = blockReduceSum(j<64 ? c1v*cW2[2*j+1] : 0.f, red);
  if (j==0){ out[(size_t)g*2] = l0 + cb2[0]; out[(size_t)g*2+1] = l1 + cb2[1]; }
  // z_e
  buf[j] = he; __syncthreads();
  float q = peb1[j];
  for (int k=0;k<128;k++) q = fmaf(buf[k], peW1[k*H+j], q);
  q = fmaxf(q, 0.f);
  __syncthreads(); sh[j] = q; __syncthreads();
  float z = peb2[j];
  for (int k=0;k<128;k++) z = fmaf(sh[k], peW2[k*H+j], z);
  float nr = sqrtf(blockReduceSum(z*z, red));
  out[(size_t)G*2 + (size_t)g*H + j] = z / fmaxf(nr, 1e-12f);
  // z_f
  __syncthreads(); buf[j] = hf; __syncthreads();
  float q2 = pfb1[j];
  for (int k=0;k<128;k++) q2 = fmaf(buf[k], pfW1[k*H+j], q2);
  q2 = fmaxf(q2, 0.f);
  __syncthreads(); sh[j] = q2; __syncthreads();
  float z2 = pfb2[j];
  for (int k=0;k<128;k++) z2 = fmaf(sh[k], pfW2[k*H+j], z2);
  float nr2 = sqrtf(blockReduceSum(z2*z2, red));
  out[(size_t)G*2 + (size_t)G*H + (size_t)g*H + j] = z2 / fmaxf(nr2, 1e-12f);
}

extern "C" void kernel_launch(void* const* d_in, const int* in_sizes, int n_in,
                              void* d_out, int out_size, void* d_ws, size_t ws_size,
                              hipStream_t stream)
{
  const float* x    = (const float*)d_in[0];
  const int*   ei   = (const int*)d_in[1];
  const float* ew   = (const float*)d_in[2];
  const int*   batch= (const int*)d_in[3];
  const int*   em   = (const int*)d_in[4];
  const float* eegW = (const float*)d_in[6];  const float* eegB = (const float*)d_in[7];
  const float* fnW  = (const float*)d_in[8];  const float* fnB  = (const float*)d_in[9];
  const float* eW1  = (const float*)d_in[10]; const float* eb1  = (const float*)d_in[11];
  const float* eW2  = (const float*)d_in[12]; const float* eb2  = (const float*)d_in[13];
  const float* cIW  = (const float*)d_in[14]; const float* cIb  = (const float*)d_in[15];
  const float* cCW  = (const float*)d_in[16]; const float* cCb  = (const float*)d_in[17];
  const float* relg = (const float*)d_in[18];
  const float* bng  = (const float*)d_in[19]; const float* bnb  = (const float*)d_in[20];
  const float* coW1 = (const float*)d_in[21]; const float* cob1 = (const float*)d_in[22];
  const float* coW2 = (const float*)d_in[23]; const float* cob2 = (const float*)d_in[24];
  const float* gW1  = (const float*)d_in[25]; const float* gb1  = (const float*)d_in[26];
  const float* gW2  = (const float*)d_in[27]; const float* gb2  = (const float*)d_in[28];
  const float* cW1  = (const float*)d_in[29]; const float* cb1  = (const float*)d_in[30];
  const float* cW2  = (const float*)d_in[31]; const float* cb2  = (const float*)d_in[32];
  const float* peW1 = (const float*)d_in[33]; const float* peb1 = (const float*)d_in[34];
  const float* peW2 = (const float*)d_in[35]; const float* peb2 = (const float*)d_in[36];
  const float* pfW1 = (const float*)d_in[37]; const float* pfb1 = (const float*)d_in[38];
  const float* pfW2 = (const float*)d_in[39]; const float* pfb2 = (const float*)d_in[40];
  float* out = (float*)d_out;

  int N = in_sizes[0] / D;           // 50000
  int E = in_sizes[2];               // 800000
  int G = out_size / (2 + 2*H);      // 500
  int NH = N*H;

  float* p = (float*)d_ws;
  float* h    = p; p += (size_t)NH;
  float* tI   = p; p += (size_t)NH;   // also overlaid as bf16 hb before layer loop
  float* tC   = p; p += (size_t)NH;
  float* csr_cf = p; p += E;
  float* csr_w  = p; p += E;
  int* csr_sc = (int*)p; p += E;
  int* csr_d  = (int*)p; p += E;
  int* start  = (int*)p; p += (N+1);
  int* cnt    = (int*)p; p += N;      // cnt, wcnt, degI, degC contiguous -> one memset
  int* wcnt   = (int*)p; p += N;
  float* degI = p; p += N;
  float* degC = p; p += N;
  float* dinvI= p; p += N;
  float* dinvC= p; p += N;
  float* bnsum= p; p += H;            // bnsum+bnsq contiguous
  float* bnsq = p; p += H;
  float* sumE = p; p += (size_t)G*H;  // sumE..cntF contiguous
  float* sumF = p; p += (size_t)G*H;
  float* cntE = p; p += G;
  float* cntF = p; p += G;

  unsigned int* hb = (unsigned int*)tI;   // bf16 h, used only before layer loop

  int gemmBlocks = (N+63)/64;
  int nper_fin = (N + 511)/512;

  hipMemsetAsync(cnt, 0, (size_t)4*N*sizeof(int), stream);  // cnt,wcnt,degI,degC
  k_hist<<<(E+255)/256,256,0,stream>>>(ei, cnt, E);
  k_scan<<<1,1024,0,stream>>>(cnt, start, N);
  k_fill2<<<(E+255)/256,256,0,stream>>>(ei, em, ew, start, wcnt,
                                        csr_sc, csr_d, csr_w, E);
  k_proj<<<gemmBlocks,256,0,stream>>>(x, em, eegW,eegB, fnW,fnB, h, hb, N);
  k_edge<<<(E+255)/256,256,0,stream>>>(hb, csr_sc, csr_d, csr_w,
                                       eW1,eb1,eW2,eb2, csr_cf, degI,degC, E);
  k_dinv<<<(N+255)/256,256,0,stream>>>(degI,degC,dinvI,dinvC,N);
  k_scale<<<(E+255)/256,256,0,stream>>>(csr_sc, csr_d, dinvI, dinvC, csr_cf, E);

  for (int l=0;l<2;l++){
    k_gemm2<<<gemmBlocks,256,0,stream>>>(h, cIW + (size_t)l*H*H,
                                         cCW + (size_t)l*H*H, tI, tC, N);
    k_aggr<<<(N+3)/4,256,0,stream>>>(tI, tC, start, csr_sc, csr_cf,
                                     dinvI, dinvC, cIb+(size_t)l*H,
                                     cCb+(size_t)l*H, relg, l, h, N);
    hipMemsetAsync(bnsum, 0, 2*H*sizeof(float), stream);
    k_stats<<<512,128,0,stream>>>(h, bnsum, bnsq, N, nper_fin);
    k_bn<<<(NH+255)/256,256,0,stream>>>(h, bnsum, bnsq,
                                        bng+(size_t)l*H, bnb+(size_t)l*H,
                                        1.0f/(float)N, NH);
  }

  hipMemsetAsync(sumE, 0, ((size_t)2*G*H + 2*G)*sizeof(float), stream);
  k_pool<<<(N+511)/512,128,0,stream>>>(h, batch, em, sumE, sumF, cntE, cntF, N, 512);
  k_head<<<G,128,0,stream>>>(sumE,sumF,cntE,cntF,
                             coW1,cob1,coW2,cob2, gW1,gb1,gW2,gb2,
                             cW1,cb1,cW2,cb2, peW1,peb1,peW2,peb2,
                             pfW1,pfb1,pfW2,pfb2, out, G);
}

// Round 5
// 1000.212 us; speedup vs baseline: 2.3132x; 1.0453x over previous
//
#include <hip/hip_runtime.h>
#include <math.h>

#define H 128
#define D 256

typedef __attribute__((ext_vector_type(8))) short bf16x8;
typedef __attribute__((ext_vector_type(4))) float f32x4;

__device__ __forceinline__ float sigmoidf_(float x){ return 1.0f/(1.0f+__expf(-x)); }

// RNE float->bf16 (as uint in low 16 bits)
__device__ __forceinline__ unsigned int bfr_(float f){
  unsigned int u = __float_as_uint(f);
  return (u + 0x7fffu + ((u>>16)&1u)) >> 16;
}

// pack |a-b| of two bf16 pairs into one uint (2 bf16)
__device__ __forceinline__ unsigned pair_df(unsigned a, unsigned b){
  float a0 = __uint_as_float(a<<16), a1 = __uint_as_float(a & 0xffff0000u);
  float b0 = __uint_as_float(b<<16), b1 = __uint_as_float(b & 0xffff0000u);
  return bfr_(fabsf(a0-b0)) | (bfr_(fabsf(a1-b1))<<16);
}

// h = relu(x @ Wsel + bsel), per-node select; writes fp32 h and bf16 hb.
__global__ __launch_bounds__(256) void k_proj(
    const float* __restrict__ x, const int* __restrict__ em,
    const float* __restrict__ We, const float* __restrict__ be,
    const float* __restrict__ Wf, const float* __restrict__ bf,
    float* __restrict__ h, unsigned int* __restrict__ hb, int N)
{
  __shared__ float lds[128][65];
  int t = threadIdx.x;
  int lane = t & 63;
  int col0 = __builtin_amdgcn_readfirstlane((t >> 6) * 32);
  int n0 = blockIdx.x * 64;
  int node = n0 + lane;

  float accE[32], accF[32];
  #pragma unroll
  for (int o=0;o<32;o++){ accE[o]=be[col0+o]; accF[o]=bf[col0+o]; }

  for (int half=0; half<2; half++){
    if (half) __syncthreads();
    #pragma unroll
    for (int c=0;c<8;c++){
      int idx = (c*256 + t)*4;
      int n = idx >> 7, k = idx & 127;
      int nn = n0 + n;
      float4 v = (nn < N) ? *reinterpret_cast<const float4*>(x + (size_t)nn*D + half*128 + k)
                          : make_float4(0.f,0.f,0.f,0.f);
      lds[k+0][n]=v.x; lds[k+1][n]=v.y; lds[k+2][n]=v.z; lds[k+3][n]=v.w;
    }
    __syncthreads();
    const float* weB = We + (size_t)(half*128)*H + col0;
    const float* wfB = Wf + (size_t)(half*128)*H + col0;
    #pragma unroll 4
    for (int k=0;k<128;k++){
      float a = lds[k][lane];
      const float* we = weB + (size_t)k*H;
      const float* wf = wfB + (size_t)k*H;
      #pragma unroll
      for (int o=0;o<32;o++){
        accE[o] = fmaf(a, we[o], accE[o]);
        accF[o] = fmaf(a, wf[o], accF[o]);
      }
    }
  }
  if (node >= N) return;
  bool e = em[node] != 0;
  float sv[32];
  #pragma unroll
  for (int o=0;o<32;o++) sv[o] = fmaxf(e?accE[o]:accF[o], 0.f);
  float4* hr = reinterpret_cast<float4*>(h + (size_t)node*H + col0);
  #pragma unroll
  for (int o4=0;o4<8;o4++)
    hr[o4] = make_float4(sv[o4*4],sv[o4*4+1],sv[o4*4+2],sv[o4*4+3]);
  unsigned int* hbr = hb + (size_t)node*64 + (col0>>1);
  #pragma unroll
  for (int o2=0;o2<16;o2++)
    hbr[o2] = bfr_(sv[o2*2]) | (bfr_(sv[o2*2+1])<<16);
}

// two GEMMs sharing A: tI = A@WI, tC = A@WC. LDS-staged, K=128.
__global__ __launch_bounds__(256) void k_gemm2(
    const float* __restrict__ A, const float* __restrict__ WI,
    const float* __restrict__ WC,
    float* __restrict__ tI, float* __restrict__ tC, int N)
{
  __shared__ float lds[128][65];
  int t = threadIdx.x;
  int lane = t & 63;
  int col0 = __builtin_amdgcn_readfirstlane((t >> 6) * 32);
  int n0 = blockIdx.x * 64;
  int node = n0 + lane;

  #pragma unroll
  for (int c=0;c<8;c++){
    int idx = (c*256 + t)*4;
    int n = idx >> 7, k = idx & 127;
    int nn = n0 + n;
    float4 v = (nn < N) ? *reinterpret_cast<const float4*>(A + (size_t)nn*H + k)
                        : make_float4(0.f,0.f,0.f,0.f);
    lds[k+0][n]=v.x; lds[k+1][n]=v.y; lds[k+2][n]=v.z; lds[k+3][n]=v.w;
  }
  __syncthreads();

  float accI[32], accC[32];
  #pragma unroll
  for (int o=0;o<32;o++){ accI[o]=0.f; accC[o]=0.f; }
  const float* wiB = WI + col0;
  const float* wcB = WC + col0;
  #pragma unroll 4
  for (int k=0;k<128;k++){
    float a = lds[k][lane];
    const float* wi = wiB + (size_t)k*H;
    const float* wc = wcB + (size_t)k*H;
    #pragma unroll
    for (int o=0;o<32;o++){
      accI[o] = fmaf(a, wi[o], accI[o]);
      accC[o] = fmaf(a, wc[o], accC[o]);
    }
  }
  if (node >= N) return;
  float4* ci = reinterpret_cast<float4*>(tI + (size_t)node*H + col0);
  float4* cc = reinterpret_cast<float4*>(tC + (size_t)node*H + col0);
  #pragma unroll
  for (int o4=0;o4<8;o4++){
    ci[o4] = make_float4(accI[o4*4],accI[o4*4+1],accI[o4*4+2],accI[o4*4+3]);
    cc[o4] = make_float4(accC[o4*4],accC[o4*4+1],accC[o4*4+2],accC[o4*4+3]);
  }
}

// ---- CSR build ----
__global__ void k_hist(const int* __restrict__ ei, int* __restrict__ cnt, int E){
  int e = blockIdx.x*blockDim.x + threadIdx.x;
  if (e < E) atomicAdd(cnt + ei[E+e], 1);
}

__global__ __launch_bounds__(1024) void k_scan(const int* __restrict__ cnt,
                                               int* __restrict__ start, int N){
  __shared__ int sm[1024];
  int t = threadIdx.x;
  int chunk = (N + 1023)/1024;
  int i0 = t*chunk, i1 = min(i0+chunk, N);
  int s = 0;
  for (int i=i0;i<i1;i++) s += cnt[i];
  sm[t] = s; __syncthreads();
  for (int d=1; d<1024; d<<=1){
    int v = (t>=d)? sm[t-d] : 0;
    __syncthreads();
    sm[t] += v;
    __syncthreads();
  }
  int base = (t==0)? 0 : sm[t-1];
  for (int i=i0;i<i1;i++){ start[i] = base; base += cnt[i]; }
  if (t == 1023) start[N] = base;
}

__global__ void k_fill2(const int* __restrict__ ei, const int* __restrict__ em,
                        const float* __restrict__ ew,
                        const int* __restrict__ start, int* __restrict__ wcnt,
                        int* __restrict__ csr_sc, int* __restrict__ csr_d,
                        float* __restrict__ csr_w, int E){
  int e = blockIdx.x*blockDim.x + threadIdx.x;
  if (e >= E) return;
  int s = ei[e], d = ei[E+e];
  int chan = (em[s] == em[d]) ? 0 : 1;
  int pos = start[d] + atomicAdd(wcnt + d, 1);
  csr_sc[pos] = (s<<1) | chan;
  csr_d[pos] = d;
  csr_w[pos] = ew[e];
}

// W1 (129x64 fp32) -> bf16 B-fragments for 16x16x32 MFMA.
// fragment f = kstep*4 + n; entry (f,lane) holds B[k=kstep*32+(lane>>4)*8+j][col=n*16+(lane&15)]
__global__ void k_prepw(const float* __restrict__ W1, unsigned short* __restrict__ W1b){
  int t = threadIdx.x;
  for (int it=0; it<4; it++){
    int le = it*256 + t;
    int f = le >> 6, lane = le & 63;
    int kstep = f >> 2, n = f & 3;
    int col = n*16 + (lane & 15);
    int k0 = kstep*32 + ((lane>>4)&3)*8;
    unsigned short* op = W1b + (size_t)le*8;
    #pragma unroll
    for (int j=0;j<8;j++)
      op[j] = (unsigned short)bfr_(W1[(size_t)(k0+j)*64 + col]);
  }
}

// per-edge MLP gate via MFMA. wave = 16 edges; K=128, N=64.
__global__ __launch_bounds__(256) void k_edgem(
    const unsigned int* __restrict__ hb,
    const int* __restrict__ csr_sc, const int* __restrict__ csr_d,
    const float* __restrict__ csr_w, const unsigned short* __restrict__ W1b,
    const float* __restrict__ W1, const float* __restrict__ b1,
    const float* __restrict__ W2, const float* __restrict__ b2,
    float* __restrict__ csr_cf,
    float* __restrict__ degI, float* __restrict__ degC, int E)
{
  int t = threadIdx.x;
  int lane = t & 63;
  int base = (blockIdx.x*4 + (t>>6)) * 16;
  if (base >= E) return;

  // B fragments: all of W1 in bf16 (64 VGPR)
  bf16x8 bfrag[16];
  const bf16x8* wb = reinterpret_cast<const bf16x8*>(W1b);
  #pragma unroll
  for (int f=0; f<16; f++) bfrag[f] = wb[f*64 + lane];

  int e = min(base + (lane & 15), E-1);
  int s = csr_sc[e] >> 1;
  int d = csr_d[e];
  const uint4* hsp = reinterpret_cast<const uint4*>(hb + (size_t)s*64);
  const uint4* hdp = reinterpret_cast<const uint4*>(hb + (size_t)d*64);
  int ko = lane >> 4;            // 0..3: k-slice within kstep

  f32x4 acc[4];
  #pragma unroll
  for (int n=0;n<4;n++) acc[n] = (f32x4){0.f,0.f,0.f,0.f};

  #pragma unroll
  for (int kstep=0;kstep<4;kstep++){
    uint4 us = hsp[kstep*4 + ko];
    uint4 ud = hdp[kstep*4 + ko];
    uint4 pa;
    pa.x = pair_df(us.x, ud.x);
    pa.y = pair_df(us.y, ud.y);
    pa.z = pair_df(us.z, ud.z);
    pa.w = pair_df(us.w, ud.w);
    bf16x8 a = *reinterpret_cast<bf16x8*>(&pa);
    #pragma unroll
    for (int n=0;n<4;n++)
      acc[n] = __builtin_amdgcn_mfma_f32_16x16x32_bf16(a, bfrag[kstep*4+n], acc[n], 0,0,0);
  }

  // epilogue: per-col params
  int colbase = lane & 15;
  float w1l[4], b1v[4], w2v[4];
  #pragma unroll
  for (int n=0;n<4;n++){
    int col = n*16 + colbase;
    w1l[n] = W1[(size_t)128*64 + col];
    b1v[n] = b1[col];
    w2v[n] = W2[col];
  }
  float wgtr[4];
  #pragma unroll
  for (int r=0;r<4;r++)
    wgtr[r] = csr_w[min(base + (lane>>4)*4 + r, E-1)];

  float part[4] = {0.f,0.f,0.f,0.f};
  #pragma unroll
  for (int n=0;n<4;n++){
    #pragma unroll
    for (int r=0;r<4;r++){
      float v = fmaxf(acc[n][r] + fmaf(wgtr[r], w1l[n], b1v[n]), 0.f);
      part[r] = fmaf(v, w2v[n], part[r]);
    }
  }
  #pragma unroll
  for (int m=1;m<16;m<<=1){
    #pragma unroll
    for (int r=0;r<4;r++) part[r] += __shfl_xor(part[r], m, 64);
  }

  if ((lane & 15) == 0){
    float bb2 = b2[0];
    #pragma unroll
    for (int r=0;r<4;r++){
      int ee = base + (lane>>4)*4 + r;
      if (ee < E){
        float g = sigmoidf_(part[r] + bb2);
        g = fminf(fmaxf(g, 0.2f), 1.2f);
        float ehat = wgtr[r] * g;
        csr_cf[ee] = ehat;
        int sc2 = csr_sc[ee];
        atomicAdd(((sc2&1) ? degC : degI) + csr_d[ee], ehat);
      }
    }
  }
}

__global__ void k_dinv(const float* __restrict__ degI, const float* __restrict__ degC,
                       float* dinvI, float* dinvC, int N){
  int i = blockIdx.x*blockDim.x + threadIdx.x;
  if (i < N){
    dinvI[i] = rsqrtf(1.f + degI[i]);
    dinvC[i] = rsqrtf(1.f + degC[i]);
  }
}

__global__ void k_scale(const int* __restrict__ csr_sc, const int* __restrict__ csr_d,
                        const float* __restrict__ dinvI, const float* __restrict__ dinvC,
                        float* __restrict__ csr_cf, int E){
  int k = blockIdx.x*blockDim.x + threadIdx.x;
  if (k >= E) return;
  int sc = csr_sc[k];
  int s = sc>>1;
  int d = csr_d[k];
  const float* dv = (sc&1) ? dinvC : dinvI;
  csr_cf[k] *= dv[s]*dv[d];
}

// one wave per dst node: gather CSR edges + fused self-loop/bias epilogue.
__global__ __launch_bounds__(256) void k_aggr(
    const float* __restrict__ tI, const float* __restrict__ tC,
    const int* __restrict__ start, const int* __restrict__ csr_sc,
    const float* __restrict__ csr_cf,
    const float* __restrict__ dinvI, const float* __restrict__ dinvC,
    const float* __restrict__ bI, const float* __restrict__ bC,
    const float* __restrict__ relg, int l,
    float* __restrict__ h, int N)
{
  int lane = threadIdx.x & 63;
  int d = blockIdx.x*4 + (threadIdx.x>>6);
  if (d >= N) return;
  float sig = sigmoidf_(relg[l]);
  int k0 = start[d], k1 = start[d+1];
  int off = lane*2;
  float ax=0.f, ay=0.f;
  for (int k=k0;k<k1;k++){
    int sc = csr_sc[k];
    float cf = csr_cf[k];
    int src = sc>>1;
    const float* t = (sc&1) ? tC : tI;
    float ce = (sc&1) ? sig*cf : cf;
    float2 v = *reinterpret_cast<const float2*>(t + (size_t)src*H + off);
    ax = fmaf(ce, v.x, ax);
    ay = fmaf(ce, v.y, ay);
  }
  float diI = dinvI[d], diC = dinvC[d];
  float rI = diI*diI, rC = diC*diC;
  float2 ti = *reinterpret_cast<const float2*>(tI + (size_t)d*H + off);
  float2 tc = *reinterpret_cast<const float2*>(tC + (size_t)d*H + off);
  float2 o;
  o.x = fmaf(ti.x, rI, bI[off])   + sig*fmaf(tc.x, rC, bC[off])   + ax;
  o.y = fmaf(ti.y, rI, bI[off+1]) + sig*fmaf(tc.y, rC, bC[off+1]) + ay;
  *reinterpret_cast<float2*>(h + (size_t)d*H + off) = o;
}

__global__ __launch_bounds__(128) void k_stats(const float* __restrict__ h,
    float* __restrict__ bnsum, float* __restrict__ bnsq, int N, int nper)
{
  int j = threadIdx.x;
  int n0 = blockIdx.x*nper, n1 = min(n0+nper, N);
  float sl=0.f, sq=0.f;
  for (int n=n0;n<n1;n++){
    float v = h[(size_t)n*H+j];
    sl += v; sq = fmaf(v,v,sq);
  }
  atomicAdd(bnsum+j, sl); atomicAdd(bnsq+j, sq);
}

__global__ void k_bn(float* __restrict__ h, const float* __restrict__ bnsum,
                     const float* __restrict__ bnsq,
                     const float* __restrict__ gamma, const float* __restrict__ beta,
                     float invN, int NH)
{
  int i = blockIdx.x*blockDim.x + threadIdx.x;
  if (i >= NH) return;
  int j = i & (H-1);
  float mu = bnsum[j]*invN;
  float var = bnsq[j]*invN - mu*mu;
  float r = rsqrtf(var + 1e-5f);
  h[i] = fmaxf(fmaf(gamma[j], (h[i]-mu)*r, beta[j]), 0.f);
}

// pool with BN+relu applied on the fly (layer-2 fusion)
__global__ __launch_bounds__(128) void k_poolbn(
    const float* __restrict__ h, const int* __restrict__ batch, const int* __restrict__ em,
    const float* __restrict__ bnsum, const float* __restrict__ bnsq,
    const float* __restrict__ gamma, const float* __restrict__ beta, float invN,
    float* __restrict__ sumE, float* __restrict__ sumF,
    float* __restrict__ cntE, float* __restrict__ cntF, int N, int nper)
{
  int j = threadIdx.x;
  int n0 = blockIdx.x*nper, n1 = min(n0+nper, N);
  if (n0 >= N) return;
  float mu = bnsum[j]*invN;
  float var = bnsq[j]*invN - mu*mu;
  float rr = rsqrtf(var + 1e-5f);
  float ga = gamma[j], be = beta[j];
  float aE=0.f, aF=0.f, ce=0.f, cfc=0.f;
  int cg = batch[n0];
  for (int n=n0;n<n1;n++){
    int g = batch[n];
    if (g != cg){
      atomicAdd(sumE+(size_t)cg*H+j, aE);
      atomicAdd(sumF+(size_t)cg*H+j, aF);
      if (j==0){ atomicAdd(cntE+cg, ce); atomicAdd(cntF+cg, cfc); }
      aE=aF=ce=cfc=0.f; cg=g;
    }
    float v = fmaxf(fmaf(ga, (h[(size_t)n*H+j]-mu)*rr, be), 0.f);
    bool eb = em[n] != 0;
    if (eb) aE += v; else aF += v;
    if (j==0){ if (eb) ce += 1.f; else cfc += 1.f; }
  }
  atomicAdd(sumE+(size_t)cg*H+j, aE);
  atomicAdd(sumF+(size_t)cg*H+j, aF);
  if (j==0){ atomicAdd(cntE+cg, ce); atomicAdd(cntF+cg, cfc); }
}

__device__ __forceinline__ float blockReduceSum(float v, float* red){
  int t = threadIdx.x;
  red[t] = v; __syncthreads();
  #pragma unroll
  for (int s=64;s>0;s>>=1){ if (t<s) red[t]+=red[t+s]; __syncthreads(); }
  float r = red[0]; __syncthreads();
  return r;
}

__global__ __launch_bounds__(128) void k_head(
    const float* __restrict__ sumE, const float* __restrict__ sumF,
    const float* __restrict__ cntE, const float* __restrict__ cntF,
    const float* __restrict__ coW1, const float* __restrict__ cob1,
    const float* __restrict__ coW2, const float* __restrict__ cob2,
    const float* __restrict__ gW1, const float* __restrict__ gb1,
    const float* __restrict__ gW2, const float* __restrict__ gb2,
    const float* __restrict__ cW1, const float* __restrict__ cb1,
    const float* __restrict__ cW2, const float* __restrict__ cb2,
    const float* __restrict__ peW1, const float* __restrict__ peb1,
    const float* __restrict__ peW2, const float* __restrict__ peb2,
    const float* __restrict__ pfW1, const float* __restrict__ pfb1,
    const float* __restrict__ pfW2, const float* __restrict__ pfb2,
    float* __restrict__ out, int G)
{
  int g = blockIdx.x, j = threadIdx.x;
  __shared__ float sh[384];
  __shared__ float red[128];
  __shared__ float hfin[128], buf[128];
  float cE = cntE[g], cF = cntF[g];
  float se = sumE[(size_t)g*H+j], sf = sumF[(size_t)g*H+j];
  float he = se/fmaxf(cE,1.f), hf = sf/fmaxf(cF,1.f);
  float hg = (se+sf)/fmaxf(cE+cF,1.f);
  sh[j]=he; sh[128+j]=hf; sh[256+j]=he*hf;
  __syncthreads();
  float a = cob1[j];
  for (int k=0;k<384;k++) a = fmaf(sh[k], coW1[k*H+j], a);
  a = fmaxf(a, 0.f);
  float r0 = blockReduceSum(a*coW2[2*j],   red);
  float r1 = blockReduceSum(a*coW2[2*j+1], red);
  float al0 = sigmoidf_(r0 + cob2[0]);
  float al1 = sigmoidf_(r1 + cob2[1]);
  float asum = al0+al1+1e-6f; al0/=asum; al1/=asum;
  float hc = al0*he + al1*hf;
  __syncthreads();
  sh[j]=hc; sh[128+j]=hg;
  __syncthreads();
  float gg = gb1[j];
  for (int k=0;k<256;k++) gg = fmaf(sh[k], gW1[k*H+j], gg);
  gg = fmaxf(gg, 0.f);
  float gt = sigmoidf_(blockReduceSum(gg*gW2[j], red) + gb2[0]);
  float hfj = gt*hc + (1.f-gt)*hg;
  hfin[j] = hfj;
  __syncthreads();
  float c1v = 0.f;
  if (j < 64){
    float c1 = cb1[j];
    for (int k=0;k<128;k++) c1 = fmaf(hfin[k], cW1[k*64+j], c1);
    c1v = fmaxf(c1, 0.f);
  }
  float l0 = blockReduceSum(j<64 ? c1v*cW2[2*j]   : 0.f, red);
  float l1 = blockReduceSum(j<64 ? c1v*cW2[2*j+1] : 0.f, red);
  if (j==0){ out[(size_t)g*2] = l0 + cb2[0]; out[(size_t)g*2+1] = l1 + cb2[1]; }
  // z_e
  buf[j] = he; __syncthreads();
  float q = peb1[j];
  for (int k=0;k<128;k++) q = fmaf(buf[k], peW1[k*H+j], q);
  q = fmaxf(q, 0.f);
  __syncthreads(); sh[j] = q; __syncthreads();
  float z = peb2[j];
  for (int k=0;k<128;k++) z = fmaf(sh[k], peW2[k*H+j], z);
  float nr = sqrtf(blockReduceSum(z*z, red));
  out[(size_t)G*2 + (size_t)g*H + j] = z / fmaxf(nr, 1e-12f);
  // z_f
  __syncthreads(); buf[j] = hf; __syncthreads();
  float q2 = pfb1[j];
  for (int k=0;k<128;k++) q2 = fmaf(buf[k], pfW1[k*H+j], q2);
  q2 = fmaxf(q2, 0.f);
  __syncthreads(); sh[j] = q2; __syncthreads();
  float z2 = pfb2[j];
  for (int k=0;k<128;k++) z2 = fmaf(sh[k], pfW2[k*H+j], z2);
  float nr2 = sqrtf(blockReduceSum(z2*z2, red));
  out[(size_t)G*2 + (size_t)G*H + (size_t)g*H + j] = z2 / fmaxf(nr2, 1e-12f);
}

extern "C" void kernel_launch(void* const* d_in, const int* in_sizes, int n_in,
                              void* d_out, int out_size, void* d_ws, size_t ws_size,
                              hipStream_t stream)
{
  const float* x    = (const float*)d_in[0];
  const int*   ei   = (const int*)d_in[1];
  const float* ew   = (const float*)d_in[2];
  const int*   batch= (const int*)d_in[3];
  const int*   em   = (const int*)d_in[4];
  const float* eegW = (const float*)d_in[6];  const float* eegB = (const float*)d_in[7];
  const float* fnW  = (const float*)d_in[8];  const float* fnB  = (const float*)d_in[9];
  const float* eW1  = (const float*)d_in[10]; const float* eb1  = (const float*)d_in[11];
  const float* eW2  = (const float*)d_in[12]; const float* eb2  = (const float*)d_in[13];
  const float* cIW  = (const float*)d_in[14]; const float* cIb  = (const float*)d_in[15];
  const float* cCW  = (const float*)d_in[16]; const float* cCb  = (const float*)d_in[17];
  const float* relg = (const float*)d_in[18];
  const float* bng  = (const float*)d_in[19]; const float* bnb  = (const float*)d_in[20];
  const float* coW1 = (const float*)d_in[21]; const float* cob1 = (const float*)d_in[22];
  const float* coW2 = (const float*)d_in[23]; const float* cob2 = (const float*)d_in[24];
  const float* gW1  = (const float*)d_in[25]; const float* gb1  = (const float*)d_in[26];
  const float* gW2  = (const float*)d_in[27]; const float* gb2  = (const float*)d_in[28];
  const float* cW1  = (const float*)d_in[29]; const float* cb1  = (const float*)d_in[30];
  const float* cW2  = (const float*)d_in[31]; const float* cb2  = (const float*)d_in[32];
  const float* peW1 = (const float*)d_in[33]; const float* peb1 = (const float*)d_in[34];
  const float* peW2 = (const float*)d_in[35]; const float* peb2 = (const float*)d_in[36];
  const float* pfW1 = (const float*)d_in[37]; const float* pfb1 = (const float*)d_in[38];
  const float* pfW2 = (const float*)d_in[39]; const float* pfb2 = (const float*)d_in[40];
  float* out = (float*)d_out;

  int N = in_sizes[0] / D;           // 50000
  int E = in_sizes[2];               // 800000
  int G = out_size / (2 + 2*H);      // 500
  int NH = N*H;

  float* p = (float*)d_ws;
  float* h    = p; p += (size_t)NH;
  float* tI   = p; p += (size_t)NH;   // overlaid as bf16 hb before layer loop
  float* tC   = p; p += (size_t)NH;
  float* csr_cf = p; p += E;
  float* csr_w  = p; p += E;
  int* csr_sc = (int*)p; p += E;
  int* csr_d  = (int*)p; p += E;
  int* start  = (int*)p; p += (N+1);
  int* cnt    = (int*)p; p += N;      // cnt, wcnt, degI, degC contiguous -> one memset
  int* wcnt   = (int*)p; p += N;
  float* degI = p; p += N;
  float* degC = p; p += N;
  float* dinvI= p; p += N;
  float* dinvC= p; p += N;
  float* bnsum= p; p += H;            // bnsum+bnsq contiguous
  float* bnsq = p; p += H;
  float* sumE = p; p += (size_t)G*H;  // sumE..cntF contiguous
  float* sumF = p; p += (size_t)G*H;
  float* cntE = p; p += G;
  float* cntF = p; p += G;
  unsigned short* W1b = (unsigned short*)p; p += 4096;  // 8192 bf16 = 16 KB

  unsigned int* hb = (unsigned int*)tI;   // bf16 h, used only before layer loop

  int gemmBlocks = (N+63)/64;
  int nper_fin = (N + 511)/512;

  hipMemsetAsync(cnt, 0, (size_t)4*N*sizeof(int), stream);  // cnt,wcnt,degI,degC
  k_hist<<<(E+255)/256,256,0,stream>>>(ei, cnt, E);
  k_scan<<<1,1024,0,stream>>>(cnt, start, N);
  k_fill2<<<(E+255)/256,256,0,stream>>>(ei, em, ew, start, wcnt,
                                        csr_sc, csr_d, csr_w, E);
  k_prepw<<<1,256,0,stream>>>(eW1, W1b);
  k_proj<<<gemmBlocks,256,0,stream>>>(x, em, eegW,eegB, fnW,fnB, h, hb, N);
  k_edgem<<<(E+63)/64,256,0,stream>>>(hb, csr_sc, csr_d, csr_w, W1b,
                                      eW1, eb1, eW2, eb2, csr_cf, degI, degC, E);
  k_dinv<<<(N+255)/256,256,0,stream>>>(degI,degC,dinvI,dinvC,N);
  k_scale<<<(E+255)/256,256,0,stream>>>(csr_sc, csr_d, dinvI, dinvC, csr_cf, E);

  for (int l=0;l<2;l++){
    k_gemm2<<<gemmBlocks,256,0,stream>>>(h, cIW + (size_t)l*H*H,
                                         cCW + (size_t)l*H*H, tI, tC, N);
    k_aggr<<<(N+3)/4,256,0,stream>>>(tI, tC, start, csr_sc, csr_cf,
                                     dinvI, dinvC, cIb+(size_t)l*H,
                                     cCb+(size_t)l*H, relg, l, h, N);
    hipMemsetAsync(bnsum, 0, 2*H*sizeof(float), stream);
    k_stats<<<512,128,0,stream>>>(h, bnsum, bnsq, N, nper_fin);
    if (l == 0){
      k_bn<<<(NH+255)/256,256,0,stream>>>(h, bnsum, bnsq,
                                          bng, bnb, 1.0f/(float)N, NH);
    }
  }

  hipMemsetAsync(sumE, 0, ((size_t)2*G*H + 2*G)*sizeof(float), stream);
  k_poolbn<<<(N+511)/512,128,0,stream>>>(h, batch, em, bnsum, bnsq,
                                         bng+(size_t)H, bnb+(size_t)H, 1.0f/(float)N,
                                         sumE, sumF, cntE, cntF, N, 512);
  k_head<<<G,128,0,stream>>>(sumE,sumF,cntE,cntF,
                             coW1,cob1,coW2,cob2, gW1,gb1,gW2,gb2,
                             cW1,cb1,cW2,cb2, peW1,peb1,peW2,peb2,
                             pfW1,pfb1,pfW2,pfb2, out, G);
}

// Round 6
// 874.242 us; speedup vs baseline: 2.6465x; 1.1441x over previous
//
#include <hip/hip_runtime.h>
#include <math.h>

#define H 128
#define D 256

typedef __attribute__((ext_vector_type(8))) short bf16x8;
typedef __attribute__((ext_vector_type(4))) float f32x4;

__device__ __forceinline__ float sigmoidf_(float x){ return 1.0f/(1.0f+__expf(-x)); }

// RNE float->bf16 (as uint in low 16 bits)
__device__ __forceinline__ unsigned int bfr_(float f){
  unsigned int u = __float_as_uint(f);
  return (u + 0x7fffu + ((u>>16)&1u)) >> 16;
}

// pack |a-b| of two bf16 pairs into one uint (2 bf16)
__device__ __forceinline__ unsigned pair_df(unsigned a, unsigned b){
  float a0 = __uint_as_float(a<<16), a1 = __uint_as_float(a & 0xffff0000u);
  float b0 = __uint_as_float(b<<16), b1 = __uint_as_float(b & 0xffff0000u);
  return bfr_(fabsf(a0-b0)) | (bfr_(fabsf(a1-b1))<<16);
}

// h = relu(x @ Wsel + bsel), per-node select; writes fp32 h and bf16 hb.
__global__ __launch_bounds__(256) void k_proj(
    const float* __restrict__ x, const int* __restrict__ em,
    const float* __restrict__ We, const float* __restrict__ be,
    const float* __restrict__ Wf, const float* __restrict__ bf,
    float* __restrict__ h, unsigned int* __restrict__ hb, int N)
{
  __shared__ float lds[128][65];
  int t = threadIdx.x;
  int lane = t & 63;
  int col0 = __builtin_amdgcn_readfirstlane((t >> 6) * 32);
  int n0 = blockIdx.x * 64;
  int node = n0 + lane;

  float accE[32], accF[32];
  #pragma unroll
  for (int o=0;o<32;o++){ accE[o]=be[col0+o]; accF[o]=bf[col0+o]; }

  for (int half=0; half<2; half++){
    if (half) __syncthreads();
    #pragma unroll
    for (int c=0;c<8;c++){
      int idx = (c*256 + t)*4;
      int n = idx >> 7, k = idx & 127;
      int nn = n0 + n;
      float4 v = (nn < N) ? *reinterpret_cast<const float4*>(x + (size_t)nn*D + half*128 + k)
                          : make_float4(0.f,0.f,0.f,0.f);
      lds[k+0][n]=v.x; lds[k+1][n]=v.y; lds[k+2][n]=v.z; lds[k+3][n]=v.w;
    }
    __syncthreads();
    const float* weB = We + (size_t)(half*128)*H + col0;
    const float* wfB = Wf + (size_t)(half*128)*H + col0;
    #pragma unroll 4
    for (int k=0;k<128;k++){
      float a = lds[k][lane];
      const float* we = weB + (size_t)k*H;
      const float* wf = wfB + (size_t)k*H;
      #pragma unroll
      for (int o=0;o<32;o++){
        accE[o] = fmaf(a, we[o], accE[o]);
        accF[o] = fmaf(a, wf[o], accF[o]);
      }
    }
  }
  if (node >= N) return;
  bool e = em[node] != 0;
  float sv[32];
  #pragma unroll
  for (int o=0;o<32;o++) sv[o] = fmaxf(e?accE[o]:accF[o], 0.f);
  float4* hr = reinterpret_cast<float4*>(h + (size_t)node*H + col0);
  #pragma unroll
  for (int o4=0;o4<8;o4++)
    hr[o4] = make_float4(sv[o4*4],sv[o4*4+1],sv[o4*4+2],sv[o4*4+3]);
  unsigned int* hbr = hb + (size_t)node*64 + (col0>>1);
  #pragma unroll
  for (int o2=0;o2<16;o2++)
    hbr[o2] = bfr_(sv[o2*2]) | (bfr_(sv[o2*2+1])<<16);
}

// two GEMMs sharing A: tI = A@WI, tC = A@WC. LDS-staged, K=128.
__global__ __launch_bounds__(256) void k_gemm2(
    const float* __restrict__ A, const float* __restrict__ WI,
    const float* __restrict__ WC,
    float* __restrict__ tI, float* __restrict__ tC, int N)
{
  __shared__ float lds[128][65];
  int t = threadIdx.x;
  int lane = t & 63;
  int col0 = __builtin_amdgcn_readfirstlane((t >> 6) * 32);
  int n0 = blockIdx.x * 64;
  int node = n0 + lane;

  #pragma unroll
  for (int c=0;c<8;c++){
    int idx = (c*256 + t)*4;
    int n = idx >> 7, k = idx & 127;
    int nn = n0 + n;
    float4 v = (nn < N) ? *reinterpret_cast<const float4*>(A + (size_t)nn*H + k)
                        : make_float4(0.f,0.f,0.f,0.f);
    lds[k+0][n]=v.x; lds[k+1][n]=v.y; lds[k+2][n]=v.z; lds[k+3][n]=v.w;
  }
  __syncthreads();

  float accI[32], accC[32];
  #pragma unroll
  for (int o=0;o<32;o++){ accI[o]=0.f; accC[o]=0.f; }
  const float* wiB = WI + col0;
  const float* wcB = WC + col0;
  #pragma unroll 4
  for (int k=0;k<128;k++){
    float a = lds[k][lane];
    const float* wi = wiB + (size_t)k*H;
    const float* wc = wcB + (size_t)k*H;
    #pragma unroll
    for (int o=0;o<32;o++){
      accI[o] = fmaf(a, wi[o], accI[o]);
      accC[o] = fmaf(a, wc[o], accC[o]);
    }
  }
  if (node >= N) return;
  float4* ci = reinterpret_cast<float4*>(tI + (size_t)node*H + col0);
  float4* cc = reinterpret_cast<float4*>(tC + (size_t)node*H + col0);
  #pragma unroll
  for (int o4=0;o4<8;o4++){
    ci[o4] = make_float4(accI[o4*4],accI[o4*4+1],accI[o4*4+2],accI[o4*4+3]);
    cc[o4] = make_float4(accC[o4*4],accC[o4*4+1],accC[o4*4+2],accC[o4*4+3]);
  }
}

// ---- CSR build ----
__global__ void k_hist(const int* __restrict__ ei, int* __restrict__ cnt, int E){
  int e = blockIdx.x*blockDim.x + threadIdx.x;
  if (e < E) atomicAdd(cnt + ei[E+e], 1);
}

__global__ __launch_bounds__(1024) void k_scan(const int* __restrict__ cnt,
                                               int* __restrict__ start, int N){
  __shared__ int sm[1024];
  int t = threadIdx.x;
  int chunk = (N + 1023)/1024;
  int i0 = t*chunk, i1 = min(i0+chunk, N);
  int s = 0;
  for (int i=i0;i<i1;i++) s += cnt[i];
  sm[t] = s; __syncthreads();
  for (int d=1; d<1024; d<<=1){
    int v = (t>=d)? sm[t-d] : 0;
    __syncthreads();
    sm[t] += v;
    __syncthreads();
  }
  int base = (t==0)? 0 : sm[t-1];
  for (int i=i0;i<i1;i++){ start[i] = base; base += cnt[i]; }
  if (t == 1023) start[N] = base;
}

__global__ void k_fill2(const int* __restrict__ ei, const int* __restrict__ em,
                        const float* __restrict__ ew,
                        const int* __restrict__ start, int* __restrict__ wcnt,
                        int* __restrict__ csr_sc, int* __restrict__ csr_d,
                        float* __restrict__ csr_w, int E){
  int e = blockIdx.x*blockDim.x + threadIdx.x;
  if (e >= E) return;
  int s = ei[e], d = ei[E+e];
  int chan = (em[s] == em[d]) ? 0 : 1;
  int pos = start[d] + atomicAdd(wcnt + d, 1);
  csr_sc[pos] = (s<<1) | chan;
  csr_d[pos] = d;
  csr_w[pos] = ew[e];
}

// W1 (129x64 fp32) -> bf16 B-fragments for 16x16x32 MFMA.
__global__ void k_prepw(const float* __restrict__ W1, unsigned short* __restrict__ W1b){
  int t = threadIdx.x;
  for (int it=0; it<4; it++){
    int le = it*256 + t;
    int f = le >> 6, lane = le & 63;
    int kstep = f >> 2, n = f & 3;
    int col = n*16 + (lane & 15);
    int k0 = kstep*32 + ((lane>>4)&3)*8;
    unsigned short* op = W1b + (size_t)le*8;
    #pragma unroll
    for (int j=0;j<8;j++)
      op[j] = (unsigned short)bfr_(W1[(size_t)(k0+j)*64 + col]);
  }
}

// per-edge MLP gate via MFMA. wave = 16 edges; K=128, N=64.
__global__ __launch_bounds__(256) void k_edgem(
    const unsigned int* __restrict__ hb,
    const int* __restrict__ csr_sc, const int* __restrict__ csr_d,
    const float* __restrict__ csr_w, const unsigned short* __restrict__ W1b,
    const float* __restrict__ W1, const float* __restrict__ b1,
    const float* __restrict__ W2, const float* __restrict__ b2,
    float* __restrict__ csr_cf,
    float* __restrict__ degI, float* __restrict__ degC, int E)
{
  int t = threadIdx.x;
  int lane = t & 63;
  int base = (blockIdx.x*4 + (t>>6)) * 16;
  if (base >= E) return;

  bf16x8 bfrag[16];
  const bf16x8* wb = reinterpret_cast<const bf16x8*>(W1b);
  #pragma unroll
  for (int f=0; f<16; f++) bfrag[f] = wb[f*64 + lane];

  int e = min(base + (lane & 15), E-1);
  int s = csr_sc[e] >> 1;
  int d = csr_d[e];
  const uint4* hsp = reinterpret_cast<const uint4*>(hb + (size_t)s*64);
  const uint4* hdp = reinterpret_cast<const uint4*>(hb + (size_t)d*64);
  int ko = lane >> 4;

  f32x4 acc[4];
  #pragma unroll
  for (int n=0;n<4;n++) acc[n] = (f32x4){0.f,0.f,0.f,0.f};

  #pragma unroll
  for (int kstep=0;kstep<4;kstep++){
    uint4 us = hsp[kstep*4 + ko];
    uint4 ud = hdp[kstep*4 + ko];
    uint4 pa;
    pa.x = pair_df(us.x, ud.x);
    pa.y = pair_df(us.y, ud.y);
    pa.z = pair_df(us.z, ud.z);
    pa.w = pair_df(us.w, ud.w);
    bf16x8 a = *reinterpret_cast<bf16x8*>(&pa);
    #pragma unroll
    for (int n=0;n<4;n++)
      acc[n] = __builtin_amdgcn_mfma_f32_16x16x32_bf16(a, bfrag[kstep*4+n], acc[n], 0,0,0);
  }

  int colbase = lane & 15;
  float w1l[4], b1v[4], w2v[4];
  #pragma unroll
  for (int n=0;n<4;n++){
    int col = n*16 + colbase;
    w1l[n] = W1[(size_t)128*64 + col];
    b1v[n] = b1[col];
    w2v[n] = W2[col];
  }
  float wgtr[4];
  #pragma unroll
  for (int r=0;r<4;r++)
    wgtr[r] = csr_w[min(base + (lane>>4)*4 + r, E-1)];

  float part[4] = {0.f,0.f,0.f,0.f};
  #pragma unroll
  for (int n=0;n<4;n++){
    #pragma unroll
    for (int r=0;r<4;r++){
      float v = fmaxf(acc[n][r] + fmaf(wgtr[r], w1l[n], b1v[n]), 0.f);
      part[r] = fmaf(v, w2v[n], part[r]);
    }
  }
  #pragma unroll
  for (int m=1;m<16;m<<=1){
    #pragma unroll
    for (int r=0;r<4;r++) part[r] += __shfl_xor(part[r], m, 64);
  }

  if ((lane & 15) == 0){
    float bb2 = b2[0];
    #pragma unroll
    for (int r=0;r<4;r++){
      int ee = base + (lane>>4)*4 + r;
      if (ee < E){
        float g = sigmoidf_(part[r] + bb2);
        g = fminf(fmaxf(g, 0.2f), 1.2f);
        float ehat = wgtr[r] * g;
        csr_cf[ee] = ehat;
        int sc2 = csr_sc[ee];
        atomicAdd(((sc2&1) ? degC : degI) + csr_d[ee], ehat);
      }
    }
  }
}

__global__ void k_dinv(const float* __restrict__ degI, const float* __restrict__ degC,
                       float* dinvI, float* dinvC, int N){
  int i = blockIdx.x*blockDim.x + threadIdx.x;
  if (i < N){
    dinvI[i] = rsqrtf(1.f + degI[i]);
    dinvC[i] = rsqrtf(1.f + degC[i]);
  }
}

__global__ void k_scale(const int* __restrict__ csr_sc, const int* __restrict__ csr_d,
                        const float* __restrict__ dinvI, const float* __restrict__ dinvC,
                        float* __restrict__ csr_cf, int E){
  int k = blockIdx.x*blockDim.x + threadIdx.x;
  if (k >= E) return;
  int sc = csr_sc[k];
  int s = sc>>1;
  int d = csr_d[k];
  const float* dv = (sc&1) ? dinvC : dinvI;
  csr_cf[k] *= dv[s]*dv[d];
}

// one wave per dst node: gather CSR edges + fused self-loop/bias epilogue.
__global__ __launch_bounds__(256) void k_aggr(
    const float* __restrict__ tI, const float* __restrict__ tC,
    const int* __restrict__ start, const int* __restrict__ csr_sc,
    const float* __restrict__ csr_cf,
    const float* __restrict__ dinvI, const float* __restrict__ dinvC,
    const float* __restrict__ bI, const float* __restrict__ bC,
    const float* __restrict__ relg, int l,
    float* __restrict__ h, int N)
{
  int lane = threadIdx.x & 63;
  int d = blockIdx.x*4 + (threadIdx.x>>6);
  if (d >= N) return;
  float sig = sigmoidf_(relg[l]);
  int k0 = start[d], k1 = start[d+1];
  int off = lane*2;
  float ax=0.f, ay=0.f;
  for (int k=k0;k<k1;k++){
    int sc = csr_sc[k];
    float cf = csr_cf[k];
    int src = sc>>1;
    const float* t = (sc&1) ? tC : tI;
    float ce = (sc&1) ? sig*cf : cf;
    float2 v = *reinterpret_cast<const float2*>(t + (size_t)src*H + off);
    ax = fmaf(ce, v.x, ax);
    ay = fmaf(ce, v.y, ay);
  }
  float diI = dinvI[d], diC = dinvC[d];
  float rI = diI*diI, rC = diC*diC;
  float2 ti = *reinterpret_cast<const float2*>(tI + (size_t)d*H + off);
  float2 tc = *reinterpret_cast<const float2*>(tC + (size_t)d*H + off);
  float2 o;
  o.x = fmaf(ti.x, rI, bI[off])   + sig*fmaf(tc.x, rC, bC[off])   + ax;
  o.y = fmaf(ti.y, rI, bI[off+1]) + sig*fmaf(tc.y, rC, bC[off+1]) + ay;
  *reinterpret_cast<float2*>(h + (size_t)d*H + off) = o;
}

__global__ __launch_bounds__(128) void k_stats(const float* __restrict__ h,
    float* __restrict__ bnsum, float* __restrict__ bnsq, int N, int nper)
{
  int j = threadIdx.x;
  int n0 = blockIdx.x*nper, n1 = min(n0+nper, N);
  if (n0 >= N) return;
  float sl=0.f, sq=0.f;
  for (int n=n0;n<n1;n++){
    float v = h[(size_t)n*H+j];
    sl += v; sq = fmaf(v,v,sq);
  }
  atomicAdd(bnsum+j, sl); atomicAdd(bnsq+j, sq);
}

__global__ void k_bn(float* __restrict__ h, const float* __restrict__ bnsum,
                     const float* __restrict__ bnsq,
                     const float* __restrict__ gamma, const float* __restrict__ beta,
                     float invN, int NH)
{
  int i = blockIdx.x*blockDim.x + threadIdx.x;
  if (i >= NH) return;
  int j = i & (H-1);
  float mu = bnsum[j]*invN;
  float var = bnsq[j]*invN - mu*mu;
  float r = rsqrtf(var + 1e-5f);
  h[i] = fmaxf(fmaf(gamma[j], (h[i]-mu)*r, beta[j]), 0.f);
}

// pool with BN+relu applied on the fly (layer-2 fusion)
__global__ __launch_bounds__(128) void k_poolbn(
    const float* __restrict__ h, const int* __restrict__ batch, const int* __restrict__ em,
    const float* __restrict__ bnsum, const float* __restrict__ bnsq,
    const float* __restrict__ gamma, const float* __restrict__ beta, float invN,
    float* __restrict__ sumE, float* __restrict__ sumF,
    float* __restrict__ cntE, float* __restrict__ cntF, int N, int nper)
{
  int j = threadIdx.x;
  int n0 = blockIdx.x*nper, n1 = min(n0+nper, N);
  if (n0 >= N) return;
  float mu = bnsum[j]*invN;
  float var = bnsq[j]*invN - mu*mu;
  float rr = rsqrtf(var + 1e-5f);
  float ga = gamma[j], be = beta[j];
  float aE=0.f, aF=0.f, ce=0.f, cfc=0.f;
  int cg = batch[n0];
  for (int n=n0;n<n1;n++){
    int g = batch[n];
    if (g != cg){
      atomicAdd(sumE+(size_t)cg*H+j, aE);
      atomicAdd(sumF+(size_t)cg*H+j, aF);
      if (j==0){ atomicAdd(cntE+cg, ce); atomicAdd(cntF+cg, cfc); }
      aE=aF=ce=cfc=0.f; cg=g;
    }
    float v = fmaxf(fmaf(ga, (h[(size_t)n*H+j]-mu)*rr, be), 0.f);
    bool eb = em[n] != 0;
    if (eb) aE += v; else aF += v;
    if (j==0){ if (eb) ce += 1.f; else cfc += 1.f; }
  }
  atomicAdd(sumE+(size_t)cg*H+j, aE);
  atomicAdd(sumF+(size_t)cg*H+j, aF);
  if (j==0){ atomicAdd(cntE+cg, ce); atomicAdd(cntF+cg, cfc); }
}

__device__ __forceinline__ float blockReduceSum(float v, float* red){
  int t = threadIdx.x;
  red[t] = v; __syncthreads();
  #pragma unroll
  for (int s=64;s>0;s>>=1){ if (t<s) red[t]+=red[t+s]; __syncthreads(); }
  float r = red[0]; __syncthreads();
  return r;
}

__global__ __launch_bounds__(128) void k_head(
    const float* __restrict__ sumE, const float* __restrict__ sumF,
    const float* __restrict__ cntE, const float* __restrict__ cntF,
    const float* __restrict__ coW1, const float* __restrict__ cob1,
    const float* __restrict__ coW2, const float* __restrict__ cob2,
    const float* __restrict__ gW1, const float* __restrict__ gb1,
    const float* __restrict__ gW2, const float* __restrict__ gb2,
    const float* __restrict__ cW1, const float* __restrict__ cb1,
    const float* __restrict__ cW2, const float* __restrict__ cb2,
    const float* __restrict__ peW1, const float* __restrict__ peb1,
    const float* __restrict__ peW2, const float* __restrict__ peb2,
    const float* __restrict__ pfW1, const float* __restrict__ pfb1,
    const float* __restrict__ pfW2, const float* __restrict__ pfb2,
    float* __restrict__ out, int G)
{
  int g = blockIdx.x, j = threadIdx.x;
  __shared__ float sh[384];
  __shared__ float red[128];
  __shared__ float hfin[128], buf[128];
  float cE = cntE[g], cF = cntF[g];
  float se = sumE[(size_t)g*H+j], sf = sumF[(size_t)g*H+j];
  float he = se/fmaxf(cE,1.f), hf = sf/fmaxf(cF,1.f);
  float hg = (se+sf)/fmaxf(cE+cF,1.f);
  sh[j]=he; sh[128+j]=hf; sh[256+j]=he*hf;
  __syncthreads();
  float a = cob1[j];
  for (int k=0;k<384;k++) a = fmaf(sh[k], coW1[k*H+j], a);
  a = fmaxf(a, 0.f);
  float r0 = blockReduceSum(a*coW2[2*j],   red);
  float r1 = blockReduceSum(a*coW2[2*j+1], red);
  float al0 = sigmoidf_(r0 + cob2[0]);
  float al1 = sigmoidf_(r1 + cob2[1]);
  float asum = al0+al1+1e-6f; al0/=asum; al1/=asum;
  float hc = al0*he + al1*hf;
  __syncthreads();
  sh[j]=hc; sh[128+j]=hg;
  __syncthreads();
  float gg = gb1[j];
  for (int k=0;k<256;k++) gg = fmaf(sh[k], gW1[k*H+j], gg);
  gg = fmaxf(gg, 0.f);
  float gt = sigmoidf_(blockReduceSum(gg*gW2[j], red) + gb2[0]);
  float hfj = gt*hc + (1.f-gt)*hg;
  hfin[j] = hfj;
  __syncthreads();
  float c1v = 0.f;
  if (j < 64){
    float c1 = cb1[j];
    for (int k=0;k<128;k++) c1 = fmaf(hfin[k], cW1[k*64+j], c1);
    c1v = fmaxf(c1, 0.f);
  }
  float l0 = blockReduceSum(j<64 ? c1v*cW2[2*j]   : 0.f, red);
  float l1 = blockReduceSum(j<64 ? c1v*cW2[2*j+1] : 0.f, red);
  if (j==0){ out[(size_t)g*2] = l0 + cb2[0]; out[(size_t)g*2+1] = l1 + cb2[1]; }
  // z_e
  buf[j] = he; __syncthreads();
  float q = peb1[j];
  for (int k=0;k<128;k++) q = fmaf(buf[k], peW1[k*H+j], q);
  q = fmaxf(q, 0.f);
  __syncthreads(); sh[j] = q; __syncthreads();
  float z = peb2[j];
  for (int k=0;k<128;k++) z = fmaf(sh[k], peW2[k*H+j], z);
  float nr = sqrtf(blockReduceSum(z*z, red));
  out[(size_t)G*2 + (size_t)g*H + j] = z / fmaxf(nr, 1e-12f);
  // z_f
  __syncthreads(); buf[j] = hf; __syncthreads();
  float q2 = pfb1[j];
  for (int k=0;k<128;k++) q2 = fmaf(buf[k], pfW1[k*H+j], q2);
  q2 = fmaxf(q2, 0.f);
  __syncthreads(); sh[j] = q2; __syncthreads();
  float z2 = pfb2[j];
  for (int k=0;k<128;k++) z2 = fmaf(sh[k], pfW2[k*H+j], z2);
  float nr2 = sqrtf(blockReduceSum(z2*z2, red));
  out[(size_t)G*2 + (size_t)G*H + (size_t)g*H + j] = z2 / fmaxf(nr2, 1e-12f);
}

extern "C" void kernel_launch(void* const* d_in, const int* in_sizes, int n_in,
                              void* d_out, int out_size, void* d_ws, size_t ws_size,
                              hipStream_t stream)
{
  const float* x    = (const float*)d_in[0];
  const int*   ei   = (const int*)d_in[1];
  const float* ew   = (const float*)d_in[2];
  const int*   batch= (const int*)d_in[3];
  const int*   em   = (const int*)d_in[4];
  const float* eegW = (const float*)d_in[6];  const float* eegB = (const float*)d_in[7];
  const float* fnW  = (const float*)d_in[8];  const float* fnB  = (const float*)d_in[9];
  const float* eW1  = (const float*)d_in[10]; const float* eb1  = (const float*)d_in[11];
  const float* eW2  = (const float*)d_in[12]; const float* eb2  = (const float*)d_in[13];
  const float* cIW  = (const float*)d_in[14]; const float* cIb  = (const float*)d_in[15];
  const float* cCW  = (const float*)d_in[16]; const float* cCb  = (const float*)d_in[17];
  const float* relg = (const float*)d_in[18];
  const float* bng  = (const float*)d_in[19]; const float* bnb  = (const float*)d_in[20];
  const float* coW1 = (const float*)d_in[21]; const float* cob1 = (const float*)d_in[22];
  const float* coW2 = (const float*)d_in[23]; const float* cob2 = (const float*)d_in[24];
  const float* gW1  = (const float*)d_in[25]; const float* gb1  = (const float*)d_in[26];
  const float* gW2  = (const float*)d_in[27]; const float* gb2  = (const float*)d_in[28];
  const float* cW1  = (const float*)d_in[29]; const float* cb1  = (const float*)d_in[30];
  const float* cW2  = (const float*)d_in[31]; const float* cb2  = (const float*)d_in[32];
  const float* peW1 = (const float*)d_in[33]; const float* peb1 = (const float*)d_in[34];
  const float* peW2 = (const float*)d_in[35]; const float* peb2 = (const float*)d_in[36];
  const float* pfW1 = (const float*)d_in[37]; const float* pfb1 = (const float*)d_in[38];
  const float* pfW2 = (const float*)d_in[39]; const float* pfb2 = (const float*)d_in[40];
  float* out = (float*)d_out;

  int N = in_sizes[0] / D;           // 50000
  int E = in_sizes[2];               // 800000
  int G = out_size / (2 + 2*H);      // 500
  int NH = N*H;

  float* p = (float*)d_ws;
  float* h    = p; p += (size_t)NH;
  float* tI   = p; p += (size_t)NH;   // overlaid as bf16 hb before layer loop
  float* tC   = p; p += (size_t)NH;
  float* csr_cf = p; p += E;
  float* csr_w  = p; p += E;
  int* csr_sc = (int*)p; p += E;
  int* csr_d  = (int*)p; p += E;
  int* start  = (int*)p; p += (N+1);
  int* cnt    = (int*)p; p += N;      // cnt, wcnt, degI, degC contiguous -> one memset
  int* wcnt   = (int*)p; p += N;
  float* degI = p; p += N;
  float* degC = p; p += N;
  float* dinvI= p; p += N;
  float* dinvC= p; p += N;
  float* bnsum= p; p += H;            // bnsum+bnsq contiguous
  float* bnsq = p; p += H;
  float* sumE = p; p += (size_t)G*H;  // sumE..cntF contiguous
  float* sumF = p; p += (size_t)G*H;
  float* cntE = p; p += G;
  float* cntF = p; p += G;
  unsigned short* W1b = (unsigned short*)p; p += 4096;  // 8192 bf16 = 16 KB

  unsigned int* hb = (unsigned int*)tI;   // bf16 h, used only before layer loop

  int gemmBlocks = (N+63)/64;
  int statBlocks = 1024;
  int nper_stat = (N + statBlocks - 1)/statBlocks;   // ~49 rows/block
  int poolBlocks = (N + 31)/32;                      // 32 rows/block

  hipMemsetAsync(cnt, 0, (size_t)4*N*sizeof(int), stream);  // cnt,wcnt,degI,degC
  k_hist<<<(E+255)/256,256,0,stream>>>(ei, cnt, E);
  k_scan<<<1,1024,0,stream>>>(cnt, start, N);
  k_fill2<<<(E+255)/256,256,0,stream>>>(ei, em, ew, start, wcnt,
                                        csr_sc, csr_d, csr_w, E);
  k_prepw<<<1,256,0,stream>>>(eW1, W1b);
  k_proj<<<gemmBlocks,256,0,stream>>>(x, em, eegW,eegB, fnW,fnB, h, hb, N);
  k_edgem<<<(E+63)/64,256,0,stream>>>(hb, csr_sc, csr_d, csr_w, W1b,
                                      eW1, eb1, eW2, eb2, csr_cf, degI, degC, E);
  k_dinv<<<(N+255)/256,256,0,stream>>>(degI,degC,dinvI,dinvC,N);
  k_scale<<<(E+255)/256,256,0,stream>>>(csr_sc, csr_d, dinvI, dinvC, csr_cf, E);

  for (int l=0;l<2;l++){
    k_gemm2<<<gemmBlocks,256,0,stream>>>(h, cIW + (size_t)l*H*H,
                                         cCW + (size_t)l*H*H, tI, tC, N);
    k_aggr<<<(N+3)/4,256,0,stream>>>(tI, tC, start, csr_sc, csr_cf,
                                     dinvI, dinvC, cIb+(size_t)l*H,
                                     cCb+(size_t)l*H, relg, l, h, N);
    hipMemsetAsync(bnsum, 0, 2*H*sizeof(float), stream);
    k_stats<<<statBlocks,128,0,stream>>>(h, bnsum, bnsq, N, nper_stat);
    if (l == 0){
      k_bn<<<(NH+255)/256,256,0,stream>>>(h, bnsum, bnsq,
                                          bng, bnb, 1.0f/(float)N, NH);
    }
  }

  hipMemsetAsync(sumE, 0, ((size_t)2*G*H + 2*G)*sizeof(float), stream);
  k_poolbn<<<poolBlocks,128,0,stream>>>(h, batch, em, bnsum, bnsq,
                                        bng+(size_t)H, bnb+(size_t)H, 1.0f/(float)N,
                                        sumE, sumF, cntE, cntF, N, 32);
  k_head<<<G,128,0,stream>>>(sumE,sumF,cntE,cntF,
                             coW1,cob1,coW2,cob2, gW1,gb1,gW2,gb2,
                             cW1,cb1,cW2,cb2, peW1,peb1,peW2,peb2,
                             pfW1,pfb1,pfW2,pfb2, out, G);
}

// Round 7
// 804.893 us; speedup vs baseline: 2.8745x; 1.0862x over previous
//
#include <hip/hip_runtime.h>
#include <math.h>

#define H 128
#define D 256

typedef __attribute__((ext_vector_type(8))) short bf16x8;
typedef __attribute__((ext_vector_type(4))) float f32x4;

__device__ __forceinline__ float sigmoidf_(float x){ return 1.0f/(1.0f+__expf(-x)); }

// RNE float->bf16 (as uint in low 16 bits)
__device__ __forceinline__ unsigned int bfr_(float f){
  unsigned int u = __float_as_uint(f);
  return (u + 0x7fffu + ((u>>16)&1u)) >> 16;
}

// split a,b into packed bf16 hi / lo words (2 bf16 each)
__device__ __forceinline__ void split2(float a, float b, unsigned &hi, unsigned &lo){
  unsigned ha = bfr_(a), hb2 = bfr_(b);
  float fa = __uint_as_float(ha<<16), fb = __uint_as_float(hb2<<16);
  unsigned la = bfr_(a - fa), lb = bfr_(b - fb);
  hi = ha | (hb2<<16); lo = la | (lb<<16);
}

// pack |a-b| of two bf16 pairs into one uint (2 bf16)
__device__ __forceinline__ unsigned pair_df(unsigned a, unsigned b){
  float a0 = __uint_as_float(a<<16), a1 = __uint_as_float(a & 0xffff0000u);
  float b0 = __uint_as_float(b<<16), b1 = __uint_as_float(b & 0xffff0000u);
  return bfr_(fabsf(a0-b0)) | (bfr_(fabsf(a1-b1))<<16);
}

// W [K x 128] fp32 -> hi/lo bf16 A-fragments for 16x16x32 MFMA.
// frag (kstep,mfrag,hl): entry lane holds W[k=kstep*32+(lane>>4)*8+j][mfrag*16+(lane&15)]
__global__ void k_prepwf(const float* __restrict__ W, unsigned short* __restrict__ out,
                         int ksteps){
  int id = blockIdx.x*blockDim.x + threadIdx.x;
  if (id >= ksteps*8*64) return;
  int lane = id & 63;
  int mfrag = (id>>6) & 7;
  int kstep = id >> 9;
  int col = mfrag*16 + (lane&15);
  int k0 = kstep*32 + (lane>>4)*8;
  unsigned short* oh = out + (size_t)(((kstep*8+mfrag)*2+0)*64 + lane)*8;
  unsigned short* ol = out + (size_t)(((kstep*8+mfrag)*2+1)*64 + lane)*8;
  #pragma unroll
  for (int j=0;j<8;j++){
    float w = W[(size_t)(k0+j)*128 + col];
    unsigned h16 = bfr_(w);
    float hf = __uint_as_float(h16<<16);
    oh[j] = (unsigned short)h16;
    ol[j] = (unsigned short)bfr_(w - hf);
  }
}

// proj via MFMA bf16x3: h = relu(x @ Wsel + bsel). wave = 16 nodes x 128 ch.
__global__ __launch_bounds__(256) void k_projm(
    const float* __restrict__ x, const int* __restrict__ em,
    const unsigned short* __restrict__ WeF, const float* __restrict__ be,
    const unsigned short* __restrict__ WfF, const float* __restrict__ bf,
    float* __restrict__ h, unsigned int* __restrict__ hb, int N)
{
  int t = threadIdx.x;
  int lane = t & 63;
  int base = (blockIdx.x*4 + (t>>6))*16;
  if (base >= N) return;
  int node = base + (lane & 15);
  int nodeL = min(node, N-1);
  int ko = lane >> 4;

  f32x4 accE[8], accF[8];
  #pragma unroll
  for (int mf=0;mf<8;mf++){ accE[mf]=(f32x4){0.f,0.f,0.f,0.f}; accF[mf]=(f32x4){0.f,0.f,0.f,0.f}; }

  const bf16x8* we = reinterpret_cast<const bf16x8*>(WeF);
  const bf16x8* wf = reinterpret_cast<const bf16x8*>(WfF);

  for (int kstep=0;kstep<8;kstep++){
    const float4* xr = reinterpret_cast<const float4*>(x + (size_t)nodeL*D + kstep*32 + ko*8);
    float4 v0 = xr[0], v1 = xr[1];
    uint4 hiu, lou;
    split2(v0.x, v0.y, hiu.x, lou.x);
    split2(v0.z, v0.w, hiu.y, lou.y);
    split2(v1.x, v1.y, hiu.z, lou.z);
    split2(v1.z, v1.w, hiu.w, lou.w);
    bf16x8 Bhi = *reinterpret_cast<bf16x8*>(&hiu);
    bf16x8 Blo = *reinterpret_cast<bf16x8*>(&lou);
    #pragma unroll
    for (int mf=0;mf<8;mf++){
      int fb = (kstep*8+mf)*2;
      bf16x8 aEh = we[(size_t)fb*64 + lane];
      bf16x8 aEl = we[(size_t)(fb+1)*64 + lane];
      accE[mf] = __builtin_amdgcn_mfma_f32_16x16x32_bf16(aEh, Bhi, accE[mf], 0,0,0);
      accE[mf] = __builtin_amdgcn_mfma_f32_16x16x32_bf16(aEh, Blo, accE[mf], 0,0,0);
      accE[mf] = __builtin_amdgcn_mfma_f32_16x16x32_bf16(aEl, Bhi, accE[mf], 0,0,0);
      bf16x8 aFh = wf[(size_t)fb*64 + lane];
      bf16x8 aFl = wf[(size_t)(fb+1)*64 + lane];
      accF[mf] = __builtin_amdgcn_mfma_f32_16x16x32_bf16(aFh, Bhi, accF[mf], 0,0,0);
      accF[mf] = __builtin_amdgcn_mfma_f32_16x16x32_bf16(aFh, Blo, accF[mf], 0,0,0);
      accF[mf] = __builtin_amdgcn_mfma_f32_16x16x32_bf16(aFl, Bhi, accF[mf], 0,0,0);
    }
  }
  if (node >= N) return;
  bool e = em[node] != 0;
  #pragma unroll
  for (int mf=0;mf<8;mf++){
    float sv[4];
    #pragma unroll
    for (int r=0;r<4;r++){
      int ch = mf*16 + ko*4 + r;
      float vE = accE[mf][r] + be[ch];
      float vF = accF[mf][r] + bf[ch];
      sv[r] = fmaxf(e ? vE : vF, 0.f);
    }
    float2* hp = reinterpret_cast<float2*>(h + (size_t)node*H + mf*16 + ko*4);
    hp[0] = make_float2(sv[0], sv[1]);
    hp[1] = make_float2(sv[2], sv[3]);
    unsigned int* hbp = hb + (size_t)node*64 + mf*8 + ko*2;
    hbp[0] = bfr_(sv[0]) | (bfr_(sv[1])<<16);
    hbp[1] = bfr_(sv[2]) | (bfr_(sv[3])<<16);
  }
}

// dual GEMM via MFMA bf16x3: tI = A@WI, tC = A@WC. K=128.
__global__ __launch_bounds__(256) void k_gemm2m(
    const float* __restrict__ A,
    const unsigned short* __restrict__ WIf, const unsigned short* __restrict__ WCf,
    float* __restrict__ tI, float* __restrict__ tC, int N)
{
  int t = threadIdx.x;
  int lane = t & 63;
  int base = (blockIdx.x*4 + (t>>6))*16;
  if (base >= N) return;
  int node = base + (lane & 15);
  int nodeL = min(node, N-1);
  int ko = lane >> 4;

  f32x4 accI[8], accC[8];
  #pragma unroll
  for (int mf=0;mf<8;mf++){ accI[mf]=(f32x4){0.f,0.f,0.f,0.f}; accC[mf]=(f32x4){0.f,0.f,0.f,0.f}; }

  const bf16x8* wi = reinterpret_cast<const bf16x8*>(WIf);
  const bf16x8* wc = reinterpret_cast<const bf16x8*>(WCf);

  for (int kstep=0;kstep<4;kstep++){
    const float4* ar = reinterpret_cast<const float4*>(A + (size_t)nodeL*H + kstep*32 + ko*8);
    float4 v0 = ar[0], v1 = ar[1];
    uint4 hiu, lou;
    split2(v0.x, v0.y, hiu.x, lou.x);
    split2(v0.z, v0.w, hiu.y, lou.y);
    split2(v1.x, v1.y, hiu.z, lou.z);
    split2(v1.z, v1.w, hiu.w, lou.w);
    bf16x8 Bhi = *reinterpret_cast<bf16x8*>(&hiu);
    bf16x8 Blo = *reinterpret_cast<bf16x8*>(&lou);
    #pragma unroll
    for (int mf=0;mf<8;mf++){
      int fb = (kstep*8+mf)*2;
      bf16x8 aIh = wi[(size_t)fb*64 + lane];
      bf16x8 aIl = wi[(size_t)(fb+1)*64 + lane];
      accI[mf] = __builtin_amdgcn_mfma_f32_16x16x32_bf16(aIh, Bhi, accI[mf], 0,0,0);
      accI[mf] = __builtin_amdgcn_mfma_f32_16x16x32_bf16(aIh, Blo, accI[mf], 0,0,0);
      accI[mf] = __builtin_amdgcn_mfma_f32_16x16x32_bf16(aIl, Bhi, accI[mf], 0,0,0);
      bf16x8 aCh = wc[(size_t)fb*64 + lane];
      bf16x8 aCl = wc[(size_t)(fb+1)*64 + lane];
      accC[mf] = __builtin_amdgcn_mfma_f32_16x16x32_bf16(aCh, Bhi, accC[mf], 0,0,0);
      accC[mf] = __builtin_amdgcn_mfma_f32_16x16x32_bf16(aCh, Blo, accC[mf], 0,0,0);
      accC[mf] = __builtin_amdgcn_mfma_f32_16x16x32_bf16(aCl, Bhi, accC[mf], 0,0,0);
    }
  }
  if (node >= N) return;
  #pragma unroll
  for (int mf=0;mf<8;mf++){
    float2* ti = reinterpret_cast<float2*>(tI + (size_t)node*H + mf*16 + ko*4);
    float2* tc = reinterpret_cast<float2*>(tC + (size_t)node*H + mf*16 + ko*4);
    ti[0] = make_float2(accI[mf][0], accI[mf][1]);
    ti[1] = make_float2(accI[mf][2], accI[mf][3]);
    tc[0] = make_float2(accC[mf][0], accC[mf][1]);
    tc[1] = make_float2(accC[mf][2], accC[mf][3]);
  }
}

// ---- CSR build ----
__global__ void k_hist(const int* __restrict__ ei, int* __restrict__ cnt, int E){
  int e = blockIdx.x*blockDim.x + threadIdx.x;
  if (e < E) atomicAdd(cnt + ei[E+e], 1);
}

__global__ __launch_bounds__(1024) void k_scan(const int* __restrict__ cnt,
                                               int* __restrict__ start, int N){
  __shared__ int sm[1024];
  int t = threadIdx.x;
  int chunk = (N + 1023)/1024;
  int i0 = t*chunk, i1 = min(i0+chunk, N);
  int s = 0;
  for (int i=i0;i<i1;i++) s += cnt[i];
  sm[t] = s; __syncthreads();
  for (int d=1; d<1024; d<<=1){
    int v = (t>=d)? sm[t-d] : 0;
    __syncthreads();
    sm[t] += v;
    __syncthreads();
  }
  int base = (t==0)? 0 : sm[t-1];
  for (int i=i0;i<i1;i++){ start[i] = base; base += cnt[i]; }
  if (t == 1023) start[N] = base;
}

__global__ void k_fill2(const int* __restrict__ ei, const int* __restrict__ em,
                        const float* __restrict__ ew,
                        const int* __restrict__ start, int* __restrict__ wcnt,
                        int* __restrict__ csr_sc, int* __restrict__ csr_d,
                        float* __restrict__ csr_w, int E){
  int e = blockIdx.x*blockDim.x + threadIdx.x;
  if (e >= E) return;
  int s = ei[e], d = ei[E+e];
  int chan = (em[s] == em[d]) ? 0 : 1;
  int pos = start[d] + atomicAdd(wcnt + d, 1);
  csr_sc[pos] = (s<<1) | chan;
  csr_d[pos] = d;
  csr_w[pos] = ew[e];
}

// W1 (129x64 fp32) -> bf16 B-fragments for 16x16x32 MFMA.
__global__ void k_prepw(const float* __restrict__ W1, unsigned short* __restrict__ W1b){
  int t = threadIdx.x;
  for (int it=0; it<4; it++){
    int le = it*256 + t;
    int f = le >> 6, lane = le & 63;
    int kstep = f >> 2, n = f & 3;
    int col = n*16 + (lane & 15);
    int k0 = kstep*32 + ((lane>>4)&3)*8;
    unsigned short* op = W1b + (size_t)le*8;
    #pragma unroll
    for (int j=0;j<8;j++)
      op[j] = (unsigned short)bfr_(W1[(size_t)(k0+j)*64 + col]);
  }
}

// per-edge MLP gate via MFMA. wave = 16 edges; K=128, N=64.
__global__ __launch_bounds__(256) void k_edgem(
    const unsigned int* __restrict__ hb,
    const int* __restrict__ csr_sc, const int* __restrict__ csr_d,
    const float* __restrict__ csr_w, const unsigned short* __restrict__ W1b,
    const float* __restrict__ W1, const float* __restrict__ b1,
    const float* __restrict__ W2, const float* __restrict__ b2,
    float* __restrict__ csr_cf,
    float* __restrict__ degI, float* __restrict__ degC, int E)
{
  int t = threadIdx.x;
  int lane = t & 63;
  int base = (blockIdx.x*4 + (t>>6)) * 16;
  if (base >= E) return;

  bf16x8 bfrag[16];
  const bf16x8* wb = reinterpret_cast<const bf16x8*>(W1b);
  #pragma unroll
  for (int f=0; f<16; f++) bfrag[f] = wb[f*64 + lane];

  int e = min(base + (lane & 15), E-1);
  int s = csr_sc[e] >> 1;
  int d = csr_d[e];
  const uint4* hsp = reinterpret_cast<const uint4*>(hb + (size_t)s*64);
  const uint4* hdp = reinterpret_cast<const uint4*>(hb + (size_t)d*64);
  int ko = lane >> 4;

  f32x4 acc[4];
  #pragma unroll
  for (int n=0;n<4;n++) acc[n] = (f32x4){0.f,0.f,0.f,0.f};

  #pragma unroll
  for (int kstep=0;kstep<4;kstep++){
    uint4 us = hsp[kstep*4 + ko];
    uint4 ud = hdp[kstep*4 + ko];
    uint4 pa;
    pa.x = pair_df(us.x, ud.x);
    pa.y = pair_df(us.y, ud.y);
    pa.z = pair_df(us.z, ud.z);
    pa.w = pair_df(us.w, ud.w);
    bf16x8 a = *reinterpret_cast<bf16x8*>(&pa);
    #pragma unroll
    for (int n=0;n<4;n++)
      acc[n] = __builtin_amdgcn_mfma_f32_16x16x32_bf16(a, bfrag[kstep*4+n], acc[n], 0,0,0);
  }

  int colbase = lane & 15;
  float w1l[4], b1v[4], w2v[4];
  #pragma unroll
  for (int n=0;n<4;n++){
    int col = n*16 + colbase;
    w1l[n] = W1[(size_t)128*64 + col];
    b1v[n] = b1[col];
    w2v[n] = W2[col];
  }
  float wgtr[4];
  #pragma unroll
  for (int r=0;r<4;r++)
    wgtr[r] = csr_w[min(base + (lane>>4)*4 + r, E-1)];

  float part[4] = {0.f,0.f,0.f,0.f};
  #pragma unroll
  for (int n=0;n<4;n++){
    #pragma unroll
    for (int r=0;r<4;r++){
      float v = fmaxf(acc[n][r] + fmaf(wgtr[r], w1l[n], b1v[n]), 0.f);
      part[r] = fmaf(v, w2v[n], part[r]);
    }
  }
  #pragma unroll
  for (int m=1;m<16;m<<=1){
    #pragma unroll
    for (int r=0;r<4;r++) part[r] += __shfl_xor(part[r], m, 64);
  }

  if ((lane & 15) == 0){
    float bb2 = b2[0];
    #pragma unroll
    for (int r=0;r<4;r++){
      int ee = base + (lane>>4)*4 + r;
      if (ee < E){
        float g = sigmoidf_(part[r] + bb2);
        g = fminf(fmaxf(g, 0.2f), 1.2f);
        float ehat = wgtr[r] * g;
        csr_cf[ee] = ehat;
        int sc2 = csr_sc[ee];
        atomicAdd(((sc2&1) ? degC : degI) + csr_d[ee], ehat);
      }
    }
  }
}

__global__ void k_dinv(const float* __restrict__ degI, const float* __restrict__ degC,
                       float* dinvI, float* dinvC, int N){
  int i = blockIdx.x*blockDim.x + threadIdx.x;
  if (i < N){
    dinvI[i] = rsqrtf(1.f + degI[i]);
    dinvC[i] = rsqrtf(1.f + degC[i]);
  }
}

__global__ void k_scale(const int* __restrict__ csr_sc, const int* __restrict__ csr_d,
                        const float* __restrict__ dinvI, const float* __restrict__ dinvC,
                        float* __restrict__ csr_cf, int E){
  int k = blockIdx.x*blockDim.x + threadIdx.x;
  if (k >= E) return;
  int sc = csr_sc[k];
  int s = sc>>1;
  int d = csr_d[k];
  const float* dv = (sc&1) ? dinvC : dinvI;
  csr_cf[k] *= dv[s]*dv[d];
}

// one wave per dst node: gather CSR edges + fused self-loop/bias epilogue.
__global__ __launch_bounds__(256) void k_aggr(
    const float* __restrict__ tI, const float* __restrict__ tC,
    const int* __restrict__ start, const int* __restrict__ csr_sc,
    const float* __restrict__ csr_cf,
    const float* __restrict__ dinvI, const float* __restrict__ dinvC,
    const float* __restrict__ bI, const float* __restrict__ bC,
    const float* __restrict__ relg, int l,
    float* __restrict__ h, int N)
{
  int lane = threadIdx.x & 63;
  int d = blockIdx.x*4 + (threadIdx.x>>6);
  if (d >= N) return;
  float sig = sigmoidf_(relg[l]);
  int k0 = start[d], k1 = start[d+1];
  int off = lane*2;
  float ax=0.f, ay=0.f;
  for (int k=k0;k<k1;k++){
    int sc = csr_sc[k];
    float cf = csr_cf[k];
    int src = sc>>1;
    const float* t = (sc&1) ? tC : tI;
    float ce = (sc&1) ? sig*cf : cf;
    float2 v = *reinterpret_cast<const float2*>(t + (size_t)src*H + off);
    ax = fmaf(ce, v.x, ax);
    ay = fmaf(ce, v.y, ay);
  }
  float diI = dinvI[d], diC = dinvC[d];
  float rI = diI*diI, rC = diC*diC;
  float2 ti = *reinterpret_cast<const float2*>(tI + (size_t)d*H + off);
  float2 tc = *reinterpret_cast<const float2*>(tC + (size_t)d*H + off);
  float2 o;
  o.x = fmaf(ti.x, rI, bI[off])   + sig*fmaf(tc.x, rC, bC[off])   + ax;
  o.y = fmaf(ti.y, rI, bI[off+1]) + sig*fmaf(tc.y, rC, bC[off+1]) + ay;
  *reinterpret_cast<float2*>(h + (size_t)d*H + off) = o;
}

__global__ __launch_bounds__(128) void k_stats(const float* __restrict__ h,
    float* __restrict__ bnsum, float* __restrict__ bnsq, int N, int nper)
{
  int j = threadIdx.x;
  int n0 = blockIdx.x*nper, n1 = min(n0+nper, N);
  if (n0 >= N) return;
  float sl=0.f, sq=0.f;
  for (int n=n0;n<n1;n++){
    float v = h[(size_t)n*H+j];
    sl += v; sq = fmaf(v,v,sq);
  }
  atomicAdd(bnsum+j, sl); atomicAdd(bnsq+j, sq);
}

__global__ void k_bn(float* __restrict__ h, const float* __restrict__ bnsum,
                     const float* __restrict__ bnsq,
                     const float* __restrict__ gamma, const float* __restrict__ beta,
                     float invN, int NH)
{
  int i = blockIdx.x*blockDim.x + threadIdx.x;
  if (i >= NH) return;
  int j = i & (H-1);
  float mu = bnsum[j]*invN;
  float var = bnsq[j]*invN - mu*mu;
  float r = rsqrtf(var + 1e-5f);
  h[i] = fmaxf(fmaf(gamma[j], (h[i]-mu)*r, beta[j]), 0.f);
}

// pool with BN+relu applied on the fly (layer-2 fusion)
__global__ __launch_bounds__(128) void k_poolbn(
    const float* __restrict__ h, const int* __restrict__ batch, const int* __restrict__ em,
    const float* __restrict__ bnsum, const float* __restrict__ bnsq,
    const float* __restrict__ gamma, const float* __restrict__ beta, float invN,
    float* __restrict__ sumE, float* __restrict__ sumF,
    float* __restrict__ cntE, float* __restrict__ cntF, int N, int nper)
{
  int j = threadIdx.x;
  int n0 = blockIdx.x*nper, n1 = min(n0+nper, N);
  if (n0 >= N) return;
  float mu = bnsum[j]*invN;
  float var = bnsq[j]*invN - mu*mu;
  float rr = rsqrtf(var + 1e-5f);
  float ga = gamma[j], be = beta[j];
  float aE=0.f, aF=0.f, ce=0.f, cfc=0.f;
  int cg = batch[n0];
  for (int n=n0;n<n1;n++){
    int g = batch[n];
    if (g != cg){
      atomicAdd(sumE+(size_t)cg*H+j, aE);
      atomicAdd(sumF+(size_t)cg*H+j, aF);
      if (j==0){ atomicAdd(cntE+cg, ce); atomicAdd(cntF+cg, cfc); }
      aE=aF=ce=cfc=0.f; cg=g;
    }
    float v = fmaxf(fmaf(ga, (h[(size_t)n*H+j]-mu)*rr, be), 0.f);
    bool eb = em[n] != 0;
    if (eb) aE += v; else aF += v;
    if (j==0){ if (eb) ce += 1.f; else cfc += 1.f; }
  }
  atomicAdd(sumE+(size_t)cg*H+j, aE);
  atomicAdd(sumF+(size_t)cg*H+j, aF);
  if (j==0){ atomicAdd(cntE+cg, ce); atomicAdd(cntF+cg, cfc); }
}

__device__ __forceinline__ float blockReduceSum(float v, float* red){
  int t = threadIdx.x;
  red[t] = v; __syncthreads();
  #pragma unroll
  for (int s=64;s>0;s>>=1){ if (t<s) red[t]+=red[t+s]; __syncthreads(); }
  float r = red[0]; __syncthreads();
  return r;
}

__global__ __launch_bounds__(128) void k_head(
    const float* __restrict__ sumE, const float* __restrict__ sumF,
    const float* __restrict__ cntE, const float* __restrict__ cntF,
    const float* __restrict__ coW1, const float* __restrict__ cob1,
    const float* __restrict__ coW2, const float* __restrict__ cob2,
    const float* __restrict__ gW1, const float* __restrict__ gb1,
    const float* __restrict__ gW2, const float* __restrict__ gb2,
    const float* __restrict__ cW1, const float* __restrict__ cb1,
    const float* __restrict__ cW2, const float* __restrict__ cb2,
    const float* __restrict__ peW1, const float* __restrict__ peb1,
    const float* __restrict__ peW2, const float* __restrict__ peb2,
    const float* __restrict__ pfW1, const float* __restrict__ pfb1,
    const float* __restrict__ pfW2, const float* __restrict__ pfb2,
    float* __restrict__ out, int G)
{
  int g = blockIdx.x, j = threadIdx.x;
  __shared__ float sh[384];
  __shared__ float red[128];
  __shared__ float hfin[128], buf[128];
  float cE = cntE[g], cF = cntF[g];
  float se = sumE[(size_t)g*H+j], sf = sumF[(size_t)g*H+j];
  float he = se/fmaxf(cE,1.f), hf = sf/fmaxf(cF,1.f);
  float hg = (se+sf)/fmaxf(cE+cF,1.f);
  sh[j]=he; sh[128+j]=hf; sh[256+j]=he*hf;
  __syncthreads();
  float a = cob1[j];
  for (int k=0;k<384;k++) a = fmaf(sh[k], coW1[k*H+j], a);
  a = fmaxf(a, 0.f);
  float r0 = blockReduceSum(a*coW2[2*j],   red);
  float r1 = blockReduceSum(a*coW2[2*j+1], red);
  float al0 = sigmoidf_(r0 + cob2[0]);
  float al1 = sigmoidf_(r1 + cob2[1]);
  float asum = al0+al1+1e-6f; al0/=asum; al1/=asum;
  float hc = al0*he + al1*hf;
  __syncthreads();
  sh[j]=hc; sh[128+j]=hg;
  __syncthreads();
  float gg = gb1[j];
  for (int k=0;k<256;k++) gg = fmaf(sh[k], gW1[k*H+j], gg);
  gg = fmaxf(gg, 0.f);
  float gt = sigmoidf_(blockReduceSum(gg*gW2[j], red) + gb2[0]);
  float hfj = gt*hc + (1.f-gt)*hg;
  hfin[j] = hfj;
  __syncthreads();
  float c1v = 0.f;
  if (j < 64){
    float c1 = cb1[j];
    for (int k=0;k<128;k++) c1 = fmaf(hfin[k], cW1[k*64+j], c1);
    c1v = fmaxf(c1, 0.f);
  }
  float l0 = blockReduceSum(j<64 ? c1v*cW2[2*j]   : 0.f, red);
  float l1 = blockReduceSum(j<64 ? c1v*cW2[2*j+1] : 0.f, red);
  if (j==0){ out[(size_t)g*2] = l0 + cb2[0]; out[(size_t)g*2+1] = l1 + cb2[1]; }
  // z_e
  buf[j] = he; __syncthreads();
  float q = peb1[j];
  for (int k=0;k<128;k++) q = fmaf(buf[k], peW1[k*H+j], q);
  q = fmaxf(q, 0.f);
  __syncthreads(); sh[j] = q; __syncthreads();
  float z = peb2[j];
  for (int k=0;k<128;k++) z = fmaf(sh[k], peW2[k*H+j], z);
  float nr = sqrtf(blockReduceSum(z*z, red));
  out[(size_t)G*2 + (size_t)g*H + j] = z / fmaxf(nr, 1e-12f);
  // z_f
  __syncthreads(); buf[j] = hf; __syncthreads();
  float q2 = pfb1[j];
  for (int k=0;k<128;k++) q2 = fmaf(buf[k], pfW1[k*H+j], q2);
  q2 = fmaxf(q2, 0.f);
  __syncthreads(); sh[j] = q2; __syncthreads();
  float z2 = pfb2[j];
  for (int k=0;k<128;k++) z2 = fmaf(sh[k], pfW2[k*H+j], z2);
  float nr2 = sqrtf(blockReduceSum(z2*z2, red));
  out[(size_t)G*2 + (size_t)G*H + (size_t)g*H + j] = z2 / fmaxf(nr2, 1e-12f);
}

extern "C" void kernel_launch(void* const* d_in, const int* in_sizes, int n_in,
                              void* d_out, int out_size, void* d_ws, size_t ws_size,
                              hipStream_t stream)
{
  const float* x    = (const float*)d_in[0];
  const int*   ei   = (const int*)d_in[1];
  const float* ew   = (const float*)d_in[2];
  const int*   batch= (const int*)d_in[3];
  const int*   em   = (const int*)d_in[4];
  const float* eegW = (const float*)d_in[6];  const float* eegB = (const float*)d_in[7];
  const float* fnW  = (const float*)d_in[8];  const float* fnB  = (const float*)d_in[9];
  const float* eW1  = (const float*)d_in[10]; const float* eb1  = (const float*)d_in[11];
  const float* eW2  = (const float*)d_in[12]; const float* eb2  = (const float*)d_in[13];
  const float* cIW  = (const float*)d_in[14]; const float* cIb  = (const float*)d_in[15];
  const float* cCW  = (const float*)d_in[16]; const float* cCb  = (const float*)d_in[17];
  const float* relg = (const float*)d_in[18];
  const float* bng  = (const float*)d_in[19]; const float* bnb  = (const float*)d_in[20];
  const float* coW1 = (const float*)d_in[21]; const float* cob1 = (const float*)d_in[22];
  const float* coW2 = (const float*)d_in[23]; const float* cob2 = (const float*)d_in[24];
  const float* gW1  = (const float*)d_in[25]; const float* gb1  = (const float*)d_in[26];
  const float* gW2  = (const float*)d_in[27]; const float* gb2  = (const float*)d_in[28];
  const float* cW1  = (const float*)d_in[29]; const float* cb1  = (const float*)d_in[30];
  const float* cW2  = (const float*)d_in[31]; const float* cb2  = (const float*)d_in[32];
  const float* peW1 = (const float*)d_in[33]; const float* peb1 = (const float*)d_in[34];
  const float* peW2 = (const float*)d_in[35]; const float* peb2 = (const float*)d_in[36];
  const float* pfW1 = (const float*)d_in[37]; const float* pfb1 = (const float*)d_in[38];
  const float* pfW2 = (const float*)d_in[39]; const float* pfb2 = (const float*)d_in[40];
  float* out = (float*)d_out;

  int N = in_sizes[0] / D;           // 50000
  int E = in_sizes[2];               // 800000
  int G = out_size / (2 + 2*H);      // 500
  int NH = N*H;

  float* p = (float*)d_ws;
  float* h    = p; p += (size_t)NH;
  float* tI   = p; p += (size_t)NH;   // overlaid as bf16 hb before layer loop
  float* tC   = p; p += (size_t)NH;
  float* csr_cf = p; p += E;
  float* csr_w  = p; p += E;
  int* csr_sc = (int*)p; p += E;
  int* csr_d  = (int*)p; p += E;
  int* start  = (int*)p; p += (N+1);
  int* cnt    = (int*)p; p += N;      // cnt, wcnt, degI, degC contiguous -> one memset
  int* wcnt   = (int*)p; p += N;
  float* degI = p; p += N;
  float* degC = p; p += N;
  float* dinvI= p; p += N;
  float* dinvC= p; p += N;
  float* bnsum= p; p += H;            // bnsum+bnsq contiguous
  float* bnsq = p; p += H;
  float* sumE = p; p += (size_t)G*H;  // sumE..cntF contiguous
  float* sumF = p; p += (size_t)G*H;
  float* cntE = p; p += G;
  float* cntF = p; p += G;
  unsigned short* W1b = (unsigned short*)p; p += 4096;   // 8192 bf16 = 16 KB
  unsigned short* WeF = (unsigned short*)p; p += 32768;  // 128 KB
  unsigned short* WfF = (unsigned short*)p; p += 32768;  // 128 KB
  unsigned short* WIf0= (unsigned short*)p; p += 16384;  // 64 KB
  unsigned short* WCf0= (unsigned short*)p; p += 16384;
  unsigned short* WIf1= (unsigned short*)p; p += 16384;
  unsigned short* WCf1= (unsigned short*)p; p += 16384;

  unsigned int* hb = (unsigned int*)tI;   // bf16 h, used only before layer loop

  int mmBlocks = ((N+15)/16 + 3)/4;   // 16 nodes/wave, 4 waves/block
  int statBlocks = 1024;
  int nper_stat = (N + statBlocks - 1)/statBlocks;
  int poolBlocks = (N + 31)/32;

  hipMemsetAsync(cnt, 0, (size_t)4*N*sizeof(int), stream);  // cnt,wcnt,degI,degC
  k_hist<<<(E+255)/256,256,0,stream>>>(ei, cnt, E);
  k_scan<<<1,1024,0,stream>>>(cnt, start, N);
  k_fill2<<<(E+255)/256,256,0,stream>>>(ei, em, ew, start, wcnt,
                                        csr_sc, csr_d, csr_w, E);
  k_prepw<<<1,256,0,stream>>>(eW1, W1b);
  k_prepwf<<<16,256,0,stream>>>(eegW, WeF, 8);
  k_prepwf<<<16,256,0,stream>>>(fnW,  WfF, 8);
  k_prepwf<<<8,256,0,stream>>>(cIW,          WIf0, 4);
  k_prepwf<<<8,256,0,stream>>>(cCW,          WCf0, 4);
  k_prepwf<<<8,256,0,stream>>>(cIW + 16384,  WIf1, 4);
  k_prepwf<<<8,256,0,stream>>>(cCW + 16384,  WCf1, 4);

  k_projm<<<mmBlocks,256,0,stream>>>(x, em, WeF, eegB, WfF, fnB, h, hb, N);
  k_edgem<<<(E+63)/64,256,0,stream>>>(hb, csr_sc, csr_d, csr_w, W1b,
                                      eW1, eb1, eW2, eb2, csr_cf, degI, degC, E);
  k_dinv<<<(N+255)/256,256,0,stream>>>(degI,degC,dinvI,dinvC,N);
  k_scale<<<(E+255)/256,256,0,stream>>>(csr_sc, csr_d, dinvI, dinvC, csr_cf, E);

  for (int l=0;l<2;l++){
    k_gemm2m<<<mmBlocks,256,0,stream>>>(h, l ? WIf1 : WIf0, l ? WCf1 : WCf0,
                                        tI, tC, N);
    k_aggr<<<(N+3)/4,256,0,stream>>>(tI, tC, start, csr_sc, csr_cf,
                                     dinvI, dinvC, cIb+(size_t)l*H,
                                     cCb+(size_t)l*H, relg, l, h, N);
    hipMemsetAsync(bnsum, 0, 2*H*sizeof(float), stream);
    k_stats<<<statBlocks,128,0,stream>>>(h, bnsum, bnsq, N, nper_stat);
    if (l == 0){
      k_bn<<<(NH+255)/256,256,0,stream>>>(h, bnsum, bnsq,
                                          bng, bnb, 1.0f/(float)N, NH);
    }
  }

  hipMemsetAsync(sumE, 0, ((size_t)2*G*H + 2*G)*sizeof(float), stream);
  k_poolbn<<<poolBlocks,128,0,stream>>>(h, batch, em, bnsum, bnsq,
                                        bng+(size_t)H, bnb+(size_t)H, 1.0f/(float)N,
                                        sumE, sumF, cntE, cntF, N, 32);
  k_head<<<G,128,0,stream>>>(sumE,sumF,cntE,cntF,
                             coW1,cob1,coW2,cob2, gW1,gb1,gW2,gb2,
                             cW1,cb1,cW2,cb2, peW1,peb1,peW2,peb2,
                             pfW1,pfb1,pfW2,pfb2, out, G);
}

// Round 8
// 786.512 us; speedup vs baseline: 2.9417x; 1.0234x over previous
//
#include <hip/hip_runtime.h>
#include <math.h>

#define H 128
#define D 256

typedef __attribute__((ext_vector_type(8))) short bf16x8;
typedef __attribute__((ext_vector_type(4))) float f32x4;

__device__ __forceinline__ float sigmoidf_(float x){ return 1.0f/(1.0f+__expf(-x)); }

// RNE float->bf16 (as uint in low 16 bits)
__device__ __forceinline__ unsigned int bfr_(float f){
  unsigned int u = __float_as_uint(f);
  return (u + 0x7fffu + ((u>>16)&1u)) >> 16;
}

// split a,b into packed bf16 hi / lo words (2 bf16 each)
__device__ __forceinline__ void split2(float a, float b, unsigned &hi, unsigned &lo){
  unsigned ha = bfr_(a), hb2 = bfr_(b);
  float fa = __uint_as_float(ha<<16), fb = __uint_as_float(hb2<<16);
  unsigned la = bfr_(a - fa), lb = bfr_(b - fb);
  hi = ha | (hb2<<16); lo = la | (lb<<16);
}

// pack |a-b| of two bf16 pairs into one uint (2 bf16)
__device__ __forceinline__ unsigned pair_df(unsigned a, unsigned b){
  float a0 = __uint_as_float(a<<16), a1 = __uint_as_float(a & 0xffff0000u);
  float b0 = __uint_as_float(b<<16), b1 = __uint_as_float(b & 0xffff0000u);
  return bfr_(fabsf(a0-b0)) | (bfr_(fabsf(a1-b1))<<16);
}

// W [K x 128] fp32 -> hi/lo bf16 A-fragments for 16x16x32 MFMA.
__global__ void k_prepwf(const float* __restrict__ W, unsigned short* __restrict__ out,
                         int ksteps){
  int id = blockIdx.x*blockDim.x + threadIdx.x;
  if (id >= ksteps*8*64) return;
  int lane = id & 63;
  int mfrag = (id>>6) & 7;
  int kstep = id >> 9;
  int col = mfrag*16 + (lane&15);
  int k0 = kstep*32 + (lane>>4)*8;
  unsigned short* oh = out + (size_t)(((kstep*8+mfrag)*2+0)*64 + lane)*8;
  unsigned short* ol = out + (size_t)(((kstep*8+mfrag)*2+1)*64 + lane)*8;
  #pragma unroll
  for (int j=0;j<8;j++){
    float w = W[(size_t)(k0+j)*128 + col];
    unsigned h16 = bfr_(w);
    float hf = __uint_as_float(h16<<16);
    oh[j] = (unsigned short)h16;
    ol[j] = (unsigned short)bfr_(w - hf);
  }
}

// proj via MFMA bf16x3: h = relu(x @ Wsel + bsel). wave = 16 nodes x 128 ch.
__global__ __launch_bounds__(256) void k_projm(
    const float* __restrict__ x, const int* __restrict__ em,
    const unsigned short* __restrict__ WeF, const float* __restrict__ be,
    const unsigned short* __restrict__ WfF, const float* __restrict__ bf,
    float* __restrict__ h, unsigned int* __restrict__ hb, int N)
{
  int t = threadIdx.x;
  int lane = t & 63;
  int base = (blockIdx.x*4 + (t>>6))*16;
  if (base >= N) return;
  int node = base + (lane & 15);
  int nodeL = min(node, N-1);
  int ko = lane >> 4;

  f32x4 accE[8], accF[8];
  #pragma unroll
  for (int mf=0;mf<8;mf++){ accE[mf]=(f32x4){0.f,0.f,0.f,0.f}; accF[mf]=(f32x4){0.f,0.f,0.f,0.f}; }

  const bf16x8* we = reinterpret_cast<const bf16x8*>(WeF);
  const bf16x8* wf = reinterpret_cast<const bf16x8*>(WfF);

  for (int kstep=0;kstep<8;kstep++){
    const float4* xr = reinterpret_cast<const float4*>(x + (size_t)nodeL*D + kstep*32 + ko*8);
    float4 v0 = xr[0], v1 = xr[1];
    uint4 hiu, lou;
    split2(v0.x, v0.y, hiu.x, lou.x);
    split2(v0.z, v0.w, hiu.y, lou.y);
    split2(v1.x, v1.y, hiu.z, lou.z);
    split2(v1.z, v1.w, hiu.w, lou.w);
    bf16x8 Bhi = *reinterpret_cast<bf16x8*>(&hiu);
    bf16x8 Blo = *reinterpret_cast<bf16x8*>(&lou);
    #pragma unroll
    for (int mf=0;mf<8;mf++){
      int fb = (kstep*8+mf)*2;
      bf16x8 aEh = we[(size_t)fb*64 + lane];
      bf16x8 aEl = we[(size_t)(fb+1)*64 + lane];
      accE[mf] = __builtin_amdgcn_mfma_f32_16x16x32_bf16(aEh, Bhi, accE[mf], 0,0,0);
      accE[mf] = __builtin_amdgcn_mfma_f32_16x16x32_bf16(aEh, Blo, accE[mf], 0,0,0);
      accE[mf] = __builtin_amdgcn_mfma_f32_16x16x32_bf16(aEl, Bhi, accE[mf], 0,0,0);
      bf16x8 aFh = wf[(size_t)fb*64 + lane];
      bf16x8 aFl = wf[(size_t)(fb+1)*64 + lane];
      accF[mf] = __builtin_amdgcn_mfma_f32_16x16x32_bf16(aFh, Bhi, accF[mf], 0,0,0);
      accF[mf] = __builtin_amdgcn_mfma_f32_16x16x32_bf16(aFh, Blo, accF[mf], 0,0,0);
      accF[mf] = __builtin_amdgcn_mfma_f32_16x16x32_bf16(aFl, Bhi, accF[mf], 0,0,0);
    }
  }
  if (node >= N) return;
  bool e = em[node] != 0;
  #pragma unroll
  for (int mf=0;mf<8;mf++){
    float sv[4];
    #pragma unroll
    for (int r=0;r<4;r++){
      int ch = mf*16 + ko*4 + r;
      float vE = accE[mf][r] + be[ch];
      float vF = accF[mf][r] + bf[ch];
      sv[r] = fmaxf(e ? vE : vF, 0.f);
    }
    float2* hp = reinterpret_cast<float2*>(h + (size_t)node*H + mf*16 + ko*4);
    hp[0] = make_float2(sv[0], sv[1]);
    hp[1] = make_float2(sv[2], sv[3]);
    unsigned int* hbp = hb + (size_t)node*64 + mf*8 + ko*2;
    hbp[0] = bfr_(sv[0]) | (bfr_(sv[1])<<16);
    hbp[1] = bfr_(sv[2]) | (bfr_(sv[3])<<16);
  }
}

// dual GEMM via MFMA bf16x3: tI = A@WI, tC = A@WC, outputs packed bf16.
__global__ __launch_bounds__(256) void k_gemm2m(
    const float* __restrict__ A,
    const unsigned short* __restrict__ WIf, const unsigned short* __restrict__ WCf,
    unsigned int* __restrict__ tIb, unsigned int* __restrict__ tCb, int N)
{
  int t = threadIdx.x;
  int lane = t & 63;
  int base = (blockIdx.x*4 + (t>>6))*16;
  if (base >= N) return;
  int node = base + (lane & 15);
  int nodeL = min(node, N-1);
  int ko = lane >> 4;

  f32x4 accI[8], accC[8];
  #pragma unroll
  for (int mf=0;mf<8;mf++){ accI[mf]=(f32x4){0.f,0.f,0.f,0.f}; accC[mf]=(f32x4){0.f,0.f,0.f,0.f}; }

  const bf16x8* wi = reinterpret_cast<const bf16x8*>(WIf);
  const bf16x8* wc = reinterpret_cast<const bf16x8*>(WCf);

  for (int kstep=0;kstep<4;kstep++){
    const float4* ar = reinterpret_cast<const float4*>(A + (size_t)nodeL*H + kstep*32 + ko*8);
    float4 v0 = ar[0], v1 = ar[1];
    uint4 hiu, lou;
    split2(v0.x, v0.y, hiu.x, lou.x);
    split2(v0.z, v0.w, hiu.y, lou.y);
    split2(v1.x, v1.y, hiu.z, lou.z);
    split2(v1.z, v1.w, hiu.w, lou.w);
    bf16x8 Bhi = *reinterpret_cast<bf16x8*>(&hiu);
    bf16x8 Blo = *reinterpret_cast<bf16x8*>(&lou);
    #pragma unroll
    for (int mf=0;mf<8;mf++){
      int fb = (kstep*8+mf)*2;
      bf16x8 aIh = wi[(size_t)fb*64 + lane];
      bf16x8 aIl = wi[(size_t)(fb+1)*64 + lane];
      accI[mf] = __builtin_amdgcn_mfma_f32_16x16x32_bf16(aIh, Bhi, accI[mf], 0,0,0);
      accI[mf] = __builtin_amdgcn_mfma_f32_16x16x32_bf16(aIh, Blo, accI[mf], 0,0,0);
      accI[mf] = __builtin_amdgcn_mfma_f32_16x16x32_bf16(aIl, Bhi, accI[mf], 0,0,0);
      bf16x8 aCh = wc[(size_t)fb*64 + lane];
      bf16x8 aCl = wc[(size_t)(fb+1)*64 + lane];
      accC[mf] = __builtin_amdgcn_mfma_f32_16x16x32_bf16(aCh, Bhi, accC[mf], 0,0,0);
      accC[mf] = __builtin_amdgcn_mfma_f32_16x16x32_bf16(aCh, Blo, accC[mf], 0,0,0);
      accC[mf] = __builtin_amdgcn_mfma_f32_16x16x32_bf16(aCl, Bhi, accC[mf], 0,0,0);
    }
  }
  if (node >= N) return;
  #pragma unroll
  for (int mf=0;mf<8;mf++){
    unsigned int* ti = tIb + (size_t)node*64 + mf*8 + ko*2;
    unsigned int* tc = tCb + (size_t)node*64 + mf*8 + ko*2;
    ti[0] = bfr_(accI[mf][0]) | (bfr_(accI[mf][1])<<16);
    ti[1] = bfr_(accI[mf][2]) | (bfr_(accI[mf][3])<<16);
    tc[0] = bfr_(accC[mf][0]) | (bfr_(accC[mf][1])<<16);
    tc[1] = bfr_(accC[mf][2]) | (bfr_(accC[mf][3])<<16);
  }
}

// ---- CSR build ----
__global__ void k_hist(const int* __restrict__ ei, int* __restrict__ cnt, int E){
  int e = blockIdx.x*blockDim.x + threadIdx.x;
  if (e < E) atomicAdd(cnt + ei[E+e], 1);
}

__global__ __launch_bounds__(1024) void k_scan(const int* __restrict__ cnt,
                                               int* __restrict__ start, int N){
  __shared__ int sm[1024];
  int t = threadIdx.x;
  int chunk = (N + 1023)/1024;
  int i0 = t*chunk, i1 = min(i0+chunk, N);
  int s = 0;
  for (int i=i0;i<i1;i++) s += cnt[i];
  sm[t] = s; __syncthreads();
  for (int d=1; d<1024; d<<=1){
    int v = (t>=d)? sm[t-d] : 0;
    __syncthreads();
    sm[t] += v;
    __syncthreads();
  }
  int base = (t==0)? 0 : sm[t-1];
  for (int i=i0;i<i1;i++){ start[i] = base; base += cnt[i]; }
  if (t == 1023) start[N] = base;
}

__global__ void k_fill2(const int* __restrict__ ei, const int* __restrict__ em,
                        const float* __restrict__ ew,
                        const int* __restrict__ start, int* __restrict__ wcnt,
                        int* __restrict__ csr_sc, int* __restrict__ csr_d,
                        float* __restrict__ csr_w, int E){
  int e = blockIdx.x*blockDim.x + threadIdx.x;
  if (e >= E) return;
  int s = ei[e], d = ei[E+e];
  int chan = (em[s] == em[d]) ? 0 : 1;
  int pos = start[d] + atomicAdd(wcnt + d, 1);
  csr_sc[pos] = (s<<1) | chan;
  csr_d[pos] = d;
  csr_w[pos] = ew[e];
}

// W1 (129x64 fp32) -> bf16 B-fragments for 16x16x32 MFMA.
__global__ void k_prepw(const float* __restrict__ W1, unsigned short* __restrict__ W1b){
  int t = threadIdx.x;
  for (int it=0; it<4; it++){
    int le = it*256 + t;
    int f = le >> 6, lane = le & 63;
    int kstep = f >> 2, n = f & 3;
    int col = n*16 + (lane & 15);
    int k0 = kstep*32 + ((lane>>4)&3)*8;
    unsigned short* op = W1b + (size_t)le*8;
    #pragma unroll
    for (int j=0;j<8;j++)
      op[j] = (unsigned short)bfr_(W1[(size_t)(k0+j)*64 + col]);
  }
}

// per-edge MLP gate via MFMA. wave = 16 edges; K=128, N=64.
__global__ __launch_bounds__(256) void k_edgem(
    const unsigned int* __restrict__ hb,
    const int* __restrict__ csr_sc, const int* __restrict__ csr_d,
    const float* __restrict__ csr_w, const unsigned short* __restrict__ W1b,
    const float* __restrict__ W1, const float* __restrict__ b1,
    const float* __restrict__ W2, const float* __restrict__ b2,
    float* __restrict__ csr_cf,
    float* __restrict__ degI, float* __restrict__ degC, int E)
{
  int t = threadIdx.x;
  int lane = t & 63;
  int base = (blockIdx.x*4 + (t>>6)) * 16;
  if (base >= E) return;

  bf16x8 bfrag[16];
  const bf16x8* wb = reinterpret_cast<const bf16x8*>(W1b);
  #pragma unroll
  for (int f=0; f<16; f++) bfrag[f] = wb[f*64 + lane];

  int e = min(base + (lane & 15), E-1);
  int s = csr_sc[e] >> 1;
  int d = csr_d[e];
  const uint4* hsp = reinterpret_cast<const uint4*>(hb + (size_t)s*64);
  const uint4* hdp = reinterpret_cast<const uint4*>(hb + (size_t)d*64);
  int ko = lane >> 4;

  f32x4 acc[4];
  #pragma unroll
  for (int n=0;n<4;n++) acc[n] = (f32x4){0.f,0.f,0.f,0.f};

  #pragma unroll
  for (int kstep=0;kstep<4;kstep++){
    uint4 us = hsp[kstep*4 + ko];
    uint4 ud = hdp[kstep*4 + ko];
    uint4 pa;
    pa.x = pair_df(us.x, ud.x);
    pa.y = pair_df(us.y, ud.y);
    pa.z = pair_df(us.z, ud.z);
    pa.w = pair_df(us.w, ud.w);
    bf16x8 a = *reinterpret_cast<bf16x8*>(&pa);
    #pragma unroll
    for (int n=0;n<4;n++)
      acc[n] = __builtin_amdgcn_mfma_f32_16x16x32_bf16(a, bfrag[kstep*4+n], acc[n], 0,0,0);
  }

  int colbase = lane & 15;
  float w1l[4], b1v[4], w2v[4];
  #pragma unroll
  for (int n=0;n<4;n++){
    int col = n*16 + colbase;
    w1l[n] = W1[(size_t)128*64 + col];
    b1v[n] = b1[col];
    w2v[n] = W2[col];
  }
  float wgtr[4];
  #pragma unroll
  for (int r=0;r<4;r++)
    wgtr[r] = csr_w[min(base + (lane>>4)*4 + r, E-1)];

  float part[4] = {0.f,0.f,0.f,0.f};
  #pragma unroll
  for (int n=0;n<4;n++){
    #pragma unroll
    for (int r=0;r<4;r++){
      float v = fmaxf(acc[n][r] + fmaf(wgtr[r], w1l[n], b1v[n]), 0.f);
      part[r] = fmaf(v, w2v[n], part[r]);
    }
  }
  #pragma unroll
  for (int m=1;m<16;m<<=1){
    #pragma unroll
    for (int r=0;r<4;r++) part[r] += __shfl_xor(part[r], m, 64);
  }

  if ((lane & 15) == 0){
    float bb2 = b2[0];
    #pragma unroll
    for (int r=0;r<4;r++){
      int ee = base + (lane>>4)*4 + r;
      if (ee < E){
        float g = sigmoidf_(part[r] + bb2);
        g = fminf(fmaxf(g, 0.2f), 1.2f);
        float ehat = wgtr[r] * g;
        csr_cf[ee] = ehat;
        int sc2 = csr_sc[ee];
        atomicAdd(((sc2&1) ? degC : degI) + csr_d[ee], ehat);
      }
    }
  }
}

__global__ void k_dinv(const float* __restrict__ degI, const float* __restrict__ degC,
                       float* dinvI, float* dinvC, int N){
  int i = blockIdx.x*blockDim.x + threadIdx.x;
  if (i < N){
    dinvI[i] = rsqrtf(1.f + degI[i]);
    dinvC[i] = rsqrtf(1.f + degC[i]);
  }
}

__global__ void k_scale(const int* __restrict__ csr_sc, const int* __restrict__ csr_d,
                        const float* __restrict__ dinvI, const float* __restrict__ dinvC,
                        float* __restrict__ csr_cf, int E){
  int k = blockIdx.x*blockDim.x + threadIdx.x;
  if (k >= E) return;
  int sc = csr_sc[k];
  int s = sc>>1;
  int d = csr_d[k];
  const float* dv = (sc&1) ? dinvC : dinvI;
  csr_cf[k] *= dv[s]*dv[d];
}

// one wave per dst node: gather bf16 CSR messages + fused self-loop/bias epilogue.
__global__ __launch_bounds__(256) void k_aggrb(
    const unsigned int* __restrict__ tIb, const unsigned int* __restrict__ tCb,
    const int* __restrict__ start, const int* __restrict__ csr_sc,
    const float* __restrict__ csr_cf,
    const float* __restrict__ dinvI, const float* __restrict__ dinvC,
    const float* __restrict__ bI, const float* __restrict__ bC,
    const float* __restrict__ relg, int l,
    float* __restrict__ h, int N)
{
  int lane = threadIdx.x & 63;
  int d = blockIdx.x*4 + (threadIdx.x>>6);
  if (d >= N) return;
  float sig = sigmoidf_(relg[l]);
  int k0 = start[d], k1 = start[d+1];
  float ax=0.f, ay=0.f;
  for (int k=k0;k<k1;k++){
    int sc = csr_sc[k];
    float cf = csr_cf[k];
    int src = sc>>1;
    const unsigned int* tb = (sc&1) ? tCb : tIb;
    float ce = (sc&1) ? sig*cf : cf;
    unsigned v = tb[(size_t)src*64 + lane];
    ax = fmaf(ce, __uint_as_float(v<<16), ax);
    ay = fmaf(ce, __uint_as_float(v & 0xffff0000u), ay);
  }
  float diI = dinvI[d], diC = dinvC[d];
  float rI = diI*diI, rC = diC*diC;
  unsigned vi = tIb[(size_t)d*64 + lane];
  unsigned vc = tCb[(size_t)d*64 + lane];
  int off = lane*2;
  float ox = fmaf(__uint_as_float(vi<<16), rI, bI[off])
           + sig*fmaf(__uint_as_float(vc<<16), rC, bC[off]) + ax;
  float oy = fmaf(__uint_as_float(vi & 0xffff0000u), rI, bI[off+1])
           + sig*fmaf(__uint_as_float(vc & 0xffff0000u), rC, bC[off+1]) + ay;
  *reinterpret_cast<float2*>(h + (size_t)d*H + off) = make_float2(ox, oy);
}

__global__ __launch_bounds__(128) void k_stats(const float* __restrict__ h,
    float* __restrict__ bnsum, float* __restrict__ bnsq, int N, int nper)
{
  int j = threadIdx.x;
  int n0 = blockIdx.x*nper, n1 = min(n0+nper, N);
  if (n0 >= N) return;
  float sl=0.f, sq=0.f;
  for (int n=n0;n<n1;n++){
    float v = h[(size_t)n*H+j];
    sl += v; sq = fmaf(v,v,sq);
  }
  atomicAdd(bnsum+j, sl); atomicAdd(bnsq+j, sq);
}

__global__ void k_bn(float* __restrict__ h, const float* __restrict__ bnsum,
                     const float* __restrict__ bnsq,
                     const float* __restrict__ gamma, const float* __restrict__ beta,
                     float invN, int NH)
{
  int i = blockIdx.x*blockDim.x + threadIdx.x;
  if (i >= NH) return;
  int j = i & (H-1);
  float mu = bnsum[j]*invN;
  float var = bnsq[j]*invN - mu*mu;
  float r = rsqrtf(var + 1e-5f);
  h[i] = fmaxf(fmaf(gamma[j], (h[i]-mu)*r, beta[j]), 0.f);
}

// pool with BN+relu applied on the fly (layer-2 fusion)
__global__ __launch_bounds__(128) void k_poolbn(
    const float* __restrict__ h, const int* __restrict__ batch, const int* __restrict__ em,
    const float* __restrict__ bnsum, const float* __restrict__ bnsq,
    const float* __restrict__ gamma, const float* __restrict__ beta, float invN,
    float* __restrict__ sumE, float* __restrict__ sumF,
    float* __restrict__ cntE, float* __restrict__ cntF, int N, int nper)
{
  int j = threadIdx.x;
  int n0 = blockIdx.x*nper, n1 = min(n0+nper, N);
  if (n0 >= N) return;
  float mu = bnsum[j]*invN;
  float var = bnsq[j]*invN - mu*mu;
  float rr = rsqrtf(var + 1e-5f);
  float ga = gamma[j], be = beta[j];
  float aE=0.f, aF=0.f, ce=0.f, cfc=0.f;
  int cg = batch[n0];
  for (int n=n0;n<n1;n++){
    int g = batch[n];
    if (g != cg){
      atomicAdd(sumE+(size_t)cg*H+j, aE);
      atomicAdd(sumF+(size_t)cg*H+j, aF);
      if (j==0){ atomicAdd(cntE+cg, ce); atomicAdd(cntF+cg, cfc); }
      aE=aF=ce=cfc=0.f; cg=g;
    }
    float v = fmaxf(fmaf(ga, (h[(size_t)n*H+j]-mu)*rr, be), 0.f);
    bool eb = em[n] != 0;
    if (eb) aE += v; else aF += v;
    if (j==0){ if (eb) ce += 1.f; else cfc += 1.f; }
  }
  atomicAdd(sumE+(size_t)cg*H+j, aE);
  atomicAdd(sumF+(size_t)cg*H+j, aF);
  if (j==0){ atomicAdd(cntE+cg, ce); atomicAdd(cntF+cg, cfc); }
}

__device__ __forceinline__ float blockReduceSum(float v, float* red){
  int t = threadIdx.x;
  red[t] = v; __syncthreads();
  #pragma unroll
  for (int s=64;s>0;s>>=1){ if (t<s) red[t]+=red[t+s]; __syncthreads(); }
  float r = red[0]; __syncthreads();
  return r;
}

__global__ __launch_bounds__(128) void k_head(
    const float* __restrict__ sumE, const float* __restrict__ sumF,
    const float* __restrict__ cntE, const float* __restrict__ cntF,
    const float* __restrict__ coW1, const float* __restrict__ cob1,
    const float* __restrict__ coW2, const float* __restrict__ cob2,
    const float* __restrict__ gW1, const float* __restrict__ gb1,
    const float* __restrict__ gW2, const float* __restrict__ gb2,
    const float* __restrict__ cW1, const float* __restrict__ cb1,
    const float* __restrict__ cW2, const float* __restrict__ cb2,
    const float* __restrict__ peW1, const float* __restrict__ peb1,
    const float* __restrict__ peW2, const float* __restrict__ peb2,
    const float* __restrict__ pfW1, const float* __restrict__ pfb1,
    const float* __restrict__ pfW2, const float* __restrict__ pfb2,
    float* __restrict__ out, int G)
{
  int g = blockIdx.x, j = threadIdx.x;
  __shared__ float sh[384];
  __shared__ float red[128];
  __shared__ float hfin[128], buf[128];
  float cE = cntE[g], cF = cntF[g];
  float se = sumE[(size_t)g*H+j], sf = sumF[(size_t)g*H+j];
  float he = se/fmaxf(cE,1.f), hf = sf/fmaxf(cF,1.f);
  float hg = (se+sf)/fmaxf(cE+cF,1.f);
  sh[j]=he; sh[128+j]=hf; sh[256+j]=he*hf;
  __syncthreads();
  float a = cob1[j];
  for (int k=0;k<384;k++) a = fmaf(sh[k], coW1[k*H+j], a);
  a = fmaxf(a, 0.f);
  float r0 = blockReduceSum(a*coW2[2*j],   red);
  float r1 = blockReduceSum(a*coW2[2*j+1], red);
  float al0 = sigmoidf_(r0 + cob2[0]);
  float al1 = sigmoidf_(r1 + cob2[1]);
  float asum = al0+al1+1e-6f; al0/=asum; al1/=asum;
  float hc = al0*he + al1*hf;
  __syncthreads();
  sh[j]=hc; sh[128+j]=hg;
  __syncthreads();
  float gg = gb1[j];
  for (int k=0;k<256;k++) gg = fmaf(sh[k], gW1[k*H+j], gg);
  gg = fmaxf(gg, 0.f);
  float gt = sigmoidf_(blockReduceSum(gg*gW2[j], red) + gb2[0]);
  float hfj = gt*hc + (1.f-gt)*hg;
  hfin[j] = hfj;
  __syncthreads();
  float c1v = 0.f;
  if (j < 64){
    float c1 = cb1[j];
    for (int k=0;k<128;k++) c1 = fmaf(hfin[k], cW1[k*64+j], c1);
    c1v = fmaxf(c1, 0.f);
  }
  float l0 = blockReduceSum(j<64 ? c1v*cW2[2*j]   : 0.f, red);
  float l1 = blockReduceSum(j<64 ? c1v*cW2[2*j+1] : 0.f, red);
  if (j==0){ out[(size_t)g*2] = l0 + cb2[0]; out[(size_t)g*2+1] = l1 + cb2[1]; }
  // z_e
  buf[j] = he; __syncthreads();
  float q = peb1[j];
  for (int k=0;k<128;k++) q = fmaf(buf[k], peW1[k*H+j], q);
  q = fmaxf(q, 0.f);
  __syncthreads(); sh[j] = q; __syncthreads();
  float z = peb2[j];
  for (int k=0;k<128;k++) z = fmaf(sh[k], peW2[k*H+j], z);
  float nr = sqrtf(blockReduceSum(z*z, red));
  out[(size_t)G*2 + (size_t)g*H + j] = z / fmaxf(nr, 1e-12f);
  // z_f
  __syncthreads(); buf[j] = hf; __syncthreads();
  float q2 = pfb1[j];
  for (int k=0;k<128;k++) q2 = fmaf(buf[k], pfW1[k*H+j], q2);
  q2 = fmaxf(q2, 0.f);
  __syncthreads(); sh[j] = q2; __syncthreads();
  float z2 = pfb2[j];
  for (int k=0;k<128;k++) z2 = fmaf(sh[k], pfW2[k*H+j], z2);
  float nr2 = sqrtf(blockReduceSum(z2*z2, red));
  out[(size_t)G*2 + (size_t)G*H + (size_t)g*H + j] = z2 / fmaxf(nr2, 1e-12f);
}

extern "C" void kernel_launch(void* const* d_in, const int* in_sizes, int n_in,
                              void* d_out, int out_size, void* d_ws, size_t ws_size,
                              hipStream_t stream)
{
  const float* x    = (const float*)d_in[0];
  const int*   ei   = (const int*)d_in[1];
  const float* ew   = (const float*)d_in[2];
  const int*   batch= (const int*)d_in[3];
  const int*   em   = (const int*)d_in[4];
  const float* eegW = (const float*)d_in[6];  const float* eegB = (const float*)d_in[7];
  const float* fnW  = (const float*)d_in[8];  const float* fnB  = (const float*)d_in[9];
  const float* eW1  = (const float*)d_in[10]; const float* eb1  = (const float*)d_in[11];
  const float* eW2  = (const float*)d_in[12]; const float* eb2  = (const float*)d_in[13];
  const float* cIW  = (const float*)d_in[14]; const float* cIb  = (const float*)d_in[15];
  const float* cCW  = (const float*)d_in[16]; const float* cCb  = (const float*)d_in[17];
  const float* relg = (const float*)d_in[18];
  const float* bng  = (const float*)d_in[19]; const float* bnb  = (const float*)d_in[20];
  const float* coW1 = (const float*)d_in[21]; const float* cob1 = (const float*)d_in[22];
  const float* coW2 = (const float*)d_in[23]; const float* cob2 = (const float*)d_in[24];
  const float* gW1  = (const float*)d_in[25]; const float* gb1  = (const float*)d_in[26];
  const float* gW2  = (const float*)d_in[27]; const float* gb2  = (const float*)d_in[28];
  const float* cW1  = (const float*)d_in[29]; const float* cb1  = (const float*)d_in[30];
  const float* cW2  = (const float*)d_in[31]; const float* cb2  = (const float*)d_in[32];
  const float* peW1 = (const float*)d_in[33]; const float* peb1 = (const float*)d_in[34];
  const float* peW2 = (const float*)d_in[35]; const float* peb2 = (const float*)d_in[36];
  const float* pfW1 = (const float*)d_in[37]; const float* pfb1 = (const float*)d_in[38];
  const float* pfW2 = (const float*)d_in[39]; const float* pfb2 = (const float*)d_in[40];
  float* out = (float*)d_out;

  int N = in_sizes[0] / D;           // 50000
  int E = in_sizes[2];               // 800000
  int G = out_size / (2 + 2*H);      // 500
  int NH = N*H;

  float* p = (float*)d_ws;
  float* h    = p; p += (size_t)NH;
  float* tI   = p; p += (size_t)NH;   // overlays: hb (pre-loop) and tIb (loop), both bf16
  float* tC   = p; p += (size_t)NH;   // overlay: tCb
  float* csr_cf = p; p += E;
  float* csr_w  = p; p += E;
  int* csr_sc = (int*)p; p += E;
  int* csr_d  = (int*)p; p += E;
  int* start  = (int*)p; p += (N+1);
  int* cnt    = (int*)p; p += N;      // cnt, wcnt, degI, degC contiguous -> one memset
  int* wcnt   = (int*)p; p += N;
  float* degI = p; p += N;
  float* degC = p; p += N;
  float* dinvI= p; p += N;
  float* dinvC= p; p += N;
  float* bnsum= p; p += H;            // bnsum+bnsq contiguous
  float* bnsq = p; p += H;
  float* sumE = p; p += (size_t)G*H;  // sumE..cntF contiguous
  float* sumF = p; p += (size_t)G*H;
  float* cntE = p; p += G;
  float* cntF = p; p += G;
  unsigned short* W1b = (unsigned short*)p; p += 4096;   // 8192 bf16 = 16 KB
  unsigned short* WeF = (unsigned short*)p; p += 32768;  // 128 KB
  unsigned short* WfF = (unsigned short*)p; p += 32768;  // 128 KB
  unsigned short* WIf0= (unsigned short*)p; p += 16384;  // 64 KB
  unsigned short* WCf0= (unsigned short*)p; p += 16384;
  unsigned short* WIf1= (unsigned short*)p; p += 16384;
  unsigned short* WCf1= (unsigned short*)p; p += 16384;

  unsigned int* hb  = (unsigned int*)tI;  // bf16 h, used only before layer loop
  unsigned int* tIb = (unsigned int*)tI;  // bf16 messages (loop)
  unsigned int* tCb = (unsigned int*)tC;

  int mmBlocks = ((N+15)/16 + 3)/4;   // 16 nodes/wave, 4 waves/block
  int statBlocks = 1024;
  int nper_stat = (N + statBlocks - 1)/statBlocks;
  int poolBlocks = (N + 31)/32;

  hipMemsetAsync(cnt, 0, (size_t)4*N*sizeof(int), stream);  // cnt,wcnt,degI,degC
  k_hist<<<(E+255)/256,256,0,stream>>>(ei, cnt, E);
  k_scan<<<1,1024,0,stream>>>(cnt, start, N);
  k_fill2<<<(E+255)/256,256,0,stream>>>(ei, em, ew, start, wcnt,
                                        csr_sc, csr_d, csr_w, E);
  k_prepw<<<1,256,0,stream>>>(eW1, W1b);
  k_prepwf<<<16,256,0,stream>>>(eegW, WeF, 8);
  k_prepwf<<<16,256,0,stream>>>(fnW,  WfF, 8);
  k_prepwf<<<8,256,0,stream>>>(cIW,          WIf0, 4);
  k_prepwf<<<8,256,0,stream>>>(cCW,          WCf0, 4);
  k_prepwf<<<8,256,0,stream>>>(cIW + 16384,  WIf1, 4);
  k_prepwf<<<8,256,0,stream>>>(cCW + 16384,  WCf1, 4);

  k_projm<<<mmBlocks,256,0,stream>>>(x, em, WeF, eegB, WfF, fnB, h, hb, N);
  k_edgem<<<(E+63)/64,256,0,stream>>>(hb, csr_sc, csr_d, csr_w, W1b,
                                      eW1, eb1, eW2, eb2, csr_cf, degI, degC, E);
  k_dinv<<<(N+255)/256,256,0,stream>>>(degI,degC,dinvI,dinvC,N);
  k_scale<<<(E+255)/256,256,0,stream>>>(csr_sc, csr_d, dinvI, dinvC, csr_cf, E);

  for (int l=0;l<2;l++){
    k_gemm2m<<<mmBlocks,256,0,stream>>>(h, l ? WIf1 : WIf0, l ? WCf1 : WCf0,
                                        tIb, tCb, N);
    k_aggrb<<<(N+3)/4,256,0,stream>>>(tIb, tCb, start, csr_sc, csr_cf,
                                      dinvI, dinvC, cIb+(size_t)l*H,
                                      cCb+(size_t)l*H, relg, l, h, N);
    hipMemsetAsync(bnsum, 0, 2*H*sizeof(float), stream);
    k_stats<<<statBlocks,128,0,stream>>>(h, bnsum, bnsq, N, nper_stat);
    if (l == 0){
      k_bn<<<(NH+255)/256,256,0,stream>>>(h, bnsum, bnsq,
                                          bng, bnb, 1.0f/(float)N, NH);
    }
  }

  hipMemsetAsync(sumE, 0, ((size_t)2*G*H + 2*G)*sizeof(float), stream);
  k_poolbn<<<poolBlocks,128,0,stream>>>(h, batch, em, bnsum, bnsq,
                                        bng+(size_t)H, bnb+(size_t)H, 1.0f/(float)N,
                                        sumE, sumF, cntE, cntF, N, 32);
  k_head<<<G,128,0,stream>>>(sumE,sumF,cntE,cntF,
                             coW1,cob1,coW2,cob2, gW1,gb1,gW2,gb2,
                             cW1,cb1,cW2,cb2, peW1,peb1,peW2,peb2,
                             pfW1,pfb1,pfW2,pfb2, out, G);
}

// Round 9
// 786.148 us; speedup vs baseline: 2.9431x; 1.0005x over previous
//
#include <hip/hip_runtime.h>
#include <math.h>

#define H 128
#define D 256

typedef __attribute__((ext_vector_type(8))) short bf16x8;
typedef __attribute__((ext_vector_type(4))) float f32x4;

__device__ __forceinline__ float sigmoidf_(float x){ return 1.0f/(1.0f+__expf(-x)); }

// RNE float->bf16 (as uint in low 16 bits)
__device__ __forceinline__ unsigned int bfr_(float f){
  unsigned int u = __float_as_uint(f);
  return (u + 0x7fffu + ((u>>16)&1u)) >> 16;
}

// split a,b into packed bf16 hi / lo words (2 bf16 each)
__device__ __forceinline__ void split2(float a, float b, unsigned &hi, unsigned &lo){
  unsigned ha = bfr_(a), hb2 = bfr_(b);
  float fa = __uint_as_float(ha<<16), fb = __uint_as_float(hb2<<16);
  unsigned la = bfr_(a - fa), lb = bfr_(b - fb);
  hi = ha | (hb2<<16); lo = la | (lb<<16);
}

// pack trunc-bf16(|a0-b0|), trunc-bf16(|a1-b1|) into one uint via v_perm
__device__ __forceinline__ unsigned pair_dft(unsigned a, unsigned b){
  float a0 = __uint_as_float(a<<16), a1 = __uint_as_float(a & 0xffff0000u);
  float b0 = __uint_as_float(b<<16), b1 = __uint_as_float(b & 0xffff0000u);
  unsigned d0 = __float_as_uint(fabsf(a0-b0));
  unsigned d1 = __float_as_uint(fabsf(a1-b1));
  return __builtin_amdgcn_perm(d1, d0, 0x07060302);  // {d1.b3,d1.b2,d0.b3,d0.b2}
}

// W [K x 128] fp32 -> hi/lo bf16 A-fragments for 16x16x32 MFMA.
__global__ void k_prepwf(const float* __restrict__ W, unsigned short* __restrict__ out,
                         int ksteps){
  int id = blockIdx.x*blockDim.x + threadIdx.x;
  if (id >= ksteps*8*64) return;
  int lane = id & 63;
  int mfrag = (id>>6) & 7;
  int kstep = id >> 9;
  int col = mfrag*16 + (lane&15);
  int k0 = kstep*32 + (lane>>4)*8;
  unsigned short* oh = out + (size_t)(((kstep*8+mfrag)*2+0)*64 + lane)*8;
  unsigned short* ol = out + (size_t)(((kstep*8+mfrag)*2+1)*64 + lane)*8;
  #pragma unroll
  for (int j=0;j<8;j++){
    float w = W[(size_t)(k0+j)*128 + col];
    unsigned h16 = bfr_(w);
    float hf = __uint_as_float(h16<<16);
    oh[j] = (unsigned short)h16;
    ol[j] = (unsigned short)bfr_(w - hf);
  }
}

// proj via MFMA bf16x3: h = relu(x @ Wsel + bsel). wave = 16 nodes x 128 ch.
__global__ __launch_bounds__(256) void k_projm(
    const float* __restrict__ x, const int* __restrict__ em,
    const unsigned short* __restrict__ WeF, const float* __restrict__ be,
    const unsigned short* __restrict__ WfF, const float* __restrict__ bf,
    float* __restrict__ h, unsigned int* __restrict__ hb, int N)
{
  int t = threadIdx.x;
  int lane = t & 63;
  int base = (blockIdx.x*4 + (t>>6))*16;
  if (base >= N) return;
  int node = base + (lane & 15);
  int nodeL = min(node, N-1);
  int ko = lane >> 4;

  f32x4 accE[8], accF[8];
  #pragma unroll
  for (int mf=0;mf<8;mf++){ accE[mf]=(f32x4){0.f,0.f,0.f,0.f}; accF[mf]=(f32x4){0.f,0.f,0.f,0.f}; }

  const bf16x8* we = reinterpret_cast<const bf16x8*>(WeF);
  const bf16x8* wf = reinterpret_cast<const bf16x8*>(WfF);

  for (int kstep=0;kstep<8;kstep++){
    const float4* xr = reinterpret_cast<const float4*>(x + (size_t)nodeL*D + kstep*32 + ko*8);
    float4 v0 = xr[0], v1 = xr[1];
    uint4 hiu, lou;
    split2(v0.x, v0.y, hiu.x, lou.x);
    split2(v0.z, v0.w, hiu.y, lou.y);
    split2(v1.x, v1.y, hiu.z, lou.z);
    split2(v1.z, v1.w, hiu.w, lou.w);
    bf16x8 Bhi = *reinterpret_cast<bf16x8*>(&hiu);
    bf16x8 Blo = *reinterpret_cast<bf16x8*>(&lou);
    #pragma unroll
    for (int mf=0;mf<8;mf++){
      int fb = (kstep*8+mf)*2;
      bf16x8 aEh = we[(size_t)fb*64 + lane];
      bf16x8 aEl = we[(size_t)(fb+1)*64 + lane];
      accE[mf] = __builtin_amdgcn_mfma_f32_16x16x32_bf16(aEh, Bhi, accE[mf], 0,0,0);
      accE[mf] = __builtin_amdgcn_mfma_f32_16x16x32_bf16(aEh, Blo, accE[mf], 0,0,0);
      accE[mf] = __builtin_amdgcn_mfma_f32_16x16x32_bf16(aEl, Bhi, accE[mf], 0,0,0);
      bf16x8 aFh = wf[(size_t)fb*64 + lane];
      bf16x8 aFl = wf[(size_t)(fb+1)*64 + lane];
      accF[mf] = __builtin_amdgcn_mfma_f32_16x16x32_bf16(aFh, Bhi, accF[mf], 0,0,0);
      accF[mf] = __builtin_amdgcn_mfma_f32_16x16x32_bf16(aFh, Blo, accF[mf], 0,0,0);
      accF[mf] = __builtin_amdgcn_mfma_f32_16x16x32_bf16(aFl, Bhi, accF[mf], 0,0,0);
    }
  }
  if (node >= N) return;
  bool e = em[node] != 0;
  #pragma unroll
  for (int mf=0;mf<8;mf++){
    float sv[4];
    #pragma unroll
    for (int r=0;r<4;r++){
      int ch = mf*16 + ko*4 + r;
      float vE = accE[mf][r] + be[ch];
      float vF = accF[mf][r] + bf[ch];
      sv[r] = fmaxf(e ? vE : vF, 0.f);
    }
    float2* hp = reinterpret_cast<float2*>(h + (size_t)node*H + mf*16 + ko*4);
    hp[0] = make_float2(sv[0], sv[1]);
    hp[1] = make_float2(sv[2], sv[3]);
    unsigned int* hbp = hb + (size_t)node*64 + mf*8 + ko*2;
    hbp[0] = bfr_(sv[0]) | (bfr_(sv[1])<<16);
    hbp[1] = bfr_(sv[2]) | (bfr_(sv[3])<<16);
  }
}

// dual GEMM via MFMA bf16x3: tI = A@WI, tC = A@WC, outputs packed bf16.
__global__ __launch_bounds__(256) void k_gemm2m(
    const float* __restrict__ A,
    const unsigned short* __restrict__ WIf, const unsigned short* __restrict__ WCf,
    unsigned int* __restrict__ tIb, unsigned int* __restrict__ tCb, int N)
{
  int t = threadIdx.x;
  int lane = t & 63;
  int base = (blockIdx.x*4 + (t>>6))*16;
  if (base >= N) return;
  int node = base + (lane & 15);
  int nodeL = min(node, N-1);
  int ko = lane >> 4;

  f32x4 accI[8], accC[8];
  #pragma unroll
  for (int mf=0;mf<8;mf++){ accI[mf]=(f32x4){0.f,0.f,0.f,0.f}; accC[mf]=(f32x4){0.f,0.f,0.f,0.f}; }

  const bf16x8* wi = reinterpret_cast<const bf16x8*>(WIf);
  const bf16x8* wc = reinterpret_cast<const bf16x8*>(WCf);

  for (int kstep=0;kstep<4;kstep++){
    const float4* ar = reinterpret_cast<const float4*>(A + (size_t)nodeL*H + kstep*32 + ko*8);
    float4 v0 = ar[0], v1 = ar[1];
    uint4 hiu, lou;
    split2(v0.x, v0.y, hiu.x, lou.x);
    split2(v0.z, v0.w, hiu.y, lou.y);
    split2(v1.x, v1.y, hiu.z, lou.z);
    split2(v1.z, v1.w, hiu.w, lou.w);
    bf16x8 Bhi = *reinterpret_cast<bf16x8*>(&hiu);
    bf16x8 Blo = *reinterpret_cast<bf16x8*>(&lou);
    #pragma unroll
    for (int mf=0;mf<8;mf++){
      int fb = (kstep*8+mf)*2;
      bf16x8 aIh = wi[(size_t)fb*64 + lane];
      bf16x8 aIl = wi[(size_t)(fb+1)*64 + lane];
      accI[mf] = __builtin_amdgcn_mfma_f32_16x16x32_bf16(aIh, Bhi, accI[mf], 0,0,0);
      accI[mf] = __builtin_amdgcn_mfma_f32_16x16x32_bf16(aIh, Blo, accI[mf], 0,0,0);
      accI[mf] = __builtin_amdgcn_mfma_f32_16x16x32_bf16(aIl, Bhi, accI[mf], 0,0,0);
      bf16x8 aCh = wc[(size_t)fb*64 + lane];
      bf16x8 aCl = wc[(size_t)(fb+1)*64 + lane];
      accC[mf] = __builtin_amdgcn_mfma_f32_16x16x32_bf16(aCh, Bhi, accC[mf], 0,0,0);
      accC[mf] = __builtin_amdgcn_mfma_f32_16x16x32_bf16(aCh, Blo, accC[mf], 0,0,0);
      accC[mf] = __builtin_amdgcn_mfma_f32_16x16x32_bf16(aCl, Bhi, accC[mf], 0,0,0);
    }
  }
  if (node >= N) return;
  #pragma unroll
  for (int mf=0;mf<8;mf++){
    unsigned int* ti = tIb + (size_t)node*64 + mf*8 + ko*2;
    unsigned int* tc = tCb + (size_t)node*64 + mf*8 + ko*2;
    ti[0] = bfr_(accI[mf][0]) | (bfr_(accI[mf][1])<<16);
    ti[1] = bfr_(accI[mf][2]) | (bfr_(accI[mf][3])<<16);
    tc[0] = bfr_(accC[mf][0]) | (bfr_(accC[mf][1])<<16);
    tc[1] = bfr_(accC[mf][2]) | (bfr_(accC[mf][3])<<16);
  }
}

// ---- CSR build ----
__global__ void k_hist(const int* __restrict__ ei, int* __restrict__ cnt, int E){
  int e = blockIdx.x*blockDim.x + threadIdx.x;
  if (e < E) atomicAdd(cnt + ei[E+e], 1);
}

__global__ __launch_bounds__(1024) void k_scan(const int* __restrict__ cnt,
                                               int* __restrict__ start, int N){
  __shared__ int sm[1024];
  int t = threadIdx.x;
  int chunk = (N + 1023)/1024;
  int i0 = t*chunk, i1 = min(i0+chunk, N);
  int s = 0;
  for (int i=i0;i<i1;i++) s += cnt[i];
  sm[t] = s; __syncthreads();
  for (int d=1; d<1024; d<<=1){
    int v = (t>=d)? sm[t-d] : 0;
    __syncthreads();
    sm[t] += v;
    __syncthreads();
  }
  int base = (t==0)? 0 : sm[t-1];
  for (int i=i0;i<i1;i++){ start[i] = base; base += cnt[i]; }
  if (t == 1023) start[N] = base;
}

__global__ void k_fill2(const int* __restrict__ ei, const int* __restrict__ em,
                        const float* __restrict__ ew,
                        const int* __restrict__ start, int* __restrict__ wcnt,
                        int* __restrict__ csr_sc, int* __restrict__ csr_d,
                        float* __restrict__ csr_w, int E){
  int e = blockIdx.x*blockDim.x + threadIdx.x;
  if (e >= E) return;
  int s = ei[e], d = ei[E+e];
  int chan = (em[s] == em[d]) ? 0 : 1;
  int pos = start[d] + atomicAdd(wcnt + d, 1);
  csr_sc[pos] = (s<<1) | chan;
  csr_d[pos] = d;
  csr_w[pos] = ew[e];
}

// W1 (129x64 fp32) -> bf16 B-fragments for 16x16x32 MFMA.
__global__ void k_prepw(const float* __restrict__ W1, unsigned short* __restrict__ W1b){
  int t = threadIdx.x;
  for (int it=0; it<4; it++){
    int le = it*256 + t;
    int f = le >> 6, lane = le & 63;
    int kstep = f >> 2, n = f & 3;
    int col = n*16 + (lane & 15);
    int k0 = kstep*32 + ((lane>>4)&3)*8;
    unsigned short* op = W1b + (size_t)le*8;
    #pragma unroll
    for (int j=0;j<8;j++)
      op[j] = (unsigned short)bfr_(W1[(size_t)(k0+j)*64 + col]);
  }
}

// per-edge MLP gate via MFMA. wave = 32 edges (2 groups of 16); K=128, N=64.
__global__ __launch_bounds__(256) void k_edgem(
    const unsigned int* __restrict__ hb,
    const int* __restrict__ csr_sc, const int* __restrict__ csr_d,
    const float* __restrict__ csr_w, const unsigned short* __restrict__ W1b,
    const float* __restrict__ W1, const float* __restrict__ b1,
    const float* __restrict__ W2, const float* __restrict__ b2,
    float* __restrict__ csr_cf,
    float* __restrict__ degI, float* __restrict__ degC, int E)
{
  int t = threadIdx.x;
  int lane = t & 63;
  int base0 = (blockIdx.x*4 + (t>>6)) * 32;
  if (base0 >= E) return;

  bf16x8 bfrag[16];
  const bf16x8* wb = reinterpret_cast<const bf16x8*>(W1b);
  #pragma unroll
  for (int f=0; f<16; f++) bfrag[f] = wb[f*64 + lane];

  int colbase = lane & 15;
  int ko = lane >> 4;
  float w1l[4], b1v[4], w2v[4];
  #pragma unroll
  for (int n=0;n<4;n++){
    int col = n*16 + colbase;
    w1l[n] = W1[(size_t)128*64 + col];
    b1v[n] = b1[col];
    w2v[n] = W2[col];
  }
  float bb2 = b2[0];

  #pragma unroll
  for (int eg=0; eg<2; eg++){
    int base = base0 + eg*16;
    if (base >= E) break;
    int e = min(base + colbase, E-1);
    int s = csr_sc[e] >> 1;
    int d = csr_d[e];
    const uint4* hsp = reinterpret_cast<const uint4*>(hb + (size_t)s*64);
    const uint4* hdp = reinterpret_cast<const uint4*>(hb + (size_t)d*64);

    f32x4 acc[4];
    #pragma unroll
    for (int n=0;n<4;n++) acc[n] = (f32x4){0.f,0.f,0.f,0.f};

    #pragma unroll
    for (int kstep=0;kstep<4;kstep++){
      uint4 us = hsp[kstep*4 + ko];
      uint4 ud = hdp[kstep*4 + ko];
      uint4 pa;
      pa.x = pair_dft(us.x, ud.x);
      pa.y = pair_dft(us.y, ud.y);
      pa.z = pair_dft(us.z, ud.z);
      pa.w = pair_dft(us.w, ud.w);
      bf16x8 a = *reinterpret_cast<bf16x8*>(&pa);
      #pragma unroll
      for (int n=0;n<4;n++)
        acc[n] = __builtin_amdgcn_mfma_f32_16x16x32_bf16(a, bfrag[kstep*4+n], acc[n], 0,0,0);
    }

    float wgtr[4];
    #pragma unroll
    for (int r=0;r<4;r++)
      wgtr[r] = csr_w[min(base + ko*4 + r, E-1)];

    float part[4] = {0.f,0.f,0.f,0.f};
    #pragma unroll
    for (int n=0;n<4;n++){
      #pragma unroll
      for (int r=0;r<4;r++){
        float v = fmaxf(acc[n][r] + fmaf(wgtr[r], w1l[n], b1v[n]), 0.f);
        part[r] = fmaf(v, w2v[n], part[r]);
      }
    }
    #pragma unroll
    for (int m=1;m<16;m<<=1){
      #pragma unroll
      for (int r=0;r<4;r++) part[r] += __shfl_xor(part[r], m, 64);
    }

    if (colbase == 0){
      #pragma unroll
      for (int r=0;r<4;r++){
        int ee = base + ko*4 + r;
        if (ee < E){
          float g = sigmoidf_(part[r] + bb2);
          g = fminf(fmaxf(g, 0.2f), 1.2f);
          float ehat = wgtr[r] * g;
          csr_cf[ee] = ehat;
          int sc2 = csr_sc[ee];
          atomicAdd(((sc2&1) ? degC : degI) + csr_d[ee], ehat);
        }
      }
    }
  }
}

__global__ void k_dinv(const float* __restrict__ degI, const float* __restrict__ degC,
                       float* dinvI, float* dinvC, int N){
  int i = blockIdx.x*blockDim.x + threadIdx.x;
  if (i < N){
    dinvI[i] = rsqrtf(1.f + degI[i]);
    dinvC[i] = rsqrtf(1.f + degC[i]);
  }
}

__global__ void k_scale(const int* __restrict__ csr_sc, const int* __restrict__ csr_d,
                        const float* __restrict__ dinvI, const float* __restrict__ dinvC,
                        float* __restrict__ csr_cf, int E){
  int k = blockIdx.x*blockDim.x + threadIdx.x;
  if (k >= E) return;
  int sc = csr_sc[k];
  int s = sc>>1;
  int d = csr_d[k];
  const float* dv = (sc&1) ? dinvC : dinvI;
  csr_cf[k] *= dv[s]*dv[d];
}

// one wave per dst node: gather bf16 CSR messages + fused self-loop/bias epilogue.
__global__ __launch_bounds__(256) void k_aggrb(
    const unsigned int* __restrict__ tIb, const unsigned int* __restrict__ tCb,
    const int* __restrict__ start, const int* __restrict__ csr_sc,
    const float* __restrict__ csr_cf,
    const float* __restrict__ dinvI, const float* __restrict__ dinvC,
    const float* __restrict__ bI, const float* __restrict__ bC,
    const float* __restrict__ relg, int l,
    float* __restrict__ h, int N)
{
  int lane = threadIdx.x & 63;
  int d = blockIdx.x*4 + (threadIdx.x>>6);
  if (d >= N) return;
  float sig = sigmoidf_(relg[l]);
  int k0 = start[d], k1 = start[d+1];
  float ax=0.f, ay=0.f;
  for (int k=k0;k<k1;k++){
    int sc = csr_sc[k];
    float cf = csr_cf[k];
    int src = sc>>1;
    const unsigned int* tb = (sc&1) ? tCb : tIb;
    float ce = (sc&1) ? sig*cf : cf;
    unsigned v = tb[(size_t)src*64 + lane];
    ax = fmaf(ce, __uint_as_float(v<<16), ax);
    ay = fmaf(ce, __uint_as_float(v & 0xffff0000u), ay);
  }
  float diI = dinvI[d], diC = dinvC[d];
  float rI = diI*diI, rC = diC*diC;
  unsigned vi = tIb[(size_t)d*64 + lane];
  unsigned vc = tCb[(size_t)d*64 + lane];
  int off = lane*2;
  float ox = fmaf(__uint_as_float(vi<<16), rI, bI[off])
           + sig*fmaf(__uint_as_float(vc<<16), rC, bC[off]) + ax;
  float oy = fmaf(__uint_as_float(vi & 0xffff0000u), rI, bI[off+1])
           + sig*fmaf(__uint_as_float(vc & 0xffff0000u), rC, bC[off+1]) + ay;
  *reinterpret_cast<float2*>(h + (size_t)d*H + off) = make_float2(ox, oy);
}

__global__ __launch_bounds__(128) void k_stats(const float* __restrict__ h,
    float* __restrict__ bnsum, float* __restrict__ bnsq, int N, int nper)
{
  int j = threadIdx.x;
  int n0 = blockIdx.x*nper, n1 = min(n0+nper, N);
  if (n0 >= N) return;
  float sl=0.f, sq=0.f;
  for (int n=n0;n<n1;n++){
    float v = h[(size_t)n*H+j];
    sl += v; sq = fmaf(v,v,sq);
  }
  atomicAdd(bnsum+j, sl); atomicAdd(bnsq+j, sq);
}

__global__ void k_bn(float* __restrict__ h, const float* __restrict__ bnsum,
                     const float* __restrict__ bnsq,
                     const float* __restrict__ gamma, const float* __restrict__ beta,
                     float invN, int NH)
{
  int i = blockIdx.x*blockDim.x + threadIdx.x;
  if (i >= NH) return;
  int j = i & (H-1);
  float mu = bnsum[j]*invN;
  float var = bnsq[j]*invN - mu*mu;
  float r = rsqrtf(var + 1e-5f);
  h[i] = fmaxf(fmaf(gamma[j], (h[i]-mu)*r, beta[j]), 0.f);
}

// pool with BN+relu applied on the fly (layer-2 fusion)
__global__ __launch_bounds__(128) void k_poolbn(
    const float* __restrict__ h, const int* __restrict__ batch, const int* __restrict__ em,
    const float* __restrict__ bnsum, const float* __restrict__ bnsq,
    const float* __restrict__ gamma, const float* __restrict__ beta, float invN,
    float* __restrict__ sumE, float* __restrict__ sumF,
    float* __restrict__ cntE, float* __restrict__ cntF, int N, int nper)
{
  int j = threadIdx.x;
  int n0 = blockIdx.x*nper, n1 = min(n0+nper, N);
  if (n0 >= N) return;
  float mu = bnsum[j]*invN;
  float var = bnsq[j]*invN - mu*mu;
  float rr = rsqrtf(var + 1e-5f);
  float ga = gamma[j], be = beta[j];
  float aE=0.f, aF=0.f, ce=0.f, cfc=0.f;
  int cg = batch[n0];
  for (int n=n0;n<n1;n++){
    int g = batch[n];
    if (g != cg){
      atomicAdd(sumE+(size_t)cg*H+j, aE);
      atomicAdd(sumF+(size_t)cg*H+j, aF);
      if (j==0){ atomicAdd(cntE+cg, ce); atomicAdd(cntF+cg, cfc); }
      aE=aF=ce=cfc=0.f; cg=g;
    }
    float v = fmaxf(fmaf(ga, (h[(size_t)n*H+j]-mu)*rr, be), 0.f);
    bool eb = em[n] != 0;
    if (eb) aE += v; else aF += v;
    if (j==0){ if (eb) ce += 1.f; else cfc += 1.f; }
  }
  atomicAdd(sumE+(size_t)cg*H+j, aE);
  atomicAdd(sumF+(size_t)cg*H+j, aF);
  if (j==0){ atomicAdd(cntE+cg, ce); atomicAdd(cntF+cg, cfc); }
}

__device__ __forceinline__ float blockReduceSum(float v, float* red){
  int t = threadIdx.x;
  red[t] = v; __syncthreads();
  #pragma unroll
  for (int s=64;s>0;s>>=1){ if (t<s) red[t]+=red[t+s]; __syncthreads(); }
  float r = red[0]; __syncthreads();
  return r;
}

__global__ __launch_bounds__(128) void k_head(
    const float* __restrict__ sumE, const float* __restrict__ sumF,
    const float* __restrict__ cntE, const float* __restrict__ cntF,
    const float* __restrict__ coW1, const float* __restrict__ cob1,
    const float* __restrict__ coW2, const float* __restrict__ cob2,
    const float* __restrict__ gW1, const float* __restrict__ gb1,
    const float* __restrict__ gW2, const float* __restrict__ gb2,
    const float* __restrict__ cW1, const float* __restrict__ cb1,
    const float* __restrict__ cW2, const float* __restrict__ cb2,
    const float* __restrict__ peW1, const float* __restrict__ peb1,
    const float* __restrict__ peW2, const float* __restrict__ peb2,
    const float* __restrict__ pfW1, const float* __restrict__ pfb1,
    const float* __restrict__ pfW2, const float* __restrict__ pfb2,
    float* __restrict__ out, int G)
{
  int g = blockIdx.x, j = threadIdx.x;
  __shared__ float sh[384];
  __shared__ float red[128];
  __shared__ float hfin[128], buf[128];
  float cE = cntE[g], cF = cntF[g];
  float se = sumE[(size_t)g*H+j], sf = sumF[(size_t)g*H+j];
  float he = se/fmaxf(cE,1.f), hf = sf/fmaxf(cF,1.f);
  float hg = (se+sf)/fmaxf(cE+cF,1.f);
  sh[j]=he; sh[128+j]=hf; sh[256+j]=he*hf;
  __syncthreads();
  float a = cob1[j];
  for (int k=0;k<384;k++) a = fmaf(sh[k], coW1[k*H+j], a);
  a = fmaxf(a, 0.f);
  float r0 = blockReduceSum(a*coW2[2*j],   red);
  float r1 = blockReduceSum(a*coW2[2*j+1], red);
  float al0 = sigmoidf_(r0 + cob2[0]);
  float al1 = sigmoidf_(r1 + cob2[1]);
  float asum = al0+al1+1e-6f; al0/=asum; al1/=asum;
  float hc = al0*he + al1*hf;
  __syncthreads();
  sh[j]=hc; sh[128+j]=hg;
  __syncthreads();
  float gg = gb1[j];
  for (int k=0;k<256;k++) gg = fmaf(sh[k], gW1[k*H+j], gg);
  gg = fmaxf(gg, 0.f);
  float gt = sigmoidf_(blockReduceSum(gg*gW2[j], red) + gb2[0]);
  float hfj = gt*hc + (1.f-gt)*hg;
  hfin[j] = hfj;
  __syncthreads();
  float c1v = 0.f;
  if (j < 64){
    float c1 = cb1[j];
    for (int k=0;k<128;k++) c1 = fmaf(hfin[k], cW1[k*64+j], c1);
    c1v = fmaxf(c1, 0.f);
  }
  float l0 = blockReduceSum(j<64 ? c1v*cW2[2*j]   : 0.f, red);
  float l1 = blockReduceSum(j<64 ? c1v*cW2[2*j+1] : 0.f, red);
  if (j==0){ out[(size_t)g*2] = l0 + cb2[0]; out[(size_t)g*2+1] = l1 + cb2[1]; }
  // z_e
  buf[j] = he; __syncthreads();
  float q = peb1[j];
  for (int k=0;k<128;k++) q = fmaf(buf[k], peW1[k*H+j], q);
  q = fmaxf(q, 0.f);
  __syncthreads(); sh[j] = q; __syncthreads();
  float z = peb2[j];
  for (int k=0;k<128;k++) z = fmaf(sh[k], peW2[k*H+j], z);
  float nr = sqrtf(blockReduceSum(z*z, red));
  out[(size_t)G*2 + (size_t)g*H + j] = z / fmaxf(nr, 1e-12f);
  // z_f
  __syncthreads(); buf[j] = hf; __syncthreads();
  float q2 = pfb1[j];
  for (int k=0;k<128;k++) q2 = fmaf(buf[k], pfW1[k*H+j], q2);
  q2 = fmaxf(q2, 0.f);
  __syncthreads(); sh[j] = q2; __syncthreads();
  float z2 = pfb2[j];
  for (int k=0;k<128;k++) z2 = fmaf(sh[k], pfW2[k*H+j], z2);
  float nr2 = sqrtf(blockReduceSum(z2*z2, red));
  out[(size_t)G*2 + (size_t)G*H + (size_t)g*H + j] = z2 / fmaxf(nr2, 1e-12f);
}

extern "C" void kernel_launch(void* const* d_in, const int* in_sizes, int n_in,
                              void* d_out, int out_size, void* d_ws, size_t ws_size,
                              hipStream_t stream)
{
  const float* x    = (const float*)d_in[0];
  const int*   ei   = (const int*)d_in[1];
  const float* ew   = (const float*)d_in[2];
  const int*   batch= (const int*)d_in[3];
  const int*   em   = (const int*)d_in[4];
  const float* eegW = (const float*)d_in[6];  const float* eegB = (const float*)d_in[7];
  const float* fnW  = (const float*)d_in[8];  const float* fnB  = (const float*)d_in[9];
  const float* eW1  = (const float*)d_in[10]; const float* eb1  = (const float*)d_in[11];
  const float* eW2  = (const float*)d_in[12]; const float* eb2  = (const float*)d_in[13];
  const float* cIW  = (const float*)d_in[14]; const float* cIb  = (const float*)d_in[15];
  const float* cCW  = (const float*)d_in[16]; const float* cCb  = (const float*)d_in[17];
  const float* relg = (const float*)d_in[18];
  const float* bng  = (const float*)d_in[19]; const float* bnb  = (const float*)d_in[20];
  const float* coW1 = (const float*)d_in[21]; const float* cob1 = (const float*)d_in[22];
  const float* coW2 = (const float*)d_in[23]; const float* cob2 = (const float*)d_in[24];
  const float* gW1  = (const float*)d_in[25]; const float* gb1  = (const float*)d_in[26];
  const float* gW2  = (const float*)d_in[27]; const float* gb2  = (const float*)d_in[28];
  const float* cW1  = (const float*)d_in[29]; const float* cb1  = (const float*)d_in[30];
  const float* cW2  = (const float*)d_in[31]; const float* cb2  = (const float*)d_in[32];
  const float* peW1 = (const float*)d_in[33]; const float* peb1 = (const float*)d_in[34];
  const float* peW2 = (const float*)d_in[35]; const float* peb2 = (const float*)d_in[36];
  const float* pfW1 = (const float*)d_in[37]; const float* pfb1 = (const float*)d_in[38];
  const float* pfW2 = (const float*)d_in[39]; const float* pfb2 = (const float*)d_in[40];
  float* out = (float*)d_out;

  int N = in_sizes[0] / D;           // 50000
  int E = in_sizes[2];               // 800000
  int G = out_size / (2 + 2*H);      // 500
  int NH = N*H;

  float* p = (float*)d_ws;
  float* h    = p; p += (size_t)NH;
  float* tI   = p; p += (size_t)NH;   // overlays: hb (pre-loop) and tIb (loop), both bf16
  float* tC   = p; p += (size_t)NH;   // overlay: tCb
  float* csr_cf = p; p += E;
  float* csr_w  = p; p += E;
  int* csr_sc = (int*)p; p += E;
  int* csr_d  = (int*)p; p += E;
  int* start  = (int*)p; p += (N+1);
  int* cnt    = (int*)p; p += N;      // cnt, wcnt, degI, degC contiguous -> one memset
  int* wcnt   = (int*)p; p += N;
  float* degI = p; p += N;
  float* degC = p; p += N;
  float* dinvI= p; p += N;
  float* dinvC= p; p += N;
  float* bnsum= p; p += H;            // bnsum+bnsq contiguous
  float* bnsq = p; p += H;
  float* sumE = p; p += (size_t)G*H;  // sumE..cntF contiguous
  float* sumF = p; p += (size_t)G*H;
  float* cntE = p; p += G;
  float* cntF = p; p += G;
  unsigned short* W1b = (unsigned short*)p; p += 4096;   // 8192 bf16 = 16 KB
  unsigned short* WeF = (unsigned short*)p; p += 32768;  // 128 KB
  unsigned short* WfF = (unsigned short*)p; p += 32768;  // 128 KB
  unsigned short* WIf0= (unsigned short*)p; p += 16384;  // 64 KB
  unsigned short* WCf0= (unsigned short*)p; p += 16384;
  unsigned short* WIf1= (unsigned short*)p; p += 16384;
  unsigned short* WCf1= (unsigned short*)p; p += 16384;

  unsigned int* hb  = (unsigned int*)tI;  // bf16 h, used only before layer loop
  unsigned int* tIb = (unsigned int*)tI;  // bf16 messages (loop)
  unsigned int* tCb = (unsigned int*)tC;

  int mmBlocks = ((N+15)/16 + 3)/4;   // 16 nodes/wave, 4 waves/block
  int edgeBlocks = (E + 127)/128;     // 32 edges/wave, 4 waves/block
  int statBlocks = 1024;
  int nper_stat = (N + statBlocks - 1)/statBlocks;
  int poolBlocks = (N + 31)/32;

  hipMemsetAsync(cnt, 0, (size_t)4*N*sizeof(int), stream);  // cnt,wcnt,degI,degC
  k_hist<<<(E+255)/256,256,0,stream>>>(ei, cnt, E);
  k_scan<<<1,1024,0,stream>>>(cnt, start, N);
  k_fill2<<<(E+255)/256,256,0,stream>>>(ei, em, ew, start, wcnt,
                                        csr_sc, csr_d, csr_w, E);
  k_prepw<<<1,256,0,stream>>>(eW1, W1b);
  k_prepwf<<<16,256,0,stream>>>(eegW, WeF, 8);
  k_prepwf<<<16,256,0,stream>>>(fnW,  WfF, 8);
  k_prepwf<<<8,256,0,stream>>>(cIW,          WIf0, 4);
  k_prepwf<<<8,256,0,stream>>>(cCW,          WCf0, 4);
  k_prepwf<<<8,256,0,stream>>>(cIW + 16384,  WIf1, 4);
  k_prepwf<<<8,256,0,stream>>>(cCW + 16384,  WCf1, 4);

  k_projm<<<mmBlocks,256,0,stream>>>(x, em, WeF, eegB, WfF, fnB, h, hb, N);
  k_edgem<<<edgeBlocks,256,0,stream>>>(hb, csr_sc, csr_d, csr_w, W1b,
                                       eW1, eb1, eW2, eb2, csr_cf, degI, degC, E);
  k_dinv<<<(N+255)/256,256,0,stream>>>(degI,degC,dinvI,dinvC,N);
  k_scale<<<(E+255)/256,256,0,stream>>>(csr_sc, csr_d, dinvI, dinvC, csr_cf, E);

  for (int l=0;l<2;l++){
    k_gemm2m<<<mmBlocks,256,0,stream>>>(h, l ? WIf1 : WIf0, l ? WCf1 : WCf0,
                                        tIb, tCb, N);
    k_aggrb<<<(N+3)/4,256,0,stream>>>(tIb, tCb, start, csr_sc, csr_cf,
                                      dinvI, dinvC, cIb+(size_t)l*H,
                                      cCb+(size_t)l*H, relg, l, h, N);
    hipMemsetAsync(bnsum, 0, 2*H*sizeof(float), stream);
    k_stats<<<statBlocks,128,0,stream>>>(h, bnsum, bnsq, N, nper_stat);
    if (l == 0){
      k_bn<<<(NH+255)/256,256,0,stream>>>(h, bnsum, bnsq,
                                          bng, bnb, 1.0f/(float)N, NH);
    }
  }

  hipMemsetAsync(sumE, 0, ((size_t)2*G*H + 2*G)*sizeof(float), stream);
  k_poolbn<<<poolBlocks,128,0,stream>>>(h, batch, em, bnsum, bnsq,
                                        bng+(size_t)H, bnb+(size_t)H, 1.0f/(float)N,
                                        sumE, sumF, cntE, cntF, N, 32);
  k_head<<<G,128,0,stream>>>(sumE,sumF,cntE,cntF,
                             coW1,cob1,coW2,cob2, gW1,gb1,gW2,gb2,
                             cW1,cb1,cW2,cb2, peW1,peb1,peW2,peb2,
                             pfW1,pfb1,pfW2,pfb2, out, G);
}

// Round 10
// 693.653 us; speedup vs baseline: 3.3355x; 1.1333x over previous
//
#include <hip/hip_runtime.h>
#include <math.h>

#define H 128
#define D 256

typedef __attribute__((ext_vector_type(8))) short bf16x8;
typedef __attribute__((ext_vector_type(4))) float f32x4;

__device__ __forceinline__ float sigmoidf_(float x){ return 1.0f/(1.0f+__expf(-x)); }

// RNE float->bf16 (as uint in low 16 bits)
__device__ __forceinline__ unsigned int bfr_(float f){
  unsigned int u = __float_as_uint(f);
  return (u + 0x7fffu + ((u>>16)&1u)) >> 16;
}

// split a,b into packed bf16 hi / lo words (2 bf16 each)
__device__ __forceinline__ void split2(float a, float b, unsigned &hi, unsigned &lo){
  unsigned ha = bfr_(a), hb2 = bfr_(b);
  float fa = __uint_as_float(ha<<16), fb = __uint_as_float(hb2<<16);
  unsigned la = bfr_(a - fa), lb = bfr_(b - fb);
  hi = ha | (hb2<<16); lo = la | (lb<<16);
}

// pack trunc-bf16(|a0-b0|), trunc-bf16(|a1-b1|) into one uint via v_perm
__device__ __forceinline__ unsigned pair_dft(unsigned a, unsigned b){
  float a0 = __uint_as_float(a<<16), a1 = __uint_as_float(a & 0xffff0000u);
  float b0 = __uint_as_float(b<<16), b1 = __uint_as_float(b & 0xffff0000u);
  unsigned d0 = __float_as_uint(fabsf(a0-b0));
  unsigned d1 = __float_as_uint(fabsf(a1-b1));
  return __builtin_amdgcn_perm(d1, d0, 0x07060302);  // {d1.b3,d1.b2,d0.b3,d0.b2}
}

// W [K x 128] fp32 -> hi/lo bf16 A-fragments for 16x16x32 MFMA.
__global__ void k_prepwf(const float* __restrict__ W, unsigned short* __restrict__ out,
                         int ksteps){
  int id = blockIdx.x*blockDim.x + threadIdx.x;
  if (id >= ksteps*8*64) return;
  int lane = id & 63;
  int mfrag = (id>>6) & 7;
  int kstep = id >> 9;
  int col = mfrag*16 + (lane&15);
  int k0 = kstep*32 + (lane>>4)*8;
  unsigned short* oh = out + (size_t)(((kstep*8+mfrag)*2+0)*64 + lane)*8;
  unsigned short* ol = out + (size_t)(((kstep*8+mfrag)*2+1)*64 + lane)*8;
  #pragma unroll
  for (int j=0;j<8;j++){
    float w = W[(size_t)(k0+j)*128 + col];
    unsigned h16 = bfr_(w);
    float hf = __uint_as_float(h16<<16);
    oh[j] = (unsigned short)h16;
    ol[j] = (unsigned short)bfr_(w - hf);
  }
}

// proj via MFMA bf16x3: h = relu(x @ Wsel + bsel). wave = 16 nodes x 128 ch.
__global__ __launch_bounds__(256) void k_projm(
    const float* __restrict__ x, const int* __restrict__ em,
    const unsigned short* __restrict__ WeF, const float* __restrict__ be,
    const unsigned short* __restrict__ WfF, const float* __restrict__ bf,
    float* __restrict__ h, unsigned int* __restrict__ hb, int N)
{
  int t = threadIdx.x;
  int lane = t & 63;
  int base = (blockIdx.x*4 + (t>>6))*16;
  if (base >= N) return;
  int node = base + (lane & 15);
  int nodeL = min(node, N-1);
  int ko = lane >> 4;

  f32x4 accE[8], accF[8];
  #pragma unroll
  for (int mf=0;mf<8;mf++){ accE[mf]=(f32x4){0.f,0.f,0.f,0.f}; accF[mf]=(f32x4){0.f,0.f,0.f,0.f}; }

  const bf16x8* we = reinterpret_cast<const bf16x8*>(WeF);
  const bf16x8* wf = reinterpret_cast<const bf16x8*>(WfF);

  for (int kstep=0;kstep<8;kstep++){
    const float4* xr = reinterpret_cast<const float4*>(x + (size_t)nodeL*D + kstep*32 + ko*8);
    float4 v0 = xr[0], v1 = xr[1];
    uint4 hiu, lou;
    split2(v0.x, v0.y, hiu.x, lou.x);
    split2(v0.z, v0.w, hiu.y, lou.y);
    split2(v1.x, v1.y, hiu.z, lou.z);
    split2(v1.z, v1.w, hiu.w, lou.w);
    bf16x8 Bhi = *reinterpret_cast<bf16x8*>(&hiu);
    bf16x8 Blo = *reinterpret_cast<bf16x8*>(&lou);
    #pragma unroll
    for (int mf=0;mf<8;mf++){
      int fb = (kstep*8+mf)*2;
      bf16x8 aEh = we[(size_t)fb*64 + lane];
      bf16x8 aEl = we[(size_t)(fb+1)*64 + lane];
      accE[mf] = __builtin_amdgcn_mfma_f32_16x16x32_bf16(aEh, Bhi, accE[mf], 0,0,0);
      accE[mf] = __builtin_amdgcn_mfma_f32_16x16x32_bf16(aEh, Blo, accE[mf], 0,0,0);
      accE[mf] = __builtin_amdgcn_mfma_f32_16x16x32_bf16(aEl, Bhi, accE[mf], 0,0,0);
      bf16x8 aFh = wf[(size_t)fb*64 + lane];
      bf16x8 aFl = wf[(size_t)(fb+1)*64 + lane];
      accF[mf] = __builtin_amdgcn_mfma_f32_16x16x32_bf16(aFh, Bhi, accF[mf], 0,0,0);
      accF[mf] = __builtin_amdgcn_mfma_f32_16x16x32_bf16(aFh, Blo, accF[mf], 0,0,0);
      accF[mf] = __builtin_amdgcn_mfma_f32_16x16x32_bf16(aFl, Bhi, accF[mf], 0,0,0);
    }
  }
  if (node >= N) return;
  bool e = em[node] != 0;
  #pragma unroll
  for (int mf=0;mf<8;mf++){
    float sv[4];
    #pragma unroll
    for (int r=0;r<4;r++){
      int ch = mf*16 + ko*4 + r;
      float vE = accE[mf][r] + be[ch];
      float vF = accF[mf][r] + bf[ch];
      sv[r] = fmaxf(e ? vE : vF, 0.f);
    }
    float2* hp = reinterpret_cast<float2*>(h + (size_t)node*H + mf*16 + ko*4);
    hp[0] = make_float2(sv[0], sv[1]);
    hp[1] = make_float2(sv[2], sv[3]);
    unsigned int* hbp = hb + (size_t)node*64 + mf*8 + ko*2;
    hbp[0] = bfr_(sv[0]) | (bfr_(sv[1])<<16);
    hbp[1] = bfr_(sv[2]) | (bfr_(sv[3])<<16);
  }
}

// dual GEMM via MFMA bf16x3: tI = A@WI, tC = A@WC, outputs packed bf16.
// Optional fused input BN+relu: if bna != null, A-values -> relu(bna[ch]*v + bnb2[ch]).
__global__ __launch_bounds__(256) void k_gemm2m(
    const float* __restrict__ A,
    const unsigned short* __restrict__ WIf, const unsigned short* __restrict__ WCf,
    const float* __restrict__ bna, const float* __restrict__ bnb2,
    unsigned int* __restrict__ tIb, unsigned int* __restrict__ tCb, int N)
{
  int t = threadIdx.x;
  int lane = t & 63;
  int base = (blockIdx.x*4 + (t>>6))*16;
  if (base >= N) return;
  int node = base + (lane & 15);
  int nodeL = min(node, N-1);
  int ko = lane >> 4;

  f32x4 accI[8], accC[8];
  #pragma unroll
  for (int mf=0;mf<8;mf++){ accI[mf]=(f32x4){0.f,0.f,0.f,0.f}; accC[mf]=(f32x4){0.f,0.f,0.f,0.f}; }

  const bf16x8* wi = reinterpret_cast<const bf16x8*>(WIf);
  const bf16x8* wc = reinterpret_cast<const bf16x8*>(WCf);
  bool doBN = (bna != nullptr);

  for (int kstep=0;kstep<4;kstep++){
    const float4* ar = reinterpret_cast<const float4*>(A + (size_t)nodeL*H + kstep*32 + ko*8);
    float4 v0 = ar[0], v1 = ar[1];
    if (doBN){
      int ch = kstep*32 + ko*8;
      const float4* a4 = reinterpret_cast<const float4*>(bna + ch);
      const float4* b4 = reinterpret_cast<const float4*>(bnb2 + ch);
      float4 a0 = a4[0], a1 = a4[1], bb0 = b4[0], bb1 = b4[1];
      v0.x = fmaxf(fmaf(a0.x, v0.x, bb0.x), 0.f);
      v0.y = fmaxf(fmaf(a0.y, v0.y, bb0.y), 0.f);
      v0.z = fmaxf(fmaf(a0.z, v0.z, bb0.z), 0.f);
      v0.w = fmaxf(fmaf(a0.w, v0.w, bb0.w), 0.f);
      v1.x = fmaxf(fmaf(a1.x, v1.x, bb1.x), 0.f);
      v1.y = fmaxf(fmaf(a1.y, v1.y, bb1.y), 0.f);
      v1.z = fmaxf(fmaf(a1.z, v1.z, bb1.z), 0.f);
      v1.w = fmaxf(fmaf(a1.w, v1.w, bb1.w), 0.f);
    }
    uint4 hiu, lou;
    split2(v0.x, v0.y, hiu.x, lou.x);
    split2(v0.z, v0.w, hiu.y, lou.y);
    split2(v1.x, v1.y, hiu.z, lou.z);
    split2(v1.z, v1.w, hiu.w, lou.w);
    bf16x8 Bhi = *reinterpret_cast<bf16x8*>(&hiu);
    bf16x8 Blo = *reinterpret_cast<bf16x8*>(&lou);
    #pragma unroll
    for (int mf=0;mf<8;mf++){
      int fb = (kstep*8+mf)*2;
      bf16x8 aIh = wi[(size_t)fb*64 + lane];
      bf16x8 aIl = wi[(size_t)(fb+1)*64 + lane];
      accI[mf] = __builtin_amdgcn_mfma_f32_16x16x32_bf16(aIh, Bhi, accI[mf], 0,0,0);
      accI[mf] = __builtin_amdgcn_mfma_f32_16x16x32_bf16(aIh, Blo, accI[mf], 0,0,0);
      accI[mf] = __builtin_amdgcn_mfma_f32_16x16x32_bf16(aIl, Bhi, accI[mf], 0,0,0);
      bf16x8 aCh = wc[(size_t)fb*64 + lane];
      bf16x8 aCl = wc[(size_t)(fb+1)*64 + lane];
      accC[mf] = __builtin_amdgcn_mfma_f32_16x16x32_bf16(aCh, Bhi, accC[mf], 0,0,0);
      accC[mf] = __builtin_amdgcn_mfma_f32_16x16x32_bf16(aCh, Blo, accC[mf], 0,0,0);
      accC[mf] = __builtin_amdgcn_mfma_f32_16x16x32_bf16(aCl, Bhi, accC[mf], 0,0,0);
    }
  }
  if (node >= N) return;
  #pragma unroll
  for (int mf=0;mf<8;mf++){
    unsigned int* ti = tIb + (size_t)node*64 + mf*8 + ko*2;
    unsigned int* tc = tCb + (size_t)node*64 + mf*8 + ko*2;
    ti[0] = bfr_(accI[mf][0]) | (bfr_(accI[mf][1])<<16);
    ti[1] = bfr_(accI[mf][2]) | (bfr_(accI[mf][3])<<16);
    tc[0] = bfr_(accC[mf][0]) | (bfr_(accC[mf][1])<<16);
    tc[1] = bfr_(accC[mf][2]) | (bfr_(accC[mf][3])<<16);
  }
}

// ---- CSR build ----
__global__ void k_hist(const int* __restrict__ ei, int* __restrict__ cnt, int E){
  int e = blockIdx.x*blockDim.x + threadIdx.x;
  if (e < E) atomicAdd(cnt + ei[E+e], 1);
}

__global__ __launch_bounds__(1024) void k_scan(const int* __restrict__ cnt,
                                               int* __restrict__ start, int N){
  __shared__ int sm[1024];
  int t = threadIdx.x;
  int chunk = (N + 1023)/1024;
  int i0 = t*chunk, i1 = min(i0+chunk, N);
  int s = 0;
  for (int i=i0;i<i1;i++) s += cnt[i];
  sm[t] = s; __syncthreads();
  for (int d=1; d<1024; d<<=1){
    int v = (t>=d)? sm[t-d] : 0;
    __syncthreads();
    sm[t] += v;
    __syncthreads();
  }
  int base = (t==0)? 0 : sm[t-1];
  for (int i=i0;i<i1;i++){ start[i] = base; base += cnt[i]; }
  if (t == 1023) start[N] = base;
}

__global__ void k_fill2(const int* __restrict__ ei, const int* __restrict__ em,
                        const float* __restrict__ ew,
                        const int* __restrict__ start, int* __restrict__ wcnt,
                        int* __restrict__ csr_sc, int* __restrict__ csr_d,
                        float* __restrict__ csr_w, int E){
  int e = blockIdx.x*blockDim.x + threadIdx.x;
  if (e >= E) return;
  int s = ei[e], d = ei[E+e];
  int chan = (em[s] == em[d]) ? 0 : 1;
  int pos = start[d] + atomicAdd(wcnt + d, 1);
  csr_sc[pos] = (s<<1) | chan;
  csr_d[pos] = d;
  csr_w[pos] = ew[e];
}

// W1 (129x64 fp32) -> bf16 B-fragments for 16x16x32 MFMA.
__global__ void k_prepw(const float* __restrict__ W1, unsigned short* __restrict__ W1b){
  int t = threadIdx.x;
  for (int it=0; it<4; it++){
    int le = it*256 + t;
    int f = le >> 6, lane = le & 63;
    int kstep = f >> 2, n = f & 3;
    int col = n*16 + (lane & 15);
    int k0 = kstep*32 + ((lane>>4)&3)*8;
    unsigned short* op = W1b + (size_t)le*8;
    #pragma unroll
    for (int j=0;j<8;j++)
      op[j] = (unsigned short)bfr_(W1[(size_t)(k0+j)*64 + col]);
  }
}

// per-edge MLP gate via MFMA. wave = 32 edges (2 groups of 16); K=128, N=64.
__global__ __launch_bounds__(256) void k_edgem(
    const unsigned int* __restrict__ hb,
    const int* __restrict__ csr_sc, const int* __restrict__ csr_d,
    const float* __restrict__ csr_w, const unsigned short* __restrict__ W1b,
    const float* __restrict__ W1, const float* __restrict__ b1,
    const float* __restrict__ W2, const float* __restrict__ b2,
    float* __restrict__ csr_cf,
    float* __restrict__ degI, float* __restrict__ degC, int E)
{
  int t = threadIdx.x;
  int lane = t & 63;
  int base0 = (blockIdx.x*4 + (t>>6)) * 32;
  if (base0 >= E) return;

  bf16x8 bfrag[16];
  const bf16x8* wb = reinterpret_cast<const bf16x8*>(W1b);
  #pragma unroll
  for (int f=0; f<16; f++) bfrag[f] = wb[f*64 + lane];

  int colbase = lane & 15;
  int ko = lane >> 4;
  float w1l[4], b1v[4], w2v[4];
  #pragma unroll
  for (int n=0;n<4;n++){
    int col = n*16 + colbase;
    w1l[n] = W1[(size_t)128*64 + col];
    b1v[n] = b1[col];
    w2v[n] = W2[col];
  }
  float bb2 = b2[0];

  #pragma unroll
  for (int eg=0; eg<2; eg++){
    int base = base0 + eg*16;
    if (base >= E) break;
    int e = min(base + colbase, E-1);
    int s = csr_sc[e] >> 1;
    int d = csr_d[e];
    const uint4* hsp = reinterpret_cast<const uint4*>(hb + (size_t)s*64);
    const uint4* hdp = reinterpret_cast<const uint4*>(hb + (size_t)d*64);

    f32x4 acc[4];
    #pragma unroll
    for (int n=0;n<4;n++) acc[n] = (f32x4){0.f,0.f,0.f,0.f};

    #pragma unroll
    for (int kstep=0;kstep<4;kstep++){
      uint4 us = hsp[kstep*4 + ko];
      uint4 ud = hdp[kstep*4 + ko];
      uint4 pa;
      pa.x = pair_dft(us.x, ud.x);
      pa.y = pair_dft(us.y, ud.y);
      pa.z = pair_dft(us.z, ud.z);
      pa.w = pair_dft(us.w, ud.w);
      bf16x8 a = *reinterpret_cast<bf16x8*>(&pa);
      #pragma unroll
      for (int n=0;n<4;n++)
        acc[n] = __builtin_amdgcn_mfma_f32_16x16x32_bf16(a, bfrag[kstep*4+n], acc[n], 0,0,0);
    }

    float wgtr[4];
    #pragma unroll
    for (int r=0;r<4;r++)
      wgtr[r] = csr_w[min(base + ko*4 + r, E-1)];

    float part[4] = {0.f,0.f,0.f,0.f};
    #pragma unroll
    for (int n=0;n<4;n++){
      #pragma unroll
      for (int r=0;r<4;r++){
        float v = fmaxf(acc[n][r] + fmaf(wgtr[r], w1l[n], b1v[n]), 0.f);
        part[r] = fmaf(v, w2v[n], part[r]);
      }
    }
    #pragma unroll
    for (int m=1;m<16;m<<=1){
      #pragma unroll
      for (int r=0;r<4;r++) part[r] += __shfl_xor(part[r], m, 64);
    }

    if (colbase == 0){
      #pragma unroll
      for (int r=0;r<4;r++){
        int ee = base + ko*4 + r;
        if (ee < E){
          float g = sigmoidf_(part[r] + bb2);
          g = fminf(fmaxf(g, 0.2f), 1.2f);
          float ehat = wgtr[r] * g;
          csr_cf[ee] = ehat;
          int sc2 = csr_sc[ee];
          atomicAdd(((sc2&1) ? degC : degI) + csr_d[ee], ehat);
        }
      }
    }
  }
}

__global__ void k_dinv(const float* __restrict__ degI, const float* __restrict__ degC,
                       float* dinvI, float* dinvC, int N){
  int i = blockIdx.x*blockDim.x + threadIdx.x;
  if (i < N){
    dinvI[i] = rsqrtf(1.f + degI[i]);
    dinvC[i] = rsqrtf(1.f + degC[i]);
  }
}

__global__ void k_scale(const int* __restrict__ csr_sc, const int* __restrict__ csr_d,
                        const float* __restrict__ dinvI, const float* __restrict__ dinvC,
                        float* __restrict__ csr_cf, int E){
  int k = blockIdx.x*blockDim.x + threadIdx.x;
  if (k >= E) return;
  int sc = csr_sc[k];
  int s = sc>>1;
  int d = csr_d[k];
  const float* dv = (sc&1) ? dinvC : dinvI;
  csr_cf[k] *= dv[s]*dv[d];
}

// BN scale/shift precompute: a = gamma*rsqrt(var+eps), b = beta - a*mu
__global__ void k_bnab(const float* __restrict__ bnsum, const float* __restrict__ bnsq,
                       const float* __restrict__ gamma, const float* __restrict__ beta,
                       float invN, float* __restrict__ bna, float* __restrict__ bnb2){
  int j = threadIdx.x;
  float mu = bnsum[j]*invN;
  float var = bnsq[j]*invN - mu*mu;
  float r = rsqrtf(var + 1e-5f);
  float a = gamma[j]*r;
  bna[j] = a;
  bnb2[j] = beta[j] - a*mu;
}

// one wave per dst node: gather bf16 CSR messages (8-deep unrolled for MLP)
// + fused self-loop/bias epilogue.
__global__ __launch_bounds__(256) void k_aggrb(
    const unsigned int* __restrict__ tIb, const unsigned int* __restrict__ tCb,
    const int* __restrict__ start, const int* __restrict__ csr_sc,
    const float* __restrict__ csr_cf,
    const float* __restrict__ dinvI, const float* __restrict__ dinvC,
    const float* __restrict__ bI, const float* __restrict__ bC,
    const float* __restrict__ relg, int l,
    float* __restrict__ h, int N)
{
  int lane = threadIdx.x & 63;
  int d = blockIdx.x*4 + (threadIdx.x>>6);
  if (d >= N) return;
  float sig = sigmoidf_(relg[l]);
  int k0 = start[d], k1 = start[d+1];
  float ax=0.f, ay=0.f;
  int k = k0;
  for (; k+8 <= k1; k += 8){
    unsigned vv[8]; float cc[8];
    #pragma unroll
    for (int u=0;u<8;u++){
      int sc = csr_sc[k+u];
      float cf = csr_cf[k+u];
      vv[u] = ((sc&1) ? tCb : tIb)[(size_t)(sc>>1)*64 + lane];
      cc[u] = (sc&1) ? sig*cf : cf;
    }
    #pragma unroll
    for (int u=0;u<8;u++){
      ax = fmaf(cc[u], __uint_as_float(vv[u]<<16), ax);
      ay = fmaf(cc[u], __uint_as_float(vv[u] & 0xffff0000u), ay);
    }
  }
  for (; k < k1; ++k){
    int sc = csr_sc[k];
    float cf = csr_cf[k];
    unsigned v = ((sc&1) ? tCb : tIb)[(size_t)(sc>>1)*64 + lane];
    float ce = (sc&1) ? sig*cf : cf;
    ax = fmaf(ce, __uint_as_float(v<<16), ax);
    ay = fmaf(ce, __uint_as_float(v & 0xffff0000u), ay);
  }
  float diI = dinvI[d], diC = dinvC[d];
  float rI = diI*diI, rC = diC*diC;
  unsigned vi = tIb[(size_t)d*64 + lane];
  unsigned vc = tCb[(size_t)d*64 + lane];
  int off = lane*2;
  float ox = fmaf(__uint_as_float(vi<<16), rI, bI[off])
           + sig*fmaf(__uint_as_float(vc<<16), rC, bC[off]) + ax;
  float oy = fmaf(__uint_as_float(vi & 0xffff0000u), rI, bI[off+1])
           + sig*fmaf(__uint_as_float(vc & 0xffff0000u), rC, bC[off+1]) + ay;
  *reinterpret_cast<float2*>(h + (size_t)d*H + off) = make_float2(ox, oy);
}

__global__ __launch_bounds__(128) void k_stats(const float* __restrict__ h,
    float* __restrict__ bnsum, float* __restrict__ bnsq, int N, int nper)
{
  int j = threadIdx.x;
  int n0 = blockIdx.x*nper, n1 = min(n0+nper, N);
  if (n0 >= N) return;
  float sl=0.f, sq=0.f;
  for (int n=n0;n<n1;n++){
    float v = h[(size_t)n*H+j];
    sl += v; sq = fmaf(v,v,sq);
  }
  atomicAdd(bnsum+j, sl); atomicAdd(bnsq+j, sq);
}

// pool with BN+relu applied on the fly (layer-2 fusion)
__global__ __launch_bounds__(128) void k_poolbn(
    const float* __restrict__ h, const int* __restrict__ batch, const int* __restrict__ em,
    const float* __restrict__ bnsum, const float* __restrict__ bnsq,
    const float* __restrict__ gamma, const float* __restrict__ beta, float invN,
    float* __restrict__ sumE, float* __restrict__ sumF,
    float* __restrict__ cntE, float* __restrict__ cntF, int N, int nper)
{
  int j = threadIdx.x;
  int n0 = blockIdx.x*nper, n1 = min(n0+nper, N);
  if (n0 >= N) return;
  float mu = bnsum[j]*invN;
  float var = bnsq[j]*invN - mu*mu;
  float rr = rsqrtf(var + 1e-5f);
  float ga = gamma[j], be = beta[j];
  float aE=0.f, aF=0.f, ce=0.f, cfc=0.f;
  int cg = batch[n0];
  for (int n=n0;n<n1;n++){
    int g = batch[n];
    if (g != cg){
      atomicAdd(sumE+(size_t)cg*H+j, aE);
      atomicAdd(sumF+(size_t)cg*H+j, aF);
      if (j==0){ atomicAdd(cntE+cg, ce); atomicAdd(cntF+cg, cfc); }
      aE=aF=ce=cfc=0.f; cg=g;
    }
    float v = fmaxf(fmaf(ga, (h[(size_t)n*H+j]-mu)*rr, be), 0.f);
    bool eb = em[n] != 0;
    if (eb) aE += v; else aF += v;
    if (j==0){ if (eb) ce += 1.f; else cfc += 1.f; }
  }
  atomicAdd(sumE+(size_t)cg*H+j, aE);
  atomicAdd(sumF+(size_t)cg*H+j, aF);
  if (j==0){ atomicAdd(cntE+cg, ce); atomicAdd(cntF+cg, cfc); }
}

__device__ __forceinline__ float blockReduceSum(float v, float* red){
  int t = threadIdx.x;
  red[t] = v; __syncthreads();
  #pragma unroll
  for (int s=64;s>0;s>>=1){ if (t<s) red[t]+=red[t+s]; __syncthreads(); }
  float r = red[0]; __syncthreads();
  return r;
}

__global__ __launch_bounds__(128) void k_head(
    const float* __restrict__ sumE, const float* __restrict__ sumF,
    const float* __restrict__ cntE, const float* __restrict__ cntF,
    const float* __restrict__ coW1, const float* __restrict__ cob1,
    const float* __restrict__ coW2, const float* __restrict__ cob2,
    const float* __restrict__ gW1, const float* __restrict__ gb1,
    const float* __restrict__ gW2, const float* __restrict__ gb2,
    const float* __restrict__ cW1, const float* __restrict__ cb1,
    const float* __restrict__ cW2, const float* __restrict__ cb2,
    const float* __restrict__ peW1, const float* __restrict__ peb1,
    const float* __restrict__ peW2, const float* __restrict__ peb2,
    const float* __restrict__ pfW1, const float* __restrict__ pfb1,
    const float* __restrict__ pfW2, const float* __restrict__ pfb2,
    float* __restrict__ out, int G)
{
  int g = blockIdx.x, j = threadIdx.x;
  __shared__ float sh[384];
  __shared__ float red[128];
  __shared__ float hfin[128], buf[128];
  float cE = cntE[g], cF = cntF[g];
  float se = sumE[(size_t)g*H+j], sf = sumF[(size_t)g*H+j];
  float he = se/fmaxf(cE,1.f), hf = sf/fmaxf(cF,1.f);
  float hg = (se+sf)/fmaxf(cE+cF,1.f);
  sh[j]=he; sh[128+j]=hf; sh[256+j]=he*hf;
  __syncthreads();
  float a = cob1[j];
  for (int k=0;k<384;k++) a = fmaf(sh[k], coW1[k*H+j], a);
  a = fmaxf(a, 0.f);
  float r0 = blockReduceSum(a*coW2[2*j],   red);
  float r1 = blockReduceSum(a*coW2[2*j+1], red);
  float al0 = sigmoidf_(r0 + cob2[0]);
  float al1 = sigmoidf_(r1 + cob2[1]);
  float asum = al0+al1+1e-6f; al0/=asum; al1/=asum;
  float hc = al0*he + al1*hf;
  __syncthreads();
  sh[j]=hc; sh[128+j]=hg;
  __syncthreads();
  float gg = gb1[j];
  for (int k=0;k<256;k++) gg = fmaf(sh[k], gW1[k*H+j], gg);
  gg = fmaxf(gg, 0.f);
  float gt = sigmoidf_(blockReduceSum(gg*gW2[j], red) + gb2[0]);
  float hfj = gt*hc + (1.f-gt)*hg;
  hfin[j] = hfj;
  __syncthreads();
  float c1v = 0.f;
  if (j < 64){
    float c1 = cb1[j];
    for (int k=0;k<128;k++) c1 = fmaf(hfin[k], cW1[k*64+j], c1);
    c1v = fmaxf(c1, 0.f);
  }
  float l0 = blockReduceSum(j<64 ? c1v*cW2[2*j]   : 0.f, red);
  float l1 = blockReduceSum(j<64 ? c1v*cW2[2*j+1] : 0.f, red);
  if (j==0){ out[(size_t)g*2] = l0 + cb2[0]; out[(size_t)g*2+1] = l1 + cb2[1]; }
  // z_e
  buf[j] = he; __syncthreads();
  float q = peb1[j];
  for (int k=0;k<128;k++) q = fmaf(buf[k], peW1[k*H+j], q);
  q = fmaxf(q, 0.f);
  __syncthreads(); sh[j] = q; __syncthreads();
  float z = peb2[j];
  for (int k=0;k<128;k++) z = fmaf(sh[k], peW2[k*H+j], z);
  float nr = sqrtf(blockReduceSum(z*z, red));
  out[(size_t)G*2 + (size_t)g*H + j] = z / fmaxf(nr, 1e-12f);
  // z_f
  __syncthreads(); buf[j] = hf; __syncthreads();
  float q2 = pfb1[j];
  for (int k=0;k<128;k++) q2 = fmaf(buf[k], pfW1[k*H+j], q2);
  q2 = fmaxf(q2, 0.f);
  __syncthreads(); sh[j] = q2; __syncthreads();
  float z2 = pfb2[j];
  for (int k=0;k<128;k++) z2 = fmaf(sh[k], pfW2[k*H+j], z2);
  float nr2 = sqrtf(blockReduceSum(z2*z2, red));
  out[(size_t)G*2 + (size_t)G*H + (size_t)g*H + j] = z2 / fmaxf(nr2, 1e-12f);
}

extern "C" void kernel_launch(void* const* d_in, const int* in_sizes, int n_in,
                              void* d_out, int out_size, void* d_ws, size_t ws_size,
                              hipStream_t stream)
{
  const float* x    = (const float*)d_in[0];
  const int*   ei   = (const int*)d_in[1];
  const float* ew   = (const float*)d_in[2];
  const int*   batch= (const int*)d_in[3];
  const int*   em   = (const int*)d_in[4];
  const float* eegW = (const float*)d_in[6];  const float* eegB = (const float*)d_in[7];
  const float* fnW  = (const float*)d_in[8];  const float* fnB  = (const float*)d_in[9];
  const float* eW1  = (const float*)d_in[10]; const float* eb1  = (const float*)d_in[11];
  const float* eW2  = (const float*)d_in[12]; const float* eb2  = (const float*)d_in[13];
  const float* cIW  = (const float*)d_in[14]; const float* cIb  = (const float*)d_in[15];
  const float* cCW  = (const float*)d_in[16]; const float* cCb  = (const float*)d_in[17];
  const float* relg = (const float*)d_in[18];
  const float* bng  = (const float*)d_in[19]; const float* bnb  = (const float*)d_in[20];
  const float* coW1 = (const float*)d_in[21]; const float* cob1 = (const float*)d_in[22];
  const float* coW2 = (const float*)d_in[23]; const float* cob2 = (const float*)d_in[24];
  const float* gW1  = (const float*)d_in[25]; const float* gb1  = (const float*)d_in[26];
  const float* gW2  = (const float*)d_in[27]; const float* gb2  = (const float*)d_in[28];
  const float* cW1  = (const float*)d_in[29]; const float* cb1  = (const float*)d_in[30];
  const float* cW2  = (const float*)d_in[31]; const float* cb2  = (const float*)d_in[32];
  const float* peW1 = (const float*)d_in[33]; const float* peb1 = (const float*)d_in[34];
  const float* peW2 = (const float*)d_in[35]; const float* peb2 = (const float*)d_in[36];
  const float* pfW1 = (const float*)d_in[37]; const float* pfb1 = (const float*)d_in[38];
  const float* pfW2 = (const float*)d_in[39]; const float* pfb2 = (const float*)d_in[40];
  float* out = (float*)d_out;

  int N = in_sizes[0] / D;           // 50000
  int E = in_sizes[2];               // 800000
  int G = out_size / (2 + 2*H);      // 500
  int NH = N*H;

  float* p = (float*)d_ws;
  float* h    = p; p += (size_t)NH;
  float* tI   = p; p += (size_t)NH;   // overlays: hb (pre-loop) and tIb (loop), both bf16
  float* tC   = p; p += (size_t)NH;   // overlay: tCb
  float* csr_cf = p; p += E;
  float* csr_w  = p; p += E;
  int* csr_sc = (int*)p; p += E;
  int* csr_d  = (int*)p; p += E;
  int* start  = (int*)p; p += (N+1);
  int* cnt    = (int*)p; p += N;      // cnt, wcnt, degI, degC contiguous -> one memset
  int* wcnt   = (int*)p; p += N;
  float* degI = p; p += N;
  float* degC = p; p += N;
  float* dinvI= p; p += N;
  float* dinvC= p; p += N;
  float* bnsum= p; p += H;            // bnsum+bnsq contiguous
  float* bnsq = p; p += H;
  float* bna  = p; p += H;
  float* bnb2 = p; p += H;
  float* sumE = p; p += (size_t)G*H;  // sumE..cntF contiguous
  float* sumF = p; p += (size_t)G*H;
  float* cntE = p; p += G;
  float* cntF = p; p += G;
  unsigned short* W1b = (unsigned short*)p; p += 4096;   // 8192 bf16 = 16 KB
  unsigned short* WeF = (unsigned short*)p; p += 32768;  // 128 KB
  unsigned short* WfF = (unsigned short*)p; p += 32768;  // 128 KB
  unsigned short* WIf0= (unsigned short*)p; p += 16384;  // 64 KB
  unsigned short* WCf0= (unsigned short*)p; p += 16384;
  unsigned short* WIf1= (unsigned short*)p; p += 16384;
  unsigned short* WCf1= (unsigned short*)p; p += 16384;

  unsigned int* hb  = (unsigned int*)tI;  // bf16 h, used only before layer loop
  unsigned int* tIb = (unsigned int*)tI;  // bf16 messages (loop)
  unsigned int* tCb = (unsigned int*)tC;

  int mmBlocks = ((N+15)/16 + 3)/4;   // 16 nodes/wave, 4 waves/block
  int edgeBlocks = (E + 127)/128;     // 32 edges/wave, 4 waves/block
  int statBlocks = 1024;
  int nper_stat = (N + statBlocks - 1)/statBlocks;
  int poolBlocks = (N + 31)/32;

  hipMemsetAsync(cnt, 0, (size_t)4*N*sizeof(int), stream);  // cnt,wcnt,degI,degC
  k_hist<<<(E+255)/256,256,0,stream>>>(ei, cnt, E);
  k_scan<<<1,1024,0,stream>>>(cnt, start, N);
  k_fill2<<<(E+255)/256,256,0,stream>>>(ei, em, ew, start, wcnt,
                                        csr_sc, csr_d, csr_w, E);
  k_prepw<<<1,256,0,stream>>>(eW1, W1b);
  k_prepwf<<<16,256,0,stream>>>(eegW, WeF, 8);
  k_prepwf<<<16,256,0,stream>>>(fnW,  WfF, 8);
  k_prepwf<<<8,256,0,stream>>>(cIW,          WIf0, 4);
  k_prepwf<<<8,256,0,stream>>>(cCW,          WCf0, 4);
  k_prepwf<<<8,256,0,stream>>>(cIW + 16384,  WIf1, 4);
  k_prepwf<<<8,256,0,stream>>>(cCW + 16384,  WCf1, 4);

  k_projm<<<mmBlocks,256,0,stream>>>(x, em, WeF, eegB, WfF, fnB, h, hb, N);
  k_edgem<<<edgeBlocks,256,0,stream>>>(hb, csr_sc, csr_d, csr_w, W1b,
                                       eW1, eb1, eW2, eb2, csr_cf, degI, degC, E);
  k_dinv<<<(N+255)/256,256,0,stream>>>(degI,degC,dinvI,dinvC,N);
  k_scale<<<(E+255)/256,256,0,stream>>>(csr_sc, csr_d, dinvI, dinvC, csr_cf, E);

  // layer 0
  k_gemm2m<<<mmBlocks,256,0,stream>>>(h, WIf0, WCf0, nullptr, nullptr, tIb, tCb, N);
  k_aggrb<<<(N+3)/4,256,0,stream>>>(tIb, tCb, start, csr_sc, csr_cf,
                                    dinvI, dinvC, cIb, cCb, relg, 0, h, N);
  hipMemsetAsync(bnsum, 0, 2*H*sizeof(float), stream);
  k_stats<<<statBlocks,128,0,stream>>>(h, bnsum, bnsq, N, nper_stat);
  k_bnab<<<1,128,0,stream>>>(bnsum, bnsq, bng, bnb, 1.0f/(float)N, bna, bnb2);

  // layer 1 (BN0 fused into GEMM input)
  k_gemm2m<<<mmBlocks,256,0,stream>>>(h, WIf1, WCf1, bna, bnb2, tIb, tCb, N);
  k_aggrb<<<(N+3)/4,256,0,stream>>>(tIb, tCb, start, csr_sc, csr_cf,
                                    dinvI, dinvC, cIb+(size_t)H, cCb+(size_t)H,
                                    relg, 1, h, N);
  hipMemsetAsync(bnsum, 0, 2*H*sizeof(float), stream);
  k_stats<<<statBlocks,128,0,stream>>>(h, bnsum, bnsq, N, nper_stat);

  hipMemsetAsync(sumE, 0, ((size_t)2*G*H + 2*G)*sizeof(float), stream);
  k_poolbn<<<poolBlocks,128,0,stream>>>(h, batch, em, bnsum, bnsq,
                                        bng+(size_t)H, bnb+(size_t)H, 1.0f/(float)N,
                                        sumE, sumF, cntE, cntF, N, 32);
  k_head<<<G,128,0,stream>>>(sumE,sumF,cntE,cntF,
                             coW1,cob1,coW2,cob2, gW1,gb1,gW2,gb2,
                             cW1,cb1,cW2,cb2, peW1,peb1,peW2,peb2,
                             pfW1,pfb1,pfW2,pfb2, out, G);
}

// Round 11
// 651.617 us; speedup vs baseline: 3.5507x; 1.0645x over previous
//
#include <hip/hip_runtime.h>
#include <math.h>

#define H 128
#define D 256

typedef __attribute__((ext_vector_type(8))) short bf16x8;
typedef __attribute__((ext_vector_type(4))) float f32x4;

__device__ __forceinline__ float sigmoidf_(float x){ return 1.0f/(1.0f+__expf(-x)); }

// RNE float->bf16 (as uint in low 16 bits)
__device__ __forceinline__ unsigned int bfr_(float f){
  unsigned int u = __float_as_uint(f);
  return (u + 0x7fffu + ((u>>16)&1u)) >> 16;
}

// split a,b into packed bf16 hi / lo words (2 bf16 each)
__device__ __forceinline__ void split2(float a, float b, unsigned &hi, unsigned &lo){
  unsigned ha = bfr_(a), hb2 = bfr_(b);
  float fa = __uint_as_float(ha<<16), fb = __uint_as_float(hb2<<16);
  unsigned la = bfr_(a - fa), lb = bfr_(b - fb);
  hi = ha | (hb2<<16); lo = la | (lb<<16);
}

// pack trunc-bf16(|a0-b0|), trunc-bf16(|a1-b1|) into one uint via v_perm
__device__ __forceinline__ unsigned pair_dft(unsigned a, unsigned b){
  float a0 = __uint_as_float(a<<16), a1 = __uint_as_float(a & 0xffff0000u);
  float b0 = __uint_as_float(b<<16), b1 = __uint_as_float(b & 0xffff0000u);
  unsigned d0 = __float_as_uint(fabsf(a0-b0));
  unsigned d1 = __float_as_uint(fabsf(a1-b1));
  return __builtin_amdgcn_perm(d1, d0, 0x07060302);  // {d1.b3,d1.b2,d0.b3,d0.b2}
}

// All weight preprocessing in ONE launch (65 blocks x 256):
// blocks [0,16): eegW->WeF (8 ksteps)  [16,32): fnW->WfF
// [32,40): cIW l0 -> WIf0 (4)  [40,48): cCW l0 -> WCf0
// [48,56): cIW l1 -> WIf1      [56,64): cCW l1 -> WCf1
// block 64: eW1 -> W1b (edge-MLP B-fragments)
__global__ void k_prepall(const float* __restrict__ eegW, const float* __restrict__ fnW,
                          const float* __restrict__ cIW, const float* __restrict__ cCW,
                          const float* __restrict__ eW1,
                          unsigned short* WeF, unsigned short* WfF,
                          unsigned short* WIf0, unsigned short* WCf0,
                          unsigned short* WIf1, unsigned short* WCf1,
                          unsigned short* W1b)
{
  int b = blockIdx.x;
  int t = threadIdx.x;
  if (b < 64){
    const float* W; unsigned short* out; int ksteps; int boff;
    if (b < 16){ W=eegW; out=WeF; ksteps=8; boff=b; }
    else if (b < 32){ W=fnW; out=WfF; ksteps=8; boff=b-16; }
    else if (b < 40){ W=cIW;        out=WIf0; ksteps=4; boff=b-32; }
    else if (b < 48){ W=cCW;        out=WCf0; ksteps=4; boff=b-40; }
    else if (b < 56){ W=cIW+16384;  out=WIf1; ksteps=4; boff=b-48; }
    else            { W=cCW+16384;  out=WCf1; ksteps=4; boff=b-56; }
    int id = boff*256 + t;
    if (id >= ksteps*8*64) return;
    int lane = id & 63;
    int mfrag = (id>>6) & 7;
    int kstep = id >> 9;
    int col = mfrag*16 + (lane&15);
    int k0 = kstep*32 + (lane>>4)*8;
    unsigned short* oh = out + (size_t)(((kstep*8+mfrag)*2+0)*64 + lane)*8;
    unsigned short* ol = out + (size_t)(((kstep*8+mfrag)*2+1)*64 + lane)*8;
    #pragma unroll
    for (int j=0;j<8;j++){
      float w = W[(size_t)(k0+j)*128 + col];
      unsigned h16 = bfr_(w);
      float hf = __uint_as_float(h16<<16);
      oh[j] = (unsigned short)h16;
      ol[j] = (unsigned short)bfr_(w - hf);
    }
  } else {
    // W1 (129x64) -> bf16 B-fragments
    for (int it=0; it<4; it++){
      int le = it*256 + t;
      int f = le >> 6, lane = le & 63;
      int kstep = f >> 2, n = f & 3;
      int col = n*16 + (lane & 15);
      int k0 = kstep*32 + ((lane>>4)&3)*8;
      unsigned short* op = W1b + (size_t)le*8;
      #pragma unroll
      for (int j=0;j<8;j++)
        op[j] = (unsigned short)bfr_(eW1[(size_t)(k0+j)*64 + col]);
    }
  }
}

// proj via MFMA bf16x3: h = relu(x @ Wsel + bsel). wave = 16 nodes x 128 ch.
__global__ __launch_bounds__(256) void k_projm(
    const float* __restrict__ x, const int* __restrict__ em,
    const unsigned short* __restrict__ WeF, const float* __restrict__ be,
    const unsigned short* __restrict__ WfF, const float* __restrict__ bf,
    float* __restrict__ h, unsigned int* __restrict__ hb, int N)
{
  int t = threadIdx.x;
  int lane = t & 63;
  int base = (blockIdx.x*4 + (t>>6))*16;
  if (base >= N) return;
  int node = base + (lane & 15);
  int nodeL = min(node, N-1);
  int ko = lane >> 4;

  f32x4 accE[8], accF[8];
  #pragma unroll
  for (int mf=0;mf<8;mf++){ accE[mf]=(f32x4){0.f,0.f,0.f,0.f}; accF[mf]=(f32x4){0.f,0.f,0.f,0.f}; }

  const bf16x8* we = reinterpret_cast<const bf16x8*>(WeF);
  const bf16x8* wf = reinterpret_cast<const bf16x8*>(WfF);

  for (int kstep=0;kstep<8;kstep++){
    const float4* xr = reinterpret_cast<const float4*>(x + (size_t)nodeL*D + kstep*32 + ko*8);
    float4 v0 = xr[0], v1 = xr[1];
    uint4 hiu, lou;
    split2(v0.x, v0.y, hiu.x, lou.x);
    split2(v0.z, v0.w, hiu.y, lou.y);
    split2(v1.x, v1.y, hiu.z, lou.z);
    split2(v1.z, v1.w, hiu.w, lou.w);
    bf16x8 Bhi = *reinterpret_cast<bf16x8*>(&hiu);
    bf16x8 Blo = *reinterpret_cast<bf16x8*>(&lou);
    #pragma unroll
    for (int mf=0;mf<8;mf++){
      int fb = (kstep*8+mf)*2;
      bf16x8 aEh = we[(size_t)fb*64 + lane];
      bf16x8 aEl = we[(size_t)(fb+1)*64 + lane];
      accE[mf] = __builtin_amdgcn_mfma_f32_16x16x32_bf16(aEh, Bhi, accE[mf], 0,0,0);
      accE[mf] = __builtin_amdgcn_mfma_f32_16x16x32_bf16(aEh, Blo, accE[mf], 0,0,0);
      accE[mf] = __builtin_amdgcn_mfma_f32_16x16x32_bf16(aEl, Bhi, accE[mf], 0,0,0);
      bf16x8 aFh = wf[(size_t)fb*64 + lane];
      bf16x8 aFl = wf[(size_t)(fb+1)*64 + lane];
      accF[mf] = __builtin_amdgcn_mfma_f32_16x16x32_bf16(aFh, Bhi, accF[mf], 0,0,0);
      accF[mf] = __builtin_amdgcn_mfma_f32_16x16x32_bf16(aFh, Blo, accF[mf], 0,0,0);
      accF[mf] = __builtin_amdgcn_mfma_f32_16x16x32_bf16(aFl, Bhi, accF[mf], 0,0,0);
    }
  }
  if (node >= N) return;
  bool e = em[node] != 0;
  #pragma unroll
  for (int mf=0;mf<8;mf++){
    float sv[4];
    #pragma unroll
    for (int r=0;r<4;r++){
      int ch = mf*16 + ko*4 + r;
      float vE = accE[mf][r] + be[ch];
      float vF = accF[mf][r] + bf[ch];
      sv[r] = fmaxf(e ? vE : vF, 0.f);
    }
    float2* hp = reinterpret_cast<float2*>(h + (size_t)node*H + mf*16 + ko*4);
    hp[0] = make_float2(sv[0], sv[1]);
    hp[1] = make_float2(sv[2], sv[3]);
    unsigned int* hbp = hb + (size_t)node*64 + mf*8 + ko*2;
    hbp[0] = bfr_(sv[0]) | (bfr_(sv[1])<<16);
    hbp[1] = bfr_(sv[2]) | (bfr_(sv[3])<<16);
  }
}

// dual GEMM via MFMA bf16x3: tI = A@WI, tC = A@WC, outputs packed bf16.
// Optional fused input BN+relu: if bna != null, A-values -> relu(bna[ch]*v + bnb2[ch]).
__global__ __launch_bounds__(256) void k_gemm2m(
    const float* __restrict__ A,
    const unsigned short* __restrict__ WIf, const unsigned short* __restrict__ WCf,
    const float* __restrict__ bna, const float* __restrict__ bnb2,
    unsigned int* __restrict__ tIb, unsigned int* __restrict__ tCb, int N)
{
  int t = threadIdx.x;
  int lane = t & 63;
  int base = (blockIdx.x*4 + (t>>6))*16;
  if (base >= N) return;
  int node = base + (lane & 15);
  int nodeL = min(node, N-1);
  int ko = lane >> 4;

  f32x4 accI[8], accC[8];
  #pragma unroll
  for (int mf=0;mf<8;mf++){ accI[mf]=(f32x4){0.f,0.f,0.f,0.f}; accC[mf]=(f32x4){0.f,0.f,0.f,0.f}; }

  const bf16x8* wi = reinterpret_cast<const bf16x8*>(WIf);
  const bf16x8* wc = reinterpret_cast<const bf16x8*>(WCf);
  bool doBN = (bna != nullptr);

  for (int kstep=0;kstep<4;kstep++){
    const float4* ar = reinterpret_cast<const float4*>(A + (size_t)nodeL*H + kstep*32 + ko*8);
    float4 v0 = ar[0], v1 = ar[1];
    if (doBN){
      int ch = kstep*32 + ko*8;
      const float4* a4 = reinterpret_cast<const float4*>(bna + ch);
      const float4* b4 = reinterpret_cast<const float4*>(bnb2 + ch);
      float4 a0 = a4[0], a1 = a4[1], bb0 = b4[0], bb1 = b4[1];
      v0.x = fmaxf(fmaf(a0.x, v0.x, bb0.x), 0.f);
      v0.y = fmaxf(fmaf(a0.y, v0.y, bb0.y), 0.f);
      v0.z = fmaxf(fmaf(a0.z, v0.z, bb0.z), 0.f);
      v0.w = fmaxf(fmaf(a0.w, v0.w, bb0.w), 0.f);
      v1.x = fmaxf(fmaf(a1.x, v1.x, bb1.x), 0.f);
      v1.y = fmaxf(fmaf(a1.y, v1.y, bb1.y), 0.f);
      v1.z = fmaxf(fmaf(a1.z, v1.z, bb1.z), 0.f);
      v1.w = fmaxf(fmaf(a1.w, v1.w, bb1.w), 0.f);
    }
    uint4 hiu, lou;
    split2(v0.x, v0.y, hiu.x, lou.x);
    split2(v0.z, v0.w, hiu.y, lou.y);
    split2(v1.x, v1.y, hiu.z, lou.z);
    split2(v1.z, v1.w, hiu.w, lou.w);
    bf16x8 Bhi = *reinterpret_cast<bf16x8*>(&hiu);
    bf16x8 Blo = *reinterpret_cast<bf16x8*>(&lou);
    #pragma unroll
    for (int mf=0;mf<8;mf++){
      int fb = (kstep*8+mf)*2;
      bf16x8 aIh = wi[(size_t)fb*64 + lane];
      bf16x8 aIl = wi[(size_t)(fb+1)*64 + lane];
      accI[mf] = __builtin_amdgcn_mfma_f32_16x16x32_bf16(aIh, Bhi, accI[mf], 0,0,0);
      accI[mf] = __builtin_amdgcn_mfma_f32_16x16x32_bf16(aIh, Blo, accI[mf], 0,0,0);
      accI[mf] = __builtin_amdgcn_mfma_f32_16x16x32_bf16(aIl, Bhi, accI[mf], 0,0,0);
      bf16x8 aCh = wc[(size_t)fb*64 + lane];
      bf16x8 aCl = wc[(size_t)(fb+1)*64 + lane];
      accC[mf] = __builtin_amdgcn_mfma_f32_16x16x32_bf16(aCh, Bhi, accC[mf], 0,0,0);
      accC[mf] = __builtin_amdgcn_mfma_f32_16x16x32_bf16(aCh, Blo, accC[mf], 0,0,0);
      accC[mf] = __builtin_amdgcn_mfma_f32_16x16x32_bf16(aCl, Bhi, accC[mf], 0,0,0);
    }
  }
  if (node >= N) return;
  #pragma unroll
  for (int mf=0;mf<8;mf++){
    unsigned int* ti = tIb + (size_t)node*64 + mf*8 + ko*2;
    unsigned int* tc = tCb + (size_t)node*64 + mf*8 + ko*2;
    ti[0] = bfr_(accI[mf][0]) | (bfr_(accI[mf][1])<<16);
    ti[1] = bfr_(accI[mf][2]) | (bfr_(accI[mf][3])<<16);
    tc[0] = bfr_(accC[mf][0]) | (bfr_(accC[mf][1])<<16);
    tc[1] = bfr_(accC[mf][2]) | (bfr_(accC[mf][3])<<16);
  }
}

// ---- CSR build ----
__global__ void k_hist(const int* __restrict__ ei, int* __restrict__ cnt, int E){
  int e = blockIdx.x*blockDim.x + threadIdx.x;
  if (e < E) atomicAdd(cnt + ei[E+e], 1);
}

__global__ __launch_bounds__(1024) void k_scan(const int* __restrict__ cnt,
                                               int* __restrict__ start, int N){
  __shared__ int sm[1024];
  int t = threadIdx.x;
  int chunk = (N + 1023)/1024;
  int i0 = t*chunk, i1 = min(i0+chunk, N);
  int s = 0;
  for (int i=i0;i<i1;i++) s += cnt[i];
  sm[t] = s; __syncthreads();
  for (int d=1; d<1024; d<<=1){
    int v = (t>=d)? sm[t-d] : 0;
    __syncthreads();
    sm[t] += v;
    __syncthreads();
  }
  int base = (t==0)? 0 : sm[t-1];
  for (int i=i0;i<i1;i++){ start[i] = base; base += cnt[i]; }
  if (t == 1023) start[N] = base;
}

__global__ void k_fill2(const int* __restrict__ ei, const int* __restrict__ em,
                        const float* __restrict__ ew,
                        const int* __restrict__ start, int* __restrict__ wcnt,
                        int* __restrict__ csr_sc, int* __restrict__ csr_d,
                        float* __restrict__ csr_w, int E){
  int e = blockIdx.x*blockDim.x + threadIdx.x;
  if (e >= E) return;
  int s = ei[e], d = ei[E+e];
  int chan = (em[s] == em[d]) ? 0 : 1;
  int pos = start[d] + atomicAdd(wcnt + d, 1);
  csr_sc[pos] = (s<<1) | chan;
  csr_d[pos] = d;
  csr_w[pos] = ew[e];
}

// per-edge MLP gate via MFMA. wave = 32 edges; W1 fragments in LDS;
// both groups' row-gathers issued upfront for deep latency hiding.
__global__ __launch_bounds__(256) void k_edgem(
    const unsigned int* __restrict__ hb,
    const int* __restrict__ csr_sc, const int* __restrict__ csr_d,
    const float* __restrict__ csr_w, const unsigned short* __restrict__ W1b,
    const float* __restrict__ W1, const float* __restrict__ b1,
    const float* __restrict__ W2, const float* __restrict__ b2,
    float* __restrict__ csr_cf,
    float* __restrict__ degI, float* __restrict__ degC, int E)
{
  __shared__ uint4 wlds[1024];   // 16 KB: all W1 B-fragments
  int t = threadIdx.x;
  {
    const uint4* src = reinterpret_cast<const uint4*>(W1b);
    #pragma unroll
    for (int i=0;i<4;i++) wlds[i*256 + t] = src[i*256 + t];
  }
  __syncthreads();

  int lane = t & 63;
  int base0 = (blockIdx.x*4 + (t>>6)) * 32;
  if (base0 >= E) return;

  int colbase = lane & 15;
  int ko = lane >> 4;
  float w1l[4], b1v[4], w2v[4];
  #pragma unroll
  for (int n=0;n<4;n++){
    int col = n*16 + colbase;
    w1l[n] = W1[(size_t)128*64 + col];
    b1v[n] = b1[col];
    w2v[n] = W2[col];
  }
  float bb2 = b2[0];

  // issue ALL gathers (2 groups x src+dst x 4 ksteps = 16 uint4) upfront
  uint4 us[2][4], ud[2][4];
  #pragma unroll
  for (int eg=0; eg<2; eg++){
    int e = min(base0 + eg*16 + colbase, E-1);
    int s = csr_sc[e] >> 1;
    int d = csr_d[e];
    const uint4* hsp = reinterpret_cast<const uint4*>(hb + (size_t)s*64);
    const uint4* hdp = reinterpret_cast<const uint4*>(hb + (size_t)d*64);
    #pragma unroll
    for (int kstep=0;kstep<4;kstep++){
      us[eg][kstep] = hsp[kstep*4 + ko];
      ud[eg][kstep] = hdp[kstep*4 + ko];
    }
  }

  const bf16x8* wl = reinterpret_cast<const bf16x8*>(wlds);
  #pragma unroll
  for (int eg=0; eg<2; eg++){
    int base = base0 + eg*16;
    if (base >= E) break;

    f32x4 acc[4];
    #pragma unroll
    for (int n=0;n<4;n++) acc[n] = (f32x4){0.f,0.f,0.f,0.f};

    #pragma unroll
    for (int kstep=0;kstep<4;kstep++){
      uint4 pa;
      pa.x = pair_dft(us[eg][kstep].x, ud[eg][kstep].x);
      pa.y = pair_dft(us[eg][kstep].y, ud[eg][kstep].y);
      pa.z = pair_dft(us[eg][kstep].z, ud[eg][kstep].z);
      pa.w = pair_dft(us[eg][kstep].w, ud[eg][kstep].w);
      bf16x8 a = *reinterpret_cast<bf16x8*>(&pa);
      #pragma unroll
      for (int n=0;n<4;n++)
        acc[n] = __builtin_amdgcn_mfma_f32_16x16x32_bf16(a, wl[(kstep*4+n)*64 + lane], acc[n], 0,0,0);
    }

    float wgtr[4];
    #pragma unroll
    for (int r=0;r<4;r++)
      wgtr[r] = csr_w[min(base + ko*4 + r, E-1)];

    float part[4] = {0.f,0.f,0.f,0.f};
    #pragma unroll
    for (int n=0;n<4;n++){
      #pragma unroll
      for (int r=0;r<4;r++){
        float v = fmaxf(acc[n][r] + fmaf(wgtr[r], w1l[n], b1v[n]), 0.f);
        part[r] = fmaf(v, w2v[n], part[r]);
      }
    }
    #pragma unroll
    for (int m=1;m<16;m<<=1){
      #pragma unroll
      for (int r=0;r<4;r++) part[r] += __shfl_xor(part[r], m, 64);
    }

    if (colbase == 0){
      #pragma unroll
      for (int r=0;r<4;r++){
        int ee = base + ko*4 + r;
        if (ee < E){
          float g = sigmoidf_(part[r] + bb2);
          g = fminf(fmaxf(g, 0.2f), 1.2f);
          float ehat = wgtr[r] * g;
          csr_cf[ee] = ehat;
          int sc2 = csr_sc[ee];
          atomicAdd(((sc2&1) ? degC : degI) + csr_d[ee], ehat);
        }
      }
    }
  }
}

__global__ void k_dinv(const float* __restrict__ degI, const float* __restrict__ degC,
                       float* dinvI, float* dinvC, int N){
  int i = blockIdx.x*blockDim.x + threadIdx.x;
  if (i < N){
    dinvI[i] = rsqrtf(1.f + degI[i]);
    dinvC[i] = rsqrtf(1.f + degC[i]);
  }
}

__global__ void k_scale(const int* __restrict__ csr_sc, const int* __restrict__ csr_d,
                        const float* __restrict__ dinvI, const float* __restrict__ dinvC,
                        float* __restrict__ csr_cf, int E){
  int k = blockIdx.x*blockDim.x + threadIdx.x;
  if (k >= E) return;
  int sc = csr_sc[k];
  int s = sc>>1;
  int d = csr_d[k];
  const float* dv = (sc&1) ? dinvC : dinvI;
  csr_cf[k] *= dv[s]*dv[d];
}

// BN scale/shift precompute: a = gamma*rsqrt(var+eps), b = beta - a*mu
__global__ void k_bnab(const float* __restrict__ bnsum, const float* __restrict__ bnsq,
                       const float* __restrict__ gamma, const float* __restrict__ beta,
                       float invN, float* __restrict__ bna, float* __restrict__ bnb2){
  int j = threadIdx.x;
  float mu = bnsum[j]*invN;
  float var = bnsq[j]*invN - mu*mu;
  float r = rsqrtf(var + 1e-5f);
  float a = gamma[j]*r;
  bna[j] = a;
  bnb2[j] = beta[j] - a*mu;
}

// one wave per dst node: gather bf16 CSR messages (8-deep unrolled)
// + fused self-loop/bias epilogue.
__global__ __launch_bounds__(256) void k_aggrb(
    const unsigned int* __restrict__ tIb, const unsigned int* __restrict__ tCb,
    const int* __restrict__ start, const int* __restrict__ csr_sc,
    const float* __restrict__ csr_cf,
    const float* __restrict__ dinvI, const float* __restrict__ dinvC,
    const float* __restrict__ bI, const float* __restrict__ bC,
    const float* __restrict__ relg, int l,
    float* __restrict__ h, int N)
{
  int lane = threadIdx.x & 63;
  int d = blockIdx.x*4 + (threadIdx.x>>6);
  if (d >= N) return;
  float sig = sigmoidf_(relg[l]);
  int k0 = start[d], k1 = start[d+1];
  float ax=0.f, ay=0.f;
  int k = k0;
  for (; k+8 <= k1; k += 8){
    unsigned vv[8]; float cc[8];
    #pragma unroll
    for (int u=0;u<8;u++){
      int sc = csr_sc[k+u];
      float cf = csr_cf[k+u];
      vv[u] = ((sc&1) ? tCb : tIb)[(size_t)(sc>>1)*64 + lane];
      cc[u] = (sc&1) ? sig*cf : cf;
    }
    #pragma unroll
    for (int u=0;u<8;u++){
      ax = fmaf(cc[u], __uint_as_float(vv[u]<<16), ax);
      ay = fmaf(cc[u], __uint_as_float(vv[u] & 0xffff0000u), ay);
    }
  }
  for (; k < k1; ++k){
    int sc = csr_sc[k];
    float cf = csr_cf[k];
    unsigned v = ((sc&1) ? tCb : tIb)[(size_t)(sc>>1)*64 + lane];
    float ce = (sc&1) ? sig*cf : cf;
    ax = fmaf(ce, __uint_as_float(v<<16), ax);
    ay = fmaf(ce, __uint_as_float(v & 0xffff0000u), ay);
  }
  float diI = dinvI[d], diC = dinvC[d];
  float rI = diI*diI, rC = diC*diC;
  unsigned vi = tIb[(size_t)d*64 + lane];
  unsigned vc = tCb[(size_t)d*64 + lane];
  int off = lane*2;
  float ox = fmaf(__uint_as_float(vi<<16), rI, bI[off])
           + sig*fmaf(__uint_as_float(vc<<16), rC, bC[off]) + ax;
  float oy = fmaf(__uint_as_float(vi & 0xffff0000u), rI, bI[off+1])
           + sig*fmaf(__uint_as_float(vc & 0xffff0000u), rC, bC[off+1]) + ay;
  *reinterpret_cast<float2*>(h + (size_t)d*H + off) = make_float2(ox, oy);
}

__global__ __launch_bounds__(128) void k_stats(const float* __restrict__ h,
    float* __restrict__ bnsum, float* __restrict__ bnsq, int N, int nper)
{
  int j = threadIdx.x;
  int n0 = blockIdx.x*nper, n1 = min(n0+nper, N);
  if (n0 >= N) return;
  float sl=0.f, sq=0.f;
  for (int n=n0;n<n1;n++){
    float v = h[(size_t)n*H+j];
    sl += v; sq = fmaf(v,v,sq);
  }
  atomicAdd(bnsum+j, sl); atomicAdd(bnsq+j, sq);
}

// pool with BN+relu applied on the fly (layer-2 fusion)
__global__ __launch_bounds__(128) void k_poolbn(
    const float* __restrict__ h, const int* __restrict__ batch, const int* __restrict__ em,
    const float* __restrict__ bnsum, const float* __restrict__ bnsq,
    const float* __restrict__ gamma, const float* __restrict__ beta, float invN,
    float* __restrict__ sumE, float* __restrict__ sumF,
    float* __restrict__ cntE, float* __restrict__ cntF, int N, int nper)
{
  int j = threadIdx.x;
  int n0 = blockIdx.x*nper, n1 = min(n0+nper, N);
  if (n0 >= N) return;
  float mu = bnsum[j]*invN;
  float var = bnsq[j]*invN - mu*mu;
  float rr = rsqrtf(var + 1e-5f);
  float ga = gamma[j], be = beta[j];
  float aE=0.f, aF=0.f, ce=0.f, cfc=0.f;
  int cg = batch[n0];
  for (int n=n0;n<n1;n++){
    int g = batch[n];
    if (g != cg){
      atomicAdd(sumE+(size_t)cg*H+j, aE);
      atomicAdd(sumF+(size_t)cg*H+j, aF);
      if (j==0){ atomicAdd(cntE+cg, ce); atomicAdd(cntF+cg, cfc); }
      aE=aF=ce=cfc=0.f; cg=g;
    }
    float v = fmaxf(fmaf(ga, (h[(size_t)n*H+j]-mu)*rr, be), 0.f);
    bool eb = em[n] != 0;
    if (eb) aE += v; else aF += v;
    if (j==0){ if (eb) ce += 1.f; else cfc += 1.f; }
  }
  atomicAdd(sumE+(size_t)cg*H+j, aE);
  atomicAdd(sumF+(size_t)cg*H+j, aF);
  if (j==0){ atomicAdd(cntE+cg, ce); atomicAdd(cntF+cg, cfc); }
}

__device__ __forceinline__ float blockReduceSum(float v, float* red){
  int t = threadIdx.x;
  red[t] = v; __syncthreads();
  #pragma unroll
  for (int s=64;s>0;s>>=1){ if (t<s) red[t]+=red[t+s]; __syncthreads(); }
  float r = red[0]; __syncthreads();
  return r;
}

__global__ __launch_bounds__(128) void k_head(
    const float* __restrict__ sumE, const float* __restrict__ sumF,
    const float* __restrict__ cntE, const float* __restrict__ cntF,
    const float* __restrict__ coW1, const float* __restrict__ cob1,
    const float* __restrict__ coW2, const float* __restrict__ cob2,
    const float* __restrict__ gW1, const float* __restrict__ gb1,
    const float* __restrict__ gW2, const float* __restrict__ gb2,
    const float* __restrict__ cW1, const float* __restrict__ cb1,
    const float* __restrict__ cW2, const float* __restrict__ cb2,
    const float* __restrict__ peW1, const float* __restrict__ peb1,
    const float* __restrict__ peW2, const float* __restrict__ peb2,
    const float* __restrict__ pfW1, const float* __restrict__ pfb1,
    const float* __restrict__ pfW2, const float* __restrict__ pfb2,
    float* __restrict__ out, int G)
{
  int g = blockIdx.x, j = threadIdx.x;
  __shared__ float sh[384];
  __shared__ float red[128];
  __shared__ float hfin[128], buf[128];
  float cE = cntE[g], cF = cntF[g];
  float se = sumE[(size_t)g*H+j], sf = sumF[(size_t)g*H+j];
  float he = se/fmaxf(cE,1.f), hf = sf/fmaxf(cF,1.f);
  float hg = (se+sf)/fmaxf(cE+cF,1.f);
  sh[j]=he; sh[128+j]=hf; sh[256+j]=he*hf;
  __syncthreads();
  float a = cob1[j];
  for (int k=0;k<384;k++) a = fmaf(sh[k], coW1[k*H+j], a);
  a = fmaxf(a, 0.f);
  float r0 = blockReduceSum(a*coW2[2*j],   red);
  float r1 = blockReduceSum(a*coW2[2*j+1], red);
  float al0 = sigmoidf_(r0 + cob2[0]);
  float al1 = sigmoidf_(r1 + cob2[1]);
  float asum = al0+al1+1e-6f; al0/=asum; al1/=asum;
  float hc = al0*he + al1*hf;
  __syncthreads();
  sh[j]=hc; sh[128+j]=hg;
  __syncthreads();
  float gg = gb1[j];
  for (int k=0;k<256;k++) gg = fmaf(sh[k], gW1[k*H+j], gg);
  gg = fmaxf(gg, 0.f);
  float gt = sigmoidf_(blockReduceSum(gg*gW2[j], red) + gb2[0]);
  float hfj = gt*hc + (1.f-gt)*hg;
  hfin[j] = hfj;
  __syncthreads();
  float c1v = 0.f;
  if (j < 64){
    float c1 = cb1[j];
    for (int k=0;k<128;k++) c1 = fmaf(hfin[k], cW1[k*64+j], c1);
    c1v = fmaxf(c1, 0.f);
  }
  float l0 = blockReduceSum(j<64 ? c1v*cW2[2*j]   : 0.f, red);
  float l1 = blockReduceSum(j<64 ? c1v*cW2[2*j+1] : 0.f, red);
  if (j==0){ out[(size_t)g*2] = l0 + cb2[0]; out[(size_t)g*2+1] = l1 + cb2[1]; }
  // z_e
  buf[j] = he; __syncthreads();
  float q = peb1[j];
  for (int k=0;k<128;k++) q = fmaf(buf[k], peW1[k*H+j], q);
  q = fmaxf(q, 0.f);
  __syncthreads(); sh[j] = q; __syncthreads();
  float z = peb2[j];
  for (int k=0;k<128;k++) z = fmaf(sh[k], peW2[k*H+j], z);
  float nr = sqrtf(blockReduceSum(z*z, red));
  out[(size_t)G*2 + (size_t)g*H + j] = z / fmaxf(nr, 1e-12f);
  // z_f
  __syncthreads(); buf[j] = hf; __syncthreads();
  float q2 = pfb1[j];
  for (int k=0;k<128;k++) q2 = fmaf(buf[k], pfW1[k*H+j], q2);
  q2 = fmaxf(q2, 0.f);
  __syncthreads(); sh[j] = q2; __syncthreads();
  float z2 = pfb2[j];
  for (int k=0;k<128;k++) z2 = fmaf(sh[k], pfW2[k*H+j], z2);
  float nr2 = sqrtf(blockReduceSum(z2*z2, red));
  out[(size_t)G*2 + (size_t)G*H + (size_t)g*H + j] = z2 / fmaxf(nr2, 1e-12f);
}

extern "C" void kernel_launch(void* const* d_in, const int* in_sizes, int n_in,
                              void* d_out, int out_size, void* d_ws, size_t ws_size,
                              hipStream_t stream)
{
  const float* x    = (const float*)d_in[0];
  const int*   ei   = (const int*)d_in[1];
  const float* ew   = (const float*)d_in[2];
  const int*   batch= (const int*)d_in[3];
  const int*   em   = (const int*)d_in[4];
  const float* eegW = (const float*)d_in[6];  const float* eegB = (const float*)d_in[7];
  const float* fnW  = (const float*)d_in[8];  const float* fnB  = (const float*)d_in[9];
  const float* eW1  = (const float*)d_in[10]; const float* eb1  = (const float*)d_in[11];
  const float* eW2  = (const float*)d_in[12]; const float* eb2  = (const float*)d_in[13];
  const float* cIW  = (const float*)d_in[14]; const float* cIb  = (const float*)d_in[15];
  const float* cCW  = (const float*)d_in[16]; const float* cCb  = (const float*)d_in[17];
  const float* relg = (const float*)d_in[18];
  const float* bng  = (const float*)d_in[19]; const float* bnb  = (const float*)d_in[20];
  const float* coW1 = (const float*)d_in[21]; const float* cob1 = (const float*)d_in[22];
  const float* coW2 = (const float*)d_in[23]; const float* cob2 = (const float*)d_in[24];
  const float* gW1  = (const float*)d_in[25]; const float* gb1  = (const float*)d_in[26];
  const float* gW2  = (const float*)d_in[27]; const float* gb2  = (const float*)d_in[28];
  const float* cW1  = (const float*)d_in[29]; const float* cb1  = (const float*)d_in[30];
  const float* cW2  = (const float*)d_in[31]; const float* cb2  = (const float*)d_in[32];
  const float* peW1 = (const float*)d_in[33]; const float* peb1 = (const float*)d_in[34];
  const float* peW2 = (const float*)d_in[35]; const float* peb2 = (const float*)d_in[36];
  const float* pfW1 = (const float*)d_in[37]; const float* pfb1 = (const float*)d_in[38];
  const float* pfW2 = (const float*)d_in[39]; const float* pfb2 = (const float*)d_in[40];
  float* out = (float*)d_out;

  int N = in_sizes[0] / D;           // 50000
  int E = in_sizes[2];               // 800000
  int G = out_size / (2 + 2*H);      // 500
  int NH = N*H;

  float* p = (float*)d_ws;
  float* h    = p; p += (size_t)NH;
  float* tI   = p; p += (size_t)NH;   // overlays: hb (pre-loop) and tIb (loop), both bf16
  float* tC   = p; p += (size_t)NH;   // overlay: tCb
  float* csr_cf = p; p += E;
  float* csr_w  = p; p += E;
  int* csr_sc = (int*)p; p += E;
  int* csr_d  = (int*)p; p += E;
  int* start  = (int*)p; p += (N+1);
  int* cnt    = (int*)p; p += N;      // cnt, wcnt, degI, degC contiguous -> one memset
  int* wcnt   = (int*)p; p += N;
  float* degI = p; p += N;
  float* degC = p; p += N;
  float* dinvI= p; p += N;
  float* dinvC= p; p += N;
  float* bnsum= p; p += H;            // bnsum+bnsq contiguous
  float* bnsq = p; p += H;
  float* bna  = p; p += H;
  float* bnb2 = p; p += H;
  float* sumE = p; p += (size_t)G*H;  // sumE..cntF contiguous
  float* sumF = p; p += (size_t)G*H;
  float* cntE = p; p += G;
  float* cntF = p; p += G;
  unsigned short* W1b = (unsigned short*)p; p += 4096;   // 8192 bf16 = 16 KB
  unsigned short* WeF = (unsigned short*)p; p += 32768;  // 128 KB
  unsigned short* WfF = (unsigned short*)p; p += 32768;  // 128 KB
  unsigned short* WIf0= (unsigned short*)p; p += 16384;  // 64 KB
  unsigned short* WCf0= (unsigned short*)p; p += 16384;
  unsigned short* WIf1= (unsigned short*)p; p += 16384;
  unsigned short* WCf1= (unsigned short*)p; p += 16384;

  unsigned int* hb  = (unsigned int*)tI;  // bf16 h, used only before layer loop
  unsigned int* tIb = (unsigned int*)tI;  // bf16 messages (loop)
  unsigned int* tCb = (unsigned int*)tC;

  int mmBlocks = ((N+15)/16 + 3)/4;   // 16 nodes/wave, 4 waves/block
  int edgeBlocks = (E + 127)/128;     // 32 edges/wave, 4 waves/block
  int statBlocks = 1024;
  int nper_stat = (N + statBlocks - 1)/statBlocks;
  int poolBlocks = (N + 31)/32;

  hipMemsetAsync(cnt, 0, (size_t)4*N*sizeof(int), stream);  // cnt,wcnt,degI,degC
  k_hist<<<(E+255)/256,256,0,stream>>>(ei, cnt, E);
  k_scan<<<1,1024,0,stream>>>(cnt, start, N);
  k_fill2<<<(E+255)/256,256,0,stream>>>(ei, em, ew, start, wcnt,
                                        csr_sc, csr_d, csr_w, E);
  k_prepall<<<65,256,0,stream>>>(eegW, fnW, cIW, cCW, eW1,
                                 WeF, WfF, WIf0, WCf0, WIf1, WCf1, W1b);

  k_projm<<<mmBlocks,256,0,stream>>>(x, em, WeF, eegB, WfF, fnB, h, hb, N);
  k_edgem<<<edgeBlocks,256,0,stream>>>(hb, csr_sc, csr_d, csr_w, W1b,
                                       eW1, eb1, eW2, eb2, csr_cf, degI, degC, E);
  k_dinv<<<(N+255)/256,256,0,stream>>>(degI,degC,dinvI,dinvC,N);
  k_scale<<<(E+255)/256,256,0,stream>>>(csr_sc, csr_d, dinvI, dinvC, csr_cf, E);

  // layer 0
  k_gemm2m<<<mmBlocks,256,0,stream>>>(h, WIf0, WCf0, nullptr, nullptr, tIb, tCb, N);
  k_aggrb<<<(N+3)/4,256,0,stream>>>(tIb, tCb, start, csr_sc, csr_cf,
                                    dinvI, dinvC, cIb, cCb, relg, 0, h, N);
  hipMemsetAsync(bnsum, 0, 2*H*sizeof(float), stream);
  k_stats<<<statBlocks,128,0,stream>>>(h, bnsum, bnsq, N, nper_stat);
  k_bnab<<<1,128,0,stream>>>(bnsum, bnsq, bng, bnb, 1.0f/(float)N, bna, bnb2);

  // layer 1 (BN0 fused into GEMM input)
  k_gemm2m<<<mmBlocks,256,0,stream>>>(h, WIf1, WCf1, bna, bnb2, tIb, tCb, N);
  k_aggrb<<<(N+3)/4,256,0,stream>>>(tIb, tCb, start, csr_sc, csr_cf,
                                    dinvI, dinvC, cIb+(size_t)H, cCb+(size_t)H,
                                    relg, 1, h, N);
  hipMemsetAsync(bnsum, 0, 2*H*sizeof(float), stream);
  k_stats<<<statBlocks,128,0,stream>>>(h, bnsum, bnsq, N, nper_stat);

  hipMemsetAsync(sumE, 0, ((size_t)2*G*H + 2*G)*sizeof(float), stream);
  k_poolbn<<<poolBlocks,128,0,stream>>>(h, batch, em, bnsum, bnsq,
                                        bng+(size_t)H, bnb+(size_t)H, 1.0f/(float)N,
                                        sumE, sumF, cntE, cntF, N, 32);
  k_head<<<G,128,0,stream>>>(sumE,sumF,cntE,cntF,
                             coW1,cob1,coW2,cob2, gW1,gb1,gW2,gb2,
                             cW1,cb1,cW2,cb2, peW1,peb1,peW2,peb2,
                             pfW1,pfb1,pfW2,pfb2, out, G);
}

// Round 12
// 597.456 us; speedup vs baseline: 3.8726x; 1.0907x over previous
//
#include <hip/hip_runtime.h>
#include <math.h>

#define H 128
#define D 256

typedef __attribute__((ext_vector_type(8))) short bf16x8;
typedef __attribute__((ext_vector_type(4))) float f32x4;

__device__ __forceinline__ float sigmoidf_(float x){ return 1.0f/(1.0f+__expf(-x)); }

// RNE float->bf16 (as uint in low 16 bits)
__device__ __forceinline__ unsigned int bfr_(float f){
  unsigned int u = __float_as_uint(f);
  return (u + 0x7fffu + ((u>>16)&1u)) >> 16;
}

// split a,b into packed bf16 hi / lo words (2 bf16 each)
__device__ __forceinline__ void split2(float a, float b, unsigned &hi, unsigned &lo){
  unsigned ha = bfr_(a), hb2 = bfr_(b);
  float fa = __uint_as_float(ha<<16), fb = __uint_as_float(hb2<<16);
  unsigned la = bfr_(a - fa), lb = bfr_(b - fb);
  hi = ha | (hb2<<16); lo = la | (lb<<16);
}

// pack trunc-bf16(|a0-b0|), trunc-bf16(|a1-b1|) into one uint via v_perm
__device__ __forceinline__ unsigned pair_dft(unsigned a, unsigned b){
  float a0 = __uint_as_float(a<<16), a1 = __uint_as_float(a & 0xffff0000u);
  float b0 = __uint_as_float(b<<16), b1 = __uint_as_float(b & 0xffff0000u);
  unsigned d0 = __float_as_uint(fabsf(a0-b0));
  unsigned d1 = __float_as_uint(fabsf(a1-b1));
  return __builtin_amdgcn_perm(d1, d0, 0x07060302);  // {d1.b3,d1.b2,d0.b3,d0.b2}
}

// All weight preprocessing in ONE launch (65 blocks x 256)
__global__ void k_prepall(const float* __restrict__ eegW, const float* __restrict__ fnW,
                          const float* __restrict__ cIW, const float* __restrict__ cCW,
                          const float* __restrict__ eW1,
                          unsigned short* WeF, unsigned short* WfF,
                          unsigned short* WIf0, unsigned short* WCf0,
                          unsigned short* WIf1, unsigned short* WCf1,
                          unsigned short* W1b)
{
  int b = blockIdx.x;
  int t = threadIdx.x;
  if (b < 64){
    const float* W; unsigned short* out; int ksteps; int boff;
    if (b < 16){ W=eegW; out=WeF; ksteps=8; boff=b; }
    else if (b < 32){ W=fnW; out=WfF; ksteps=8; boff=b-16; }
    else if (b < 40){ W=cIW;        out=WIf0; ksteps=4; boff=b-32; }
    else if (b < 48){ W=cCW;        out=WCf0; ksteps=4; boff=b-40; }
    else if (b < 56){ W=cIW+16384;  out=WIf1; ksteps=4; boff=b-48; }
    else            { W=cCW+16384;  out=WCf1; ksteps=4; boff=b-56; }
    int id = boff*256 + t;
    if (id >= ksteps*8*64) return;
    int lane = id & 63;
    int mfrag = (id>>6) & 7;
    int kstep = id >> 9;
    int col = mfrag*16 + (lane&15);
    int k0 = kstep*32 + (lane>>4)*8;
    unsigned short* oh = out + (size_t)(((kstep*8+mfrag)*2+0)*64 + lane)*8;
    unsigned short* ol = out + (size_t)(((kstep*8+mfrag)*2+1)*64 + lane)*8;
    #pragma unroll
    for (int j=0;j<8;j++){
      float w = W[(size_t)(k0+j)*128 + col];
      unsigned h16 = bfr_(w);
      float hf = __uint_as_float(h16<<16);
      oh[j] = (unsigned short)h16;
      ol[j] = (unsigned short)bfr_(w - hf);
    }
  } else {
    for (int it=0; it<4; it++){
      int le = it*256 + t;
      int f = le >> 6, lane = le & 63;
      int kstep = f >> 2, n = f & 3;
      int col = n*16 + (lane & 15);
      int k0 = kstep*32 + ((lane>>4)&3)*8;
      unsigned short* op = W1b + (size_t)le*8;
      #pragma unroll
      for (int j=0;j<8;j++)
        op[j] = (unsigned short)bfr_(eW1[(size_t)(k0+j)*64 + col]);
    }
  }
}

// proj via MFMA bf16x3, depth-2 prefetch of x rows. wave = 16 nodes x 128 ch.
__global__ __launch_bounds__(256) void k_projm(
    const float* __restrict__ x, const int* __restrict__ em,
    const unsigned short* __restrict__ WeF, const float* __restrict__ be,
    const unsigned short* __restrict__ WfF, const float* __restrict__ bf,
    float* __restrict__ h, unsigned int* __restrict__ hb, int N)
{
  int t = threadIdx.x;
  int lane = t & 63;
  int base = (blockIdx.x*4 + (t>>6))*16;
  if (base >= N) return;
  int node = base + (lane & 15);
  int nodeL = min(node, N-1);
  int ko = lane >> 4;

  f32x4 accE[8], accF[8];
  #pragma unroll
  for (int mf=0;mf<8;mf++){ accE[mf]=(f32x4){0.f,0.f,0.f,0.f}; accF[mf]=(f32x4){0.f,0.f,0.f,0.f}; }

  const bf16x8* we = reinterpret_cast<const bf16x8*>(WeF);
  const bf16x8* wf = reinterpret_cast<const bf16x8*>(WfF);
  const float4* xr0 = reinterpret_cast<const float4*>(x + (size_t)nodeL*D + ko*8);

  float4 nv0 = xr0[0], nv1 = xr0[1];
  #pragma unroll
  for (int kstep=0;kstep<8;kstep++){
    float4 v0 = nv0, v1 = nv1;
    if (kstep < 7){
      nv0 = xr0[(kstep+1)*8];      // +32 floats = 8 float4
      nv1 = xr0[(kstep+1)*8 + 1];
    }
    uint4 hiu, lou;
    split2(v0.x, v0.y, hiu.x, lou.x);
    split2(v0.z, v0.w, hiu.y, lou.y);
    split2(v1.x, v1.y, hiu.z, lou.z);
    split2(v1.z, v1.w, hiu.w, lou.w);
    bf16x8 Bhi = *reinterpret_cast<bf16x8*>(&hiu);
    bf16x8 Blo = *reinterpret_cast<bf16x8*>(&lou);
    #pragma unroll
    for (int mf=0;mf<8;mf++){
      int fb = (kstep*8+mf)*2;
      bf16x8 aEh = we[(size_t)fb*64 + lane];
      bf16x8 aEl = we[(size_t)(fb+1)*64 + lane];
      accE[mf] = __builtin_amdgcn_mfma_f32_16x16x32_bf16(aEh, Bhi, accE[mf], 0,0,0);
      accE[mf] = __builtin_amdgcn_mfma_f32_16x16x32_bf16(aEh, Blo, accE[mf], 0,0,0);
      accE[mf] = __builtin_amdgcn_mfma_f32_16x16x32_bf16(aEl, Bhi, accE[mf], 0,0,0);
      bf16x8 aFh = wf[(size_t)fb*64 + lane];
      bf16x8 aFl = wf[(size_t)(fb+1)*64 + lane];
      accF[mf] = __builtin_amdgcn_mfma_f32_16x16x32_bf16(aFh, Bhi, accF[mf], 0,0,0);
      accF[mf] = __builtin_amdgcn_mfma_f32_16x16x32_bf16(aFh, Blo, accF[mf], 0,0,0);
      accF[mf] = __builtin_amdgcn_mfma_f32_16x16x32_bf16(aFl, Bhi, accF[mf], 0,0,0);
    }
  }
  if (node >= N) return;
  bool e = em[node] != 0;
  #pragma unroll
  for (int mf=0;mf<8;mf++){
    float sv[4];
    #pragma unroll
    for (int r=0;r<4;r++){
      int ch = mf*16 + ko*4 + r;
      float vE = accE[mf][r] + be[ch];
      float vF = accF[mf][r] + bf[ch];
      sv[r] = fmaxf(e ? vE : vF, 0.f);
    }
    float2* hp = reinterpret_cast<float2*>(h + (size_t)node*H + mf*16 + ko*4);
    hp[0] = make_float2(sv[0], sv[1]);
    hp[1] = make_float2(sv[2], sv[3]);
    unsigned int* hbp = hb + (size_t)node*64 + mf*8 + ko*2;
    hbp[0] = bfr_(sv[0]) | (bfr_(sv[1])<<16);
    hbp[1] = bfr_(sv[2]) | (bfr_(sv[3])<<16);
  }
}

// dual GEMM via MFMA bf16x3: tI = A@WI, tC = A@WC, outputs packed bf16.
__global__ __launch_bounds__(256) void k_gemm2m(
    const float* __restrict__ A,
    const unsigned short* __restrict__ WIf, const unsigned short* __restrict__ WCf,
    const float* __restrict__ bna, const float* __restrict__ bnb2,
    unsigned int* __restrict__ tIb, unsigned int* __restrict__ tCb, int N)
{
  int t = threadIdx.x;
  int lane = t & 63;
  int base = (blockIdx.x*4 + (t>>6))*16;
  if (base >= N) return;
  int node = base + (lane & 15);
  int nodeL = min(node, N-1);
  int ko = lane >> 4;

  f32x4 accI[8], accC[8];
  #pragma unroll
  for (int mf=0;mf<8;mf++){ accI[mf]=(f32x4){0.f,0.f,0.f,0.f}; accC[mf]=(f32x4){0.f,0.f,0.f,0.f}; }

  const bf16x8* wi = reinterpret_cast<const bf16x8*>(WIf);
  const bf16x8* wc = reinterpret_cast<const bf16x8*>(WCf);
  bool doBN = (bna != nullptr);

  #pragma unroll
  for (int kstep=0;kstep<4;kstep++){
    const float4* ar = reinterpret_cast<const float4*>(A + (size_t)nodeL*H + kstep*32 + ko*8);
    float4 v0 = ar[0], v1 = ar[1];
    if (doBN){
      int ch = kstep*32 + ko*8;
      const float4* a4 = reinterpret_cast<const float4*>(bna + ch);
      const float4* b4 = reinterpret_cast<const float4*>(bnb2 + ch);
      float4 a0 = a4[0], a1 = a4[1], bb0 = b4[0], bb1 = b4[1];
      v0.x = fmaxf(fmaf(a0.x, v0.x, bb0.x), 0.f);
      v0.y = fmaxf(fmaf(a0.y, v0.y, bb0.y), 0.f);
      v0.z = fmaxf(fmaf(a0.z, v0.z, bb0.z), 0.f);
      v0.w = fmaxf(fmaf(a0.w, v0.w, bb0.w), 0.f);
      v1.x = fmaxf(fmaf(a1.x, v1.x, bb1.x), 0.f);
      v1.y = fmaxf(fmaf(a1.y, v1.y, bb1.y), 0.f);
      v1.z = fmaxf(fmaf(a1.z, v1.z, bb1.z), 0.f);
      v1.w = fmaxf(fmaf(a1.w, v1.w, bb1.w), 0.f);
    }
    uint4 hiu, lou;
    split2(v0.x, v0.y, hiu.x, lou.x);
    split2(v0.z, v0.w, hiu.y, lou.y);
    split2(v1.x, v1.y, hiu.z, lou.z);
    split2(v1.z, v1.w, hiu.w, lou.w);
    bf16x8 Bhi = *reinterpret_cast<bf16x8*>(&hiu);
    bf16x8 Blo = *reinterpret_cast<bf16x8*>(&lou);
    #pragma unroll
    for (int mf=0;mf<8;mf++){
      int fb = (kstep*8+mf)*2;
      bf16x8 aIh = wi[(size_t)fb*64 + lane];
      bf16x8 aIl = wi[(size_t)(fb+1)*64 + lane];
      accI[mf] = __builtin_amdgcn_mfma_f32_16x16x32_bf16(aIh, Bhi, accI[mf], 0,0,0);
      accI[mf] = __builtin_amdgcn_mfma_f32_16x16x32_bf16(aIh, Blo, accI[mf], 0,0,0);
      accI[mf] = __builtin_amdgcn_mfma_f32_16x16x32_bf16(aIl, Bhi, accI[mf], 0,0,0);
      bf16x8 aCh = wc[(size_t)fb*64 + lane];
      bf16x8 aCl = wc[(size_t)(fb+1)*64 + lane];
      accC[mf] = __builtin_amdgcn_mfma_f32_16x16x32_bf16(aCh, Bhi, accC[mf], 0,0,0);
      accC[mf] = __builtin_amdgcn_mfma_f32_16x16x32_bf16(aCh, Blo, accC[mf], 0,0,0);
      accC[mf] = __builtin_amdgcn_mfma_f32_16x16x32_bf16(aCl, Bhi, accC[mf], 0,0,0);
    }
  }
  if (node >= N) return;
  #pragma unroll
  for (int mf=0;mf<8;mf++){
    unsigned int* ti = tIb + (size_t)node*64 + mf*8 + ko*2;
    unsigned int* tc = tCb + (size_t)node*64 + mf*8 + ko*2;
    ti[0] = bfr_(accI[mf][0]) | (bfr_(accI[mf][1])<<16);
    ti[1] = bfr_(accI[mf][2]) | (bfr_(accI[mf][3])<<16);
    tc[0] = bfr_(accC[mf][0]) | (bfr_(accC[mf][1])<<16);
    tc[1] = bfr_(accC[mf][2]) | (bfr_(accC[mf][3])<<16);
  }
}

// ---- CSR build ----
__global__ void k_hist(const int* __restrict__ ei, int* __restrict__ cnt, int E){
  int e = blockIdx.x*blockDim.x + threadIdx.x;
  if (e < E) atomicAdd(cnt + ei[E+e], 1);
}

// multi-block scan, phase A: per-block exclusive scan + block sums
__global__ __launch_bounds__(1024) void k_scanA(const int* __restrict__ cnt,
                                                int* __restrict__ start,
                                                int* __restrict__ bsum, int N){
  __shared__ int wsum[16];
  int t = threadIdx.x;
  int lane = t & 63, wid = t >> 6;
  int i = blockIdx.x*1024 + t;
  int v = (i < N) ? cnt[i] : 0;
  int s = v;
  #pragma unroll
  for (int d=1; d<64; d<<=1){
    int u = __shfl_up(s, d, 64);
    if (lane >= d) s += u;
  }
  if (lane == 63) wsum[wid] = s;
  __syncthreads();
  if (wid == 0){
    int w = (lane < 16) ? wsum[lane] : 0;
    #pragma unroll
    for (int d=1; d<16; d<<=1){
      int u = __shfl_up(w, d, 64);
      if (lane >= d) w += u;
    }
    if (lane < 16) wsum[lane] = w;
  }
  __syncthreads();
  int incl = s + ((wid > 0) ? wsum[wid-1] : 0);
  if (i < N) start[i] = incl - v;
  if (t == 1023) bsum[blockIdx.x] = incl;
}

// phase C: add block-prefix offsets; last block writes start[N]
__global__ __launch_bounds__(1024) void k_scanC(int* __restrict__ start,
                                                const int* __restrict__ bsum,
                                                int N, int nb){
  int b = blockIdx.x, t = threadIdx.x;
  int o = 0;
  for (int j=0;j<b;j++) o += bsum[j];
  int i = b*1024 + t;
  if (i < N) start[i] += o;
  if (b == nb-1 && t == 0) start[N] = o + bsum[b];
}

__global__ void k_fill2(const int* __restrict__ ei, const int* __restrict__ em,
                        const float* __restrict__ ew,
                        const int* __restrict__ start, int* __restrict__ wcnt,
                        int* __restrict__ csr_sc, int* __restrict__ csr_d,
                        float* __restrict__ csr_w, int E){
  int e = blockIdx.x*blockDim.x + threadIdx.x;
  if (e >= E) return;
  int s = ei[e], d = ei[E+e];
  int chan = (em[s] == em[d]) ? 0 : 1;
  int pos = start[d] + atomicAdd(wcnt + d, 1);
  csr_sc[pos] = (s<<1) | chan;
  csr_d[pos] = d;
  csr_w[pos] = ew[e];
}

// per-edge MLP gate via MFMA. wave = 32 edges; W1 fragments in LDS;
// both groups' row-gathers issued upfront for deep latency hiding.
__global__ __launch_bounds__(256) void k_edgem(
    const unsigned int* __restrict__ hb,
    const int* __restrict__ csr_sc, const int* __restrict__ csr_d,
    const float* __restrict__ csr_w, const unsigned short* __restrict__ W1b,
    const float* __restrict__ W1, const float* __restrict__ b1,
    const float* __restrict__ W2, const float* __restrict__ b2,
    float* __restrict__ csr_cf,
    float* __restrict__ degI, float* __restrict__ degC, int E)
{
  __shared__ uint4 wlds[1024];   // 16 KB: all W1 B-fragments
  int t = threadIdx.x;
  {
    const uint4* src = reinterpret_cast<const uint4*>(W1b);
    #pragma unroll
    for (int i=0;i<4;i++) wlds[i*256 + t] = src[i*256 + t];
  }
  __syncthreads();

  int lane = t & 63;
  int base0 = (blockIdx.x*4 + (t>>6)) * 32;
  if (base0 >= E) return;

  int colbase = lane & 15;
  int ko = lane >> 4;
  float w1l[4], b1v[4], w2v[4];
  #pragma unroll
  for (int n=0;n<4;n++){
    int col = n*16 + colbase;
    w1l[n] = W1[(size_t)128*64 + col];
    b1v[n] = b1[col];
    w2v[n] = W2[col];
  }
  float bb2 = b2[0];

  uint4 us[2][4], ud[2][4];
  #pragma unroll
  for (int eg=0; eg<2; eg++){
    int e = min(base0 + eg*16 + colbase, E-1);
    int s = csr_sc[e] >> 1;
    int d = csr_d[e];
    const uint4* hsp = reinterpret_cast<const uint4*>(hb + (size_t)s*64);
    const uint4* hdp = reinterpret_cast<const uint4*>(hb + (size_t)d*64);
    #pragma unroll
    for (int kstep=0;kstep<4;kstep++){
      us[eg][kstep] = hsp[kstep*4 + ko];
      ud[eg][kstep] = hdp[kstep*4 + ko];
    }
  }

  const bf16x8* wl = reinterpret_cast<const bf16x8*>(wlds);
  #pragma unroll
  for (int eg=0; eg<2; eg++){
    int base = base0 + eg*16;
    if (base >= E) break;

    f32x4 acc[4];
    #pragma unroll
    for (int n=0;n<4;n++) acc[n] = (f32x4){0.f,0.f,0.f,0.f};

    #pragma unroll
    for (int kstep=0;kstep<4;kstep++){
      uint4 pa;
      pa.x = pair_dft(us[eg][kstep].x, ud[eg][kstep].x);
      pa.y = pair_dft(us[eg][kstep].y, ud[eg][kstep].y);
      pa.z = pair_dft(us[eg][kstep].z, ud[eg][kstep].z);
      pa.w = pair_dft(us[eg][kstep].w, ud[eg][kstep].w);
      bf16x8 a = *reinterpret_cast<bf16x8*>(&pa);
      #pragma unroll
      for (int n=0;n<4;n++)
        acc[n] = __builtin_amdgcn_mfma_f32_16x16x32_bf16(a, wl[(kstep*4+n)*64 + lane], acc[n], 0,0,0);
    }

    float wgtr[4];
    #pragma unroll
    for (int r=0;r<4;r++)
      wgtr[r] = csr_w[min(base + ko*4 + r, E-1)];

    float part[4] = {0.f,0.f,0.f,0.f};
    #pragma unroll
    for (int n=0;n<4;n++){
      #pragma unroll
      for (int r=0;r<4;r++){
        float v = fmaxf(acc[n][r] + fmaf(wgtr[r], w1l[n], b1v[n]), 0.f);
        part[r] = fmaf(v, w2v[n], part[r]);
      }
    }
    #pragma unroll
    for (int m=1;m<16;m<<=1){
      #pragma unroll
      for (int r=0;r<4;r++) part[r] += __shfl_xor(part[r], m, 64);
    }

    if (colbase == 0){
      #pragma unroll
      for (int r=0;r<4;r++){
        int ee = base + ko*4 + r;
        if (ee < E){
          float g = sigmoidf_(part[r] + bb2);
          g = fminf(fmaxf(g, 0.2f), 1.2f);
          float ehat = wgtr[r] * g;
          csr_cf[ee] = ehat;
          int sc2 = csr_sc[ee];
          atomicAdd(((sc2&1) ? degC : degI) + csr_d[ee], ehat);
        }
      }
    }
  }
}

__global__ void k_dinv(const float* __restrict__ degI, const float* __restrict__ degC,
                       float* dinvI, float* dinvC, int N){
  int i = blockIdx.x*blockDim.x + threadIdx.x;
  if (i < N){
    dinvI[i] = rsqrtf(1.f + degI[i]);
    dinvC[i] = rsqrtf(1.f + degC[i]);
  }
}

__global__ void k_scale(const int* __restrict__ csr_sc, const int* __restrict__ csr_d,
                        const float* __restrict__ dinvI, const float* __restrict__ dinvC,
                        float* __restrict__ csr_cf, int E){
  int k = blockIdx.x*blockDim.x + threadIdx.x;
  if (k >= E) return;
  int sc = csr_sc[k];
  int s = sc>>1;
  int d = csr_d[k];
  const float* dv = (sc&1) ? dinvC : dinvI;
  csr_cf[k] *= dv[s]*dv[d];
}

// BN scale/shift precompute: a = gamma*rsqrt(var+eps), b = beta - a*mu
__global__ void k_bnab(const float* __restrict__ bnsum, const float* __restrict__ bnsq,
                       const float* __restrict__ gamma, const float* __restrict__ beta,
                       float invN, float* __restrict__ bna, float* __restrict__ bnb2){
  int j = threadIdx.x;
  float mu = bnsum[j]*invN;
  float var = bnsq[j]*invN - mu*mu;
  float r = rsqrtf(var + 1e-5f);
  float a = gamma[j]*r;
  bna[j] = a;
  bnb2[j] = beta[j] - a*mu;
}

// one wave per dst node: gather bf16 CSR messages (8-deep unrolled)
// + fused self-loop/bias epilogue.
__global__ __launch_bounds__(256) void k_aggrb(
    const unsigned int* __restrict__ tIb, const unsigned int* __restrict__ tCb,
    const int* __restrict__ start, const int* __restrict__ csr_sc,
    const float* __restrict__ csr_cf,
    const float* __restrict__ dinvI, const float* __restrict__ dinvC,
    const float* __restrict__ bI, const float* __restrict__ bC,
    const float* __restrict__ relg, int l,
    float* __restrict__ h, int N)
{
  int lane = threadIdx.x & 63;
  int d = blockIdx.x*4 + (threadIdx.x>>6);
  if (d >= N) return;
  float sig = sigmoidf_(relg[l]);
  int k0 = start[d], k1 = start[d+1];
  float ax=0.f, ay=0.f;
  int k = k0;
  for (; k+8 <= k1; k += 8){
    unsigned vv[8]; float cc[8];
    #pragma unroll
    for (int u=0;u<8;u++){
      int sc = csr_sc[k+u];
      float cf = csr_cf[k+u];
      vv[u] = ((sc&1) ? tCb : tIb)[(size_t)(sc>>1)*64 + lane];
      cc[u] = (sc&1) ? sig*cf : cf;
    }
    #pragma unroll
    for (int u=0;u<8;u++){
      ax = fmaf(cc[u], __uint_as_float(vv[u]<<16), ax);
      ay = fmaf(cc[u], __uint_as_float(vv[u] & 0xffff0000u), ay);
    }
  }
  for (; k < k1; ++k){
    int sc = csr_sc[k];
    float cf = csr_cf[k];
    unsigned v = ((sc&1) ? tCb : tIb)[(size_t)(sc>>1)*64 + lane];
    float ce = (sc&1) ? sig*cf : cf;
    ax = fmaf(ce, __uint_as_float(v<<16), ax);
    ay = fmaf(ce, __uint_as_float(v & 0xffff0000u), ay);
  }
  float diI = dinvI[d], diC = dinvC[d];
  float rI = diI*diI, rC = diC*diC;
  unsigned vi = tIb[(size_t)d*64 + lane];
  unsigned vc = tCb[(size_t)d*64 + lane];
  int off = lane*2;
  float ox = fmaf(__uint_as_float(vi<<16), rI, bI[off])
           + sig*fmaf(__uint_as_float(vc<<16), rC, bC[off]) + ax;
  float oy = fmaf(__uint_as_float(vi & 0xffff0000u), rI, bI[off+1])
           + sig*fmaf(__uint_as_float(vc & 0xffff0000u), rC, bC[off+1]) + ay;
  *reinterpret_cast<float2*>(h + (size_t)d*H + off) = make_float2(ox, oy);
}

__global__ __launch_bounds__(128) void k_stats(const float* __restrict__ h,
    float* __restrict__ bnsum, float* __restrict__ bnsq, int N, int nper)
{
  int j = threadIdx.x;
  int n0 = blockIdx.x*nper, n1 = min(n0+nper, N);
  if (n0 >= N) return;
  float sl=0.f, sq=0.f;
  for (int n=n0;n<n1;n++){
    float v = h[(size_t)n*H+j];
    sl += v; sq = fmaf(v,v,sq);
  }
  atomicAdd(bnsum+j, sl); atomicAdd(bnsq+j, sq);
}

// pool with BN+relu applied on the fly (layer-2 fusion)
__global__ __launch_bounds__(128) void k_poolbn(
    const float* __restrict__ h, const int* __restrict__ batch, const int* __restrict__ em,
    const float* __restrict__ bnsum, const float* __restrict__ bnsq,
    const float* __restrict__ gamma, const float* __restrict__ beta, float invN,
    float* __restrict__ sumE, float* __restrict__ sumF,
    float* __restrict__ cntE, float* __restrict__ cntF, int N, int nper)
{
  int j = threadIdx.x;
  int n0 = blockIdx.x*nper, n1 = min(n0+nper, N);
  if (n0 >= N) return;
  float mu = bnsum[j]*invN;
  float var = bnsq[j]*invN - mu*mu;
  float rr = rsqrtf(var + 1e-5f);
  float ga = gamma[j], be = beta[j];
  float aE=0.f, aF=0.f, ce=0.f, cfc=0.f;
  int cg = batch[n0];
  for (int n=n0;n<n1;n++){
    int g = batch[n];
    if (g != cg){
      atomicAdd(sumE+(size_t)cg*H+j, aE);
      atomicAdd(sumF+(size_t)cg*H+j, aF);
      if (j==0){ atomicAdd(cntE+cg, ce); atomicAdd(cntF+cg, cfc); }
      aE=aF=ce=cfc=0.f; cg=g;
    }
    float v = fmaxf(fmaf(ga, (h[(size_t)n*H+j]-mu)*rr, be), 0.f);
    bool eb = em[n] != 0;
    if (eb) aE += v; else aF += v;
    if (j==0){ if (eb) ce += 1.f; else cfc += 1.f; }
  }
  atomicAdd(sumE+(size_t)cg*H+j, aE);
  atomicAdd(sumF+(size_t)cg*H+j, aF);
  if (j==0){ atomicAdd(cntE+cg, ce); atomicAdd(cntF+cg, cfc); }
}

__device__ __forceinline__ float blockReduceSum(float v, float* red){
  int t = threadIdx.x;
  red[t] = v; __syncthreads();
  #pragma unroll
  for (int s=64;s>0;s>>=1){ if (t<s) red[t]+=red[t+s]; __syncthreads(); }
  float r = red[0]; __syncthreads();
  return r;
}

__global__ __launch_bounds__(128) void k_head(
    const float* __restrict__ sumE, const float* __restrict__ sumF,
    const float* __restrict__ cntE, const float* __restrict__ cntF,
    const float* __restrict__ coW1, const float* __restrict__ cob1,
    const float* __restrict__ coW2, const float* __restrict__ cob2,
    const float* __restrict__ gW1, const float* __restrict__ gb1,
    const float* __restrict__ gW2, const float* __restrict__ gb2,
    const float* __restrict__ cW1, const float* __restrict__ cb1,
    const float* __restrict__ cW2, const float* __restrict__ cb2,
    const float* __restrict__ peW1, const float* __restrict__ peb1,
    const float* __restrict__ peW2, const float* __restrict__ peb2,
    const float* __restrict__ pfW1, const float* __restrict__ pfb1,
    const float* __restrict__ pfW2, const float* __restrict__ pfb2,
    float* __restrict__ out, int G)
{
  int g = blockIdx.x, j = threadIdx.x;
  __shared__ float sh[384];
  __shared__ float red[128];
  __shared__ float hfin[128], buf[128];
  float cE = cntE[g], cF = cntF[g];
  float se = sumE[(size_t)g*H+j], sf = sumF[(size_t)g*H+j];
  float he = se/fmaxf(cE,1.f), hf = sf/fmaxf(cF,1.f);
  float hg = (se+sf)/fmaxf(cE+cF,1.f);
  sh[j]=he; sh[128+j]=hf; sh[256+j]=he*hf;
  __syncthreads();
  float a = cob1[j];
  for (int k=0;k<384;k++) a = fmaf(sh[k], coW1[k*H+j], a);
  a = fmaxf(a, 0.f);
  float r0 = blockReduceSum(a*coW2[2*j],   red);
  float r1 = blockReduceSum(a*coW2[2*j+1], red);
  float al0 = sigmoidf_(r0 + cob2[0]);
  float al1 = sigmoidf_(r1 + cob2[1]);
  float asum = al0+al1+1e-6f; al0/=asum; al1/=asum;
  float hc = al0*he + al1*hf;
  __syncthreads();
  sh[j]=hc; sh[128+j]=hg;
  __syncthreads();
  float gg = gb1[j];
  for (int k=0;k<256;k++) gg = fmaf(sh[k], gW1[k*H+j], gg);
  gg = fmaxf(gg, 0.f);
  float gt = sigmoidf_(blockReduceSum(gg*gW2[j], red) + gb2[0]);
  float hfj = gt*hc + (1.f-gt)*hg;
  hfin[j] = hfj;
  __syncthreads();
  float c1v = 0.f;
  if (j < 64){
    float c1 = cb1[j];
    for (int k=0;k<128;k++) c1 = fmaf(hfin[k], cW1[k*64+j], c1);
    c1v = fmaxf(c1, 0.f);
  }
  float l0 = blockReduceSum(j<64 ? c1v*cW2[2*j]   : 0.f, red);
  float l1 = blockReduceSum(j<64 ? c1v*cW2[2*j+1] : 0.f, red);
  if (j==0){ out[(size_t)g*2] = l0 + cb2[0]; out[(size_t)g*2+1] = l1 + cb2[1]; }
  // z_e
  buf[j] = he; __syncthreads();
  float q = peb1[j];
  for (int k=0;k<128;k++) q = fmaf(buf[k], peW1[k*H+j], q);
  q = fmaxf(q, 0.f);
  __syncthreads(); sh[j] = q; __syncthreads();
  float z = peb2[j];
  for (int k=0;k<128;k++) z = fmaf(sh[k], peW2[k*H+j], z);
  float nr = sqrtf(blockReduceSum(z*z, red));
  out[(size_t)G*2 + (size_t)g*H + j] = z / fmaxf(nr, 1e-12f);
  // z_f
  __syncthreads(); buf[j] = hf; __syncthreads();
  float q2 = pfb1[j];
  for (int k=0;k<128;k++) q2 = fmaf(buf[k], pfW1[k*H+j], q2);
  q2 = fmaxf(q2, 0.f);
  __syncthreads(); sh[j] = q2; __syncthreads();
  float z2 = pfb2[j];
  for (int k=0;k<128;k++) z2 = fmaf(sh[k], pfW2[k*H+j], z2);
  float nr2 = sqrtf(blockReduceSum(z2*z2, red));
  out[(size_t)G*2 + (size_t)G*H + (size_t)g*H + j] = z2 / fmaxf(nr2, 1e-12f);
}

extern "C" void kernel_launch(void* const* d_in, const int* in_sizes, int n_in,
                              void* d_out, int out_size, void* d_ws, size_t ws_size,
                              hipStream_t stream)
{
  const float* x    = (const float*)d_in[0];
  const int*   ei   = (const int*)d_in[1];
  const float* ew   = (const float*)d_in[2];
  const int*   batch= (const int*)d_in[3];
  const int*   em   = (const int*)d_in[4];
  const float* eegW = (const float*)d_in[6];  const float* eegB = (const float*)d_in[7];
  const float* fnW  = (const float*)d_in[8];  const float* fnB  = (const float*)d_in[9];
  const float* eW1  = (const float*)d_in[10]; const float* eb1  = (const float*)d_in[11];
  const float* eW2  = (const float*)d_in[12]; const float* eb2  = (const float*)d_in[13];
  const float* cIW  = (const float*)d_in[14]; const float* cIb  = (const float*)d_in[15];
  const float* cCW  = (const float*)d_in[16]; const float* cCb  = (const float*)d_in[17];
  const float* relg = (const float*)d_in[18];
  const float* bng  = (const float*)d_in[19]; const float* bnb  = (const float*)d_in[20];
  const float* coW1 = (const float*)d_in[21]; const float* cob1 = (const float*)d_in[22];
  const float* coW2 = (const float*)d_in[23]; const float* cob2 = (const float*)d_in[24];
  const float* gW1  = (const float*)d_in[25]; const float* gb1  = (const float*)d_in[26];
  const float* gW2  = (const float*)d_in[27]; const float* gb2  = (const float*)d_in[28];
  const float* cW1  = (const float*)d_in[29]; const float* cb1  = (const float*)d_in[30];
  const float* cW2  = (const float*)d_in[31]; const float* cb2  = (const float*)d_in[32];
  const float* peW1 = (const float*)d_in[33]; const float* peb1 = (const float*)d_in[34];
  const float* peW2 = (const float*)d_in[35]; const float* peb2 = (const float*)d_in[36];
  const float* pfW1 = (const float*)d_in[37]; const float* pfb1 = (const float*)d_in[38];
  const float* pfW2 = (const float*)d_in[39]; const float* pfb2 = (const float*)d_in[40];
  float* out = (float*)d_out;

  int N = in_sizes[0] / D;           // 50000
  int E = in_sizes[2];               // 800000
  int G = out_size / (2 + 2*H);      // 500
  int NH = N*H;

  float* p = (float*)d_ws;
  float* h    = p; p += (size_t)NH;
  float* tI   = p; p += (size_t)NH;   // overlays: hb (pre-loop) and tIb (loop), both bf16
  float* tC   = p; p += (size_t)NH;   // overlay: tCb
  float* csr_cf = p; p += E;
  float* csr_w  = p; p += E;
  int* csr_sc = (int*)p; p += E;
  int* csr_d  = (int*)p; p += E;
  int* start  = (int*)p; p += (N+1);
  int* cnt    = (int*)p; p += N;      // cnt, wcnt, degI, degC contiguous -> one memset
  int* wcnt   = (int*)p; p += N;
  float* degI = p; p += N;
  float* degC = p; p += N;
  float* dinvI= p; p += N;
  float* dinvC= p; p += N;
  float* bnsum= p; p += H;            // bnsum+bnsq contiguous
  float* bnsq = p; p += H;
  float* bna  = p; p += H;
  float* bnb2 = p; p += H;
  float* sumE = p; p += (size_t)G*H;  // sumE..cntF contiguous
  float* sumF = p; p += (size_t)G*H;
  float* cntE = p; p += G;
  float* cntF = p; p += G;
  int* bsum   = (int*)p; p += 64;
  unsigned short* W1b = (unsigned short*)p; p += 4096;   // 8192 bf16 = 16 KB
  unsigned short* WeF = (unsigned short*)p; p += 32768;  // 128 KB
  unsigned short* WfF = (unsigned short*)p; p += 32768;  // 128 KB
  unsigned short* WIf0= (unsigned short*)p; p += 16384;  // 64 KB
  unsigned short* WCf0= (unsigned short*)p; p += 16384;
  unsigned short* WIf1= (unsigned short*)p; p += 16384;
  unsigned short* WCf1= (unsigned short*)p; p += 16384;

  unsigned int* hb  = (unsigned int*)tI;  // bf16 h, used only before layer loop
  unsigned int* tIb = (unsigned int*)tI;  // bf16 messages (loop)
  unsigned int* tCb = (unsigned int*)tC;

  int mmBlocks = ((N+15)/16 + 3)/4;   // 16 nodes/wave, 4 waves/block
  int edgeBlocks = (E + 127)/128;     // 32 edges/wave, 4 waves/block
  int statBlocks = 1024;
  int nper_stat = (N + statBlocks - 1)/statBlocks;
  int poolBlocks = (N + 31)/32;
  int scanBlocks = (N + 1023)/1024;

  hipMemsetAsync(cnt, 0, (size_t)4*N*sizeof(int), stream);  // cnt,wcnt,degI,degC
  k_hist<<<(E+255)/256,256,0,stream>>>(ei, cnt, E);
  k_scanA<<<scanBlocks,1024,0,stream>>>(cnt, start, bsum, N);
  k_scanC<<<scanBlocks,1024,0,stream>>>(start, bsum, N, scanBlocks);
  k_fill2<<<(E+255)/256,256,0,stream>>>(ei, em, ew, start, wcnt,
                                        csr_sc, csr_d, csr_w, E);
  k_prepall<<<65,256,0,stream>>>(eegW, fnW, cIW, cCW, eW1,
                                 WeF, WfF, WIf0, WCf0, WIf1, WCf1, W1b);

  k_projm<<<mmBlocks,256,0,stream>>>(x, em, WeF, eegB, WfF, fnB, h, hb, N);
  k_edgem<<<edgeBlocks,256,0,stream>>>(hb, csr_sc, csr_d, csr_w, W1b,
                                       eW1, eb1, eW2, eb2, csr_cf, degI, degC, E);
  k_dinv<<<(N+255)/256,256,0,stream>>>(degI,degC,dinvI,dinvC,N);
  k_scale<<<(E+255)/256,256,0,stream>>>(csr_sc, csr_d, dinvI, dinvC, csr_cf, E);

  // layer 0
  k_gemm2m<<<mmBlocks,256,0,stream>>>(h, WIf0, WCf0, nullptr, nullptr, tIb, tCb, N);
  k_aggrb<<<(N+3)/4,256,0,stream>>>(tIb, tCb, start, csr_sc, csr_cf,
                                    dinvI, dinvC, cIb, cCb, relg, 0, h, N);
  hipMemsetAsync(bnsum, 0, 2*H*sizeof(float), stream);
  k_stats<<<statBlocks,128,0,stream>>>(h, bnsum, bnsq, N, nper_stat);
  k_bnab<<<1,128,0,stream>>>(bnsum, bnsq, bng, bnb, 1.0f/(float)N, bna, bnb2);

  // layer 1 (BN0 fused into GEMM input)
  k_gemm2m<<<mmBlocks,256,0,stream>>>(h, WIf1, WCf1, bna, bnb2, tIb, tCb, N);
  k_aggrb<<<(N+3)/4,256,0,stream>>>(tIb, tCb, start, csr_sc, csr_cf,
                                    dinvI, dinvC, cIb+(size_t)H, cCb+(size_t)H,
                                    relg, 1, h, N);
  hipMemsetAsync(bnsum, 0, 2*H*sizeof(float), stream);
  k_stats<<<statBlocks,128,0,stream>>>(h, bnsum, bnsq, N, nper_stat);

  hipMemsetAsync(sumE, 0, ((size_t)2*G*H + 2*G)*sizeof(float), stream);
  k_poolbn<<<poolBlocks,128,0,stream>>>(h, batch, em, bnsum, bnsq,
                                        bng+(size_t)H, bnb+(size_t)H, 1.0f/(float)N,
                                        sumE, sumF, cntE, cntF, N, 32);
  k_head<<<G,128,0,stream>>>(sumE,sumF,cntE,cntF,
                             coW1,cob1,coW2,cob2, gW1,gb1,gW2,gb2,
                             cW1,cb1,cW2,cb2, peW1,peb1,peW2,peb2,
                             pfW1,pfb1,pfW2,pfb2, out, G);
}

// Round 13
// 560.835 us; speedup vs baseline: 4.1254x; 1.0653x over previous
//
#include <hip/hip_runtime.h>
#include <math.h>

#define H 128
#define D 256

typedef __attribute__((ext_vector_type(8))) short bf16x8;
typedef __attribute__((ext_vector_type(4))) float f32x4;

__device__ __forceinline__ float sigmoidf_(float x){ return 1.0f/(1.0f+__expf(-x)); }

// RNE float->bf16 (as uint in low 16 bits)
__device__ __forceinline__ unsigned int bfr_(float f){
  unsigned int u = __float_as_uint(f);
  return (u + 0x7fffu + ((u>>16)&1u)) >> 16;
}

// split a,b into packed bf16 hi / lo words (2 bf16 each)
__device__ __forceinline__ void split2(float a, float b, unsigned &hi, unsigned &lo){
  unsigned ha = bfr_(a), hb2 = bfr_(b);
  float fa = __uint_as_float(ha<<16), fb = __uint_as_float(hb2<<16);
  unsigned la = bfr_(a - fa), lb = bfr_(b - fb);
  hi = ha | (hb2<<16); lo = la | (lb<<16);
}

// pack trunc-bf16(|a0-b0|), trunc-bf16(|a1-b1|) into one uint via v_perm
__device__ __forceinline__ unsigned pair_dft(unsigned a, unsigned b){
  float a0 = __uint_as_float(a<<16), a1 = __uint_as_float(a & 0xffff0000u);
  float b0 = __uint_as_float(b<<16), b1 = __uint_as_float(b & 0xffff0000u);
  unsigned d0 = __float_as_uint(fabsf(a0-b0));
  unsigned d1 = __float_as_uint(fabsf(a1-b1));
  return __builtin_amdgcn_perm(d1, d0, 0x07060302);
}

// All weight preprocessing in ONE launch (65 blocks x 256)
__global__ void k_prepall(const float* __restrict__ eegW, const float* __restrict__ fnW,
                          const float* __restrict__ cIW, const float* __restrict__ cCW,
                          const float* __restrict__ eW1,
                          unsigned short* WeF, unsigned short* WfF,
                          unsigned short* WIf0, unsigned short* WCf0,
                          unsigned short* WIf1, unsigned short* WCf1,
                          unsigned short* W1b)
{
  int b = blockIdx.x;
  int t = threadIdx.x;
  if (b < 64){
    const float* W; unsigned short* out; int ksteps; int boff;
    if (b < 16){ W=eegW; out=WeF; ksteps=8; boff=b; }
    else if (b < 32){ W=fnW; out=WfF; ksteps=8; boff=b-16; }
    else if (b < 40){ W=cIW;        out=WIf0; ksteps=4; boff=b-32; }
    else if (b < 48){ W=cCW;        out=WCf0; ksteps=4; boff=b-40; }
    else if (b < 56){ W=cIW+16384;  out=WIf1; ksteps=4; boff=b-48; }
    else            { W=cCW+16384;  out=WCf1; ksteps=4; boff=b-56; }
    int id = boff*256 + t;
    if (id >= ksteps*8*64) return;
    int lane = id & 63;
    int mfrag = (id>>6) & 7;
    int kstep = id >> 9;
    int col = mfrag*16 + (lane&15);
    int k0 = kstep*32 + (lane>>4)*8;
    unsigned short* oh = out + (size_t)(((kstep*8+mfrag)*2+0)*64 + lane)*8;
    unsigned short* ol = out + (size_t)(((kstep*8+mfrag)*2+1)*64 + lane)*8;
    #pragma unroll
    for (int j=0;j<8;j++){
      float w = W[(size_t)(k0+j)*128 + col];
      unsigned h16 = bfr_(w);
      float hf = __uint_as_float(h16<<16);
      oh[j] = (unsigned short)h16;
      ol[j] = (unsigned short)bfr_(w - hf);
    }
  } else {
    for (int it=0; it<4; it++){
      int le = it*256 + t;
      int f = le >> 6, lane = le & 63;
      int kstep = f >> 2, n = f & 3;
      int col = n*16 + (lane & 15);
      int k0 = kstep*32 + ((lane>>4)&3)*8;
      unsigned short* op = W1b + (size_t)le*8;
      #pragma unroll
      for (int j=0;j<8;j++)
        op[j] = (unsigned short)bfr_(eW1[(size_t)(k0+j)*64 + col]);
    }
  }
}

// build modality-partitioned node list: E nodes first (16-padded), then F nodes
__global__ void k_part(const int* __restrict__ em, const int* __restrict__ escan,
                       int* __restrict__ nodelist, int N){
  int i = blockIdx.x*blockDim.x + threadIdx.x;
  int NE = escan[N];
  int NEpad = (NE+15)&~15;
  if (i < N){
    int pos = em[i] ? escan[i] : NEpad + (i - escan[i]);
    nodelist[pos] = i;
  }
  if (i < 16){
    if (NE + i < NEpad) nodelist[NE + i] = 0;
    int TOT = NEpad + (N - NE);
    int TOTpad = (TOT+15)&~15;
    if (TOT + i < TOTpad) nodelist[TOT + i] = 0;
  }
}

// proj via MFMA bf16x3, modality-partitioned: each wave handles 16 nodes of ONE
// modality (one weight set, 192 MFMAs).
__global__ __launch_bounds__(256) void k_projm(
    const float* __restrict__ x, const int* __restrict__ nodelist,
    const int* __restrict__ escan, int N,
    const unsigned short* __restrict__ WeF, const float* __restrict__ be,
    const unsigned short* __restrict__ WfF, const float* __restrict__ bf,
    float* __restrict__ h, unsigned int* __restrict__ hb)
{
  int t = threadIdx.x;
  int lane = t & 63;
  int base = (blockIdx.x*4 + (t>>6))*16;
  int NE = escan[N];
  int NEpad = (NE+15)&~15;
  int TOT = NEpad + (N - NE);
  if (base >= TOT) return;
  bool isE = (base < NEpad);
  int slot = base + (lane & 15);
  bool valid = isE ? (slot < NE) : (slot < TOT);
  int node = nodelist[slot];
  int ko = lane >> 4;

  f32x4 acc[8];
  #pragma unroll
  for (int mf=0;mf<8;mf++) acc[mf]=(f32x4){0.f,0.f,0.f,0.f};

  const bf16x8* wsel = reinterpret_cast<const bf16x8*>(isE ? WeF : WfF);
  const float* bsel = isE ? be : bf;
  const float4* xr0 = reinterpret_cast<const float4*>(x + (size_t)node*D + ko*8);

  for (int kstep=0;kstep<8;kstep++){
    float4 v0 = xr0[kstep*8], v1 = xr0[kstep*8 + 1];
    uint4 hiu, lou;
    split2(v0.x, v0.y, hiu.x, lou.x);
    split2(v0.z, v0.w, hiu.y, lou.y);
    split2(v1.x, v1.y, hiu.z, lou.z);
    split2(v1.z, v1.w, hiu.w, lou.w);
    bf16x8 Bhi = *reinterpret_cast<bf16x8*>(&hiu);
    bf16x8 Blo = *reinterpret_cast<bf16x8*>(&lou);
    #pragma unroll
    for (int mf=0;mf<8;mf++){
      int fb = (kstep*8+mf)*2;
      bf16x8 ah = wsel[(size_t)fb*64 + lane];
      bf16x8 al = wsel[(size_t)(fb+1)*64 + lane];
      acc[mf] = __builtin_amdgcn_mfma_f32_16x16x32_bf16(ah, Bhi, acc[mf], 0,0,0);
      acc[mf] = __builtin_amdgcn_mfma_f32_16x16x32_bf16(ah, Blo, acc[mf], 0,0,0);
      acc[mf] = __builtin_amdgcn_mfma_f32_16x16x32_bf16(al, Bhi, acc[mf], 0,0,0);
    }
  }
  if (!valid) return;
  #pragma unroll
  for (int mf=0;mf<8;mf++){
    float sv[4];
    #pragma unroll
    for (int r=0;r<4;r++){
      int ch = mf*16 + ko*4 + r;
      sv[r] = fmaxf(acc[mf][r] + bsel[ch], 0.f);
    }
    float2* hp = reinterpret_cast<float2*>(h + (size_t)node*H + mf*16 + ko*4);
    hp[0] = make_float2(sv[0], sv[1]);
    hp[1] = make_float2(sv[2], sv[3]);
    unsigned int* hbp = hb + (size_t)node*64 + mf*8 + ko*2;
    hbp[0] = bfr_(sv[0]) | (bfr_(sv[1])<<16);
    hbp[1] = bfr_(sv[2]) | (bfr_(sv[3])<<16);
  }
}

// dual GEMM via MFMA bf16x3: tI = A@WI, tC = A@WC, outputs packed bf16.
__global__ __launch_bounds__(256) void k_gemm2m(
    const float* __restrict__ A,
    const unsigned short* __restrict__ WIf, const unsigned short* __restrict__ WCf,
    const float* __restrict__ bna, const float* __restrict__ bnb2,
    unsigned int* __restrict__ tIb, unsigned int* __restrict__ tCb, int N)
{
  int t = threadIdx.x;
  int lane = t & 63;
  int base = (blockIdx.x*4 + (t>>6))*16;
  if (base >= N) return;
  int node = base + (lane & 15);
  int nodeL = min(node, N-1);
  int ko = lane >> 4;

  f32x4 accI[8], accC[8];
  #pragma unroll
  for (int mf=0;mf<8;mf++){ accI[mf]=(f32x4){0.f,0.f,0.f,0.f}; accC[mf]=(f32x4){0.f,0.f,0.f,0.f}; }

  const bf16x8* wi = reinterpret_cast<const bf16x8*>(WIf);
  const bf16x8* wc = reinterpret_cast<const bf16x8*>(WCf);
  bool doBN = (bna != nullptr);

  #pragma unroll
  for (int kstep=0;kstep<4;kstep++){
    const float4* ar = reinterpret_cast<const float4*>(A + (size_t)nodeL*H + kstep*32 + ko*8);
    float4 v0 = ar[0], v1 = ar[1];
    if (doBN){
      int ch = kstep*32 + ko*8;
      const float4* a4 = reinterpret_cast<const float4*>(bna + ch);
      const float4* b4 = reinterpret_cast<const float4*>(bnb2 + ch);
      float4 a0 = a4[0], a1 = a4[1], bb0 = b4[0], bb1 = b4[1];
      v0.x = fmaxf(fmaf(a0.x, v0.x, bb0.x), 0.f);
      v0.y = fmaxf(fmaf(a0.y, v0.y, bb0.y), 0.f);
      v0.z = fmaxf(fmaf(a0.z, v0.z, bb0.z), 0.f);
      v0.w = fmaxf(fmaf(a0.w, v0.w, bb0.w), 0.f);
      v1.x = fmaxf(fmaf(a1.x, v1.x, bb1.x), 0.f);
      v1.y = fmaxf(fmaf(a1.y, v1.y, bb1.y), 0.f);
      v1.z = fmaxf(fmaf(a1.z, v1.z, bb1.z), 0.f);
      v1.w = fmaxf(fmaf(a1.w, v1.w, bb1.w), 0.f);
    }
    uint4 hiu, lou;
    split2(v0.x, v0.y, hiu.x, lou.x);
    split2(v0.z, v0.w, hiu.y, lou.y);
    split2(v1.x, v1.y, hiu.z, lou.z);
    split2(v1.z, v1.w, hiu.w, lou.w);
    bf16x8 Bhi = *reinterpret_cast<bf16x8*>(&hiu);
    bf16x8 Blo = *reinterpret_cast<bf16x8*>(&lou);
    #pragma unroll
    for (int mf=0;mf<8;mf++){
      int fb = (kstep*8+mf)*2;
      bf16x8 aIh = wi[(size_t)fb*64 + lane];
      bf16x8 aIl = wi[(size_t)(fb+1)*64 + lane];
      accI[mf] = __builtin_amdgcn_mfma_f32_16x16x32_bf16(aIh, Bhi, accI[mf], 0,0,0);
      accI[mf] = __builtin_amdgcn_mfma_f32_16x16x32_bf16(aIh, Blo, accI[mf], 0,0,0);
      accI[mf] = __builtin_amdgcn_mfma_f32_16x16x32_bf16(aIl, Bhi, accI[mf], 0,0,0);
      bf16x8 aCh = wc[(size_t)fb*64 + lane];
      bf16x8 aCl = wc[(size_t)(fb+1)*64 + lane];
      accC[mf] = __builtin_amdgcn_mfma_f32_16x16x32_bf16(aCh, Bhi, accC[mf], 0,0,0);
      accC[mf] = __builtin_amdgcn_mfma_f32_16x16x32_bf16(aCh, Blo, accC[mf], 0,0,0);
      accC[mf] = __builtin_amdgcn_mfma_f32_16x16x32_bf16(aCl, Bhi, accC[mf], 0,0,0);
    }
  }
  if (node >= N) return;
  #pragma unroll
  for (int mf=0;mf<8;mf++){
    unsigned int* ti = tIb + (size_t)node*64 + mf*8 + ko*2;
    unsigned int* tc = tCb + (size_t)node*64 + mf*8 + ko*2;
    ti[0] = bfr_(accI[mf][0]) | (bfr_(accI[mf][1])<<16);
    ti[1] = bfr_(accI[mf][2]) | (bfr_(accI[mf][3])<<16);
    tc[0] = bfr_(accC[mf][0]) | (bfr_(accC[mf][1])<<16);
    tc[1] = bfr_(accC[mf][2]) | (bfr_(accC[mf][3])<<16);
  }
}

// ---- CSR build ----
__global__ void k_hist(const int* __restrict__ ei, int* __restrict__ cnt, int E){
  int e = blockIdx.x*blockDim.x + threadIdx.x;
  if (e < E) atomicAdd(cnt + ei[E+e], 1);
}

// multi-block scan, phase A
__global__ __launch_bounds__(1024) void k_scanA(const int* __restrict__ cnt,
                                                int* __restrict__ start,
                                                int* __restrict__ bsum, int N){
  __shared__ int wsum[16];
  int t = threadIdx.x;
  int lane = t & 63, wid = t >> 6;
  int i = blockIdx.x*1024 + t;
  int v = (i < N) ? cnt[i] : 0;
  int s = v;
  #pragma unroll
  for (int d=1; d<64; d<<=1){
    int u = __shfl_up(s, d, 64);
    if (lane >= d) s += u;
  }
  if (lane == 63) wsum[wid] = s;
  __syncthreads();
  if (wid == 0){
    int w = (lane < 16) ? wsum[lane] : 0;
    #pragma unroll
    for (int d=1; d<16; d<<=1){
      int u = __shfl_up(w, d, 64);
      if (lane >= d) w += u;
    }
    if (lane < 16) wsum[lane] = w;
  }
  __syncthreads();
  int incl = s + ((wid > 0) ? wsum[wid-1] : 0);
  if (i < N) start[i] = incl - v;
  if (t == 1023) bsum[blockIdx.x] = incl;
}

// phase C
__global__ __launch_bounds__(1024) void k_scanC(int* __restrict__ start,
                                                const int* __restrict__ bsum,
                                                int N, int nb){
  int b = blockIdx.x, t = threadIdx.x;
  int o = 0;
  for (int j=0;j<b;j++) o += bsum[j];
  int i = b*1024 + t;
  if (i < N) start[i] += o;
  if (b == nb-1 && t == 0) start[N] = o + bsum[b];
}

__global__ void k_fill2(const int* __restrict__ ei, const int* __restrict__ em,
                        const float* __restrict__ ew,
                        const int* __restrict__ start, int* __restrict__ wcnt,
                        int* __restrict__ csr_sc, int* __restrict__ csr_d,
                        float* __restrict__ csr_w, int E){
  int e = blockIdx.x*blockDim.x + threadIdx.x;
  if (e >= E) return;
  int s = ei[e], d = ei[E+e];
  int chan = (em[s] == em[d]) ? 0 : 1;
  int pos = start[d] + atomicAdd(wcnt + d, 1);
  csr_sc[pos] = (s<<1) | chan;
  csr_d[pos] = d;
  csr_w[pos] = ew[e];
}

// per-edge MLP gate via MFMA. wave = 32 edges; W1 fragments in LDS.
__global__ __launch_bounds__(256) void k_edgem(
    const unsigned int* __restrict__ hb,
    const int* __restrict__ csr_sc, const int* __restrict__ csr_d,
    const float* __restrict__ csr_w, const unsigned short* __restrict__ W1b,
    const float* __restrict__ W1, const float* __restrict__ b1,
    const float* __restrict__ W2, const float* __restrict__ b2,
    float* __restrict__ csr_cf,
    float* __restrict__ degI, float* __restrict__ degC, int E)
{
  __shared__ uint4 wlds[1024];
  int t = threadIdx.x;
  {
    const uint4* src = reinterpret_cast<const uint4*>(W1b);
    #pragma unroll
    for (int i=0;i<4;i++) wlds[i*256 + t] = src[i*256 + t];
  }
  __syncthreads();

  int lane = t & 63;
  int base0 = (blockIdx.x*4 + (t>>6)) * 32;
  if (base0 >= E) return;

  int colbase = lane & 15;
  int ko = lane >> 4;
  float w1l[4], b1v[4], w2v[4];
  #pragma unroll
  for (int n=0;n<4;n++){
    int col = n*16 + colbase;
    w1l[n] = W1[(size_t)128*64 + col];
    b1v[n] = b1[col];
    w2v[n] = W2[col];
  }
  float bb2 = b2[0];

  uint4 us[2][4], ud[2][4];
  #pragma unroll
  for (int eg=0; eg<2; eg++){
    int e = min(base0 + eg*16 + colbase, E-1);
    int s = csr_sc[e] >> 1;
    int d = csr_d[e];
    const uint4* hsp = reinterpret_cast<const uint4*>(hb + (size_t)s*64);
    const uint4* hdp = reinterpret_cast<const uint4*>(hb + (size_t)d*64);
    #pragma unroll
    for (int kstep=0;kstep<4;kstep++){
      us[eg][kstep] = hsp[kstep*4 + ko];
      ud[eg][kstep] = hdp[kstep*4 + ko];
    }
  }

  const bf16x8* wl = reinterpret_cast<const bf16x8*>(wlds);
  #pragma unroll
  for (int eg=0; eg<2; eg++){
    int base = base0 + eg*16;
    if (base >= E) break;

    f32x4 acc[4];
    #pragma unroll
    for (int n=0;n<4;n++) acc[n] = (f32x4){0.f,0.f,0.f,0.f};

    #pragma unroll
    for (int kstep=0;kstep<4;kstep++){
      uint4 pa;
      pa.x = pair_dft(us[eg][kstep].x, ud[eg][kstep].x);
      pa.y = pair_dft(us[eg][kstep].y, ud[eg][kstep].y);
      pa.z = pair_dft(us[eg][kstep].z, ud[eg][kstep].z);
      pa.w = pair_dft(us[eg][kstep].w, ud[eg][kstep].w);
      bf16x8 a = *reinterpret_cast<bf16x8*>(&pa);
      #pragma unroll
      for (int n=0;n<4;n++)
        acc[n] = __builtin_amdgcn_mfma_f32_16x16x32_bf16(a, wl[(kstep*4+n)*64 + lane], acc[n], 0,0,0);
    }

    float wgtr[4];
    #pragma unroll
    for (int r=0;r<4;r++)
      wgtr[r] = csr_w[min(base + ko*4 + r, E-1)];

    float part[4] = {0.f,0.f,0.f,0.f};
    #pragma unroll
    for (int n=0;n<4;n++){
      #pragma unroll
      for (int r=0;r<4;r++){
        float v = fmaxf(acc[n][r] + fmaf(wgtr[r], w1l[n], b1v[n]), 0.f);
        part[r] = fmaf(v, w2v[n], part[r]);
      }
    }
    #pragma unroll
    for (int m=1;m<16;m<<=1){
      #pragma unroll
      for (int r=0;r<4;r++) part[r] += __shfl_xor(part[r], m, 64);
    }

    if (colbase == 0){
      #pragma unroll
      for (int r=0;r<4;r++){
        int ee = base + ko*4 + r;
        if (ee < E){
          float g = sigmoidf_(part[r] + bb2);
          g = fminf(fmaxf(g, 0.2f), 1.2f);
          float ehat = wgtr[r] * g;
          csr_cf[ee] = ehat;
          int sc2 = csr_sc[ee];
          atomicAdd(((sc2&1) ? degC : degI) + csr_d[ee], ehat);
        }
      }
    }
  }
}

__global__ void k_dinv(const float* __restrict__ degI, const float* __restrict__ degC,
                       float* dinvI, float* dinvC, int N){
  int i = blockIdx.x*blockDim.x + threadIdx.x;
  if (i < N){
    dinvI[i] = rsqrtf(1.f + degI[i]);
    dinvC[i] = rsqrtf(1.f + degC[i]);
  }
}

__global__ void k_scale(const int* __restrict__ csr_sc, const int* __restrict__ csr_d,
                        const float* __restrict__ dinvI, const float* __restrict__ dinvC,
                        float* __restrict__ csr_cf, int E){
  int k = blockIdx.x*blockDim.x + threadIdx.x;
  if (k >= E) return;
  int sc = csr_sc[k];
  int s = sc>>1;
  int d = csr_d[k];
  const float* dv = (sc&1) ? dinvC : dinvI;
  csr_cf[k] *= dv[s]*dv[d];
}

// BN scale/shift precompute
__global__ void k_bnab(const float* __restrict__ bnsum, const float* __restrict__ bnsq,
                       const float* __restrict__ gamma, const float* __restrict__ beta,
                       float invN, float* __restrict__ bna, float* __restrict__ bnb2){
  int j = threadIdx.x;
  float mu = bnsum[j]*invN;
  float var = bnsq[j]*invN - mu*mu;
  float r = rsqrtf(var + 1e-5f);
  float a = gamma[j]*r;
  bna[j] = a;
  bnb2[j] = beta[j] - a*mu;
}

// one wave per dst node: gather bf16 CSR messages (8-deep unrolled)
__global__ __launch_bounds__(256) void k_aggrb(
    const unsigned int* __restrict__ tIb, const unsigned int* __restrict__ tCb,
    const int* __restrict__ start, const int* __restrict__ csr_sc,
    const float* __restrict__ csr_cf,
    const float* __restrict__ dinvI, const float* __restrict__ dinvC,
    const float* __restrict__ bI, const float* __restrict__ bC,
    const float* __restrict__ relg, int l,
    float* __restrict__ h, int N)
{
  int lane = threadIdx.x & 63;
  int d = blockIdx.x*4 + (threadIdx.x>>6);
  if (d >= N) return;
  float sig = sigmoidf_(relg[l]);
  int k0 = start[d], k1 = start[d+1];
  float ax=0.f, ay=0.f;
  int k = k0;
  for (; k+8 <= k1; k += 8){
    unsigned vv[8]; float cc[8];
    #pragma unroll
    for (int u=0;u<8;u++){
      int sc = csr_sc[k+u];
      float cf = csr_cf[k+u];
      vv[u] = ((sc&1) ? tCb : tIb)[(size_t)(sc>>1)*64 + lane];
      cc[u] = (sc&1) ? sig*cf : cf;
    }
    #pragma unroll
    for (int u=0;u<8;u++){
      ax = fmaf(cc[u], __uint_as_float(vv[u]<<16), ax);
      ay = fmaf(cc[u], __uint_as_float(vv[u] & 0xffff0000u), ay);
    }
  }
  for (; k < k1; ++k){
    int sc = csr_sc[k];
    float cf = csr_cf[k];
    unsigned v = ((sc&1) ? tCb : tIb)[(size_t)(sc>>1)*64 + lane];
    float ce = (sc&1) ? sig*cf : cf;
    ax = fmaf(ce, __uint_as_float(v<<16), ax);
    ay = fmaf(ce, __uint_as_float(v & 0xffff0000u), ay);
  }
  float diI = dinvI[d], diC = dinvC[d];
  float rI = diI*diI, rC = diC*diC;
  unsigned vi = tIb[(size_t)d*64 + lane];
  unsigned vc = tCb[(size_t)d*64 + lane];
  int off = lane*2;
  float ox = fmaf(__uint_as_float(vi<<16), rI, bI[off])
           + sig*fmaf(__uint_as_float(vc<<16), rC, bC[off]) + ax;
  float oy = fmaf(__uint_as_float(vi & 0xffff0000u), rI, bI[off+1])
           + sig*fmaf(__uint_as_float(vc & 0xffff0000u), rC, bC[off+1]) + ay;
  *reinterpret_cast<float2*>(h + (size_t)d*H + off) = make_float2(ox, oy);
}

__global__ __launch_bounds__(128) void k_stats(const float* __restrict__ h,
    float* __restrict__ bnsum, float* __restrict__ bnsq, int N, int nper)
{
  int j = threadIdx.x;
  int n0 = blockIdx.x*nper, n1 = min(n0+nper, N);
  if (n0 >= N) return;
  float sl=0.f, sq=0.f;
  for (int n=n0;n<n1;n++){
    float v = h[(size_t)n*H+j];
    sl += v; sq = fmaf(v,v,sq);
  }
  atomicAdd(bnsum+j, sl); atomicAdd(bnsq+j, sq);
}

// pool with BN+relu applied on the fly
__global__ __launch_bounds__(128) void k_poolbn(
    const float* __restrict__ h, const int* __restrict__ batch, const int* __restrict__ em,
    const float* __restrict__ bnsum, const float* __restrict__ bnsq,
    const float* __restrict__ gamma, const float* __restrict__ beta, float invN,
    float* __restrict__ sumE, float* __restrict__ sumF,
    float* __restrict__ cntE, float* __restrict__ cntF, int N, int nper)
{
  int j = threadIdx.x;
  int n0 = blockIdx.x*nper, n1 = min(n0+nper, N);
  if (n0 >= N) return;
  float mu = bnsum[j]*invN;
  float var = bnsq[j]*invN - mu*mu;
  float rr = rsqrtf(var + 1e-5f);
  float ga = gamma[j], be = beta[j];
  float aE=0.f, aF=0.f, ce=0.f, cfc=0.f;
  int cg = batch[n0];
  for (int n=n0;n<n1;n++){
    int g = batch[n];
    if (g != cg){
      atomicAdd(sumE+(size_t)cg*H+j, aE);
      atomicAdd(sumF+(size_t)cg*H+j, aF);
      if (j==0){ atomicAdd(cntE+cg, ce); atomicAdd(cntF+cg, cfc); }
      aE=aF=ce=cfc=0.f; cg=g;
    }
    float v = fmaxf(fmaf(ga, (h[(size_t)n*H+j]-mu)*rr, be), 0.f);
    bool eb = em[n] != 0;
    if (eb) aE += v; else aF += v;
    if (j==0){ if (eb) ce += 1.f; else cfc += 1.f; }
  }
  atomicAdd(sumE+(size_t)cg*H+j, aE);
  atomicAdd(sumF+(size_t)cg*H+j, aF);
  if (j==0){ atomicAdd(cntE+cg, ce); atomicAdd(cntF+cg, cfc); }
}

__device__ __forceinline__ float blockReduceSum(float v, float* red){
  int t = threadIdx.x;
  red[t] = v; __syncthreads();
  #pragma unroll
  for (int s=64;s>0;s>>=1){ if (t<s) red[t]+=red[t+s]; __syncthreads(); }
  float r = red[0]; __syncthreads();
  return r;
}

__global__ __launch_bounds__(128) void k_head(
    const float* __restrict__ sumE, const float* __restrict__ sumF,
    const float* __restrict__ cntE, const float* __restrict__ cntF,
    const float* __restrict__ coW1, const float* __restrict__ cob1,
    const float* __restrict__ coW2, const float* __restrict__ cob2,
    const float* __restrict__ gW1, const float* __restrict__ gb1,
    const float* __restrict__ gW2, const float* __restrict__ gb2,
    const float* __restrict__ cW1, const float* __restrict__ cb1,
    const float* __restrict__ cW2, const float* __restrict__ cb2,
    const float* __restrict__ peW1, const float* __restrict__ peb1,
    const float* __restrict__ peW2, const float* __restrict__ peb2,
    const float* __restrict__ pfW1, const float* __restrict__ pfb1,
    const float* __restrict__ pfW2, const float* __restrict__ pfb2,
    float* __restrict__ out, int G)
{
  int g = blockIdx.x, j = threadIdx.x;
  __shared__ float sh[384];
  __shared__ float red[128];
  __shared__ float hfin[128], buf[128];
  float cE = cntE[g], cF = cntF[g];
  float se = sumE[(size_t)g*H+j], sf = sumF[(size_t)g*H+j];
  float he = se/fmaxf(cE,1.f), hf = sf/fmaxf(cF,1.f);
  float hg = (se+sf)/fmaxf(cE+cF,1.f);
  sh[j]=he; sh[128+j]=hf; sh[256+j]=he*hf;
  __syncthreads();
  float a = cob1[j];
  for (int k=0;k<384;k++) a = fmaf(sh[k], coW1[k*H+j], a);
  a = fmaxf(a, 0.f);
  float r0 = blockReduceSum(a*coW2[2*j],   red);
  float r1 = blockReduceSum(a*coW2[2*j+1], red);
  float al0 = sigmoidf_(r0 + cob2[0]);
  float al1 = sigmoidf_(r1 + cob2[1]);
  float asum = al0+al1+1e-6f; al0/=asum; al1/=asum;
  float hc = al0*he + al1*hf;
  __syncthreads();
  sh[j]=hc; sh[128+j]=hg;
  __syncthreads();
  float gg = gb1[j];
  for (int k=0;k<256;k++) gg = fmaf(sh[k], gW1[k*H+j], gg);
  gg = fmaxf(gg, 0.f);
  float gt = sigmoidf_(blockReduceSum(gg*gW2[j], red) + gb2[0]);
  float hfj = gt*hc + (1.f-gt)*hg;
  hfin[j] = hfj;
  __syncthreads();
  float c1v = 0.f;
  if (j < 64){
    float c1 = cb1[j];
    for (int k=0;k<128;k++) c1 = fmaf(hfin[k], cW1[k*64+j], c1);
    c1v = fmaxf(c1, 0.f);
  }
  float l0 = blockReduceSum(j<64 ? c1v*cW2[2*j]   : 0.f, red);
  float l1 = blockReduceSum(j<64 ? c1v*cW2[2*j+1] : 0.f, red);
  if (j==0){ out[(size_t)g*2] = l0 + cb2[0]; out[(size_t)g*2+1] = l1 + cb2[1]; }
  // z_e
  buf[j] = he; __syncthreads();
  float q = peb1[j];
  for (int k=0;k<128;k++) q = fmaf(buf[k], peW1[k*H+j], q);
  q = fmaxf(q, 0.f);
  __syncthreads(); sh[j] = q; __syncthreads();
  float z = peb2[j];
  for (int k=0;k<128;k++) z = fmaf(sh[k], peW2[k*H+j], z);
  float nr = sqrtf(blockReduceSum(z*z, red));
  out[(size_t)G*2 + (size_t)g*H + j] = z / fmaxf(nr, 1e-12f);
  // z_f
  __syncthreads(); buf[j] = hf; __syncthreads();
  float q2 = pfb1[j];
  for (int k=0;k<128;k++) q2 = fmaf(buf[k], pfW1[k*H+j], q2);
  q2 = fmaxf(q2, 0.f);
  __syncthreads(); sh[j] = q2; __syncthreads();
  float z2 = pfb2[j];
  for (int k=0;k<128;k++) z2 = fmaf(sh[k], pfW2[k*H+j], z2);
  float nr2 = sqrtf(blockReduceSum(z2*z2, red));
  out[(size_t)G*2 + (size_t)G*H + (size_t)g*H + j] = z2 / fmaxf(nr2, 1e-12f);
}

extern "C" void kernel_launch(void* const* d_in, const int* in_sizes, int n_in,
                              void* d_out, int out_size, void* d_ws, size_t ws_size,
                              hipStream_t stream)
{
  const float* x    = (const float*)d_in[0];
  const int*   ei   = (const int*)d_in[1];
  const float* ew   = (const float*)d_in[2];
  const int*   batch= (const int*)d_in[3];
  const int*   em   = (const int*)d_in[4];
  const float* eegW = (const float*)d_in[6];  const float* eegB = (const float*)d_in[7];
  const float* fnW  = (const float*)d_in[8];  const float* fnB  = (const float*)d_in[9];
  const float* eW1  = (const float*)d_in[10]; const float* eb1  = (const float*)d_in[11];
  const float* eW2  = (const float*)d_in[12]; const float* eb2  = (const float*)d_in[13];
  const float* cIW  = (const float*)d_in[14]; const float* cIb  = (const float*)d_in[15];
  const float* cCW  = (const float*)d_in[16]; const float* cCb  = (const float*)d_in[17];
  const float* relg = (const float*)d_in[18];
  const float* bng  = (const float*)d_in[19]; const float* bnb  = (const float*)d_in[20];
  const float* coW1 = (const float*)d_in[21]; const float* cob1 = (const float*)d_in[22];
  const float* coW2 = (const float*)d_in[23]; const float* cob2 = (const float*)d_in[24];
  const float* gW1  = (const float*)d_in[25]; const float* gb1  = (const float*)d_in[26];
  const float* gW2  = (const float*)d_in[27]; const float* gb2  = (const float*)d_in[28];
  const float* cW1  = (const float*)d_in[29]; const float* cb1  = (const float*)d_in[30];
  const float* cW2  = (const float*)d_in[31]; const float* cb2  = (const float*)d_in[32];
  const float* peW1 = (const float*)d_in[33]; const float* peb1 = (const float*)d_in[34];
  const float* peW2 = (const float*)d_in[35]; const float* peb2 = (const float*)d_in[36];
  const float* pfW1 = (const float*)d_in[37]; const float* pfb1 = (const float*)d_in[38];
  const float* pfW2 = (const float*)d_in[39]; const float* pfb2 = (const float*)d_in[40];
  float* out = (float*)d_out;

  int N = in_sizes[0] / D;           // 50000
  int E = in_sizes[2];               // 800000
  int G = out_size / (2 + 2*H);      // 500
  int NH = N*H;

  float* p = (float*)d_ws;
  float* h    = p; p += (size_t)NH;
  float* tI   = p; p += (size_t)NH;   // overlays: hb (pre-loop) and tIb (loop), both bf16
  float* tC   = p; p += (size_t)NH;   // overlay: tCb
  float* csr_cf = p; p += E;
  float* csr_w  = p; p += E;
  int* csr_sc = (int*)p; p += E;
  int* csr_d  = (int*)p; p += E;
  int* start  = (int*)p; p += (N+1);
  int* cnt    = (int*)p; p += N;      // cnt, wcnt, degI, degC contiguous -> one memset
  int* wcnt   = (int*)p; p += N;
  float* degI = p; p += N;
  float* degC = p; p += N;
  float* dinvI= p; p += N;
  float* dinvC= p; p += N;
  float* bnsum= p; p += H;
  float* bnsq = p; p += H;
  float* bna  = p; p += H;
  float* bnb2 = p; p += H;
  float* sumE = p; p += (size_t)G*H;
  float* sumF = p; p += (size_t)G*H;
  float* cntE = p; p += G;
  float* cntF = p; p += G;
  int* bsum   = (int*)p; p += 64;
  int* bsum2  = (int*)p; p += 64;
  int* escan  = (int*)p; p += (N+1);
  int* nodelist = (int*)p; p += (N+32);
  unsigned short* W1b = (unsigned short*)p; p += 4096;
  unsigned short* WeF = (unsigned short*)p; p += 32768;
  unsigned short* WfF = (unsigned short*)p; p += 32768;
  unsigned short* WIf0= (unsigned short*)p; p += 16384;
  unsigned short* WCf0= (unsigned short*)p; p += 16384;
  unsigned short* WIf1= (unsigned short*)p; p += 16384;
  unsigned short* WCf1= (unsigned short*)p; p += 16384;

  unsigned int* hb  = (unsigned int*)tI;
  unsigned int* tIb = (unsigned int*)tI;
  unsigned int* tCb = (unsigned int*)tC;

  int mmBlocks = ((N+15)/16 + 3)/4;
  int projBlocks = (((N+32)/16) + 3)/4;   // covers padded partitioned list
  int edgeBlocks = (E + 127)/128;
  int statBlocks = 1024;
  int nper_stat = (N + statBlocks - 1)/statBlocks;
  int poolBlocks = (N + 31)/32;
  int scanBlocks = (N + 1023)/1024;

  hipMemsetAsync(cnt, 0, (size_t)4*N*sizeof(int), stream);
  k_hist<<<(E+255)/256,256,0,stream>>>(ei, cnt, E);
  k_scanA<<<scanBlocks,1024,0,stream>>>(cnt, start, bsum, N);
  k_scanC<<<scanBlocks,1024,0,stream>>>(start, bsum, N, scanBlocks);
  k_scanA<<<scanBlocks,1024,0,stream>>>(em, escan, bsum2, N);
  k_scanC<<<scanBlocks,1024,0,stream>>>(escan, bsum2, N, scanBlocks);
  k_part<<<(N+255)/256,256,0,stream>>>(em, escan, nodelist, N);
  k_fill2<<<(E+255)/256,256,0,stream>>>(ei, em, ew, start, wcnt,
                                        csr_sc, csr_d, csr_w, E);
  k_prepall<<<65,256,0,stream>>>(eegW, fnW, cIW, cCW, eW1,
                                 WeF, WfF, WIf0, WCf0, WIf1, WCf1, W1b);

  k_projm<<<projBlocks,256,0,stream>>>(x, nodelist, escan, N,
                                       WeF, eegB, WfF, fnB, h, hb);
  k_edgem<<<edgeBlocks,256,0,stream>>>(hb, csr_sc, csr_d, csr_w, W1b,
                                       eW1, eb1, eW2, eb2, csr_cf, degI, degC, E);
  k_dinv<<<(N+255)/256,256,0,stream>>>(degI,degC,dinvI,dinvC,N);
  k_scale<<<(E+255)/256,256,0,stream>>>(csr_sc, csr_d, dinvI, dinvC, csr_cf, E);

  // layer 0
  k_gemm2m<<<mmBlocks,256,0,stream>>>(h, WIf0, WCf0, nullptr, nullptr, tIb, tCb, N);
  k_aggrb<<<(N+3)/4,256,0,stream>>>(tIb, tCb, start, csr_sc, csr_cf,
                                    dinvI, dinvC, cIb, cCb, relg, 0, h, N);
  hipMemsetAsync(bnsum, 0, 2*H*sizeof(float), stream);
  k_stats<<<statBlocks,128,0,stream>>>(h, bnsum, bnsq, N, nper_stat);
  k_bnab<<<1,128,0,stream>>>(bnsum, bnsq, bng, bnb, 1.0f/(float)N, bna, bnb2);

  // layer 1 (BN0 fused into GEMM input)
  k_gemm2m<<<mmBlocks,256,0,stream>>>(h, WIf1, WCf1, bna, bnb2, tIb, tCb, N);
  k_aggrb<<<(N+3)/4,256,0,stream>>>(tIb, tCb, start, csr_sc, csr_cf,
                                    dinvI, dinvC, cIb+(size_t)H, cCb+(size_t)H,
                                    relg, 1, h, N);
  hipMemsetAsync(bnsum, 0, 2*H*sizeof(float), stream);
  k_stats<<<statBlocks,128,0,stream>>>(h, bnsum, bnsq, N, nper_stat);

  hipMemsetAsync(sumE, 0, ((size_t)2*G*H + 2*G)*sizeof(float), stream);
  k_poolbn<<<poolBlocks,128,0,stream>>>(h, batch, em, bnsum, bnsq,
                                        bng+(size_t)H, bnb+(size_t)H, 1.0f/(float)N,
                                        sumE, sumF, cntE, cntF, N, 32);
  k_head<<<G,128,0,stream>>>(sumE,sumF,cntE,cntF,
                             coW1,cob1,coW2,cob2, gW1,gb1,gW2,gb2,
                             cW1,cb1,cW2,cb2, peW1,peb1,peW2,peb2,
                             pfW1,pfb1,pfW2,pfb2, out, G);
}

// Round 14
// 553.164 us; speedup vs baseline: 4.1826x; 1.0139x over previous
//
#include <hip/hip_runtime.h>
#include <math.h>

#define H 128
#define D 256

typedef __attribute__((ext_vector_type(8))) short bf16x8;
typedef __attribute__((ext_vector_type(4))) float f32x4;

__device__ __forceinline__ float sigmoidf_(float x){ return 1.0f/(1.0f+__expf(-x)); }

// RNE float->bf16 (as uint in low 16 bits)
__device__ __forceinline__ unsigned int bfr_(float f){
  unsigned int u = __float_as_uint(f);
  return (u + 0x7fffu + ((u>>16)&1u)) >> 16;
}

// split a,b into packed bf16 hi / lo words (2 bf16 each)
__device__ __forceinline__ void split2(float a, float b, unsigned &hi, unsigned &lo){
  unsigned ha = bfr_(a), hb2 = bfr_(b);
  float fa = __uint_as_float(ha<<16), fb = __uint_as_float(hb2<<16);
  unsigned la = bfr_(a - fa), lb = bfr_(b - fb);
  hi = ha | (hb2<<16); lo = la | (lb<<16);
}

// pack trunc-bf16(|a0-b0|), trunc-bf16(|a1-b1|) into one uint via v_perm
__device__ __forceinline__ unsigned pair_dft(unsigned a, unsigned b){
  float a0 = __uint_as_float(a<<16), a1 = __uint_as_float(a & 0xffff0000u);
  float b0 = __uint_as_float(b<<16), b1 = __uint_as_float(b & 0xffff0000u);
  unsigned d0 = __float_as_uint(fabsf(a0-b0));
  unsigned d1 = __float_as_uint(fabsf(a1-b1));
  return __builtin_amdgcn_perm(d1, d0, 0x07060302);
}

// All weight preprocessing in ONE launch (65 blocks x 256)
__global__ void k_prepall(const float* __restrict__ eegW, const float* __restrict__ fnW,
                          const float* __restrict__ cIW, const float* __restrict__ cCW,
                          const float* __restrict__ eW1,
                          unsigned short* WeF, unsigned short* WfF,
                          unsigned short* WIf0, unsigned short* WCf0,
                          unsigned short* WIf1, unsigned short* WCf1,
                          unsigned short* W1b)
{
  int b = blockIdx.x;
  int t = threadIdx.x;
  if (b < 64){
    const float* W; unsigned short* out; int ksteps; int boff;
    if (b < 16){ W=eegW; out=WeF; ksteps=8; boff=b; }
    else if (b < 32){ W=fnW; out=WfF; ksteps=8; boff=b-16; }
    else if (b < 40){ W=cIW;        out=WIf0; ksteps=4; boff=b-32; }
    else if (b < 48){ W=cCW;        out=WCf0; ksteps=4; boff=b-40; }
    else if (b < 56){ W=cIW+16384;  out=WIf1; ksteps=4; boff=b-48; }
    else            { W=cCW+16384;  out=WCf1; ksteps=4; boff=b-56; }
    int id = boff*256 + t;
    if (id >= ksteps*8*64) return;
    int lane = id & 63;
    int mfrag = (id>>6) & 7;
    int kstep = id >> 9;
    int col = mfrag*16 + (lane&15);
    int k0 = kstep*32 + (lane>>4)*8;
    unsigned short* oh = out + (size_t)(((kstep*8+mfrag)*2+0)*64 + lane)*8;
    unsigned short* ol = out + (size_t)(((kstep*8+mfrag)*2+1)*64 + lane)*8;
    #pragma unroll
    for (int j=0;j<8;j++){
      float w = W[(size_t)(k0+j)*128 + col];
      unsigned h16 = bfr_(w);
      float hf = __uint_as_float(h16<<16);
      oh[j] = (unsigned short)h16;
      ol[j] = (unsigned short)bfr_(w - hf);
    }
  } else {
    for (int it=0; it<4; it++){
      int le = it*256 + t;
      int f = le >> 6, lane = le & 63;
      int kstep = f >> 2, n = f & 3;
      int col = n*16 + (lane & 15);
      int k0 = kstep*32 + ((lane>>4)&3)*8;
      unsigned short* op = W1b + (size_t)le*8;
      #pragma unroll
      for (int j=0;j<8;j++)
        op[j] = (unsigned short)bfr_(eW1[(size_t)(k0+j)*64 + col]);
    }
  }
}

// build modality-partitioned node list
__global__ void k_part(const int* __restrict__ em, const int* __restrict__ escan,
                       int* __restrict__ nodelist, int N){
  int i = blockIdx.x*blockDim.x + threadIdx.x;
  int NE = escan[N];
  int NEpad = (NE+15)&~15;
  if (i < N){
    int pos = em[i] ? escan[i] : NEpad + (i - escan[i]);
    nodelist[pos] = i;
  }
  if (i < 16){
    if (NE + i < NEpad) nodelist[NE + i] = 0;
    int TOT = NEpad + (N - NE);
    int TOTpad = (TOT+15)&~15;
    if (TOT + i < TOTpad) nodelist[TOT + i] = 0;
  }
}

// proj via MFMA bf16x3, modality-partitioned.
__global__ __launch_bounds__(256) void k_projm(
    const float* __restrict__ x, const int* __restrict__ nodelist,
    const int* __restrict__ escan, int N,
    const unsigned short* __restrict__ WeF, const float* __restrict__ be,
    const unsigned short* __restrict__ WfF, const float* __restrict__ bf,
    float* __restrict__ h, unsigned int* __restrict__ hb)
{
  int t = threadIdx.x;
  int lane = t & 63;
  int base = (blockIdx.x*4 + (t>>6))*16;
  int NE = escan[N];
  int NEpad = (NE+15)&~15;
  int TOT = NEpad + (N - NE);
  if (base >= TOT) return;
  bool isE = (base < NEpad);
  int slot = base + (lane & 15);
  bool valid = isE ? (slot < NE) : (slot < TOT);
  int node = nodelist[slot];
  int ko = lane >> 4;

  f32x4 acc[8];
  #pragma unroll
  for (int mf=0;mf<8;mf++) acc[mf]=(f32x4){0.f,0.f,0.f,0.f};

  const bf16x8* wsel = reinterpret_cast<const bf16x8*>(isE ? WeF : WfF);
  const float* bsel = isE ? be : bf;
  const float4* xr0 = reinterpret_cast<const float4*>(x + (size_t)node*D + ko*8);

  for (int kstep=0;kstep<8;kstep++){
    float4 v0 = xr0[kstep*8], v1 = xr0[kstep*8 + 1];
    uint4 hiu, lou;
    split2(v0.x, v0.y, hiu.x, lou.x);
    split2(v0.z, v0.w, hiu.y, lou.y);
    split2(v1.x, v1.y, hiu.z, lou.z);
    split2(v1.z, v1.w, hiu.w, lou.w);
    bf16x8 Bhi = *reinterpret_cast<bf16x8*>(&hiu);
    bf16x8 Blo = *reinterpret_cast<bf16x8*>(&lou);
    #pragma unroll
    for (int mf=0;mf<8;mf++){
      int fb = (kstep*8+mf)*2;
      bf16x8 ah = wsel[(size_t)fb*64 + lane];
      bf16x8 al = wsel[(size_t)(fb+1)*64 + lane];
      acc[mf] = __builtin_amdgcn_mfma_f32_16x16x32_bf16(ah, Bhi, acc[mf], 0,0,0);
      acc[mf] = __builtin_amdgcn_mfma_f32_16x16x32_bf16(ah, Blo, acc[mf], 0,0,0);
      acc[mf] = __builtin_amdgcn_mfma_f32_16x16x32_bf16(al, Bhi, acc[mf], 0,0,0);
    }
  }
  if (!valid) return;
  #pragma unroll
  for (int mf=0;mf<8;mf++){
    float sv[4];
    #pragma unroll
    for (int r=0;r<4;r++){
      int ch = mf*16 + ko*4 + r;
      sv[r] = fmaxf(acc[mf][r] + bsel[ch], 0.f);
    }
    float2* hp = reinterpret_cast<float2*>(h + (size_t)node*H + mf*16 + ko*4);
    hp[0] = make_float2(sv[0], sv[1]);
    hp[1] = make_float2(sv[2], sv[3]);
    unsigned int* hbp = hb + (size_t)node*64 + mf*8 + ko*2;
    hbp[0] = bfr_(sv[0]) | (bfr_(sv[1])<<16);
    hbp[1] = bfr_(sv[2]) | (bfr_(sv[3])<<16);
  }
}

// dual GEMM via MFMA bf16x3: tI = A@WI, tC = A@WC, outputs packed bf16.
__global__ __launch_bounds__(256) void k_gemm2m(
    const float* __restrict__ A,
    const unsigned short* __restrict__ WIf, const unsigned short* __restrict__ WCf,
    const float* __restrict__ bna, const float* __restrict__ bnb2,
    unsigned int* __restrict__ tIb, unsigned int* __restrict__ tCb, int N)
{
  int t = threadIdx.x;
  int lane = t & 63;
  int base = (blockIdx.x*4 + (t>>6))*16;
  if (base >= N) return;
  int node = base + (lane & 15);
  int nodeL = min(node, N-1);
  int ko = lane >> 4;

  f32x4 accI[8], accC[8];
  #pragma unroll
  for (int mf=0;mf<8;mf++){ accI[mf]=(f32x4){0.f,0.f,0.f,0.f}; accC[mf]=(f32x4){0.f,0.f,0.f,0.f}; }

  const bf16x8* wi = reinterpret_cast<const bf16x8*>(WIf);
  const bf16x8* wc = reinterpret_cast<const bf16x8*>(WCf);
  bool doBN = (bna != nullptr);

  #pragma unroll
  for (int kstep=0;kstep<4;kstep++){
    const float4* ar = reinterpret_cast<const float4*>(A + (size_t)nodeL*H + kstep*32 + ko*8);
    float4 v0 = ar[0], v1 = ar[1];
    if (doBN){
      int ch = kstep*32 + ko*8;
      const float4* a4 = reinterpret_cast<const float4*>(bna + ch);
      const float4* b4 = reinterpret_cast<const float4*>(bnb2 + ch);
      float4 a0 = a4[0], a1 = a4[1], bb0 = b4[0], bb1 = b4[1];
      v0.x = fmaxf(fmaf(a0.x, v0.x, bb0.x), 0.f);
      v0.y = fmaxf(fmaf(a0.y, v0.y, bb0.y), 0.f);
      v0.z = fmaxf(fmaf(a0.z, v0.z, bb0.z), 0.f);
      v0.w = fmaxf(fmaf(a0.w, v0.w, bb0.w), 0.f);
      v1.x = fmaxf(fmaf(a1.x, v1.x, bb1.x), 0.f);
      v1.y = fmaxf(fmaf(a1.y, v1.y, bb1.y), 0.f);
      v1.z = fmaxf(fmaf(a1.z, v1.z, bb1.z), 0.f);
      v1.w = fmaxf(fmaf(a1.w, v1.w, bb1.w), 0.f);
    }
    uint4 hiu, lou;
    split2(v0.x, v0.y, hiu.x, lou.x);
    split2(v0.z, v0.w, hiu.y, lou.y);
    split2(v1.x, v1.y, hiu.z, lou.z);
    split2(v1.z, v1.w, hiu.w, lou.w);
    bf16x8 Bhi = *reinterpret_cast<bf16x8*>(&hiu);
    bf16x8 Blo = *reinterpret_cast<bf16x8*>(&lou);
    #pragma unroll
    for (int mf=0;mf<8;mf++){
      int fb = (kstep*8+mf)*2;
      bf16x8 aIh = wi[(size_t)fb*64 + lane];
      bf16x8 aIl = wi[(size_t)(fb+1)*64 + lane];
      accI[mf] = __builtin_amdgcn_mfma_f32_16x16x32_bf16(aIh, Bhi, accI[mf], 0,0,0);
      accI[mf] = __builtin_amdgcn_mfma_f32_16x16x32_bf16(aIh, Blo, accI[mf], 0,0,0);
      accI[mf] = __builtin_amdgcn_mfma_f32_16x16x32_bf16(aIl, Bhi, accI[mf], 0,0,0);
      bf16x8 aCh = wc[(size_t)fb*64 + lane];
      bf16x8 aCl = wc[(size_t)(fb+1)*64 + lane];
      accC[mf] = __builtin_amdgcn_mfma_f32_16x16x32_bf16(aCh, Bhi, accC[mf], 0,0,0);
      accC[mf] = __builtin_amdgcn_mfma_f32_16x16x32_bf16(aCh, Blo, accC[mf], 0,0,0);
      accC[mf] = __builtin_amdgcn_mfma_f32_16x16x32_bf16(aCl, Bhi, accC[mf], 0,0,0);
    }
  }
  if (node >= N) return;
  #pragma unroll
  for (int mf=0;mf<8;mf++){
    unsigned int* ti = tIb + (size_t)node*64 + mf*8 + ko*2;
    unsigned int* tc = tCb + (size_t)node*64 + mf*8 + ko*2;
    ti[0] = bfr_(accI[mf][0]) | (bfr_(accI[mf][1])<<16);
    ti[1] = bfr_(accI[mf][2]) | (bfr_(accI[mf][3])<<16);
    tc[0] = bfr_(accC[mf][0]) | (bfr_(accC[mf][1])<<16);
    tc[1] = bfr_(accC[mf][2]) | (bfr_(accC[mf][3])<<16);
  }
}

// ---- CSR build ----
__global__ void k_hist(const int* __restrict__ ei, int* __restrict__ cnt, int E){
  int e = blockIdx.x*blockDim.x + threadIdx.x;
  if (e < E) atomicAdd(cnt + ei[E+e], 1);
}

// multi-block scan, phase A
__global__ __launch_bounds__(1024) void k_scanA(const int* __restrict__ cnt,
                                                int* __restrict__ start,
                                                int* __restrict__ bsum, int N){
  __shared__ int wsum[16];
  int t = threadIdx.x;
  int lane = t & 63, wid = t >> 6;
  int i = blockIdx.x*1024 + t;
  int v = (i < N) ? cnt[i] : 0;
  int s = v;
  #pragma unroll
  for (int d=1; d<64; d<<=1){
    int u = __shfl_up(s, d, 64);
    if (lane >= d) s += u;
  }
  if (lane == 63) wsum[wid] = s;
  __syncthreads();
  if (wid == 0){
    int w = (lane < 16) ? wsum[lane] : 0;
    #pragma unroll
    for (int d=1; d<16; d<<=1){
      int u = __shfl_up(w, d, 64);
      if (lane >= d) w += u;
    }
    if (lane < 16) wsum[lane] = w;
  }
  __syncthreads();
  int incl = s + ((wid > 0) ? wsum[wid-1] : 0);
  if (i < N) start[i] = incl - v;
  if (t == 1023) bsum[blockIdx.x] = incl;
}

// phase C
__global__ __launch_bounds__(1024) void k_scanC(int* __restrict__ start,
                                                const int* __restrict__ bsum,
                                                int N, int nb){
  int b = blockIdx.x, t = threadIdx.x;
  int o = 0;
  for (int j=0;j<b;j++) o += bsum[j];
  int i = b*1024 + t;
  if (i < N) start[i] += o;
  if (b == nb-1 && t == 0) start[N] = o + bsum[b];
}

// fill packed CSR records: one int4 {sc, d, w, 0} per edge (single 16B store)
__global__ void k_fill2(const int* __restrict__ ei, const int* __restrict__ em,
                        const float* __restrict__ ew,
                        const int* __restrict__ start, int* __restrict__ wcnt,
                        int4* __restrict__ csr_rec, int E){
  int e = blockIdx.x*blockDim.x + threadIdx.x;
  if (e >= E) return;
  int s = ei[e], d = ei[E+e];
  int chan = (em[s] == em[d]) ? 0 : 1;
  int pos = start[d] + atomicAdd(wcnt + d, 1);
  csr_rec[pos] = make_int4((s<<1) | chan, d, __float_as_int(ew[e]), 0);
}

// per-edge MLP gate via MFMA. wave = 32 edges; W1 fragments in LDS.
__global__ __launch_bounds__(256) void k_edgem(
    const unsigned int* __restrict__ hb,
    const int4* __restrict__ csr_rec, const unsigned short* __restrict__ W1b,
    const float* __restrict__ W1, const float* __restrict__ b1,
    const float* __restrict__ W2, const float* __restrict__ b2,
    float* __restrict__ csr_cf,
    float* __restrict__ degI, float* __restrict__ degC, int E)
{
  __shared__ uint4 wlds[1024];
  int t = threadIdx.x;
  {
    const uint4* src = reinterpret_cast<const uint4*>(W1b);
    #pragma unroll
    for (int i=0;i<4;i++) wlds[i*256 + t] = src[i*256 + t];
  }
  __syncthreads();

  int lane = t & 63;
  int base0 = (blockIdx.x*4 + (t>>6)) * 32;
  if (base0 >= E) return;

  int colbase = lane & 15;
  int ko = lane >> 4;
  float w1l[4], b1v[4], w2v[4];
  #pragma unroll
  for (int n=0;n<4;n++){
    int col = n*16 + colbase;
    w1l[n] = W1[(size_t)128*64 + col];
    b1v[n] = b1[col];
    w2v[n] = W2[col];
  }
  float bb2 = b2[0];

  uint4 us[2][4], ud[2][4];
  #pragma unroll
  for (int eg=0; eg<2; eg++){
    int e = min(base0 + eg*16 + colbase, E-1);
    int4 rec = csr_rec[e];
    int s = rec.x >> 1;
    int d = rec.y;
    const uint4* hsp = reinterpret_cast<const uint4*>(hb + (size_t)s*64);
    const uint4* hdp = reinterpret_cast<const uint4*>(hb + (size_t)d*64);
    #pragma unroll
    for (int kstep=0;kstep<4;kstep++){
      us[eg][kstep] = hsp[kstep*4 + ko];
      ud[eg][kstep] = hdp[kstep*4 + ko];
    }
  }

  const bf16x8* wl = reinterpret_cast<const bf16x8*>(wlds);
  #pragma unroll
  for (int eg=0; eg<2; eg++){
    int base = base0 + eg*16;
    if (base >= E) break;

    f32x4 acc[4];
    #pragma unroll
    for (int n=0;n<4;n++) acc[n] = (f32x4){0.f,0.f,0.f,0.f};

    #pragma unroll
    for (int kstep=0;kstep<4;kstep++){
      uint4 pa;
      pa.x = pair_dft(us[eg][kstep].x, ud[eg][kstep].x);
      pa.y = pair_dft(us[eg][kstep].y, ud[eg][kstep].y);
      pa.z = pair_dft(us[eg][kstep].z, ud[eg][kstep].z);
      pa.w = pair_dft(us[eg][kstep].w, ud[eg][kstep].w);
      bf16x8 a = *reinterpret_cast<bf16x8*>(&pa);
      #pragma unroll
      for (int n=0;n<4;n++)
        acc[n] = __builtin_amdgcn_mfma_f32_16x16x32_bf16(a, wl[(kstep*4+n)*64 + lane], acc[n], 0,0,0);
    }

    float wgtr[4];
    int4 recr[4];
    #pragma unroll
    for (int r=0;r<4;r++){
      recr[r] = csr_rec[min(base + ko*4 + r, E-1)];
      wgtr[r] = __int_as_float(recr[r].z);
    }

    float part[4] = {0.f,0.f,0.f,0.f};
    #pragma unroll
    for (int n=0;n<4;n++){
      #pragma unroll
      for (int r=0;r<4;r++){
        float v = fmaxf(acc[n][r] + fmaf(wgtr[r], w1l[n], b1v[n]), 0.f);
        part[r] = fmaf(v, w2v[n], part[r]);
      }
    }
    #pragma unroll
    for (int m=1;m<16;m<<=1){
      #pragma unroll
      for (int r=0;r<4;r++) part[r] += __shfl_xor(part[r], m, 64);
    }

    if (colbase == 0){
      #pragma unroll
      for (int r=0;r<4;r++){
        int ee = base + ko*4 + r;
        if (ee < E){
          float g = sigmoidf_(part[r] + bb2);
          g = fminf(fmaxf(g, 0.2f), 1.2f);
          float ehat = wgtr[r] * g;
          csr_cf[ee] = ehat;
          atomicAdd(((recr[r].x & 1) ? degC : degI) + recr[r].y, ehat);
        }
      }
    }
  }
}

__global__ void k_dinv(const float* __restrict__ degI, const float* __restrict__ degC,
                       float* dinvI, float* dinvC, int N){
  int i = blockIdx.x*blockDim.x + threadIdx.x;
  if (i < N){
    dinvI[i] = rsqrtf(1.f + degI[i]);
    dinvC[i] = rsqrtf(1.f + degC[i]);
  }
}

__global__ void k_scale(const int4* __restrict__ csr_rec,
                        const float* __restrict__ dinvI, const float* __restrict__ dinvC,
                        float* __restrict__ csr_cf, int E){
  int k = blockIdx.x*blockDim.x + threadIdx.x;
  if (k >= E) return;
  int4 rec = csr_rec[k];
  int s = rec.x >> 1;
  const float* dv = (rec.x & 1) ? dinvC : dinvI;
  csr_cf[k] *= dv[s]*dv[rec.y];
}

// BN scale/shift precompute
__global__ void k_bnab(const float* __restrict__ bnsum, const float* __restrict__ bnsq,
                       const float* __restrict__ gamma, const float* __restrict__ beta,
                       float invN, float* __restrict__ bna, float* __restrict__ bnb2){
  int j = threadIdx.x;
  float mu = bnsum[j]*invN;
  float var = bnsq[j]*invN - mu*mu;
  float r = rsqrtf(var + 1e-5f);
  float a = gamma[j]*r;
  bna[j] = a;
  bnb2[j] = beta[j] - a*mu;
}

// one wave per dst node: gather bf16 CSR messages (8-deep unrolled)
__global__ __launch_bounds__(256) void k_aggrb(
    const unsigned int* __restrict__ tIb, const unsigned int* __restrict__ tCb,
    const int* __restrict__ start, const int4* __restrict__ csr_rec,
    const float* __restrict__ csr_cf,
    const float* __restrict__ dinvI, const float* __restrict__ dinvC,
    const float* __restrict__ bI, const float* __restrict__ bC,
    const float* __restrict__ relg, int l,
    float* __restrict__ h, int N)
{
  int lane = threadIdx.x & 63;
  int d = blockIdx.x*4 + (threadIdx.x>>6);
  if (d >= N) return;
  float sig = sigmoidf_(relg[l]);
  int k0 = start[d], k1 = start[d+1];
  float ax=0.f, ay=0.f;
  int k = k0;
  for (; k+8 <= k1; k += 8){
    unsigned vv[8]; float cc[8];
    #pragma unroll
    for (int u=0;u<8;u++){
      int sc = csr_rec[k+u].x;
      float cf = csr_cf[k+u];
      vv[u] = ((sc&1) ? tCb : tIb)[(size_t)(sc>>1)*64 + lane];
      cc[u] = (sc&1) ? sig*cf : cf;
    }
    #pragma unroll
    for (int u=0;u<8;u++){
      ax = fmaf(cc[u], __uint_as_float(vv[u]<<16), ax);
      ay = fmaf(cc[u], __uint_as_float(vv[u] & 0xffff0000u), ay);
    }
  }
  for (; k < k1; ++k){
    int sc = csr_rec[k].x;
    float cf = csr_cf[k];
    unsigned v = ((sc&1) ? tCb : tIb)[(size_t)(sc>>1)*64 + lane];
    float ce = (sc&1) ? sig*cf : cf;
    ax = fmaf(ce, __uint_as_float(v<<16), ax);
    ay = fmaf(ce, __uint_as_float(v & 0xffff0000u), ay);
  }
  float diI = dinvI[d], diC = dinvC[d];
  float rI = diI*diI, rC = diC*diC;
  unsigned vi = tIb[(size_t)d*64 + lane];
  unsigned vc = tCb[(size_t)d*64 + lane];
  int off = lane*2;
  float ox = fmaf(__uint_as_float(vi<<16), rI, bI[off])
           + sig*fmaf(__uint_as_float(vc<<16), rC, bC[off]) + ax;
  float oy = fmaf(__uint_as_float(vi & 0xffff0000u), rI, bI[off+1])
           + sig*fmaf(__uint_as_float(vc & 0xffff0000u), rC, bC[off+1]) + ay;
  *reinterpret_cast<float2*>(h + (size_t)d*H + off) = make_float2(ox, oy);
}

__global__ __launch_bounds__(128) void k_stats(const float* __restrict__ h,
    float* __restrict__ bnsum, float* __restrict__ bnsq, int N, int nper)
{
  int j = threadIdx.x;
  int n0 = blockIdx.x*nper, n1 = min(n0+nper, N);
  if (n0 >= N) return;
  float sl=0.f, sq=0.f;
  for (int n=n0;n<n1;n++){
    float v = h[(size_t)n*H+j];
    sl += v; sq = fmaf(v,v,sq);
  }
  atomicAdd(bnsum+j, sl); atomicAdd(bnsq+j, sq);
}

// pool with BN+relu applied on the fly
__global__ __launch_bounds__(128) void k_poolbn(
    const float* __restrict__ h, const int* __restrict__ batch, const int* __restrict__ em,
    const float* __restrict__ bnsum, const float* __restrict__ bnsq,
    const float* __restrict__ gamma, const float* __restrict__ beta, float invN,
    float* __restrict__ sumE, float* __restrict__ sumF,
    float* __restrict__ cntE, float* __restrict__ cntF, int N, int nper)
{
  int j = threadIdx.x;
  int n0 = blockIdx.x*nper, n1 = min(n0+nper, N);
  if (n0 >= N) return;
  float mu = bnsum[j]*invN;
  float var = bnsq[j]*invN - mu*mu;
  float rr = rsqrtf(var + 1e-5f);
  float ga = gamma[j], be = beta[j];
  float aE=0.f, aF=0.f, ce=0.f, cfc=0.f;
  int cg = batch[n0];
  for (int n=n0;n<n1;n++){
    int g = batch[n];
    if (g != cg){
      atomicAdd(sumE+(size_t)cg*H+j, aE);
      atomicAdd(sumF+(size_t)cg*H+j, aF);
      if (j==0){ atomicAdd(cntE+cg, ce); atomicAdd(cntF+cg, cfc); }
      aE=aF=ce=cfc=0.f; cg=g;
    }
    float v = fmaxf(fmaf(ga, (h[(size_t)n*H+j]-mu)*rr, be), 0.f);
    bool eb = em[n] != 0;
    if (eb) aE += v; else aF += v;
    if (j==0){ if (eb) ce += 1.f; else cfc += 1.f; }
  }
  atomicAdd(sumE+(size_t)cg*H+j, aE);
  atomicAdd(sumF+(size_t)cg*H+j, aF);
  if (j==0){ atomicAdd(cntE+cg, ce); atomicAdd(cntF+cg, cfc); }
}

__device__ __forceinline__ float blockReduceSum(float v, float* red){
  int t = threadIdx.x;
  red[t] = v; __syncthreads();
  #pragma unroll
  for (int s=64;s>0;s>>=1){ if (t<s) red[t]+=red[t+s]; __syncthreads(); }
  float r = red[0]; __syncthreads();
  return r;
}

__global__ __launch_bounds__(128) void k_head(
    const float* __restrict__ sumE, const float* __restrict__ sumF,
    const float* __restrict__ cntE, const float* __restrict__ cntF,
    const float* __restrict__ coW1, const float* __restrict__ cob1,
    const float* __restrict__ coW2, const float* __restrict__ cob2,
    const float* __restrict__ gW1, const float* __restrict__ gb1,
    const float* __restrict__ gW2, const float* __restrict__ gb2,
    const float* __restrict__ cW1, const float* __restrict__ cb1,
    const float* __restrict__ cW2, const float* __restrict__ cb2,
    const float* __restrict__ peW1, const float* __restrict__ peb1,
    const float* __restrict__ peW2, const float* __restrict__ peb2,
    const float* __restrict__ pfW1, const float* __restrict__ pfb1,
    const float* __restrict__ pfW2, const float* __restrict__ pfb2,
    float* __restrict__ out, int G)
{
  int g = blockIdx.x, j = threadIdx.x;
  __shared__ float sh[384];
  __shared__ float red[128];
  __shared__ float hfin[128], buf[128];
  float cE = cntE[g], cF = cntF[g];
  float se = sumE[(size_t)g*H+j], sf = sumF[(size_t)g*H+j];
  float he = se/fmaxf(cE,1.f), hf = sf/fmaxf(cF,1.f);
  float hg = (se+sf)/fmaxf(cE+cF,1.f);
  sh[j]=he; sh[128+j]=hf; sh[256+j]=he*hf;
  __syncthreads();
  float a = cob1[j];
  for (int k=0;k<384;k++) a = fmaf(sh[k], coW1[k*H+j], a);
  a = fmaxf(a, 0.f);
  float r0 = blockReduceSum(a*coW2[2*j],   red);
  float r1 = blockReduceSum(a*coW2[2*j+1], red);
  float al0 = sigmoidf_(r0 + cob2[0]);
  float al1 = sigmoidf_(r1 + cob2[1]);
  float asum = al0+al1+1e-6f; al0/=asum; al1/=asum;
  float hc = al0*he + al1*hf;
  __syncthreads();
  sh[j]=hc; sh[128+j]=hg;
  __syncthreads();
  float gg = gb1[j];
  for (int k=0;k<256;k++) gg = fmaf(sh[k], gW1[k*H+j], gg);
  gg = fmaxf(gg, 0.f);
  float gt = sigmoidf_(blockReduceSum(gg*gW2[j], red) + gb2[0]);
  float hfj = gt*hc + (1.f-gt)*hg;
  hfin[j] = hfj;
  __syncthreads();
  float c1v = 0.f;
  if (j < 64){
    float c1 = cb1[j];
    for (int k=0;k<128;k++) c1 = fmaf(hfin[k], cW1[k*64+j], c1);
    c1v = fmaxf(c1, 0.f);
  }
  float l0 = blockReduceSum(j<64 ? c1v*cW2[2*j]   : 0.f, red);
  float l1 = blockReduceSum(j<64 ? c1v*cW2[2*j+1] : 0.f, red);
  if (j==0){ out[(size_t)g*2] = l0 + cb2[0]; out[(size_t)g*2+1] = l1 + cb2[1]; }
  // z_e
  buf[j] = he; __syncthreads();
  float q = peb1[j];
  for (int k=0;k<128;k++) q = fmaf(buf[k], peW1[k*H+j], q);
  q = fmaxf(q, 0.f);
  __syncthreads(); sh[j] = q; __syncthreads();
  float z = peb2[j];
  for (int k=0;k<128;k++) z = fmaf(sh[k], peW2[k*H+j], z);
  float nr = sqrtf(blockReduceSum(z*z, red));
  out[(size_t)G*2 + (size_t)g*H + j] = z / fmaxf(nr, 1e-12f);
  // z_f
  __syncthreads(); buf[j] = hf; __syncthreads();
  float q2 = pfb1[j];
  for (int k=0;k<128;k++) q2 = fmaf(buf[k], pfW1[k*H+j], q2);
  q2 = fmaxf(q2, 0.f);
  __syncthreads(); sh[j] = q2; __syncthreads();
  float z2 = pfb2[j];
  for (int k=0;k<128;k++) z2 = fmaf(sh[k], pfW2[k*H+j], z2);
  float nr2 = sqrtf(blockReduceSum(z2*z2, red));
  out[(size_t)G*2 + (size_t)G*H + (size_t)g*H + j] = z2 / fmaxf(nr2, 1e-12f);
}

extern "C" void kernel_launch(void* const* d_in, const int* in_sizes, int n_in,
                              void* d_out, int out_size, void* d_ws, size_t ws_size,
                              hipStream_t stream)
{
  const float* x    = (const float*)d_in[0];
  const int*   ei   = (const int*)d_in[1];
  const float* ew   = (const float*)d_in[2];
  const int*   batch= (const int*)d_in[3];
  const int*   em   = (const int*)d_in[4];
  const float* eegW = (const float*)d_in[6];  const float* eegB = (const float*)d_in[7];
  const float* fnW  = (const float*)d_in[8];  const float* fnB  = (const float*)d_in[9];
  const float* eW1  = (const float*)d_in[10]; const float* eb1  = (const float*)d_in[11];
  const float* eW2  = (const float*)d_in[12]; const float* eb2  = (const float*)d_in[13];
  const float* cIW  = (const float*)d_in[14]; const float* cIb  = (const float*)d_in[15];
  const float* cCW  = (const float*)d_in[16]; const float* cCb  = (const float*)d_in[17];
  const float* relg = (const float*)d_in[18];
  const float* bng  = (const float*)d_in[19]; const float* bnb  = (const float*)d_in[20];
  const float* coW1 = (const float*)d_in[21]; const float* cob1 = (const float*)d_in[22];
  const float* coW2 = (const float*)d_in[23]; const float* cob2 = (const float*)d_in[24];
  const float* gW1  = (const float*)d_in[25]; const float* gb1  = (const float*)d_in[26];
  const float* gW2  = (const float*)d_in[27]; const float* gb2  = (const float*)d_in[28];
  const float* cW1  = (const float*)d_in[29]; const float* cb1  = (const float*)d_in[30];
  const float* cW2  = (const float*)d_in[31]; const float* cb2  = (const float*)d_in[32];
  const float* peW1 = (const float*)d_in[33]; const float* peb1 = (const float*)d_in[34];
  const float* peW2 = (const float*)d_in[35]; const float* peb2 = (const float*)d_in[36];
  const float* pfW1 = (const float*)d_in[37]; const float* pfb1 = (const float*)d_in[38];
  const float* pfW2 = (const float*)d_in[39]; const float* pfb2 = (const float*)d_in[40];
  float* out = (float*)d_out;

  int N = in_sizes[0] / D;           // 50000
  int E = in_sizes[2];               // 800000
  int G = out_size / (2 + 2*H);      // 500
  int NH = N*H;

  float* p = (float*)d_ws;
  float* h    = p; p += (size_t)NH;
  float* tI   = p; p += (size_t)NH;   // overlays: hb (pre-loop) and tIb (loop), both bf16
  float* tC   = p; p += (size_t)NH;   // overlay: tCb
  float* csr_cf = p; p += E;
  int4* csr_rec = (int4*)p; p += (size_t)4*E;
  int* start  = (int*)p; p += (N+1);
  int* cnt    = (int*)p; p += N;      // cnt, wcnt, degI, degC contiguous -> one memset
  int* wcnt   = (int*)p; p += N;
  float* degI = p; p += N;
  float* degC = p; p += N;
  float* dinvI= p; p += N;
  float* dinvC= p; p += N;
  float* bnsum= p; p += H;
  float* bnsq = p; p += H;
  float* bna  = p; p += H;
  float* bnb2 = p; p += H;
  float* sumE = p; p += (size_t)G*H;
  float* sumF = p; p += (size_t)G*H;
  float* cntE = p; p += G;
  float* cntF = p; p += G;
  int* bsum   = (int*)p; p += 64;
  int* bsum2  = (int*)p; p += 64;
  int* escan  = (int*)p; p += (N+1);
  int* nodelist = (int*)p; p += (N+32);
  unsigned short* W1b = (unsigned short*)p; p += 4096;
  unsigned short* WeF = (unsigned short*)p; p += 32768;
  unsigned short* WfF = (unsigned short*)p; p += 32768;
  unsigned short* WIf0= (unsigned short*)p; p += 16384;
  unsigned short* WCf0= (unsigned short*)p; p += 16384;
  unsigned short* WIf1= (unsigned short*)p; p += 16384;
  unsigned short* WCf1= (unsigned short*)p; p += 16384;

  unsigned int* hb  = (unsigned int*)tI;
  unsigned int* tIb = (unsigned int*)tI;
  unsigned int* tCb = (unsigned int*)tC;

  int mmBlocks = ((N+15)/16 + 3)/4;
  int projBlocks = (((N+32)/16) + 3)/4;
  int edgeBlocks = (E + 127)/128;
  int statBlocks = 1024;
  int nper_stat = (N + statBlocks - 1)/statBlocks;
  int poolBlocks = (N + 31)/32;
  int scanBlocks = (N + 1023)/1024;

  hipMemsetAsync(cnt, 0, (size_t)4*N*sizeof(int), stream);
  k_hist<<<(E+255)/256,256,0,stream>>>(ei, cnt, E);
  k_scanA<<<scanBlocks,1024,0,stream>>>(cnt, start, bsum, N);
  k_scanC<<<scanBlocks,1024,0,stream>>>(start, bsum, N, scanBlocks);
  k_scanA<<<scanBlocks,1024,0,stream>>>(em, escan, bsum2, N);
  k_scanC<<<scanBlocks,1024,0,stream>>>(escan, bsum2, N, scanBlocks);
  k_part<<<(N+255)/256,256,0,stream>>>(em, escan, nodelist, N);
  k_fill2<<<(E+255)/256,256,0,stream>>>(ei, em, ew, start, wcnt, csr_rec, E);
  k_prepall<<<65,256,0,stream>>>(eegW, fnW, cIW, cCW, eW1,
                                 WeF, WfF, WIf0, WCf0, WIf1, WCf1, W1b);

  k_projm<<<projBlocks,256,0,stream>>>(x, nodelist, escan, N,
                                       WeF, eegB, WfF, fnB, h, hb);
  k_edgem<<<edgeBlocks,256,0,stream>>>(hb, csr_rec, W1b,
                                       eW1, eb1, eW2, eb2, csr_cf, degI, degC, E);
  k_dinv<<<(N+255)/256,256,0,stream>>>(degI,degC,dinvI,dinvC,N);
  k_scale<<<(E+255)/256,256,0,stream>>>(csr_rec, dinvI, dinvC, csr_cf, E);

  // layer 0
  k_gemm2m<<<mmBlocks,256,0,stream>>>(h, WIf0, WCf0, nullptr, nullptr, tIb, tCb, N);
  k_aggrb<<<(N+3)/4,256,0,stream>>>(tIb, tCb, start, csr_rec, csr_cf,
                                    dinvI, dinvC, cIb, cCb, relg, 0, h, N);
  hipMemsetAsync(bnsum, 0, 2*H*sizeof(float), stream);
  k_stats<<<statBlocks,128,0,stream>>>(h, bnsum, bnsq, N, nper_stat);
  k_bnab<<<1,128,0,stream>>>(bnsum, bnsq, bng, bnb, 1.0f/(float)N, bna, bnb2);

  // layer 1 (BN0 fused into GEMM input)
  k_gemm2m<<<mmBlocks,256,0,stream>>>(h, WIf1, WCf1, bna, bnb2, tIb, tCb, N);
  k_aggrb<<<(N+3)/4,256,0,stream>>>(tIb, tCb, start, csr_rec, csr_cf,
                                    dinvI, dinvC, cIb+(size_t)H, cCb+(size_t)H,
                                    relg, 1, h, N);
  hipMemsetAsync(bnsum, 0, 2*H*sizeof(float), stream);
  k_stats<<<statBlocks,128,0,stream>>>(h, bnsum, bnsq, N, nper_stat);

  hipMemsetAsync(sumE, 0, ((size_t)2*G*H + 2*G)*sizeof(float), stream);
  k_poolbn<<<poolBlocks,128,0,stream>>>(h, batch, em, bnsum, bnsq,
                                        bng+(size_t)H, bnb+(size_t)H, 1.0f/(float)N,
                                        sumE, sumF, cntE, cntF, N, 32);
  k_head<<<G,128,0,stream>>>(sumE,sumF,cntE,cntF,
                             coW1,cob1,coW2,cob2, gW1,gb1,gW2,gb2,
                             cW1,cb1,cW2,cb2, peW1,peb1,peW2,peb2,
                             pfW1,pfb1,pfW2,pfb2, out, G);
}

// Round 15
// 548.546 us; speedup vs baseline: 4.2179x; 1.0084x over previous
//
#include <hip/hip_runtime.h>
#include <math.h>

#define H 128
#define D 256

typedef __attribute__((ext_vector_type(8))) short bf16x8;
typedef __attribute__((ext_vector_type(4))) float f32x4;

__device__ __forceinline__ float sigmoidf_(float x){ return 1.0f/(1.0f+__expf(-x)); }

// RNE float->bf16 (as uint in low 16 bits)
__device__ __forceinline__ unsigned int bfr_(float f){
  unsigned int u = __float_as_uint(f);
  return (u + 0x7fffu + ((u>>16)&1u)) >> 16;
}
__device__ __forceinline__ float bf2f_(unsigned u){ return __uint_as_float(u<<16); }

// split a,b into packed bf16 hi / lo words (2 bf16 each)
__device__ __forceinline__ void split2(float a, float b, unsigned &hi, unsigned &lo){
  unsigned ha = bfr_(a), hb2 = bfr_(b);
  float fa = __uint_as_float(ha<<16), fb = __uint_as_float(hb2<<16);
  unsigned la = bfr_(a - fa), lb = bfr_(b - fb);
  hi = ha | (hb2<<16); lo = la | (lb<<16);
}

// pack trunc-bf16(|a0-b0|), trunc-bf16(|a1-b1|) into one uint via v_perm
__device__ __forceinline__ unsigned pair_dft(unsigned a, unsigned b){
  float a0 = __uint_as_float(a<<16), a1 = __uint_as_float(a & 0xffff0000u);
  float b0 = __uint_as_float(b<<16), b1 = __uint_as_float(b & 0xffff0000u);
  unsigned d0 = __float_as_uint(fabsf(a0-b0));
  unsigned d1 = __float_as_uint(fabsf(a1-b1));
  return __builtin_amdgcn_perm(d1, d0, 0x07060302);
}

// All weight preprocessing in ONE launch (65 blocks x 256)
__global__ void k_prepall(const float* __restrict__ eegW, const float* __restrict__ fnW,
                          const float* __restrict__ cIW, const float* __restrict__ cCW,
                          const float* __restrict__ eW1,
                          unsigned short* WeF, unsigned short* WfF,
                          unsigned short* WIf0, unsigned short* WCf0,
                          unsigned short* WIf1, unsigned short* WCf1,
                          unsigned short* W1b)
{
  int b = blockIdx.x;
  int t = threadIdx.x;
  if (b < 64){
    const float* W; unsigned short* out; int ksteps; int boff;
    if (b < 16){ W=eegW; out=WeF; ksteps=8; boff=b; }
    else if (b < 32){ W=fnW; out=WfF; ksteps=8; boff=b-16; }
    else if (b < 40){ W=cIW;        out=WIf0; ksteps=4; boff=b-32; }
    else if (b < 48){ W=cCW;        out=WCf0; ksteps=4; boff=b-40; }
    else if (b < 56){ W=cIW+16384;  out=WIf1; ksteps=4; boff=b-48; }
    else            { W=cCW+16384;  out=WCf1; ksteps=4; boff=b-56; }
    int id = boff*256 + t;
    if (id >= ksteps*8*64) return;
    int lane = id & 63;
    int mfrag = (id>>6) & 7;
    int kstep = id >> 9;
    int col = mfrag*16 + (lane&15);
    int k0 = kstep*32 + (lane>>4)*8;
    unsigned short* oh = out + (size_t)(((kstep*8+mfrag)*2+0)*64 + lane)*8;
    unsigned short* ol = out + (size_t)(((kstep*8+mfrag)*2+1)*64 + lane)*8;
    #pragma unroll
    for (int j=0;j<8;j++){
      float w = W[(size_t)(k0+j)*128 + col];
      unsigned h16 = bfr_(w);
      float hf = __uint_as_float(h16<<16);
      oh[j] = (unsigned short)h16;
      ol[j] = (unsigned short)bfr_(w - hf);
    }
  } else {
    for (int it=0; it<4; it++){
      int le = it*256 + t;
      int f = le >> 6, lane = le & 63;
      int kstep = f >> 2, n = f & 3;
      int col = n*16 + (lane & 15);
      int k0 = kstep*32 + ((lane>>4)&3)*8;
      unsigned short* op = W1b + (size_t)le*8;
      #pragma unroll
      for (int j=0;j<8;j++)
        op[j] = (unsigned short)bfr_(eW1[(size_t)(k0+j)*64 + col]);
    }
  }
}

// build modality-partitioned node list
__global__ void k_part(const int* __restrict__ em, const int* __restrict__ escan,
                       int* __restrict__ nodelist, int N){
  int i = blockIdx.x*blockDim.x + threadIdx.x;
  int NE = escan[N];
  int NEpad = (NE+15)&~15;
  if (i < N){
    int pos = em[i] ? escan[i] : NEpad + (i - escan[i]);
    nodelist[pos] = i;
  }
  if (i < 16){
    if (NE + i < NEpad) nodelist[NE + i] = 0;
    int TOT = NEpad + (N - NE);
    int TOTpad = (TOT+15)&~15;
    if (TOT + i < TOTpad) nodelist[TOT + i] = 0;
  }
}

// proj via MFMA bf16x3, modality-partitioned.
__global__ __launch_bounds__(256) void k_projm(
    const float* __restrict__ x, const int* __restrict__ nodelist,
    const int* __restrict__ escan, int N,
    const unsigned short* __restrict__ WeF, const float* __restrict__ be,
    const unsigned short* __restrict__ WfF, const float* __restrict__ bf,
    float* __restrict__ h, unsigned int* __restrict__ hb)
{
  int t = threadIdx.x;
  int lane = t & 63;
  int base = (blockIdx.x*4 + (t>>6))*16;
  int NE = escan[N];
  int NEpad = (NE+15)&~15;
  int TOT = NEpad + (N - NE);
  if (base >= TOT) return;
  bool isE = (base < NEpad);
  int slot = base + (lane & 15);
  bool valid = isE ? (slot < NE) : (slot < TOT);
  int node = nodelist[slot];
  int ko = lane >> 4;

  f32x4 acc[8];
  #pragma unroll
  for (int mf=0;mf<8;mf++) acc[mf]=(f32x4){0.f,0.f,0.f,0.f};

  const bf16x8* wsel = reinterpret_cast<const bf16x8*>(isE ? WeF : WfF);
  const float* bsel = isE ? be : bf;
  const float4* xr0 = reinterpret_cast<const float4*>(x + (size_t)node*D + ko*8);

  for (int kstep=0;kstep<8;kstep++){
    float4 v0 = xr0[kstep*8], v1 = xr0[kstep*8 + 1];
    uint4 hiu, lou;
    split2(v0.x, v0.y, hiu.x, lou.x);
    split2(v0.z, v0.w, hiu.y, lou.y);
    split2(v1.x, v1.y, hiu.z, lou.z);
    split2(v1.z, v1.w, hiu.w, lou.w);
    bf16x8 Bhi = *reinterpret_cast<bf16x8*>(&hiu);
    bf16x8 Blo = *reinterpret_cast<bf16x8*>(&lou);
    #pragma unroll
    for (int mf=0;mf<8;mf++){
      int fb = (kstep*8+mf)*2;
      bf16x8 ah = wsel[(size_t)fb*64 + lane];
      bf16x8 al = wsel[(size_t)(fb+1)*64 + lane];
      acc[mf] = __builtin_amdgcn_mfma_f32_16x16x32_bf16(ah, Bhi, acc[mf], 0,0,0);
      acc[mf] = __builtin_amdgcn_mfma_f32_16x16x32_bf16(ah, Blo, acc[mf], 0,0,0);
      acc[mf] = __builtin_amdgcn_mfma_f32_16x16x32_bf16(al, Bhi, acc[mf], 0,0,0);
    }
  }
  if (!valid) return;
  #pragma unroll
  for (int mf=0;mf<8;mf++){
    float sv[4];
    #pragma unroll
    for (int r=0;r<4;r++){
      int ch = mf*16 + ko*4 + r;
      sv[r] = fmaxf(acc[mf][r] + bsel[ch], 0.f);
    }
    float2* hp = reinterpret_cast<float2*>(h + (size_t)node*H + mf*16 + ko*4);
    hp[0] = make_float2(sv[0], sv[1]);
    hp[1] = make_float2(sv[2], sv[3]);
    unsigned int* hbp = hb + (size_t)node*64 + mf*8 + ko*2;
    hbp[0] = bfr_(sv[0]) | (bfr_(sv[1])<<16);
    hbp[1] = bfr_(sv[2]) | (bfr_(sv[3])<<16);
  }
}

// dual GEMM via MFMA bf16x3: tI = A@WI, tC = A@WC, outputs packed bf16.
__global__ __launch_bounds__(256) void k_gemm2m(
    const float* __restrict__ A,
    const unsigned short* __restrict__ WIf, const unsigned short* __restrict__ WCf,
    const float* __restrict__ bna, const float* __restrict__ bnb2,
    unsigned int* __restrict__ tIb, unsigned int* __restrict__ tCb, int N)
{
  int t = threadIdx.x;
  int lane = t & 63;
  int base = (blockIdx.x*4 + (t>>6))*16;
  if (base >= N) return;
  int node = base + (lane & 15);
  int nodeL = min(node, N-1);
  int ko = lane >> 4;

  f32x4 accI[8], accC[8];
  #pragma unroll
  for (int mf=0;mf<8;mf++){ accI[mf]=(f32x4){0.f,0.f,0.f,0.f}; accC[mf]=(f32x4){0.f,0.f,0.f,0.f}; }

  const bf16x8* wi = reinterpret_cast<const bf16x8*>(WIf);
  const bf16x8* wc = reinterpret_cast<const bf16x8*>(WCf);
  bool doBN = (bna != nullptr);

  #pragma unroll
  for (int kstep=0;kstep<4;kstep++){
    const float4* ar = reinterpret_cast<const float4*>(A + (size_t)nodeL*H + kstep*32 + ko*8);
    float4 v0 = ar[0], v1 = ar[1];
    if (doBN){
      int ch = kstep*32 + ko*8;
      const float4* a4 = reinterpret_cast<const float4*>(bna + ch);
      const float4* b4 = reinterpret_cast<const float4*>(bnb2 + ch);
      float4 a0 = a4[0], a1 = a4[1], bb0 = b4[0], bb1 = b4[1];
      v0.x = fmaxf(fmaf(a0.x, v0.x, bb0.x), 0.f);
      v0.y = fmaxf(fmaf(a0.y, v0.y, bb0.y), 0.f);
      v0.z = fmaxf(fmaf(a0.z, v0.z, bb0.z), 0.f);
      v0.w = fmaxf(fmaf(a0.w, v0.w, bb0.w), 0.f);
      v1.x = fmaxf(fmaf(a1.x, v1.x, bb1.x), 0.f);
      v1.y = fmaxf(fmaf(a1.y, v1.y, bb1.y), 0.f);
      v1.z = fmaxf(fmaf(a1.z, v1.z, bb1.z), 0.f);
      v1.w = fmaxf(fmaf(a1.w, v1.w, bb1.w), 0.f);
    }
    uint4 hiu, lou;
    split2(v0.x, v0.y, hiu.x, lou.x);
    split2(v0.z, v0.w, hiu.y, lou.y);
    split2(v1.x, v1.y, hiu.z, lou.z);
    split2(v1.z, v1.w, hiu.w, lou.w);
    bf16x8 Bhi = *reinterpret_cast<bf16x8*>(&hiu);
    bf16x8 Blo = *reinterpret_cast<bf16x8*>(&lou);
    #pragma unroll
    for (int mf=0;mf<8;mf++){
      int fb = (kstep*8+mf)*2;
      bf16x8 aIh = wi[(size_t)fb*64 + lane];
      bf16x8 aIl = wi[(size_t)(fb+1)*64 + lane];
      accI[mf] = __builtin_amdgcn_mfma_f32_16x16x32_bf16(aIh, Bhi, accI[mf], 0,0,0);
      accI[mf] = __builtin_amdgcn_mfma_f32_16x16x32_bf16(aIh, Blo, accI[mf], 0,0,0);
      accI[mf] = __builtin_amdgcn_mfma_f32_16x16x32_bf16(aIl, Bhi, accI[mf], 0,0,0);
      bf16x8 aCh = wc[(size_t)fb*64 + lane];
      bf16x8 aCl = wc[(size_t)(fb+1)*64 + lane];
      accC[mf] = __builtin_amdgcn_mfma_f32_16x16x32_bf16(aCh, Bhi, accC[mf], 0,0,0);
      accC[mf] = __builtin_amdgcn_mfma_f32_16x16x32_bf16(aCh, Blo, accC[mf], 0,0,0);
      accC[mf] = __builtin_amdgcn_mfma_f32_16x16x32_bf16(aCl, Bhi, accC[mf], 0,0,0);
    }
  }
  if (node >= N) return;
  #pragma unroll
  for (int mf=0;mf<8;mf++){
    unsigned int* ti = tIb + (size_t)node*64 + mf*8 + ko*2;
    unsigned int* tc = tCb + (size_t)node*64 + mf*8 + ko*2;
    ti[0] = bfr_(accI[mf][0]) | (bfr_(accI[mf][1])<<16);
    ti[1] = bfr_(accI[mf][2]) | (bfr_(accI[mf][3])<<16);
    tc[0] = bfr_(accC[mf][0]) | (bfr_(accC[mf][1])<<16);
    tc[1] = bfr_(accC[mf][2]) | (bfr_(accC[mf][3])<<16);
  }
}

// ---- CSR build ----
__global__ void k_hist(const int* __restrict__ ei, int* __restrict__ cnt, int E){
  int e = blockIdx.x*blockDim.x + threadIdx.x;
  if (e < E) atomicAdd(cnt + ei[E+e], 1);
}

// multi-block scan, phase A
__global__ __launch_bounds__(1024) void k_scanA(const int* __restrict__ cnt,
                                                int* __restrict__ start,
                                                int* __restrict__ bsum, int N){
  __shared__ int wsum[16];
  int t = threadIdx.x;
  int lane = t & 63, wid = t >> 6;
  int i = blockIdx.x*1024 + t;
  int v = (i < N) ? cnt[i] : 0;
  int s = v;
  #pragma unroll
  for (int d=1; d<64; d<<=1){
    int u = __shfl_up(s, d, 64);
    if (lane >= d) s += u;
  }
  if (lane == 63) wsum[wid] = s;
  __syncthreads();
  if (wid == 0){
    int w = (lane < 16) ? wsum[lane] : 0;
    #pragma unroll
    for (int d=1; d<16; d<<=1){
      int u = __shfl_up(w, d, 64);
      if (lane >= d) w += u;
    }
    if (lane < 16) wsum[lane] = w;
  }
  __syncthreads();
  int incl = s + ((wid > 0) ? wsum[wid-1] : 0);
  if (i < N) start[i] = incl - v;
  if (t == 1023) bsum[blockIdx.x] = incl;
}

// phase C
__global__ __launch_bounds__(1024) void k_scanC(int* __restrict__ start,
                                                const int* __restrict__ bsum,
                                                int N, int nb){
  int b = blockIdx.x, t = threadIdx.x;
  int o = 0;
  for (int j=0;j<b;j++) o += bsum[j];
  int i = b*1024 + t;
  if (i < N) start[i] += o;
  if (b == nb-1 && t == 0) start[N] = o + bsum[b];
}

// fill packed 8B CSR records: {x=(s<<1)|chan, y=(d<<16)|bf16(w)}  (N < 65536)
__global__ void k_fill2(const int* __restrict__ ei, const int* __restrict__ em,
                        const float* __restrict__ ew,
                        const int* __restrict__ start, int* __restrict__ wcnt,
                        int2* __restrict__ csr_rec, int E){
  int e = blockIdx.x*blockDim.x + threadIdx.x;
  if (e >= E) return;
  int s = ei[e], d = ei[E+e];
  int chan = (em[s] == em[d]) ? 0 : 1;
  int pos = start[d] + atomicAdd(wcnt + d, 1);
  csr_rec[pos] = make_int2((s<<1) | chan, (d<<16) | (int)bfr_(ew[e]));
}

// per-edge MLP gate via MFMA. wave = 32 edges; W1 fragments in LDS.
__global__ __launch_bounds__(256) void k_edgem(
    const unsigned int* __restrict__ hb,
    const int2* __restrict__ csr_rec, const unsigned short* __restrict__ W1b,
    const float* __restrict__ W1, const float* __restrict__ b1,
    const float* __restrict__ W2, const float* __restrict__ b2,
    float* __restrict__ csr_cf,
    float* __restrict__ degI, float* __restrict__ degC, int E)
{
  __shared__ uint4 wlds[1024];
  int t = threadIdx.x;
  {
    const uint4* src = reinterpret_cast<const uint4*>(W1b);
    #pragma unroll
    for (int i=0;i<4;i++) wlds[i*256 + t] = src[i*256 + t];
  }
  __syncthreads();

  int lane = t & 63;
  int base0 = (blockIdx.x*4 + (t>>6)) * 32;
  if (base0 >= E) return;

  int colbase = lane & 15;
  int ko = lane >> 4;
  float w1l[4], b1v[4], w2v[4];
  #pragma unroll
  for (int n=0;n<4;n++){
    int col = n*16 + colbase;
    w1l[n] = W1[(size_t)128*64 + col];
    b1v[n] = b1[col];
    w2v[n] = W2[col];
  }
  float bb2 = b2[0];

  uint4 us[2][4], ud[2][4];
  #pragma unroll
  for (int eg=0; eg<2; eg++){
    int e = min(base0 + eg*16 + colbase, E-1);
    int2 rec = csr_rec[e];
    int s = rec.x >> 1;
    int d = ((unsigned)rec.y) >> 16;
    const uint4* hsp = reinterpret_cast<const uint4*>(hb + (size_t)s*64);
    const uint4* hdp = reinterpret_cast<const uint4*>(hb + (size_t)d*64);
    #pragma unroll
    for (int kstep=0;kstep<4;kstep++){
      us[eg][kstep] = hsp[kstep*4 + ko];
      ud[eg][kstep] = hdp[kstep*4 + ko];
    }
  }

  const bf16x8* wl = reinterpret_cast<const bf16x8*>(wlds);
  #pragma unroll
  for (int eg=0; eg<2; eg++){
    int base = base0 + eg*16;
    if (base >= E) break;

    f32x4 acc[4];
    #pragma unroll
    for (int n=0;n<4;n++) acc[n] = (f32x4){0.f,0.f,0.f,0.f};

    #pragma unroll
    for (int kstep=0;kstep<4;kstep++){
      uint4 pa;
      pa.x = pair_dft(us[eg][kstep].x, ud[eg][kstep].x);
      pa.y = pair_dft(us[eg][kstep].y, ud[eg][kstep].y);
      pa.z = pair_dft(us[eg][kstep].z, ud[eg][kstep].z);
      pa.w = pair_dft(us[eg][kstep].w, ud[eg][kstep].w);
      bf16x8 a = *reinterpret_cast<bf16x8*>(&pa);
      #pragma unroll
      for (int n=0;n<4;n++)
        acc[n] = __builtin_amdgcn_mfma_f32_16x16x32_bf16(a, wl[(kstep*4+n)*64 + lane], acc[n], 0,0,0);
    }

    float wgtr[4];
    int2 recr[4];
    #pragma unroll
    for (int r=0;r<4;r++){
      recr[r] = csr_rec[min(base + ko*4 + r, E-1)];
      wgtr[r] = bf2f_((unsigned)recr[r].y & 0xffffu);
    }

    float part[4] = {0.f,0.f,0.f,0.f};
    #pragma unroll
    for (int n=0;n<4;n++){
      #pragma unroll
      for (int r=0;r<4;r++){
        float v = fmaxf(acc[n][r] + fmaf(wgtr[r], w1l[n], b1v[n]), 0.f);
        part[r] = fmaf(v, w2v[n], part[r]);
      }
    }
    #pragma unroll
    for (int m=1;m<16;m<<=1){
      #pragma unroll
      for (int r=0;r<4;r++) part[r] += __shfl_xor(part[r], m, 64);
    }

    if (colbase == 0){
      #pragma unroll
      for (int r=0;r<4;r++){
        int ee = base + ko*4 + r;
        if (ee < E){
          float g = sigmoidf_(part[r] + bb2);
          g = fminf(fmaxf(g, 0.2f), 1.2f);
          float ehat = wgtr[r] * g;
          csr_cf[ee] = ehat;
          int dd = ((unsigned)recr[r].y) >> 16;
          atomicAdd(((recr[r].x & 1) ? degC : degI) + dd, ehat);
        }
      }
    }
  }
}

__global__ void k_dinv(const float* __restrict__ degI, const float* __restrict__ degC,
                       float* dinvI, float* dinvC, int N){
  int i = blockIdx.x*blockDim.x + threadIdx.x;
  if (i < N){
    dinvI[i] = rsqrtf(1.f + degI[i]);
    dinvC[i] = rsqrtf(1.f + degC[i]);
  }
}

__global__ void k_scale(const int2* __restrict__ csr_rec,
                        const float* __restrict__ dinvI, const float* __restrict__ dinvC,
                        float* __restrict__ csr_cf, int E){
  int k = blockIdx.x*blockDim.x + threadIdx.x;
  if (k >= E) return;
  int2 rec = csr_rec[k];
  int s = rec.x >> 1;
  int d = ((unsigned)rec.y) >> 16;
  const float* dv = (rec.x & 1) ? dinvC : dinvI;
  csr_cf[k] *= dv[s]*dv[d];
}

// BN scale/shift precompute
__global__ void k_bnab(const float* __restrict__ bnsum, const float* __restrict__ bnsq,
                       const float* __restrict__ gamma, const float* __restrict__ beta,
                       float invN, float* __restrict__ bna, float* __restrict__ bnb2){
  int j = threadIdx.x;
  float mu = bnsum[j]*invN;
  float var = bnsq[j]*invN - mu*mu;
  float r = rsqrtf(var + 1e-5f);
  float a = gamma[j]*r;
  bna[j] = a;
  bnb2[j] = beta[j] - a*mu;
}

// one wave per dst node: gather bf16 CSR messages (8-deep unrolled)
__global__ __launch_bounds__(256) void k_aggrb(
    const unsigned int* __restrict__ tIb, const unsigned int* __restrict__ tCb,
    const int* __restrict__ start, const int2* __restrict__ csr_rec,
    const float* __restrict__ csr_cf,
    const float* __restrict__ dinvI, const float* __restrict__ dinvC,
    const float* __restrict__ bI, const float* __restrict__ bC,
    const float* __restrict__ relg, int l,
    float* __restrict__ h, int N)
{
  int lane = threadIdx.x & 63;
  int d = blockIdx.x*4 + (threadIdx.x>>6);
  if (d >= N) return;
  float sig = sigmoidf_(relg[l]);
  int k0 = start[d], k1 = start[d+1];
  float ax=0.f, ay=0.f;
  int k = k0;
  for (; k+8 <= k1; k += 8){
    unsigned vv[8]; float cc[8];
    #pragma unroll
    for (int u=0;u<8;u++){
      int sc = csr_rec[k+u].x;
      float cf = csr_cf[k+u];
      vv[u] = ((sc&1) ? tCb : tIb)[(size_t)(sc>>1)*64 + lane];
      cc[u] = (sc&1) ? sig*cf : cf;
    }
    #pragma unroll
    for (int u=0;u<8;u++){
      ax = fmaf(cc[u], __uint_as_float(vv[u]<<16), ax);
      ay = fmaf(cc[u], __uint_as_float(vv[u] & 0xffff0000u), ay);
    }
  }
  for (; k < k1; ++k){
    int sc = csr_rec[k].x;
    float cf = csr_cf[k];
    unsigned v = ((sc&1) ? tCb : tIb)[(size_t)(sc>>1)*64 + lane];
    float ce = (sc&1) ? sig*cf : cf;
    ax = fmaf(ce, __uint_as_float(v<<16), ax);
    ay = fmaf(ce, __uint_as_float(v & 0xffff0000u), ay);
  }
  float diI = dinvI[d], diC = dinvC[d];
  float rI = diI*diI, rC = diC*diC;
  unsigned vi = tIb[(size_t)d*64 + lane];
  unsigned vc = tCb[(size_t)d*64 + lane];
  int off = lane*2;
  float ox = fmaf(__uint_as_float(vi<<16), rI, bI[off])
           + sig*fmaf(__uint_as_float(vc<<16), rC, bC[off]) + ax;
  float oy = fmaf(__uint_as_float(vi & 0xffff0000u), rI, bI[off+1])
           + sig*fmaf(__uint_as_float(vc & 0xffff0000u), rC, bC[off+1]) + ay;
  *reinterpret_cast<float2*>(h + (size_t)d*H + off) = make_float2(ox, oy);
}

__global__ __launch_bounds__(128) void k_stats(const float* __restrict__ h,
    float* __restrict__ bnsum, float* __restrict__ bnsq, int N, int nper)
{
  int j = threadIdx.x;
  int n0 = blockIdx.x*nper, n1 = min(n0+nper, N);
  if (n0 >= N) return;
  float sl=0.f, sq=0.f;
  for (int n=n0;n<n1;n++){
    float v = h[(size_t)n*H+j];
    sl += v; sq = fmaf(v,v,sq);
  }
  atomicAdd(bnsum+j, sl); atomicAdd(bnsq+j, sq);
}

// pool with BN+relu applied on the fly
__global__ __launch_bounds__(128) void k_poolbn(
    const float* __restrict__ h, const int* __restrict__ batch, const int* __restrict__ em,
    const float* __restrict__ bnsum, const float* __restrict__ bnsq,
    const float* __restrict__ gamma, const float* __restrict__ beta, float invN,
    float* __restrict__ sumE, float* __restrict__ sumF,
    float* __restrict__ cntE, float* __restrict__ cntF, int N, int nper)
{
  int j = threadIdx.x;
  int n0 = blockIdx.x*nper, n1 = min(n0+nper, N);
  if (n0 >= N) return;
  float mu = bnsum[j]*invN;
  float var = bnsq[j]*invN - mu*mu;
  float rr = rsqrtf(var + 1e-5f);
  float ga = gamma[j], be = beta[j];
  float aE=0.f, aF=0.f, ce=0.f, cfc=0.f;
  int cg = batch[n0];
  for (int n=n0;n<n1;n++){
    int g = batch[n];
    if (g != cg){
      atomicAdd(sumE+(size_t)cg*H+j, aE);
      atomicAdd(sumF+(size_t)cg*H+j, aF);
      if (j==0){ atomicAdd(cntE+cg, ce); atomicAdd(cntF+cg, cfc); }
      aE=aF=ce=cfc=0.f; cg=g;
    }
    float v = fmaxf(fmaf(ga, (h[(size_t)n*H+j]-mu)*rr, be), 0.f);
    bool eb = em[n] != 0;
    if (eb) aE += v; else aF += v;
    if (j==0){ if (eb) ce += 1.f; else cfc += 1.f; }
  }
  atomicAdd(sumE+(size_t)cg*H+j, aE);
  atomicAdd(sumF+(size_t)cg*H+j, aF);
  if (j==0){ atomicAdd(cntE+cg, ce); atomicAdd(cntF+cg, cfc); }
}

__device__ __forceinline__ float blockReduceSum(float v, float* red){
  int t = threadIdx.x;
  red[t] = v; __syncthreads();
  #pragma unroll
  for (int s=64;s>0;s>>=1){ if (t<s) red[t]+=red[t+s]; __syncthreads(); }
  float r = red[0]; __syncthreads();
  return r;
}

__global__ __launch_bounds__(128) void k_head(
    const float* __restrict__ sumE, const float* __restrict__ sumF,
    const float* __restrict__ cntE, const float* __restrict__ cntF,
    const float* __restrict__ coW1, const float* __restrict__ cob1,
    const float* __restrict__ coW2, const float* __restrict__ cob2,
    const float* __restrict__ gW1, const float* __restrict__ gb1,
    const float* __restrict__ gW2, const float* __restrict__ gb2,
    const float* __restrict__ cW1, const float* __restrict__ cb1,
    const float* __restrict__ cW2, const float* __restrict__ cb2,
    const float* __restrict__ peW1, const float* __restrict__ peb1,
    const float* __restrict__ peW2, const float* __restrict__ peb2,
    const float* __restrict__ pfW1, const float* __restrict__ pfb1,
    const float* __restrict__ pfW2, const float* __restrict__ pfb2,
    float* __restrict__ out, int G)
{
  int g = blockIdx.x, j = threadIdx.x;
  __shared__ float sh[384];
  __shared__ float red[128];
  __shared__ float hfin[128], buf[128];
  float cE = cntE[g], cF = cntF[g];
  float se = sumE[(size_t)g*H+j], sf = sumF[(size_t)g*H+j];
  float he = se/fmaxf(cE,1.f), hf = sf/fmaxf(cF,1.f);
  float hg = (se+sf)/fmaxf(cE+cF,1.f);
  sh[j]=he; sh[128+j]=hf; sh[256+j]=he*hf;
  __syncthreads();
  float a = cob1[j];
  for (int k=0;k<384;k++) a = fmaf(sh[k], coW1[k*H+j], a);
  a = fmaxf(a, 0.f);
  float r0 = blockReduceSum(a*coW2[2*j],   red);
  float r1 = blockReduceSum(a*coW2[2*j+1], red);
  float al0 = sigmoidf_(r0 + cob2[0]);
  float al1 = sigmoidf_(r1 + cob2[1]);
  float asum = al0+al1+1e-6f; al0/=asum; al1/=asum;
  float hc = al0*he + al1*hf;
  __syncthreads();
  sh[j]=hc; sh[128+j]=hg;
  __syncthreads();
  float gg = gb1[j];
  for (int k=0;k<256;k++) gg = fmaf(sh[k], gW1[k*H+j], gg);
  gg = fmaxf(gg, 0.f);
  float gt = sigmoidf_(blockReduceSum(gg*gW2[j], red) + gb2[0]);
  float hfj = gt*hc + (1.f-gt)*hg;
  hfin[j] = hfj;
  __syncthreads();
  float c1v = 0.f;
  if (j < 64){
    float c1 = cb1[j];
    for (int k=0;k<128;k++) c1 = fmaf(hfin[k], cW1[k*64+j], c1);
    c1v = fmaxf(c1, 0.f);
  }
  float l0 = blockReduceSum(j<64 ? c1v*cW2[2*j]   : 0.f, red);
  float l1 = blockReduceSum(j<64 ? c1v*cW2[2*j+1] : 0.f, red);
  if (j==0){ out[(size_t)g*2] = l0 + cb2[0]; out[(size_t)g*2+1] = l1 + cb2[1]; }
  // z_e
  buf[j] = he; __syncthreads();
  float q = peb1[j];
  for (int k=0;k<128;k++) q = fmaf(buf[k], peW1[k*H+j], q);
  q = fmaxf(q, 0.f);
  __syncthreads(); sh[j] = q; __syncthreads();
  float z = peb2[j];
  for (int k=0;k<128;k++) z = fmaf(sh[k], peW2[k*H+j], z);
  float nr = sqrtf(blockReduceSum(z*z, red));
  out[(size_t)G*2 + (size_t)g*H + j] = z / fmaxf(nr, 1e-12f);
  // z_f
  __syncthreads(); buf[j] = hf; __syncthreads();
  float q2 = pfb1[j];
  for (int k=0;k<128;k++) q2 = fmaf(buf[k], pfW1[k*H+j], q2);
  q2 = fmaxf(q2, 0.f);
  __syncthreads(); sh[j] = q2; __syncthreads();
  float z2 = pfb2[j];
  for (int k=0;k<128;k++) z2 = fmaf(sh[k], pfW2[k*H+j], z2);
  float nr2 = sqrtf(blockReduceSum(z2*z2, red));
  out[(size_t)G*2 + (size_t)G*H + (size_t)g*H + j] = z2 / fmaxf(nr2, 1e-12f);
}

extern "C" void kernel_launch(void* const* d_in, const int* in_sizes, int n_in,
                              void* d_out, int out_size, void* d_ws, size_t ws_size,
                              hipStream_t stream)
{
  const float* x    = (const float*)d_in[0];
  const int*   ei   = (const int*)d_in[1];
  const float* ew   = (const float*)d_in[2];
  const int*   batch= (const int*)d_in[3];
  const int*   em   = (const int*)d_in[4];
  const float* eegW = (const float*)d_in[6];  const float* eegB = (const float*)d_in[7];
  const float* fnW  = (const float*)d_in[8];  const float* fnB  = (const float*)d_in[9];
  const float* eW1  = (const float*)d_in[10]; const float* eb1  = (const float*)d_in[11];
  const float* eW2  = (const float*)d_in[12]; const float* eb2  = (const float*)d_in[13];
  const float* cIW  = (const float*)d_in[14]; const float* cIb  = (const float*)d_in[15];
  const float* cCW  = (const float*)d_in[16]; const float* cCb  = (const float*)d_in[17];
  const float* relg = (const float*)d_in[18];
  const float* bng  = (const float*)d_in[19]; const float* bnb  = (const float*)d_in[20];
  const float* coW1 = (const float*)d_in[21]; const float* cob1 = (const float*)d_in[22];
  const float* coW2 = (const float*)d_in[23]; const float* cob2 = (const float*)d_in[24];
  const float* gW1  = (const float*)d_in[25]; const float* gb1  = (const float*)d_in[26];
  const float* gW2  = (const float*)d_in[27]; const float* gb2  = (const float*)d_in[28];
  const float* cW1  = (const float*)d_in[29]; const float* cb1  = (const float*)d_in[30];
  const float* cW2  = (const float*)d_in[31]; const float* cb2  = (const float*)d_in[32];
  const float* peW1 = (const float*)d_in[33]; const float* peb1 = (const float*)d_in[34];
  const float* peW2 = (const float*)d_in[35]; const float* peb2 = (const float*)d_in[36];
  const float* pfW1 = (const float*)d_in[37]; const float* pfb1 = (const float*)d_in[38];
  const float* pfW2 = (const float*)d_in[39]; const float* pfb2 = (const float*)d_in[40];
  float* out = (float*)d_out;

  int N = in_sizes[0] / D;           // 50000
  int E = in_sizes[2];               // 800000
  int G = out_size / (2 + 2*H);      // 500
  int NH = N*H;

  float* p = (float*)d_ws;
  float* h    = p; p += (size_t)NH;
  float* tI   = p; p += (size_t)NH;
  float* tC   = p; p += (size_t)NH;
  float* csr_cf = p; p += E;
  int2* csr_rec = (int2*)p; p += (size_t)2*E;
  int* start  = (int*)p; p += (N+1);
  int* cnt    = (int*)p; p += N;
  int* wcnt   = (int*)p; p += N;
  float* degI = p; p += N;
  float* degC = p; p += N;
  float* dinvI= p; p += N;
  float* dinvC= p; p += N;
  float* bnsum= p; p += H;
  float* bnsq = p; p += H;
  float* bna  = p; p += H;
  float* bnb2 = p; p += H;
  float* sumE = p; p += (size_t)G*H;
  float* sumF = p; p += (size_t)G*H;
  float* cntE = p; p += G;
  float* cntF = p; p += G;
  int* bsum   = (int*)p; p += 64;
  int* bsum2  = (int*)p; p += 64;
  int* escan  = (int*)p; p += (N+1);
  int* nodelist = (int*)p; p += (N+32);
  unsigned short* W1b = (unsigned short*)p; p += 4096;
  unsigned short* WeF = (unsigned short*)p; p += 32768;
  unsigned short* WfF = (unsigned short*)p; p += 32768;
  unsigned short* WIf0= (unsigned short*)p; p += 16384;
  unsigned short* WCf0= (unsigned short*)p; p += 16384;
  unsigned short* WIf1= (unsigned short*)p; p += 16384;
  unsigned short* WCf1= (unsigned short*)p; p += 16384;

  unsigned int* hb  = (unsigned int*)tI;
  unsigned int* tIb = (unsigned int*)tI;
  unsigned int* tCb = (unsigned int*)tC;

  int mmBlocks = ((N+15)/16 + 3)/4;
  int projBlocks = (((N+32)/16) + 3)/4;
  int edgeBlocks = (E + 127)/128;
  int statBlocks = 1024;
  int nper_stat = (N + statBlocks - 1)/statBlocks;
  int poolBlocks = (N + 31)/32;
  int scanBlocks = (N + 1023)/1024;

  hipMemsetAsync(cnt, 0, (size_t)4*N*sizeof(int), stream);
  k_hist<<<(E+255)/256,256,0,stream>>>(ei, cnt, E);
  k_scanA<<<scanBlocks,1024,0,stream>>>(cnt, start, bsum, N);
  k_scanC<<<scanBlocks,1024,0,stream>>>(start, bsum, N, scanBlocks);
  k_scanA<<<scanBlocks,1024,0,stream>>>(em, escan, bsum2, N);
  k_scanC<<<scanBlocks,1024,0,stream>>>(escan, bsum2, N, scanBlocks);
  k_part<<<(N+255)/256,256,0,stream>>>(em, escan, nodelist, N);
  k_fill2<<<(E+255)/256,256,0,stream>>>(ei, em, ew, start, wcnt, csr_rec, E);
  k_prepall<<<65,256,0,stream>>>(eegW, fnW, cIW, cCW, eW1,
                                 WeF, WfF, WIf0, WCf0, WIf1, WCf1, W1b);

  k_projm<<<projBlocks,256,0,stream>>>(x, nodelist, escan, N,
                                       WeF, eegB, WfF, fnB, h, hb);
  k_edgem<<<edgeBlocks,256,0,stream>>>(hb, csr_rec, W1b,
                                       eW1, eb1, eW2, eb2, csr_cf, degI, degC, E);
  k_dinv<<<(N+255)/256,256,0,stream>>>(degI,degC,dinvI,dinvC,N);
  k_scale<<<(E+255)/256,256,0,stream>>>(csr_rec, dinvI, dinvC, csr_cf, E);

  // layer 0
  k_gemm2m<<<mmBlocks,256,0,stream>>>(h, WIf0, WCf0, nullptr, nullptr, tIb, tCb, N);
  k_aggrb<<<(N+3)/4,256,0,stream>>>(tIb, tCb, start, csr_rec, csr_cf,
                                    dinvI, dinvC, cIb, cCb, relg, 0, h, N);
  hipMemsetAsync(bnsum, 0, 2*H*sizeof(float), stream);
  k_stats<<<statBlocks,128,0,stream>>>(h, bnsum, bnsq, N, nper_stat);
  k_bnab<<<1,128,0,stream>>>(bnsum, bnsq, bng, bnb, 1.0f/(float)N, bna, bnb2);

  // layer 1 (BN0 fused into GEMM input)
  k_gemm2m<<<mmBlocks,256,0,stream>>>(h, WIf1, WCf1, bna, bnb2, tIb, tCb, N);
  k_aggrb<<<(N+3)/4,256,0,stream>>>(tIb, tCb, start, csr_rec, csr_cf,
                                    dinvI, dinvC, cIb+(size_t)H, cCb+(size_t)H,
                                    relg, 1, h, N);
  hipMemsetAsync(bnsum, 0, 2*H*sizeof(float), stream);
  k_stats<<<statBlocks,128,0,stream>>>(h, bnsum, bnsq, N, nper_stat);

  hipMemsetAsync(sumE, 0, ((size_t)2*G*H + 2*G)*sizeof(float), stream);
  k_poolbn<<<poolBlocks,128,0,stream>>>(h, batch, em, bnsum, bnsq,
                                        bng+(size_t)H, bnb+(size_t)H, 1.0f/(float)N,
                                        sumE, sumF, cntE, cntF, N, 32);
  k_head<<<G,128,0,stream>>>(sumE,sumF,cntE,cntF,
                             coW1,cob1,coW2,cob2, gW1,gb1,gW2,gb2,
                             cW1,cb1,cW2,cb2, peW1,peb1,peW2,peb2,
                             pfW1,pfb1,pfW2,pfb2, out, G);
}